// Round 3
// baseline (266.789 us; speedup 1.0000x reference)
//
#include <hip/hip_runtime.h>
#include <hip/hip_bf16.h>
#include <cstdint>
#include <type_traits>

typedef __attribute__((ext_vector_type(8))) __bf16 bf16x8;
typedef __attribute__((ext_vector_type(4))) float f32x4;
typedef __attribute__((ext_vector_type(2))) long longx2;

struct bf2frag { bf16x8 k0, k1; };

__device__ __forceinline__ float bf2f(unsigned short u) {
  union { uint32_t i; float f; } v; v.i = (uint32_t)u << 16; return v.f;
}
__device__ __forceinline__ unsigned short f2bf(float f) {
  union { float f; uint32_t i; } v{f};
  uint32_t r = v.i + 0x7fffu + ((v.i >> 16) & 1u);
  return (unsigned short)(r >> 16);
}

__device__ __forceinline__ void gll(const void* g, void* l) {
  __builtin_amdgcn_global_load_lds(
      (const __attribute__((address_space(1))) uint32_t*)(uintptr_t)g,
      (__attribute__((address_space(3))) uint32_t*)(uint32_t)(uintptr_t)l,
      16, 0, 0);
}

__device__ __forceinline__ void bar() {
  asm volatile("" ::: "memory");
  __builtin_amdgcn_s_barrier();
  asm volatile("" ::: "memory");
}

#define VMCNT(n) asm volatile("s_waitcnt vmcnt(" #n ")" ::: "memory")

template <int N>
__device__ __forceinline__ void vmw() {
  if constexpr (N == 0) { VMCNT(0); }
  else if constexpr (N == 1) { VMCNT(1); }
  else if constexpr (N == 2) { VMCNT(2); }
  else if constexpr (N == 3) { VMCNT(3); }
  else if constexpr (N == 4) { VMCNT(4); }
  else if constexpr (N == 5) { VMCNT(5); }
  else if constexpr (N == 6) { VMCNT(6); }
  else if constexpr (N == 7) { VMCNT(7); }
  else if constexpr (N == 8) { VMCNT(8); }
  else if constexpr (N == 9) { VMCNT(9); }
  else if constexpr (N == 10) { VMCNT(10); }
  else { VMCNT(12); }
}

__device__ __forceinline__ f32x4 mma(bf16x8 a, bf16x8 b, f32x4 c) {
  return __builtin_amdgcn_mfma_f32_16x16x32_bf16(a, b, c, 0, 0, 0);
}
__device__ __forceinline__ f32x4 mma(long a, long b, f32x4 c) {
  return __builtin_amdgcn_mfma_f32_16x16x32_fp8_fp8(a, b, c, 0, 0, 0);
}
__device__ __forceinline__ f32x4 mmak(const bf2frag& a, const bf2frag& b, f32x4 c, int k2) {
  return k2 ? mma(a.k1, b.k1, c) : mma(a.k0, b.k0, c);
}
__device__ __forceinline__ f32x4 mmak(longx2 a, longx2 b, f32x4 c, int k2) {
  return mma(a[k2], b[k2], c);
}

// k-interleave store permutation for fp8 buffers (unit u=8B: slot p(u)=(u&3)*2+(u>>2))
__device__ __forceinline__ int perm64(int m) {
  return (m & ~63) | (((m >> 3) & 3) << 4) | (((m >> 5) & 1) << 3) | (m & 7);
}

// ---------------- GroupNorm stats ----------------
__global__ __launch_bounds__(256) void stats_partial_k(const float* __restrict__ x,
                                                       float* __restrict__ part) {
  const int g = blockIdx.x >> 3, p = blockIdx.x & 7;
  const float* base = x + (long)g * 16 * 18432 + (long)p * 2304;
  float s = 0.f, ss = 0.f;
  for (int idx = threadIdx.x; idx < 16 * 576; idx += 256) {
    const int c = idx / 576, i4 = idx % 576;
    const float4 v = *(const float4*)(base + (long)c * 18432 + i4 * 4);
    s += v.x + v.y + v.z + v.w;
    ss += v.x * v.x + v.y * v.y + v.z * v.z + v.w * v.w;
  }
  __shared__ float rs[256], rss[256];
  rs[threadIdx.x] = s; rss[threadIdx.x] = ss;
  __syncthreads();
  for (int o = 128; o > 0; o >>= 1) {
    if ((int)threadIdx.x < o) { rs[threadIdx.x] += rs[threadIdx.x + o]; rss[threadIdx.x] += rss[threadIdx.x + o]; }
    __syncthreads();
  }
  if (threadIdx.x == 0) { part[blockIdx.x * 2] = rs[0]; part[blockIdx.x * 2 + 1] = rss[0]; }
}

__global__ void stats_final_k(const float* __restrict__ part, float* __restrict__ stats) {
  const int g = threadIdx.x;
  if (g < 32) {
    float s = 0.f, ss = 0.f;
    for (int p = 0; p < 8; ++p) { s += part[(g * 8 + p) * 2]; ss += part[(g * 8 + p) * 2 + 1]; }
    const float mean = s / 294912.0f;
    const float var = ss / 294912.0f - mean * mean;
    stats[g * 2] = mean;
    stats[g * 2 + 1] = rsqrtf(var + 1e-6f);
  }
}

// ---------------- GN apply + transpose to (spatial, channel) bf16 ----------------
__global__ __launch_bounds__(256) void gn_transpose_k(const float* __restrict__ x,
                                                      const float* __restrict__ stats,
                                                      const float* __restrict__ gamma,
                                                      const float* __restrict__ beta,
                                                      unsigned short* __restrict__ hnT) {
  __shared__ float tile[64][65];
  const int c0 = blockIdx.x * 64, n0 = blockIdx.y * 64;
  const int tn = threadIdx.x & 63, tr = threadIdx.x >> 6;
  for (int cc = tr; cc < 64; cc += 4) {
    const int c = c0 + cc, g = c >> 4;
    const float mean = stats[g * 2], rstd = stats[g * 2 + 1];
    const float v = x[(long)c * 18432 + n0 + tn];
    tile[cc][tn] = (v - mean) * rstd * gamma[c] + beta[c];
  }
  __syncthreads();
  for (int nn = tr; nn < 64; nn += 4) {
    hnT[(long)(n0 + nn) * 512 + c0 + tn] = f2bf(tile[tn][nn]);
  }
}

// ---------------- fp32 -> bf16 weight pack ----------------
__global__ __launch_bounds__(256) void pack_bf16_k(const float* __restrict__ w,
                                                   unsigned short* __restrict__ o) {
  const int i = (blockIdx.x * 256 + threadIdx.x) * 4;
  const float4 v = *(const float4*)(w + i);
  ushort4 u; u.x = f2bf(v.x); u.y = f2bf(v.y); u.z = f2bf(v.z); u.w = f2bf(v.w);
  *(ushort4*)(o + i) = u;
}

__global__ void pack_bias_k(const float* __restrict__ bq, const float* __restrict__ bk,
                            float* __restrict__ bqk) {
  const int t = threadIdx.x;
  bqk[t] = (t < 512) ? bq[t] : bk[t - 512];
}

// ---------------- per-row 1/L combine from per-tile sums (NT tiles of rows) ----------------
__global__ __launch_bounds__(256) void combine_k(const float* __restrict__ rs,
                                                 float* __restrict__ linv, int ntile) {
  const int row = blockIdx.x * 256 + threadIdx.x;  // [0, 18432)
  const int t = row / 2304, r = row % 2304;
  float L = 0.f;
  for (int x = 0; x < ntile; ++x) L += rs[((long)(t * ntile + x)) * 2304 + r];
  linv[row] = 1.0f / L;
}

// ================= BMx256x64 NT GEMM, XCD-swizzled, bf16/fp8 =================
// C[n*ldc+m] = alpha*sum_k A[m,k]*B[n,k] (+bias)(+resid)
// BM=256: 512 thr, 8 waves (2m x 4n), 1 block/CU, P2=0 8-phase, setprio ON
//   (T5-positive regime: lockstep waves, single block).
// BM=128: 256 thr, 4 waves (1m x 4n), 2 blocks/CU co-resident, P2=1, setprio OFF.
// R12: S moved BM=128/P2=1 -> BM=256/P2=0. R10 (barrier halving) and R11
//   (setprio removal) were both NULL on S => schedule knobs on the 4-wave/2-block
//   machine are exonerated. Structural A/B vs the bf16-proven 8-wave machine:
//   identical grid quantization (648 vs 1296 blocks, both 2.53 rounds), identical
//   epilogue/IO -- only the execution structure differs. PV untouched (KT=36,
//   R9-proven on BM=128).
// P2=0 (8-phase snake): (m0,n0)->(m0,n1)->(m1,n1)->(m1,n0); A-half reused 2 phases.
//   Stages: p0:A0(W+1)->s^1  p1:B1(W+1)->s^1  p2:B0(W+2)->s  p3:A1(W+2)->s.
//   Prologue: [B0(0),A0(0),B1(0),A1(0),B0(1),A1(1)].
//   vmcnt (gll units): V0=GB+2GA @p0-end, V3=2GB+GA @p3-end, VP=GB+GA prologue.
//   BM=256/fp8 -> 3/3/2; BM=256/bf16 -> 6/6/4.
// P2=1 (2-phase, 4 barriers/K-step):
//   P0: read A0,B0,B1; stage [A0,B1,A1](W+1)->s^1 (A1 LAST); mfma (m0 x n0,n1).
//   P1: read A1; stage B0(W+2)->s; mfma (m1 x n1,n0).
//   Waits: @P0-end vmcnt(2GA+2GB); @P1-end vmcnt(GA+GB); tail GA then 0.
//   Prologue: [B0(0),A0(0),B1(0),A1(0),B0(1)].
// STATS scratch: NSLOT = waves-per-n-column (8 for BM=256, 4 for BM=128).
// OUT_MODE: 0 bf16, 1 f32+resid, 2 fp8 e4m3 k-interleaved. STATS: exp+rowsums
// (rowsums tile index = bx over gx m-tiles). SCALEN: *linv[n].
// MODE0: bz=bid%8 per XCD; MODE1/2: XCD y/x-chunking.
template <int BM, int BIAS_MODE, int OUT_MODE, int STATS, int SCALEN, int MODE, int FP8, int P2>
__global__ __launch_bounds__(512, 2) void gemm256(const void* __restrict__ A, long lda, long sAz,
                                                  const void* __restrict__ B, long ldb, long sBz,
                                                  void* __restrict__ Cp, long ldc, long sCz,
                                                  const float* __restrict__ bias,
                                                  const float* __restrict__ resid,
                                                  float* __restrict__ rowsums,
                                                  const float* __restrict__ linv,
                                                  float alpha, int K, int gx, int gy) {
  constexpr int EB = FP8 ? 1 : 2;                    // element bytes
  constexpr int THREADS = (BM == 256) ? 512 : 256;
  constexpr int HBA = (BM / 2) * 64 * EB;            // bytes per A half
  constexpr int HBB = 128 * 64 * EB;                 // bytes per B half
  constexpr int GA = HBA / (THREADS * 16);           // gll per A-half stage
  constexpr int GB = HBB / (THREADS * 16);           // gll per B-half stage
  constexpr int V0 = GB + 2 * GA, V3 = 2 * GB + GA, VP = GB + GA;
  constexpr int NSLOT = (BM == 256) ? 8 : 4;
  constexpr int PRIO = !P2;                          // setprio only on 1-block path
  __shared__ alignas(16) unsigned char As[2][2][HBA];
  __shared__ alignas(16) unsigned char Bs[2][2][HBB];
  using ABt2 = typename std::conditional<FP8, longx2, bf2frag>::type;

  const int tid = threadIdx.x;
  const int lane = tid & 63, wid = tid >> 6;
  const int wm = (BM == 256) ? (wid & 1) : 0;
  const int wn = (BM == 256) ? (wid >> 1) : wid;
  int bx, by, bz;
  {
    const int g8 = blockIdx.x & 7, n = blockIdx.x >> 3;
    if (MODE == 0) { bz = g8; bx = n % gx; by = n / gx; }
    else if (MODE == 1) { bz = 0; bx = n % gx; by = g8 * gy + n / gx; }
    else { bz = 0; by = n % gy; bx = g8 * gx + n / gy; }
  }
  const unsigned char* Ab = (const unsigned char*)A + ((long)bz * sAz + (long)bx * BM * lda) * EB;
  const unsigned char* Bb = (const unsigned char*)B + ((long)bz * sBz + (long)by * 256 * ldb) * EB;

  // ---- staging (global -> LDS, pre-swizzled source; fp8 global is k-interleaved) ----
  auto stageA = [&](int slot, int h, int k0) {
    if constexpr (!FP8) {
      const int ksw = ((tid & 7) << 3) ^ (((tid >> 3) & 7) << 3);
#pragma unroll
      for (int call = 0; call < GA; ++call) {
        const int r = call * (THREADS / 8) + (tid >> 3);
        const int grow = ((r >> 6) << 7) + h * 64 + (r & 63);
        gll(Ab + ((long)grow * lda + k0) * 2 + ksw * 2, &As[slot][h][call * THREADS * 16 + tid * 16]);
      }
    } else {
#pragma unroll
      for (int call = 0; call < GA; ++call) {
        const int l = call * (THREADS / 4) + (tid >> 2);
        const int grow = ((l >> 6) << 7) + h * 64 + (l & 63);
        const int x = (((l & 3) ^ ((l >> 2) & 3)) << 4);
        gll(Ab + (long)grow * lda + k0 + (((tid & 3) << 4) ^ x),
            &As[slot][h][call * THREADS * 16 + tid * 16]);
      }
    }
  };
  auto stageB = [&](int slot, int h, int k0) {
    if constexpr (!FP8) {
      const int ksw = ((tid & 7) << 3) ^ (((tid >> 3) & 7) << 3);
#pragma unroll
      for (int call = 0; call < GB; ++call) {
        const int r = call * (THREADS / 8) + (tid >> 3);
        const int grow = ((r >> 5) << 6) + h * 32 + (r & 31);
        gll(Bb + ((long)grow * ldb + k0) * 2 + ksw * 2, &Bs[slot][h][call * THREADS * 16 + tid * 16]);
      }
    } else {
#pragma unroll
      for (int call = 0; call < GB; ++call) {
        const int l = call * (THREADS / 4) + (tid >> 2);
        const int grow = ((l >> 5) << 6) + h * 32 + (l & 31);
        const int x = (((l & 3) ^ ((l >> 2) & 3)) << 4);
        gll(Bb + (long)grow * ldb + k0 + (((tid & 3) << 4) ^ x),
            &Bs[slot][h][call * THREADS * 16 + tid * 16]);
      }
    }
  };
  // ---- LDS -> fragment reads (same swizzle; fp8 = ONE b128 for both k2 slices) ----
  auto ldA = [&](int slot, int mh, int fq) -> ABt2 {
    const int r = wm * 64 + fq * 16 + (lane & 15);
    if constexpr (!FP8) {
      bf2frag f;
      const int kk0 = (((lane >> 4) << 3)) ^ ((r & 7) << 3);
      const int kk1 = (32 + ((lane >> 4) << 3)) ^ ((r & 7) << 3);
      f.k0 = *reinterpret_cast<const bf16x8*>(&As[slot][mh][r * 128 + kk0 * 2]);
      f.k1 = *reinterpret_cast<const bf16x8*>(&As[slot][mh][r * 128 + kk1 * 2]);
      return f;
    } else {
      const int x = (((r & 3) ^ ((r >> 2) & 3)) << 4);
      const int kk = ((lane >> 4) << 4) ^ x;
      return *reinterpret_cast<const longx2*>(&As[slot][mh][r * 64 + kk]);
    }
  };
  auto ldB = [&](int slot, int nh, int g) -> ABt2 {
    const int r = wn * 32 + g * 16 + (lane & 15);
    if constexpr (!FP8) {
      bf2frag f;
      const int kk0 = (((lane >> 4) << 3)) ^ ((r & 7) << 3);
      const int kk1 = (32 + ((lane >> 4) << 3)) ^ ((r & 7) << 3);
      f.k0 = *reinterpret_cast<const bf16x8*>(&Bs[slot][nh][r * 128 + kk0 * 2]);
      f.k1 = *reinterpret_cast<const bf16x8*>(&Bs[slot][nh][r * 128 + kk1 * 2]);
      return f;
    } else {
      const int x = (((r & 3) ^ ((r >> 2) & 3)) << 4);
      const int kk = ((lane >> 4) << 4) ^ x;
      return *reinterpret_cast<const longx2*>(&Bs[slot][nh][r * 64 + kk]);
    }
  };

  f32x4 acc[8][4] = {};
  ABt2 a[4], b0[2], b1[2];

#define READ_A(SLOT, MH)                                                     \
  _Pragma("unroll") for (int fq = 0; fq < 4; ++fq) a[fq] = ldA(SLOT, MH, fq);
#define READ_B(SLOT, NH, DST)                                                \
  _Pragma("unroll") for (int g = 0; g < 2; ++g) DST[g] = ldB(SLOT, NH, g);
#define MFMA_QUAD(MH, NH, BARR)                                              \
  if constexpr (PRIO) __builtin_amdgcn_s_setprio(1);                         \
  _Pragma("unroll") for (int fq = 0; fq < 4; ++fq)                           \
    _Pragma("unroll") for (int g = 0; g < 2; ++g)                            \
      _Pragma("unroll") for (int k2 = 0; k2 < 2; ++k2)                       \
        acc[(MH) * 4 + fq][(NH) * 2 + g] =                                   \
            mmak(a[fq], BARR[g], acc[(MH) * 4 + fq][(NH) * 2 + g], k2);      \
  if constexpr (PRIO) __builtin_amdgcn_s_setprio(0);

  const int KT = K >> 6;
  // Prologue queue: [B0(0), A0(0), B1(0), A1(0), B0(1)] (+A1(1) for P2=0)
  stageB(0, 0, 0);
  stageA(0, 0, 0);
  stageB(0, 1, 0);
  stageA(0, 1, 0);
  stageB(1, 0, 64);
  if constexpr (!P2) stageA(1, 1, 64);
  vmw<VP>();
  bar();

  if constexpr (!P2) {
    for (int W = 0; W < KT; ++W) {
      const int s = W & 1;
      const int kn1 = (W + 1) << 6, kn2 = (W + 2) << 6;
      const bool st1 = (W + 1 < KT), st2 = (W + 2 < KT);
      // p0: (m0,n0)
      READ_A(s, 0)
      READ_B(s, 0, b0)
      if (st1) stageA(s ^ 1, 0, kn1);
      bar();
      MFMA_QUAD(0, 0, b0)
      if (st1) { vmw<V0>(); }
      bar();
      // p1: (m0,n1)
      READ_B(s, 1, b1)
      if (st1) stageB(s ^ 1, 1, kn1);
      bar();
      MFMA_QUAD(0, 1, b1)
      bar();
      // p2: (m1,n1)
      READ_A(s, 1)
      if (st2) stageB(s, 0, kn2);
      bar();
      MFMA_QUAD(1, 1, b1)
      bar();
      // p3: (m1,n0)
      if (st2) stageA(s, 1, kn2);
      bar();
      MFMA_QUAD(1, 0, b0)
      if (st2) { vmw<V3>(); } else { vmw<0>(); }
      bar();
    }
  } else {
    for (int W = 0; W < KT; ++W) {
      const int s = W & 1;
      const int kn1 = (W + 1) << 6, kn2 = (W + 2) << 6;
      const bool st1 = (W + 1 < KT), st2 = (W + 2 < KT);
      // P0: (m0 x n0,n1); stage next A-slot fully + B1(W+1). A1 issued LAST.
      READ_A(s, 0)
      READ_B(s, 0, b0)
      READ_B(s, 1, b1)
      if (st1) { stageA(s ^ 1, 0, kn1); stageB(s ^ 1, 1, kn1); stageA(s ^ 1, 1, kn1); }
      bar();
      MFMA_QUAD(0, 0, b0)
      MFMA_QUAD(0, 1, b1)
      if (st1) { vmw<2 * (GA + GB)>(); } else { vmw<0>(); }
      bar();
      // P1: (m1 x n1,n0); stage B0(W+2) into current slot (B0(W) consumed in P0).
      READ_A(s, 1)
      if (st2) stageB(s, 0, kn2);
      bar();
      MFMA_QUAD(1, 1, b1)
      MFMA_QUAD(1, 0, b0)
      if (st2) { vmw<GA + GB>(); } else if (st1) { vmw<GA>(); } else { vmw<0>(); }
      bar();
    }
  }

  // epilogue: acc[M][N], M = mh*4+fq (m-off = mh*64+fq*16), N = nh*2+g
  const int mg0 = bx * BM + wm * 128 + ((lane >> 4) << 2);
  const int ng0 = by * 256 + wn * 64 + (lane & 15);
  float* red = (float*)&As[0][0][0];  // STATS scratch: 256 rows x NSLOT f32
#pragma unroll
  for (int N = 0; N < 4; ++N) {
    const int n = ng0 + (N >> 1) * 32 + (N & 1) * 16;
    const float bn = (BIAS_MODE == 2) ? bias[n] : 0.f;
    const float sc = SCALEN ? linv[(long)bz * 2304 + n] : 1.0f;
    float eN = 0.f;
#pragma unroll
    for (int M = 0; M < 8; ++M) {
      const int m = mg0 + (M >> 2) * 64 + (M & 3) * 16;
      const f32x4 av = acc[M][N];
      float vals[4];
#pragma unroll
      for (int j = 0; j < 4; ++j) {
        vals[j] = av[j] * alpha + ((BIAS_MODE == 1) ? bias[m + j] : bn);
        if (SCALEN) vals[j] *= sc;
        if (STATS) { vals[j] = __expf(vals[j]); eN += vals[j]; }
      }
      if (OUT_MODE == 0) {
        ushort4 o; o.x = f2bf(vals[0]); o.y = f2bf(vals[1]); o.z = f2bf(vals[2]); o.w = f2bf(vals[3]);
        *(ushort4*)((unsigned short*)Cp + (long)bz * sCz + (long)n * ldc + m) = o;
      } else if (OUT_MODE == 2) {
        int pk = __builtin_amdgcn_cvt_pk_fp8_f32(vals[0], vals[1], 0, false);
        pk = __builtin_amdgcn_cvt_pk_fp8_f32(vals[2], vals[3], pk, true);
        *(int*)((unsigned char*)Cp + (long)bz * sCz + (long)n * ldc + perm64(m)) = pk;
      } else {
        const float* rp = resid + (long)n * ldc + m;
        float4 o; o.x = vals[0] + rp[0]; o.y = vals[1] + rp[1]; o.z = vals[2] + rp[2]; o.w = vals[3] + rp[3];
        *(float4*)((float*)Cp + (long)bz * sCz + (long)n * ldc + m) = o;
      }
    }
    if (STATS) {
      const int nloc = wn * 64 + (N >> 1) * 32 + (N & 1) * 16 + (lane & 15);
      const int slot = wm * 4 + (lane >> 4);
      red[nloc * NSLOT + slot] = eN;
    }
  }
  if (STATS) {
    bar();
    if (tid < 256) {
      float L = 0.f;
#pragma unroll
      for (int s2 = 0; s2 < NSLOT; ++s2) L += red[tid * NSLOT + s2];
      rowsums[((long)(bz * gx + bx)) * 2304 + by * 256 + tid] = L;
    }
  }
#undef READ_A
#undef READ_B
#undef MFMA_QUAD
}

extern "C" void kernel_launch(void* const* d_in, const int* in_sizes, int n_in,
                              void* d_out, int out_size, void* d_ws, size_t ws_size,
                              hipStream_t stream) {
  const float* x = (const float*)d_in[0];
  const float* gamma = (const float*)d_in[1];
  const float* beta = (const float*)d_in[2];
  const float* wq = (const float*)d_in[3];
  const float* bq = (const float*)d_in[4];
  const float* wk = (const float*)d_in[5];
  const float* bk = (const float*)d_in[6];
  const float* wv = (const float*)d_in[7];
  const float* bv = (const float*)d_in[8];
  const float* wo = (const float*)d_in[9];
  const float* bo = (const float*)d_in[10];
  float* out = (float*)d_out;

  char* ws = (char*)d_ws;
  size_t off = 0;
  auto alloc = [&](size_t bytes) {
    char* p = ws + off;
    off = (off + bytes + 255) & ~(size_t)255;
    return p;
  };
  float* part = (float*)alloc(256 * 2 * sizeof(float));
  float* stats = (float*)alloc(32 * 2 * sizeof(float));
  unsigned short* wqkb = (unsigned short*)alloc((size_t)2 * 262144 * 2);
  unsigned short* wvb = (unsigned short*)alloc((size_t)262144 * 2);
  unsigned short* wob = (unsigned short*)alloc((size_t)262144 * 2);
  float* bqk = (float*)alloc(1024 * sizeof(float));
  float* rowsums = (float*)alloc((size_t)8 * 18 * 2304 * sizeof(float));
  float* linv = (float*)alloc((size_t)18432 * sizeof(float));
  unsigned short* hnT = (unsigned short*)alloc((size_t)18432 * 512 * 2);
  unsigned char* qkA = (unsigned char*)alloc((size_t)18432 * 1024);      // fp8 k-interleaved
  unsigned char* vT = (unsigned char*)alloc((size_t)512 * 18432);        // fp8 k-interleaved
  unsigned char* Sm = (unsigned char*)alloc((size_t)8 * 2304 * 2304);    // fp8 E k-interleaved
  unsigned short* Ob = hnT;  // alias: hnT fully consumed after qk/v GEMMs
  (void)ws_size; (void)in_sizes; (void)n_in; (void)out_size;

  stats_partial_k<<<dim3(256), dim3(256), 0, stream>>>(x, part);
  stats_final_k<<<dim3(1), dim3(64), 0, stream>>>(part, stats);
  gn_transpose_k<<<dim3(8, 288), dim3(256), 0, stream>>>(x, stats, gamma, beta, hnT);
  pack_bf16_k<<<dim3(256), dim3(256), 0, stream>>>(wq, wqkb);
  pack_bf16_k<<<dim3(256), dim3(256), 0, stream>>>(wk, wqkb + 262144);
  pack_bf16_k<<<dim3(256), dim3(256), 0, stream>>>(wv, wvb);
  pack_bf16_k<<<dim3(256), dim3(256), 0, stream>>>(wo, wob);
  pack_bias_k<<<dim3(1), dim3(1024), 0, stream>>>(bq, bk, bqk);

  // qk fused: A=[Wq;Wk] bf16, B=hnT bf16 -> q,k fp8 interleaved [sp][1024]. MODE1: 288 blocks.
  gemm256<256, 1, 2, 0, 0, 1, 0, 0><<<dim3(288), dim3(512), 0, stream>>>(
      wqkb, 512, 0, hnT, 512, 0, (void*)qkA, 1024, 0, bqk, nullptr, nullptr, nullptr,
      1.0f, 512, 4, 9);
  // v: A=hnT bf16, B=Wv bf16 -> vT fp8 interleaved [co][18432]. MODE2: 144 blocks.
  gemm256<256, 2, 2, 0, 0, 2, 0, 0><<<dim3(144), dim3(512), 0, stream>>>(
      hnT, 512, 0, wvb, 512, 0, (void*)vT, 18432, 0, bv, nullptr, nullptr, nullptr,
      1.0f, 512, 9, 2);
  // S: per t: A=k fp8, B=q fp8 -> E=exp(alpha*S) fp8 interleaved + rowsums.
  // R12: BM=256 (512 thr, 1 block/CU, 8-phase, setprio): 9x9x8 = 648 blocks MODE0.
  gemm256<256, 0, 2, 1, 0, 0, 1, 0><<<dim3(648), dim3(512), 0, stream>>>(
      qkA + 512, 1024, (long)2304 * 1024, qkA, 1024, (long)2304 * 1024, (void*)Sm, 2304,
      (long)2304 * 2304, nullptr, nullptr, rowsums, nullptr,
      0.044194173824159216f, 512, 9, 9);
  combine_k<<<dim3(72), dim3(256), 0, stream>>>(rowsums, linv, 9);
  // PV: per t: A=vT fp8, B=E fp8 -> O bf16 [(t,i)*512+c], rows scaled by linv.
  // BM=128 (256 thr, 2 blocks/CU), P2=1 (no setprio): 288 blocks MODE0.
  gemm256<128, 0, 0, 0, 1, 0, 1, 1><<<dim3(288), dim3(256), 0, stream>>>(
      vT, 18432, 2304, Sm, 2304, (long)2304 * 2304, (void*)Ob, 512, (long)2304 * 512,
      nullptr, nullptr, nullptr, linv, 1.0f, 2304, 4, 0);
  // final: A=O bf16, B=Wo bf16 -> out[co*18432+sp] = x + acc + bo[co]. MODE2: 144 blocks.
  gemm256<256, 2, 1, 0, 0, 2, 0, 0><<<dim3(144), dim3(512), 0, stream>>>(
      Ob, 512, 0, wob, 512, 0, (void*)out, 18432, 0, bo, x, nullptr, nullptr,
      1.0f, 512, 9, 2);
}

// Round 4
// 254.529 us; speedup vs baseline: 1.0482x; 1.0482x over previous
//
#include <hip/hip_runtime.h>
#include <hip/hip_bf16.h>
#include <cstdint>
#include <type_traits>

typedef __attribute__((ext_vector_type(8))) __bf16 bf16x8;
typedef __attribute__((ext_vector_type(4))) float f32x4;
typedef __attribute__((ext_vector_type(2))) long longx2;

struct bf2frag { bf16x8 k0, k1; };

__device__ __forceinline__ float bf2f(unsigned short u) {
  union { uint32_t i; float f; } v; v.i = (uint32_t)u << 16; return v.f;
}
__device__ __forceinline__ unsigned short f2bf(float f) {
  union { float f; uint32_t i; } v{f};
  uint32_t r = v.i + 0x7fffu + ((v.i >> 16) & 1u);
  return (unsigned short)(r >> 16);
}

__device__ __forceinline__ void gll(const void* g, void* l) {
  __builtin_amdgcn_global_load_lds(
      (const __attribute__((address_space(1))) uint32_t*)(uintptr_t)g,
      (__attribute__((address_space(3))) uint32_t*)(uint32_t)(uintptr_t)l,
      16, 0, 0);
}

__device__ __forceinline__ void bar() {
  asm volatile("" ::: "memory");
  __builtin_amdgcn_s_barrier();
  asm volatile("" ::: "memory");
}

#define VMCNT(n) asm volatile("s_waitcnt vmcnt(" #n ")" ::: "memory")

template <int N>
__device__ __forceinline__ void vmw() {
  if constexpr (N == 0) { VMCNT(0); }
  else if constexpr (N == 1) { VMCNT(1); }
  else if constexpr (N == 2) { VMCNT(2); }
  else if constexpr (N == 3) { VMCNT(3); }
  else if constexpr (N == 4) { VMCNT(4); }
  else if constexpr (N == 5) { VMCNT(5); }
  else if constexpr (N == 6) { VMCNT(6); }
  else if constexpr (N == 7) { VMCNT(7); }
  else if constexpr (N == 8) { VMCNT(8); }
  else if constexpr (N == 9) { VMCNT(9); }
  else if constexpr (N == 10) { VMCNT(10); }
  else { VMCNT(12); }
}

__device__ __forceinline__ f32x4 mma(bf16x8 a, bf16x8 b, f32x4 c) {
  return __builtin_amdgcn_mfma_f32_16x16x32_bf16(a, b, c, 0, 0, 0);
}
__device__ __forceinline__ f32x4 mma(long a, long b, f32x4 c) {
  return __builtin_amdgcn_mfma_f32_16x16x32_fp8_fp8(a, b, c, 0, 0, 0);
}
__device__ __forceinline__ f32x4 mmak(const bf2frag& a, const bf2frag& b, f32x4 c, int k2) {
  return k2 ? mma(a.k1, b.k1, c) : mma(a.k0, b.k0, c);
}
__device__ __forceinline__ f32x4 mmak(longx2 a, longx2 b, f32x4 c, int k2) {
  return mma(a[k2], b[k2], c);
}

// k-interleave store permutation for fp8 buffers (unit u=8B: slot p(u)=(u&3)*2+(u>>2))
__device__ __forceinline__ int perm64(int m) {
  return (m & ~63) | (((m >> 3) & 3) << 4) | (((m >> 5) & 1) << 3) | (m & 7);
}

// ---------------- GroupNorm stats ----------------
__global__ __launch_bounds__(256) void stats_partial_k(const float* __restrict__ x,
                                                       float* __restrict__ part) {
  const int g = blockIdx.x >> 3, p = blockIdx.x & 7;
  const float* base = x + (long)g * 16 * 18432 + (long)p * 2304;
  float s = 0.f, ss = 0.f;
  for (int idx = threadIdx.x; idx < 16 * 576; idx += 256) {
    const int c = idx / 576, i4 = idx % 576;
    const float4 v = *(const float4*)(base + (long)c * 18432 + i4 * 4);
    s += v.x + v.y + v.z + v.w;
    ss += v.x * v.x + v.y * v.y + v.z * v.z + v.w * v.w;
  }
  __shared__ float rs[256], rss[256];
  rs[threadIdx.x] = s; rss[threadIdx.x] = ss;
  __syncthreads();
  for (int o = 128; o > 0; o >>= 1) {
    if ((int)threadIdx.x < o) { rs[threadIdx.x] += rs[threadIdx.x + o]; rss[threadIdx.x] += rss[threadIdx.x + o]; }
    __syncthreads();
  }
  if (threadIdx.x == 0) { part[blockIdx.x * 2] = rs[0]; part[blockIdx.x * 2 + 1] = rss[0]; }
}

__global__ void stats_final_k(const float* __restrict__ part, float* __restrict__ stats) {
  const int g = threadIdx.x;
  if (g < 32) {
    float s = 0.f, ss = 0.f;
    for (int p = 0; p < 8; ++p) { s += part[(g * 8 + p) * 2]; ss += part[(g * 8 + p) * 2 + 1]; }
    const float mean = s / 294912.0f;
    const float var = ss / 294912.0f - mean * mean;
    stats[g * 2] = mean;
    stats[g * 2 + 1] = rsqrtf(var + 1e-6f);
  }
}

// ---------------- GN apply + transpose to (spatial, channel) bf16 ----------------
__global__ __launch_bounds__(256) void gn_transpose_k(const float* __restrict__ x,
                                                      const float* __restrict__ stats,
                                                      const float* __restrict__ gamma,
                                                      const float* __restrict__ beta,
                                                      unsigned short* __restrict__ hnT) {
  __shared__ float tile[64][65];
  const int c0 = blockIdx.x * 64, n0 = blockIdx.y * 64;
  const int tn = threadIdx.x & 63, tr = threadIdx.x >> 6;
  for (int cc = tr; cc < 64; cc += 4) {
    const int c = c0 + cc, g = c >> 4;
    const float mean = stats[g * 2], rstd = stats[g * 2 + 1];
    const float v = x[(long)c * 18432 + n0 + tn];
    tile[cc][tn] = (v - mean) * rstd * gamma[c] + beta[c];
  }
  __syncthreads();
  for (int nn = tr; nn < 64; nn += 4) {
    hnT[(long)(n0 + nn) * 512 + c0 + tn] = f2bf(tile[tn][nn]);
  }
}

// ---------------- fp32 -> bf16 weight pack ----------------
__global__ __launch_bounds__(256) void pack_bf16_k(const float* __restrict__ w,
                                                   unsigned short* __restrict__ o) {
  const int i = (blockIdx.x * 256 + threadIdx.x) * 4;
  const float4 v = *(const float4*)(w + i);
  ushort4 u; u.x = f2bf(v.x); u.y = f2bf(v.y); u.z = f2bf(v.z); u.w = f2bf(v.w);
  *(ushort4*)(o + i) = u;
}

__global__ void pack_bias_k(const float* __restrict__ bq, const float* __restrict__ bk,
                            float* __restrict__ bqk) {
  const int t = threadIdx.x;
  bqk[t] = (t < 512) ? bq[t] : bk[t - 512];
}

// ---------------- per-row 1/L combine from per-tile sums (NT tiles of rows) ----------------
__global__ __launch_bounds__(256) void combine_k(const float* __restrict__ rs,
                                                 float* __restrict__ linv, int ntile) {
  const int row = blockIdx.x * 256 + threadIdx.x;  // [0, 18432)
  const int t = row / 2304, r = row % 2304;
  float L = 0.f;
  for (int x = 0; x < ntile; ++x) L += rs[((long)(t * ntile + x)) * 2304 + r];
  linv[row] = 1.0f / L;
}

// ================= BMxBNx64 NT GEMM, XCD-swizzled, bf16/fp8 =================
// C[n*ldc+m] = alpha*sum_k A[m,k]*B[n,k] (+bias)(+resid)
// WL=0, BM=256: 512 thr, 8 waves (2m x 4n), 1 block/CU, P2=0, setprio ON.
// WL=0, BM=128: 256 thr, 4 waves (1m x 4n, BN=256), 2 blocks/CU, P2=1, no prio.
// WL=1 (R13):   BM=128 x BN=128, 256 thr, 4 waves (2m x 2n, 64x64/wave),
//   acc=64 VGPR -> ~160/wave, launch_bounds(256,3) -> 3 blocks/CU (96KB LDS).
//   Theory: S at 2 waves/SIMD is stall-bound (MfmaUtil 25 + VALUBusy 23,
//   >50% no-issue; R10/R11/R12 schedule knobs all null; R12 showed fewer,
//   more-lockstep waves is WORSE). 3 independent blocks/SIMD + fine-grain
//   2592-block grid (tail 18.5% -> ~5%) attacks the stall directly.
//   A-halves use B-style 32-row stripe interleave: global row =
//   (r>>5)*64 + h*32 + (r&31); wave wm covers rows [wm*64, wm*64+64).
// P2=0 (8-phase snake): see prior rounds; vmcnt V0=GB+2GA, V3=2GB+GA, VP=GB+GA.
// P2=1 (2-phase): P0: read A0,B0,B1; stage [A0,B1,A1](W+1) -> s^1; mfma m0x{n0,n1}.
//   P1: read A1; stage B0(W+2) -> s; mfma m1x{n1,n0}.
//   Waits: @P0-end vmcnt(2GA+2GB); @P1-end vmcnt(GA+GB); tail GA then 0.
// STATS: exp+rowsums (tile index bx over gx m-tiles). SCALEN: *linv[n].
// OUT_MODE: 0 bf16, 1 f32+resid, 2 fp8 e4m3 k-interleaved.
// MODE0: bz=bid%8 per XCD; MODE1/2: XCD y/x-chunking.
template <int BM, int BIAS_MODE, int OUT_MODE, int STATS, int SCALEN, int MODE, int FP8, int P2,
          int WL = 0>
__global__ __launch_bounds__((BM == 256) ? 512 : 256, WL ? 3 : 2)
void gemm256(const void* __restrict__ A, long lda, long sAz,
             const void* __restrict__ B, long ldb, long sBz,
             void* __restrict__ Cp, long ldc, long sCz,
             const float* __restrict__ bias,
             const float* __restrict__ resid,
             float* __restrict__ rowsums,
             const float* __restrict__ linv,
             float alpha, int K, int gx, int gy) {
  constexpr int EB = FP8 ? 1 : 2;                    // element bytes
  constexpr int THREADS = (BM == 256) ? 512 : 256;
  constexpr int BN = WL ? 128 : 256;                 // n-tile
  constexpr int HBA = (BM / 2) * 64 * EB;            // bytes per A half
  constexpr int HBB = (BN / 2) * 64 * EB;            // bytes per B half
  constexpr int GA = HBA / (THREADS * 16);           // gll per A-half stage
  constexpr int GB = HBB / (THREADS * 16);           // gll per B-half stage
  constexpr int V0 = GB + 2 * GA, V3 = 2 * GB + GA, VP = GB + GA;
  constexpr int NSLOT = WL ? 8 : ((BM == 256) ? 8 : 4);
  constexpr int MR = WL ? 4 : 8;                     // acc M-frags per wave
  constexpr int FQ = WL ? 2 : 4;                     // A-frags per (mh) phase
  constexpr int PRIO = !P2;                          // setprio only on 1-block path
  __shared__ alignas(16) unsigned char As[2][2][HBA];
  __shared__ alignas(16) unsigned char Bs[2][2][HBB];
  using ABt2 = typename std::conditional<FP8, longx2, bf2frag>::type;

  const int tid = threadIdx.x;
  const int lane = tid & 63, wid = tid >> 6;
  const int wm = WL ? (wid >> 1) : ((BM == 256) ? (wid & 1) : 0);
  const int wn = WL ? (wid & 1) : ((BM == 256) ? (wid >> 1) : wid);
  int bx, by, bz;
  {
    const int g8 = blockIdx.x & 7, n = blockIdx.x >> 3;
    if (MODE == 0) { bz = g8; bx = n % gx; by = n / gx; }
    else if (MODE == 1) { bz = 0; bx = n % gx; by = g8 * gy + n / gx; }
    else { bz = 0; by = n % gy; bx = g8 * gx + n / gy; }
  }
  const unsigned char* Ab = (const unsigned char*)A + ((long)bz * sAz + (long)bx * BM * lda) * EB;
  const unsigned char* Bb = (const unsigned char*)B + ((long)bz * sBz + (long)by * BN * ldb) * EB;

  // ---- staging (global -> LDS, pre-swizzled source; fp8 global is k-interleaved) ----
  auto stageA = [&](int slot, int h, int k0) {
    if constexpr (!FP8) {
      const int ksw = ((tid & 7) << 3) ^ (((tid >> 3) & 7) << 3);
#pragma unroll
      for (int call = 0; call < GA; ++call) {
        const int r = call * (THREADS / 8) + (tid >> 3);
        const int grow = ((r >> 6) << 7) + h * 64 + (r & 63);
        gll(Ab + ((long)grow * lda + k0) * 2 + ksw * 2, &As[slot][h][call * THREADS * 16 + tid * 16]);
      }
    } else {
#pragma unroll
      for (int call = 0; call < GA; ++call) {
        const int l = call * (THREADS / 4) + (tid >> 2);
        const int grow = WL ? (((l >> 5) << 6) + h * 32 + (l & 31))
                            : (((l >> 6) << 7) + h * 64 + (l & 63));
        const int x = (((l & 3) ^ ((l >> 2) & 3)) << 4);
        gll(Ab + (long)grow * lda + k0 + (((tid & 3) << 4) ^ x),
            &As[slot][h][call * THREADS * 16 + tid * 16]);
      }
    }
  };
  auto stageB = [&](int slot, int h, int k0) {
    if constexpr (!FP8) {
      const int ksw = ((tid & 7) << 3) ^ (((tid >> 3) & 7) << 3);
#pragma unroll
      for (int call = 0; call < GB; ++call) {
        const int r = call * (THREADS / 8) + (tid >> 3);
        const int grow = ((r >> 5) << 6) + h * 32 + (r & 31);
        gll(Bb + ((long)grow * ldb + k0) * 2 + ksw * 2, &Bs[slot][h][call * THREADS * 16 + tid * 16]);
      }
    } else {
#pragma unroll
      for (int call = 0; call < GB; ++call) {
        const int l = call * (THREADS / 4) + (tid >> 2);
        const int grow = ((l >> 5) << 6) + h * 32 + (l & 31);
        const int x = (((l & 3) ^ ((l >> 2) & 3)) << 4);
        gll(Bb + (long)grow * ldb + k0 + (((tid & 3) << 4) ^ x),
            &Bs[slot][h][call * THREADS * 16 + tid * 16]);
      }
    }
  };
  // ---- LDS -> fragment reads (same swizzle; fp8 = ONE b128 for both k2 slices) ----
  auto ldA = [&](int slot, int mh, int fq) -> ABt2 {
    const int r = (WL ? wm * 32 : wm * 64) + fq * 16 + (lane & 15);
    if constexpr (!FP8) {
      bf2frag f;
      const int kk0 = (((lane >> 4) << 3)) ^ ((r & 7) << 3);
      const int kk1 = (32 + ((lane >> 4) << 3)) ^ ((r & 7) << 3);
      f.k0 = *reinterpret_cast<const bf16x8*>(&As[slot][mh][r * 128 + kk0 * 2]);
      f.k1 = *reinterpret_cast<const bf16x8*>(&As[slot][mh][r * 128 + kk1 * 2]);
      return f;
    } else {
      const int x = (((r & 3) ^ ((r >> 2) & 3)) << 4);
      const int kk = ((lane >> 4) << 4) ^ x;
      return *reinterpret_cast<const longx2*>(&As[slot][mh][r * 64 + kk]);
    }
  };
  auto ldB = [&](int slot, int nh, int g) -> ABt2 {
    const int r = wn * 32 + g * 16 + (lane & 15);
    if constexpr (!FP8) {
      bf2frag f;
      const int kk0 = (((lane >> 4) << 3)) ^ ((r & 7) << 3);
      const int kk1 = (32 + ((lane >> 4) << 3)) ^ ((r & 7) << 3);
      f.k0 = *reinterpret_cast<const bf16x8*>(&Bs[slot][nh][r * 128 + kk0 * 2]);
      f.k1 = *reinterpret_cast<const bf16x8*>(&Bs[slot][nh][r * 128 + kk1 * 2]);
      return f;
    } else {
      const int x = (((r & 3) ^ ((r >> 2) & 3)) << 4);
      const int kk = ((lane >> 4) << 4) ^ x;
      return *reinterpret_cast<const longx2*>(&Bs[slot][nh][r * 64 + kk]);
    }
  };

  f32x4 acc[MR][4] = {};
  ABt2 a[4], b0[2], b1[2];

#define READ_A(SLOT, MH)                                                     \
  _Pragma("unroll") for (int fq = 0; fq < FQ; ++fq) a[fq] = ldA(SLOT, MH, fq);
#define READ_B(SLOT, NH, DST)                                                \
  _Pragma("unroll") for (int g = 0; g < 2; ++g) DST[g] = ldB(SLOT, NH, g);
#define MFMA_QUAD(MH, NH, BARR)                                              \
  if constexpr (PRIO) __builtin_amdgcn_s_setprio(1);                         \
  _Pragma("unroll") for (int fq = 0; fq < FQ; ++fq)                          \
    _Pragma("unroll") for (int g = 0; g < 2; ++g)                            \
      _Pragma("unroll") for (int k2 = 0; k2 < 2; ++k2)                       \
        acc[(MH) * FQ + fq][(NH) * 2 + g] =                                  \
            mmak(a[fq], BARR[g], acc[(MH) * FQ + fq][(NH) * 2 + g], k2);     \
  if constexpr (PRIO) __builtin_amdgcn_s_setprio(0);

  const int KT = K >> 6;
  // Prologue queue: [B0(0), A0(0), B1(0), A1(0), B0(1)] (+A1(1) for P2=0)
  stageB(0, 0, 0);
  stageA(0, 0, 0);
  stageB(0, 1, 0);
  stageA(0, 1, 0);
  stageB(1, 0, 64);
  if constexpr (!P2) stageA(1, 1, 64);
  vmw<VP>();
  bar();

  if constexpr (!P2) {
    for (int W = 0; W < KT; ++W) {
      const int s = W & 1;
      const int kn1 = (W + 1) << 6, kn2 = (W + 2) << 6;
      const bool st1 = (W + 1 < KT), st2 = (W + 2 < KT);
      // p0: (m0,n0)
      READ_A(s, 0)
      READ_B(s, 0, b0)
      if (st1) stageA(s ^ 1, 0, kn1);
      bar();
      MFMA_QUAD(0, 0, b0)
      if (st1) { vmw<V0>(); }
      bar();
      // p1: (m0,n1)
      READ_B(s, 1, b1)
      if (st1) stageB(s ^ 1, 1, kn1);
      bar();
      MFMA_QUAD(0, 1, b1)
      bar();
      // p2: (m1,n1)
      READ_A(s, 1)
      if (st2) stageB(s, 0, kn2);
      bar();
      MFMA_QUAD(1, 1, b1)
      bar();
      // p3: (m1,n0)
      if (st2) stageA(s, 1, kn2);
      bar();
      MFMA_QUAD(1, 0, b0)
      if (st2) { vmw<V3>(); } else { vmw<0>(); }
      bar();
    }
  } else {
    for (int W = 0; W < KT; ++W) {
      const int s = W & 1;
      const int kn1 = (W + 1) << 6, kn2 = (W + 2) << 6;
      const bool st1 = (W + 1 < KT), st2 = (W + 2 < KT);
      // P0: (m0 x n0,n1); stage next A-slot fully + B1(W+1). A1 issued LAST.
      READ_A(s, 0)
      READ_B(s, 0, b0)
      READ_B(s, 1, b1)
      if (st1) { stageA(s ^ 1, 0, kn1); stageB(s ^ 1, 1, kn1); stageA(s ^ 1, 1, kn1); }
      bar();
      MFMA_QUAD(0, 0, b0)
      MFMA_QUAD(0, 1, b1)
      if (st1) { vmw<2 * (GA + GB)>(); } else { vmw<0>(); }
      bar();
      // P1: (m1 x n1,n0); stage B0(W+2) into current slot (B0(W) consumed in P0).
      READ_A(s, 1)
      if (st2) stageB(s, 0, kn2);
      bar();
      MFMA_QUAD(1, 1, b1)
      MFMA_QUAD(1, 0, b0)
      if (st2) { vmw<GA + GB>(); } else if (st1) { vmw<GA>(); } else { vmw<0>(); }
      bar();
    }
  }

  // epilogue: acc[M][N].
  // WL=0: M = mh*4+fq, m-off = (M>>2)*64 + (M&3)*16, wave m-base wm*128.
  // WL=1: M = mh*2+fq, m-off = (M>>1)*32 + (M&1)*16, wave m-base wm*64.
  const int mg0 = bx * BM + (WL ? wm * 64 : wm * 128) + ((lane >> 4) << 2);
  const int ng0 = by * BN + wn * 64 + (lane & 15);
  float* red = (float*)&As[0][0][0];  // STATS scratch: BN rows x NSLOT f32
#pragma unroll
  for (int N = 0; N < 4; ++N) {
    const int n = ng0 + (N >> 1) * 32 + (N & 1) * 16;
    const float bn = (BIAS_MODE == 2) ? bias[n] : 0.f;
    const float sc = SCALEN ? linv[(long)bz * 2304 + n] : 1.0f;
    float eN = 0.f;
#pragma unroll
    for (int M = 0; M < MR; ++M) {
      const int m = mg0 + (WL ? ((M >> 1) * 32 + (M & 1) * 16) : ((M >> 2) * 64 + (M & 3) * 16));
      const f32x4 av = acc[M][N];
      float vals[4];
#pragma unroll
      for (int j = 0; j < 4; ++j) {
        vals[j] = av[j] * alpha + ((BIAS_MODE == 1) ? bias[m + j] : bn);
        if (SCALEN) vals[j] *= sc;
        if (STATS) { vals[j] = __expf(vals[j]); eN += vals[j]; }
      }
      if (OUT_MODE == 0) {
        ushort4 o; o.x = f2bf(vals[0]); o.y = f2bf(vals[1]); o.z = f2bf(vals[2]); o.w = f2bf(vals[3]);
        *(ushort4*)((unsigned short*)Cp + (long)bz * sCz + (long)n * ldc + m) = o;
      } else if (OUT_MODE == 2) {
        int pk = __builtin_amdgcn_cvt_pk_fp8_f32(vals[0], vals[1], 0, false);
        pk = __builtin_amdgcn_cvt_pk_fp8_f32(vals[2], vals[3], pk, true);
        *(int*)((unsigned char*)Cp + (long)bz * sCz + (long)n * ldc + perm64(m)) = pk;
      } else {
        const float* rp = resid + (long)n * ldc + m;
        float4 o; o.x = vals[0] + rp[0]; o.y = vals[1] + rp[1]; o.z = vals[2] + rp[2]; o.w = vals[3] + rp[3];
        *(float4*)((float*)Cp + (long)bz * sCz + (long)n * ldc + m) = o;
      }
    }
    if (STATS) {
      const int nloc = wn * 64 + (N >> 1) * 32 + (N & 1) * 16 + (lane & 15);
      const int slot = wm * 4 + (lane >> 4);
      red[nloc * NSLOT + slot] = eN;
    }
  }
  if (STATS) {
    bar();
    if (tid < BN) {
      float L = 0.f;
#pragma unroll
      for (int s2 = 0; s2 < NSLOT; ++s2) L += red[tid * NSLOT + s2];
      rowsums[((long)(bz * gx + bx)) * 2304 + by * BN + tid] = L;
    }
  }
#undef READ_A
#undef READ_B
#undef MFMA_QUAD
}

extern "C" void kernel_launch(void* const* d_in, const int* in_sizes, int n_in,
                              void* d_out, int out_size, void* d_ws, size_t ws_size,
                              hipStream_t stream) {
  const float* x = (const float*)d_in[0];
  const float* gamma = (const float*)d_in[1];
  const float* beta = (const float*)d_in[2];
  const float* wq = (const float*)d_in[3];
  const float* bq = (const float*)d_in[4];
  const float* wk = (const float*)d_in[5];
  const float* bk = (const float*)d_in[6];
  const float* wv = (const float*)d_in[7];
  const float* bv = (const float*)d_in[8];
  const float* wo = (const float*)d_in[9];
  const float* bo = (const float*)d_in[10];
  float* out = (float*)d_out;

  char* ws = (char*)d_ws;
  size_t off = 0;
  auto alloc = [&](size_t bytes) {
    char* p = ws + off;
    off = (off + bytes + 255) & ~(size_t)255;
    return p;
  };
  float* part = (float*)alloc(256 * 2 * sizeof(float));
  float* stats = (float*)alloc(32 * 2 * sizeof(float));
  unsigned short* wqkb = (unsigned short*)alloc((size_t)2 * 262144 * 2);
  unsigned short* wvb = (unsigned short*)alloc((size_t)262144 * 2);
  unsigned short* wob = (unsigned short*)alloc((size_t)262144 * 2);
  float* bqk = (float*)alloc(1024 * sizeof(float));
  float* rowsums = (float*)alloc((size_t)8 * 18 * 2304 * sizeof(float));
  float* linv = (float*)alloc((size_t)18432 * sizeof(float));
  unsigned short* hnT = (unsigned short*)alloc((size_t)18432 * 512 * 2);
  unsigned char* qkA = (unsigned char*)alloc((size_t)18432 * 1024);      // fp8 k-interleaved
  unsigned char* vT = (unsigned char*)alloc((size_t)512 * 18432);        // fp8 k-interleaved
  unsigned char* Sm = (unsigned char*)alloc((size_t)8 * 2304 * 2304);    // fp8 E k-interleaved
  unsigned short* Ob = hnT;  // alias: hnT fully consumed after qk/v GEMMs
  (void)ws_size; (void)in_sizes; (void)n_in; (void)out_size;

  stats_partial_k<<<dim3(256), dim3(256), 0, stream>>>(x, part);
  stats_final_k<<<dim3(1), dim3(64), 0, stream>>>(part, stats);
  gn_transpose_k<<<dim3(8, 288), dim3(256), 0, stream>>>(x, stats, gamma, beta, hnT);
  pack_bf16_k<<<dim3(256), dim3(256), 0, stream>>>(wq, wqkb);
  pack_bf16_k<<<dim3(256), dim3(256), 0, stream>>>(wk, wqkb + 262144);
  pack_bf16_k<<<dim3(256), dim3(256), 0, stream>>>(wv, wvb);
  pack_bf16_k<<<dim3(256), dim3(256), 0, stream>>>(wo, wob);
  pack_bias_k<<<dim3(1), dim3(1024), 0, stream>>>(bq, bk, bqk);

  // qk fused: A=[Wq;Wk] bf16, B=hnT bf16 -> q,k fp8 interleaved [sp][1024]. MODE1: 288 blocks.
  gemm256<256, 1, 2, 0, 0, 1, 0, 0><<<dim3(288), dim3(512), 0, stream>>>(
      wqkb, 512, 0, hnT, 512, 0, (void*)qkA, 1024, 0, bqk, nullptr, nullptr, nullptr,
      1.0f, 512, 4, 9);
  // v: A=hnT bf16, B=Wv bf16 -> vT fp8 interleaved [co][18432]. MODE2: 144 blocks.
  gemm256<256, 2, 2, 0, 0, 2, 0, 0><<<dim3(144), dim3(512), 0, stream>>>(
      hnT, 512, 0, wvb, 512, 0, (void*)vT, 18432, 0, bv, nullptr, nullptr, nullptr,
      1.0f, 512, 9, 2);
  // S: per t: A=k fp8, B=q fp8 -> E=exp(alpha*S) fp8 interleaved + rowsums.
  // R13: WL=1 128x128 tiles, 3 blocks/CU: 18x18x8 = 2592 blocks MODE0.
  gemm256<128, 0, 2, 1, 0, 0, 1, 1, 1><<<dim3(2592), dim3(256), 0, stream>>>(
      qkA + 512, 1024, (long)2304 * 1024, qkA, 1024, (long)2304 * 1024, (void*)Sm, 2304,
      (long)2304 * 2304, nullptr, nullptr, rowsums, nullptr,
      0.044194173824159216f, 512, 18, 18);
  combine_k<<<dim3(72), dim3(256), 0, stream>>>(rowsums, linv, 18);
  // PV: per t: A=vT fp8, B=E fp8 -> O bf16 [(t,i)*512+c], rows scaled by linv.
  // BM=128 (256 thr, 2 blocks/CU), P2=1 (no setprio): 288 blocks MODE0.
  gemm256<128, 0, 0, 0, 1, 0, 1, 1><<<dim3(288), dim3(256), 0, stream>>>(
      vT, 18432, 2304, Sm, 2304, (long)2304 * 2304, (void*)Ob, 512, (long)2304 * 512,
      nullptr, nullptr, nullptr, linv, 1.0f, 2304, 4, 0);
  // final: A=O bf16, B=Wo bf16 -> out[co*18432+sp] = x + acc + bo[co]. MODE2: 144 blocks.
  gemm256<256, 2, 1, 0, 0, 2, 0, 0><<<dim3(144), dim3(512), 0, stream>>>(
      Ob, 512, 0, wob, 512, 0, (void*)out, 18432, 0, bo, x, nullptr, nullptr,
      1.0f, 512, 9, 2);
}

// Round 5
// 244.684 us; speedup vs baseline: 1.0903x; 1.0402x over previous
//
#include <hip/hip_runtime.h>
#include <hip/hip_bf16.h>
#include <cstdint>
#include <type_traits>

typedef __attribute__((ext_vector_type(8))) __bf16 bf16x8;
typedef __attribute__((ext_vector_type(4))) float f32x4;
typedef __attribute__((ext_vector_type(2))) long longx2;

struct bf2frag { bf16x8 k0, k1; };

__device__ __forceinline__ float bf2f(unsigned short u) {
  union { uint32_t i; float f; } v; v.i = (uint32_t)u << 16; return v.f;
}
__device__ __forceinline__ unsigned short f2bf(float f) {
  union { float f; uint32_t i; } v{f};
  uint32_t r = v.i + 0x7fffu + ((v.i >> 16) & 1u);
  return (unsigned short)(r >> 16);
}

__device__ __forceinline__ void gll(const void* g, void* l) {
  __builtin_amdgcn_global_load_lds(
      (const __attribute__((address_space(1))) uint32_t*)(uintptr_t)g,
      (__attribute__((address_space(3))) uint32_t*)(uint32_t)(uintptr_t)l,
      16, 0, 0);
}

__device__ __forceinline__ void bar() {
  asm volatile("" ::: "memory");
  __builtin_amdgcn_s_barrier();
  asm volatile("" ::: "memory");
}

#define VMCNT(n) asm volatile("s_waitcnt vmcnt(" #n ")" ::: "memory")

template <int N>
__device__ __forceinline__ void vmw() {
  if constexpr (N == 0) { VMCNT(0); }
  else if constexpr (N == 1) { VMCNT(1); }
  else if constexpr (N == 2) { VMCNT(2); }
  else if constexpr (N == 3) { VMCNT(3); }
  else if constexpr (N == 4) { VMCNT(4); }
  else if constexpr (N == 5) { VMCNT(5); }
  else if constexpr (N == 6) { VMCNT(6); }
  else if constexpr (N == 7) { VMCNT(7); }
  else if constexpr (N == 8) { VMCNT(8); }
  else if constexpr (N == 9) { VMCNT(9); }
  else if constexpr (N == 10) { VMCNT(10); }
  else { VMCNT(12); }
}

__device__ __forceinline__ f32x4 mma(bf16x8 a, bf16x8 b, f32x4 c) {
  return __builtin_amdgcn_mfma_f32_16x16x32_bf16(a, b, c, 0, 0, 0);
}
__device__ __forceinline__ f32x4 mma(long a, long b, f32x4 c) {
  return __builtin_amdgcn_mfma_f32_16x16x32_fp8_fp8(a, b, c, 0, 0, 0);
}
__device__ __forceinline__ f32x4 mmak(const bf2frag& a, const bf2frag& b, f32x4 c, int k2) {
  return k2 ? mma(a.k1, b.k1, c) : mma(a.k0, b.k0, c);
}
__device__ __forceinline__ f32x4 mmak(longx2 a, longx2 b, f32x4 c, int k2) {
  return mma(a[k2], b[k2], c);
}

// k-interleave store permutation for fp8 buffers (unit u=8B: slot p(u)=(u&3)*2+(u>>2))
__device__ __forceinline__ int perm64(int m) {
  return (m & ~63) | (((m >> 3) & 3) << 4) | (((m >> 5) & 1) << 3) | (m & 7);
}

// ---------------- GroupNorm stats ----------------
__global__ __launch_bounds__(256) void stats_partial_k(const float* __restrict__ x,
                                                       float* __restrict__ part) {
  const int g = blockIdx.x >> 3, p = blockIdx.x & 7;
  const float* base = x + (long)g * 16 * 18432 + (long)p * 2304;
  float s = 0.f, ss = 0.f;
  for (int idx = threadIdx.x; idx < 16 * 576; idx += 256) {
    const int c = idx / 576, i4 = idx % 576;
    const float4 v = *(const float4*)(base + (long)c * 18432 + i4 * 4);
    s += v.x + v.y + v.z + v.w;
    ss += v.x * v.x + v.y * v.y + v.z * v.z + v.w * v.w;
  }
  __shared__ float rs[256], rss[256];
  rs[threadIdx.x] = s; rss[threadIdx.x] = ss;
  __syncthreads();
  for (int o = 128; o > 0; o >>= 1) {
    if ((int)threadIdx.x < o) { rs[threadIdx.x] += rs[threadIdx.x + o]; rss[threadIdx.x] += rss[threadIdx.x + o]; }
    __syncthreads();
  }
  if (threadIdx.x == 0) { part[blockIdx.x * 2] = rs[0]; part[blockIdx.x * 2 + 1] = rss[0]; }
}

__global__ void stats_final_k(const float* __restrict__ part, float* __restrict__ stats) {
  const int g = threadIdx.x;
  if (g < 32) {
    float s = 0.f, ss = 0.f;
    for (int p = 0; p < 8; ++p) { s += part[(g * 8 + p) * 2]; ss += part[(g * 8 + p) * 2 + 1]; }
    const float mean = s / 294912.0f;
    const float var = ss / 294912.0f - mean * mean;
    stats[g * 2] = mean;
    stats[g * 2 + 1] = rsqrtf(var + 1e-6f);
  }
}

// ---------------- GN apply + transpose to (spatial, channel) bf16 ----------------
__global__ __launch_bounds__(256) void gn_transpose_k(const float* __restrict__ x,
                                                      const float* __restrict__ stats,
                                                      const float* __restrict__ gamma,
                                                      const float* __restrict__ beta,
                                                      unsigned short* __restrict__ hnT) {
  __shared__ float tile[64][65];
  const int c0 = blockIdx.x * 64, n0 = blockIdx.y * 64;
  const int tn = threadIdx.x & 63, tr = threadIdx.x >> 6;
  for (int cc = tr; cc < 64; cc += 4) {
    const int c = c0 + cc, g = c >> 4;
    const float mean = stats[g * 2], rstd = stats[g * 2 + 1];
    const float v = x[(long)c * 18432 + n0 + tn];
    tile[cc][tn] = (v - mean) * rstd * gamma[c] + beta[c];
  }
  __syncthreads();
  for (int nn = tr; nn < 64; nn += 4) {
    hnT[(long)(n0 + nn) * 512 + c0 + tn] = f2bf(tile[tn][nn]);
  }
}

// ---------------- fp32 -> bf16 weight pack ----------------
__global__ __launch_bounds__(256) void pack_bf16_k(const float* __restrict__ w,
                                                   unsigned short* __restrict__ o) {
  const int i = (blockIdx.x * 256 + threadIdx.x) * 4;
  const float4 v = *(const float4*)(w + i);
  ushort4 u; u.x = f2bf(v.x); u.y = f2bf(v.y); u.z = f2bf(v.z); u.w = f2bf(v.w);
  *(ushort4*)(o + i) = u;
}

__global__ void pack_bias_k(const float* __restrict__ bq, const float* __restrict__ bk,
                            float* __restrict__ bqk) {
  const int t = threadIdx.x;
  bqk[t] = (t < 512) ? bq[t] : bk[t - 512];
}

// ---------------- per-row 1/L combine from per-tile sums (NT tiles of rows) ----------------
__global__ __launch_bounds__(256) void combine_k(const float* __restrict__ rs,
                                                 float* __restrict__ linv, int ntile) {
  const int row = blockIdx.x * 256 + threadIdx.x;  // [0, 18432)
  const int t = row / 2304, r = row % 2304;
  float L = 0.f;
  for (int x = 0; x < ntile; ++x) L += rs[((long)(t * ntile + x)) * 2304 + r];
  linv[row] = 1.0f / L;
}

// ================= BMxBNx64 NT GEMM, XCD-swizzled, bf16/fp8 =================
// C[n*ldc+m] = alpha*sum_k A[m,k]*B[n,k] (+bias)(+resid)
// WL=0, BM=256: 512 thr, 8 waves (2m x 4n), 1 block/CU, P2=0, setprio ON.
// WL=0, BM=128: 256 thr, 4 waves (1m x 4n, BN=256), 2 blocks/CU, P2=1, no prio.
// WL=1: BM=128 x BN=128, 256 thr, 4 waves (2m x 2n, 64x64/wave).
//   fp8: 32KB LDS -> 3 blocks/CU (R13, S: proven win). bf16: 64KB LDS -> 2
//   blocks/CU (launch_bounds min-waves 2). R14: qk moved BM=256 (288 blocks,
//   1.125 rounds -> 2-round makespan, 44% idle; MfmaUtil 11.7) -> WL=1 bf16:
//   1152 blocks / 512 slots = 2.25 -> 3 rounds of quarter-size blocks ~ 0.75x,
//   plus 2-block/CU latency overlap. Only new code: WL grow stripe in bf16
//   stageA (ldA/ldB/epilogue algebra already WL-aware, refcheck'd via S R13).
//   A/B halves use 32-row stripe interleave: grow = (r>>5)*64 + h*32 + (r&31);
//   wave wm covers rows [wm*64, wm*64+64).
// P2=0 (8-phase snake): see prior rounds; vmcnt V0=GB+2GA, V3=2GB+GA, VP=GB+GA.
// P2=1 (2-phase): P0: read A0,B0,B1; stage [A0,B1,A1](W+1) -> s^1; mfma m0x{n0,n1}.
//   P1: read A1; stage B0(W+2) -> s; mfma m1x{n1,n0}.
//   Waits: @P0-end vmcnt(2GA+2GB); @P1-end vmcnt(GA+GB); tail GA then 0.
// STATS: exp+rowsums (tile index bx over gx m-tiles). SCALEN: *linv[n].
// OUT_MODE: 0 bf16, 1 f32+resid, 2 fp8 e4m3 k-interleaved.
// MODE0: bz=bid%8 per XCD; MODE1/2: XCD y/x-chunking.
template <int BM, int BIAS_MODE, int OUT_MODE, int STATS, int SCALEN, int MODE, int FP8, int P2,
          int WL = 0>
__global__ __launch_bounds__((BM == 256) ? 512 : 256, (WL && FP8) ? 3 : 2)
void gemm256(const void* __restrict__ A, long lda, long sAz,
             const void* __restrict__ B, long ldb, long sBz,
             void* __restrict__ Cp, long ldc, long sCz,
             const float* __restrict__ bias,
             const float* __restrict__ resid,
             float* __restrict__ rowsums,
             const float* __restrict__ linv,
             float alpha, int K, int gx, int gy) {
  constexpr int EB = FP8 ? 1 : 2;                    // element bytes
  constexpr int THREADS = (BM == 256) ? 512 : 256;
  constexpr int BN = WL ? 128 : 256;                 // n-tile
  constexpr int HBA = (BM / 2) * 64 * EB;            // bytes per A half
  constexpr int HBB = (BN / 2) * 64 * EB;            // bytes per B half
  constexpr int GA = HBA / (THREADS * 16);           // gll per A-half stage
  constexpr int GB = HBB / (THREADS * 16);           // gll per B-half stage
  constexpr int V0 = GB + 2 * GA, V3 = 2 * GB + GA, VP = GB + GA;
  constexpr int NSLOT = WL ? 8 : ((BM == 256) ? 8 : 4);
  constexpr int MR = WL ? 4 : 8;                     // acc M-frags per wave
  constexpr int FQ = WL ? 2 : 4;                     // A-frags per (mh) phase
  constexpr int PRIO = !P2;                          // setprio only on 1-block path
  __shared__ alignas(16) unsigned char As[2][2][HBA];
  __shared__ alignas(16) unsigned char Bs[2][2][HBB];
  using ABt2 = typename std::conditional<FP8, longx2, bf2frag>::type;

  const int tid = threadIdx.x;
  const int lane = tid & 63, wid = tid >> 6;
  const int wm = WL ? (wid >> 1) : ((BM == 256) ? (wid & 1) : 0);
  const int wn = WL ? (wid & 1) : ((BM == 256) ? (wid >> 1) : wid);
  int bx, by, bz;
  {
    const int g8 = blockIdx.x & 7, n = blockIdx.x >> 3;
    if (MODE == 0) { bz = g8; bx = n % gx; by = n / gx; }
    else if (MODE == 1) { bz = 0; bx = n % gx; by = g8 * gy + n / gx; }
    else { bz = 0; by = n % gy; bx = g8 * gx + n / gy; }
  }
  const unsigned char* Ab = (const unsigned char*)A + ((long)bz * sAz + (long)bx * BM * lda) * EB;
  const unsigned char* Bb = (const unsigned char*)B + ((long)bz * sBz + (long)by * BN * ldb) * EB;

  // ---- staging (global -> LDS, pre-swizzled source; fp8 global is k-interleaved) ----
  auto stageA = [&](int slot, int h, int k0) {
    if constexpr (!FP8) {
      const int ksw = ((tid & 7) << 3) ^ (((tid >> 3) & 7) << 3);
#pragma unroll
      for (int call = 0; call < GA; ++call) {
        const int r = call * (THREADS / 8) + (tid >> 3);
        const int grow = WL ? (((r >> 5) << 6) + h * 32 + (r & 31))
                            : (((r >> 6) << 7) + h * 64 + (r & 63));
        gll(Ab + ((long)grow * lda + k0) * 2 + ksw * 2, &As[slot][h][call * THREADS * 16 + tid * 16]);
      }
    } else {
#pragma unroll
      for (int call = 0; call < GA; ++call) {
        const int l = call * (THREADS / 4) + (tid >> 2);
        const int grow = WL ? (((l >> 5) << 6) + h * 32 + (l & 31))
                            : (((l >> 6) << 7) + h * 64 + (l & 63));
        const int x = (((l & 3) ^ ((l >> 2) & 3)) << 4);
        gll(Ab + (long)grow * lda + k0 + (((tid & 3) << 4) ^ x),
            &As[slot][h][call * THREADS * 16 + tid * 16]);
      }
    }
  };
  auto stageB = [&](int slot, int h, int k0) {
    if constexpr (!FP8) {
      const int ksw = ((tid & 7) << 3) ^ (((tid >> 3) & 7) << 3);
#pragma unroll
      for (int call = 0; call < GB; ++call) {
        const int r = call * (THREADS / 8) + (tid >> 3);
        const int grow = ((r >> 5) << 6) + h * 32 + (r & 31);
        gll(Bb + ((long)grow * ldb + k0) * 2 + ksw * 2, &Bs[slot][h][call * THREADS * 16 + tid * 16]);
      }
    } else {
#pragma unroll
      for (int call = 0; call < GB; ++call) {
        const int l = call * (THREADS / 4) + (tid >> 2);
        const int grow = ((l >> 5) << 6) + h * 32 + (l & 31);
        const int x = (((l & 3) ^ ((l >> 2) & 3)) << 4);
        gll(Bb + (long)grow * ldb + k0 + (((tid & 3) << 4) ^ x),
            &Bs[slot][h][call * THREADS * 16 + tid * 16]);
      }
    }
  };
  // ---- LDS -> fragment reads (same swizzle; fp8 = ONE b128 for both k2 slices) ----
  auto ldA = [&](int slot, int mh, int fq) -> ABt2 {
    const int r = (WL ? wm * 32 : wm * 64) + fq * 16 + (lane & 15);
    if constexpr (!FP8) {
      bf2frag f;
      const int kk0 = (((lane >> 4) << 3)) ^ ((r & 7) << 3);
      const int kk1 = (32 + ((lane >> 4) << 3)) ^ ((r & 7) << 3);
      f.k0 = *reinterpret_cast<const bf16x8*>(&As[slot][mh][r * 128 + kk0 * 2]);
      f.k1 = *reinterpret_cast<const bf16x8*>(&As[slot][mh][r * 128 + kk1 * 2]);
      return f;
    } else {
      const int x = (((r & 3) ^ ((r >> 2) & 3)) << 4);
      const int kk = ((lane >> 4) << 4) ^ x;
      return *reinterpret_cast<const longx2*>(&As[slot][mh][r * 64 + kk]);
    }
  };
  auto ldB = [&](int slot, int nh, int g) -> ABt2 {
    const int r = wn * 32 + g * 16 + (lane & 15);
    if constexpr (!FP8) {
      bf2frag f;
      const int kk0 = (((lane >> 4) << 3)) ^ ((r & 7) << 3);
      const int kk1 = (32 + ((lane >> 4) << 3)) ^ ((r & 7) << 3);
      f.k0 = *reinterpret_cast<const bf16x8*>(&Bs[slot][nh][r * 128 + kk0 * 2]);
      f.k1 = *reinterpret_cast<const bf16x8*>(&Bs[slot][nh][r * 128 + kk1 * 2]);
      return f;
    } else {
      const int x = (((r & 3) ^ ((r >> 2) & 3)) << 4);
      const int kk = ((lane >> 4) << 4) ^ x;
      return *reinterpret_cast<const longx2*>(&Bs[slot][nh][r * 64 + kk]);
    }
  };

  f32x4 acc[MR][4] = {};
  ABt2 a[4], b0[2], b1[2];

#define READ_A(SLOT, MH)                                                     \
  _Pragma("unroll") for (int fq = 0; fq < FQ; ++fq) a[fq] = ldA(SLOT, MH, fq);
#define READ_B(SLOT, NH, DST)                                                \
  _Pragma("unroll") for (int g = 0; g < 2; ++g) DST[g] = ldB(SLOT, NH, g);
#define MFMA_QUAD(MH, NH, BARR)                                              \
  if constexpr (PRIO) __builtin_amdgcn_s_setprio(1);                         \
  _Pragma("unroll") for (int fq = 0; fq < FQ; ++fq)                          \
    _Pragma("unroll") for (int g = 0; g < 2; ++g)                            \
      _Pragma("unroll") for (int k2 = 0; k2 < 2; ++k2)                       \
        acc[(MH) * FQ + fq][(NH) * 2 + g] =                                  \
            mmak(a[fq], BARR[g], acc[(MH) * FQ + fq][(NH) * 2 + g], k2);     \
  if constexpr (PRIO) __builtin_amdgcn_s_setprio(0);

  const int KT = K >> 6;
  // Prologue queue: [B0(0), A0(0), B1(0), A1(0), B0(1)] (+A1(1) for P2=0)
  stageB(0, 0, 0);
  stageA(0, 0, 0);
  stageB(0, 1, 0);
  stageA(0, 1, 0);
  stageB(1, 0, 64);
  if constexpr (!P2) stageA(1, 1, 64);
  vmw<VP>();
  bar();

  if constexpr (!P2) {
    for (int W = 0; W < KT; ++W) {
      const int s = W & 1;
      const int kn1 = (W + 1) << 6, kn2 = (W + 2) << 6;
      const bool st1 = (W + 1 < KT), st2 = (W + 2 < KT);
      // p0: (m0,n0)
      READ_A(s, 0)
      READ_B(s, 0, b0)
      if (st1) stageA(s ^ 1, 0, kn1);
      bar();
      MFMA_QUAD(0, 0, b0)
      if (st1) { vmw<V0>(); }
      bar();
      // p1: (m0,n1)
      READ_B(s, 1, b1)
      if (st1) stageB(s ^ 1, 1, kn1);
      bar();
      MFMA_QUAD(0, 1, b1)
      bar();
      // p2: (m1,n1)
      READ_A(s, 1)
      if (st2) stageB(s, 0, kn2);
      bar();
      MFMA_QUAD(1, 1, b1)
      bar();
      // p3: (m1,n0)
      if (st2) stageA(s, 1, kn2);
      bar();
      MFMA_QUAD(1, 0, b0)
      if (st2) { vmw<V3>(); } else { vmw<0>(); }
      bar();
    }
  } else {
    for (int W = 0; W < KT; ++W) {
      const int s = W & 1;
      const int kn1 = (W + 1) << 6, kn2 = (W + 2) << 6;
      const bool st1 = (W + 1 < KT), st2 = (W + 2 < KT);
      // P0: (m0 x n0,n1); stage next A-slot fully + B1(W+1). A1 issued LAST.
      READ_A(s, 0)
      READ_B(s, 0, b0)
      READ_B(s, 1, b1)
      if (st1) { stageA(s ^ 1, 0, kn1); stageB(s ^ 1, 1, kn1); stageA(s ^ 1, 1, kn1); }
      bar();
      MFMA_QUAD(0, 0, b0)
      MFMA_QUAD(0, 1, b1)
      if (st1) { vmw<2 * (GA + GB)>(); } else { vmw<0>(); }
      bar();
      // P1: (m1 x n1,n0); stage B0(W+2) into current slot (B0(W) consumed in P0).
      READ_A(s, 1)
      if (st2) stageB(s, 0, kn2);
      bar();
      MFMA_QUAD(1, 1, b1)
      MFMA_QUAD(1, 0, b0)
      if (st2) { vmw<GA + GB>(); } else if (st1) { vmw<GA>(); } else { vmw<0>(); }
      bar();
    }
  }

  // epilogue: acc[M][N].
  // WL=0: M = mh*4+fq, m-off = (M>>2)*64 + (M&3)*16, wave m-base wm*128.
  // WL=1: M = mh*2+fq, m-off = (M>>1)*32 + (M&1)*16, wave m-base wm*64.
  const int mg0 = bx * BM + (WL ? wm * 64 : wm * 128) + ((lane >> 4) << 2);
  const int ng0 = by * BN + wn * 64 + (lane & 15);
  float* red = (float*)&As[0][0][0];  // STATS scratch: BN rows x NSLOT f32
#pragma unroll
  for (int N = 0; N < 4; ++N) {
    const int n = ng0 + (N >> 1) * 32 + (N & 1) * 16;
    const float bn = (BIAS_MODE == 2) ? bias[n] : 0.f;
    const float sc = SCALEN ? linv[(long)bz * 2304 + n] : 1.0f;
    float eN = 0.f;
#pragma unroll
    for (int M = 0; M < MR; ++M) {
      const int m = mg0 + (WL ? ((M >> 1) * 32 + (M & 1) * 16) : ((M >> 2) * 64 + (M & 3) * 16));
      const f32x4 av = acc[M][N];
      float vals[4];
#pragma unroll
      for (int j = 0; j < 4; ++j) {
        vals[j] = av[j] * alpha + ((BIAS_MODE == 1) ? bias[m + j] : bn);
        if (SCALEN) vals[j] *= sc;
        if (STATS) { vals[j] = __expf(vals[j]); eN += vals[j]; }
      }
      if (OUT_MODE == 0) {
        ushort4 o; o.x = f2bf(vals[0]); o.y = f2bf(vals[1]); o.z = f2bf(vals[2]); o.w = f2bf(vals[3]);
        *(ushort4*)((unsigned short*)Cp + (long)bz * sCz + (long)n * ldc + m) = o;
      } else if (OUT_MODE == 2) {
        int pk = __builtin_amdgcn_cvt_pk_fp8_f32(vals[0], vals[1], 0, false);
        pk = __builtin_amdgcn_cvt_pk_fp8_f32(vals[2], vals[3], pk, true);
        *(int*)((unsigned char*)Cp + (long)bz * sCz + (long)n * ldc + perm64(m)) = pk;
      } else {
        const float* rp = resid + (long)n * ldc + m;
        float4 o; o.x = vals[0] + rp[0]; o.y = vals[1] + rp[1]; o.z = vals[2] + rp[2]; o.w = vals[3] + rp[3];
        *(float4*)((float*)Cp + (long)bz * sCz + (long)n * ldc + m) = o;
      }
    }
    if (STATS) {
      const int nloc = wn * 64 + (N >> 1) * 32 + (N & 1) * 16 + (lane & 15);
      const int slot = wm * 4 + (lane >> 4);
      red[nloc * NSLOT + slot] = eN;
    }
  }
  if (STATS) {
    bar();
    if (tid < BN) {
      float L = 0.f;
#pragma unroll
      for (int s2 = 0; s2 < NSLOT; ++s2) L += red[tid * NSLOT + s2];
      rowsums[((long)(bz * gx + bx)) * 2304 + by * BN + tid] = L;
    }
  }
#undef READ_A
#undef READ_B
#undef MFMA_QUAD
}

extern "C" void kernel_launch(void* const* d_in, const int* in_sizes, int n_in,
                              void* d_out, int out_size, void* d_ws, size_t ws_size,
                              hipStream_t stream) {
  const float* x = (const float*)d_in[0];
  const float* gamma = (const float*)d_in[1];
  const float* beta = (const float*)d_in[2];
  const float* wq = (const float*)d_in[3];
  const float* bq = (const float*)d_in[4];
  const float* wk = (const float*)d_in[5];
  const float* bk = (const float*)d_in[6];
  const float* wv = (const float*)d_in[7];
  const float* bv = (const float*)d_in[8];
  const float* wo = (const float*)d_in[9];
  const float* bo = (const float*)d_in[10];
  float* out = (float*)d_out;

  char* ws = (char*)d_ws;
  size_t off = 0;
  auto alloc = [&](size_t bytes) {
    char* p = ws + off;
    off = (off + bytes + 255) & ~(size_t)255;
    return p;
  };
  float* part = (float*)alloc(256 * 2 * sizeof(float));
  float* stats = (float*)alloc(32 * 2 * sizeof(float));
  unsigned short* wqkb = (unsigned short*)alloc((size_t)2 * 262144 * 2);
  unsigned short* wvb = (unsigned short*)alloc((size_t)262144 * 2);
  unsigned short* wob = (unsigned short*)alloc((size_t)262144 * 2);
  float* bqk = (float*)alloc(1024 * sizeof(float));
  float* rowsums = (float*)alloc((size_t)8 * 18 * 2304 * sizeof(float));
  float* linv = (float*)alloc((size_t)18432 * sizeof(float));
  unsigned short* hnT = (unsigned short*)alloc((size_t)18432 * 512 * 2);
  unsigned char* qkA = (unsigned char*)alloc((size_t)18432 * 1024);      // fp8 k-interleaved
  unsigned char* vT = (unsigned char*)alloc((size_t)512 * 18432);        // fp8 k-interleaved
  unsigned char* Sm = (unsigned char*)alloc((size_t)8 * 2304 * 2304);    // fp8 E k-interleaved
  unsigned short* Ob = hnT;  // alias: hnT fully consumed after qk/v GEMMs
  (void)ws_size; (void)in_sizes; (void)n_in; (void)out_size;

  stats_partial_k<<<dim3(256), dim3(256), 0, stream>>>(x, part);
  stats_final_k<<<dim3(1), dim3(64), 0, stream>>>(part, stats);
  gn_transpose_k<<<dim3(8, 288), dim3(256), 0, stream>>>(x, stats, gamma, beta, hnT);
  pack_bf16_k<<<dim3(256), dim3(256), 0, stream>>>(wq, wqkb);
  pack_bf16_k<<<dim3(256), dim3(256), 0, stream>>>(wk, wqkb + 262144);
  pack_bf16_k<<<dim3(256), dim3(256), 0, stream>>>(wv, wvb);
  pack_bf16_k<<<dim3(256), dim3(256), 0, stream>>>(wo, wob);
  pack_bias_k<<<dim3(1), dim3(1024), 0, stream>>>(bq, bk, bqk);

  // qk fused: A=[Wq;Wk] bf16, B=hnT bf16 -> q,k fp8 interleaved [sp][1024].
  // R14: WL=1 bf16 (128x128, 2 blocks/CU): 8x144x(8 XCD) = 1152 blocks MODE1.
  gemm256<128, 1, 2, 0, 0, 1, 0, 1, 1><<<dim3(1152), dim3(256), 0, stream>>>(
      wqkb, 512, 0, hnT, 512, 0, (void*)qkA, 1024, 0, bqk, nullptr, nullptr, nullptr,
      1.0f, 512, 8, 18);
  // v: A=hnT bf16, B=Wv bf16 -> vT fp8 interleaved [co][18432]. MODE2: 144 blocks.
  gemm256<256, 2, 2, 0, 0, 2, 0, 0><<<dim3(144), dim3(512), 0, stream>>>(
      hnT, 512, 0, wvb, 512, 0, (void*)vT, 18432, 0, bv, nullptr, nullptr, nullptr,
      1.0f, 512, 9, 2);
  // S: per t: A=k fp8, B=q fp8 -> E=exp(alpha*S) fp8 interleaved + rowsums.
  // WL=1 128x128 tiles, 3 blocks/CU: 18x18x8 = 2592 blocks MODE0.
  gemm256<128, 0, 2, 1, 0, 0, 1, 1, 1><<<dim3(2592), dim3(256), 0, stream>>>(
      qkA + 512, 1024, (long)2304 * 1024, qkA, 1024, (long)2304 * 1024, (void*)Sm, 2304,
      (long)2304 * 2304, nullptr, nullptr, rowsums, nullptr,
      0.044194173824159216f, 512, 18, 18);
  combine_k<<<dim3(72), dim3(256), 0, stream>>>(rowsums, linv, 18);
  // PV: per t: A=vT fp8, B=E fp8 -> O bf16 [(t,i)*512+c], rows scaled by linv.
  // BM=128 (256 thr, 2 blocks/CU), P2=1 (no setprio): 288 blocks MODE0.
  gemm256<128, 0, 0, 0, 1, 0, 1, 1><<<dim3(288), dim3(256), 0, stream>>>(
      vT, 18432, 2304, Sm, 2304, (long)2304 * 2304, (void*)Ob, 512, (long)2304 * 512,
      nullptr, nullptr, nullptr, linv, 1.0f, 2304, 4, 0);
  // final: A=O bf16, B=Wo bf16 -> out[co*18432+sp] = x + acc + bo[co]. MODE2: 144 blocks.
  gemm256<256, 2, 1, 0, 0, 2, 0, 0><<<dim3(144), dim3(512), 0, stream>>>(
      Ob, 512, 0, wob, 512, 0, (void*)out, 18432, 0, bo, x, nullptr, nullptr,
      1.0f, 512, 9, 2);
}

// Round 6
// 234.279 us; speedup vs baseline: 1.1388x; 1.0444x over previous
//
#include <hip/hip_runtime.h>
#include <hip/hip_bf16.h>
#include <cstdint>
#include <type_traits>

typedef __attribute__((ext_vector_type(8))) __bf16 bf16x8;
typedef __attribute__((ext_vector_type(4))) float f32x4;
typedef __attribute__((ext_vector_type(2))) long longx2;

struct bf2frag { bf16x8 k0, k1; };

__device__ __forceinline__ float bf2f(unsigned short u) {
  union { uint32_t i; float f; } v; v.i = (uint32_t)u << 16; return v.f;
}
__device__ __forceinline__ unsigned short f2bf(float f) {
  union { float f; uint32_t i; } v{f};
  uint32_t r = v.i + 0x7fffu + ((v.i >> 16) & 1u);
  return (unsigned short)(r >> 16);
}

__device__ __forceinline__ void gll(const void* g, void* l) {
  __builtin_amdgcn_global_load_lds(
      (const __attribute__((address_space(1))) uint32_t*)(uintptr_t)g,
      (__attribute__((address_space(3))) uint32_t*)(uint32_t)(uintptr_t)l,
      16, 0, 0);
}

__device__ __forceinline__ void bar() {
  asm volatile("" ::: "memory");
  __builtin_amdgcn_s_barrier();
  asm volatile("" ::: "memory");
}

#define VMCNT(n) asm volatile("s_waitcnt vmcnt(" #n ")" ::: "memory")

template <int N>
__device__ __forceinline__ void vmw() {
  if constexpr (N == 0) { VMCNT(0); }
  else if constexpr (N == 1) { VMCNT(1); }
  else if constexpr (N == 2) { VMCNT(2); }
  else if constexpr (N == 3) { VMCNT(3); }
  else if constexpr (N == 4) { VMCNT(4); }
  else if constexpr (N == 5) { VMCNT(5); }
  else if constexpr (N == 6) { VMCNT(6); }
  else if constexpr (N == 7) { VMCNT(7); }
  else if constexpr (N == 8) { VMCNT(8); }
  else if constexpr (N == 9) { VMCNT(9); }
  else if constexpr (N == 10) { VMCNT(10); }
  else { VMCNT(12); }
}

__device__ __forceinline__ f32x4 mma(bf16x8 a, bf16x8 b, f32x4 c) {
  return __builtin_amdgcn_mfma_f32_16x16x32_bf16(a, b, c, 0, 0, 0);
}
__device__ __forceinline__ f32x4 mma(long a, long b, f32x4 c) {
  return __builtin_amdgcn_mfma_f32_16x16x32_fp8_fp8(a, b, c, 0, 0, 0);
}
__device__ __forceinline__ f32x4 mmak(const bf2frag& a, const bf2frag& b, f32x4 c, int k2) {
  return k2 ? mma(a.k1, b.k1, c) : mma(a.k0, b.k0, c);
}
__device__ __forceinline__ f32x4 mmak(longx2 a, longx2 b, f32x4 c, int k2) {
  return mma(a[k2], b[k2], c);
}

// k-interleave store permutation for fp8 buffers (unit u=8B: slot p(u)=(u&3)*2+(u>>2))
__device__ __forceinline__ int perm64(int m) {
  return (m & ~63) | (((m >> 3) & 3) << 4) | (((m >> 5) & 1) << 3) | (m & 7);
}

// ---------------- GroupNorm stats ----------------
__global__ __launch_bounds__(256) void stats_partial_k(const float* __restrict__ x,
                                                       float* __restrict__ part) {
  const int g = blockIdx.x >> 3, p = blockIdx.x & 7;
  const float* base = x + (long)g * 16 * 18432 + (long)p * 2304;
  float s = 0.f, ss = 0.f;
  for (int idx = threadIdx.x; idx < 16 * 576; idx += 256) {
    const int c = idx / 576, i4 = idx % 576;
    const float4 v = *(const float4*)(base + (long)c * 18432 + i4 * 4);
    s += v.x + v.y + v.z + v.w;
    ss += v.x * v.x + v.y * v.y + v.z * v.z + v.w * v.w;
  }
  __shared__ float rs[256], rss[256];
  rs[threadIdx.x] = s; rss[threadIdx.x] = ss;
  __syncthreads();
  for (int o = 128; o > 0; o >>= 1) {
    if ((int)threadIdx.x < o) { rs[threadIdx.x] += rs[threadIdx.x + o]; rss[threadIdx.x] += rss[threadIdx.x + o]; }
    __syncthreads();
  }
  if (threadIdx.x == 0) { part[blockIdx.x * 2] = rs[0]; part[blockIdx.x * 2 + 1] = rss[0]; }
}

__global__ void stats_final_k(const float* __restrict__ part, float* __restrict__ stats) {
  const int g = threadIdx.x;
  if (g < 32) {
    float s = 0.f, ss = 0.f;
    for (int p = 0; p < 8; ++p) { s += part[(g * 8 + p) * 2]; ss += part[(g * 8 + p) * 2 + 1]; }
    const float mean = s / 294912.0f;
    const float var = ss / 294912.0f - mean * mean;
    stats[g * 2] = mean;
    stats[g * 2 + 1] = rsqrtf(var + 1e-6f);
  }
}

// ---------------- GN apply + transpose to (spatial, channel) bf16 ----------------
__global__ __launch_bounds__(256) void gn_transpose_k(const float* __restrict__ x,
                                                      const float* __restrict__ stats,
                                                      const float* __restrict__ gamma,
                                                      const float* __restrict__ beta,
                                                      unsigned short* __restrict__ hnT) {
  __shared__ float tile[64][65];
  const int c0 = blockIdx.x * 64, n0 = blockIdx.y * 64;
  const int tn = threadIdx.x & 63, tr = threadIdx.x >> 6;
  for (int cc = tr; cc < 64; cc += 4) {
    const int c = c0 + cc, g = c >> 4;
    const float mean = stats[g * 2], rstd = stats[g * 2 + 1];
    const float v = x[(long)c * 18432 + n0 + tn];
    tile[cc][tn] = (v - mean) * rstd * gamma[c] + beta[c];
  }
  __syncthreads();
  for (int nn = tr; nn < 64; nn += 4) {
    hnT[(long)(n0 + nn) * 512 + c0 + tn] = f2bf(tile[tn][nn]);
  }
}

// ---------------- fp32 -> bf16 weight pack ----------------
__global__ __launch_bounds__(256) void pack_bf16_k(const float* __restrict__ w,
                                                   unsigned short* __restrict__ o) {
  const int i = (blockIdx.x * 256 + threadIdx.x) * 4;
  const float4 v = *(const float4*)(w + i);
  ushort4 u; u.x = f2bf(v.x); u.y = f2bf(v.y); u.z = f2bf(v.z); u.w = f2bf(v.w);
  *(ushort4*)(o + i) = u;
}

__global__ void pack_bias_k(const float* __restrict__ bq, const float* __restrict__ bk,
                            float* __restrict__ bqk) {
  const int t = threadIdx.x;
  bqk[t] = (t < 512) ? bq[t] : bk[t - 512];
}

// ---------------- per-row 1/L combine from per-tile sums (NT tiles of rows) ----------------
__global__ __launch_bounds__(256) void combine_k(const float* __restrict__ rs,
                                                 float* __restrict__ linv, int ntile) {
  const int row = blockIdx.x * 256 + threadIdx.x;  // [0, 18432)
  const int t = row / 2304, r = row % 2304;
  float L = 0.f;
  for (int x = 0; x < ntile; ++x) L += rs[((long)(t * ntile + x)) * 2304 + r];
  linv[row] = 1.0f / L;
}

// ================= BMxBNx64 NT GEMM, XCD-swizzled, bf16/fp8 =================
// C[n*ldc+m] = alpha*sum_k A[m,k]*B[n,k] (+bias)(+resid)
// WL=0, BM=256: 512 thr, 8 waves (2m x 4n), 1 block/CU, P2=0, setprio ON.
// WL=0, BM=128: 256 thr, 4 waves (1m x 4n, BN=256), 2 blocks/CU, P2=1, no prio.
// WL=1: BM=128 x BN=128, 256 thr, 4 waves (2m x 2n, 64x64/wave).
//   fp8: 32KB LDS -> 3 blocks/CU (R13 S, R15 PV). bf16: 64KB LDS -> 2 blocks/CU
//   (R14 qk). Ladder: R13 S 66->58 (TLP), R14 qk 59->~45 (makespan), R15 PV
//   58->? (PV was 288 blocks / 512 slots = 0.56 rounds, Occupancy 9.5%,
//   VALUBusy 11.7 -- parallelism-starved; -> 576 blocks x 3/CU, 0.75 rounds).
//   A/B halves use 32-row stripe interleave: grow = (r>>5)*64 + h*32 + (r&31);
//   wave wm covers rows [wm*64, wm*64+64).
// P2=0 (8-phase snake): see prior rounds; vmcnt V0=GB+2GA, V3=2GB+GA, VP=GB+GA.
// P2=1 (2-phase): P0: read A0,B0,B1; stage [A0,B1,A1](W+1) -> s^1; mfma m0x{n0,n1}.
//   P1: read A1; stage B0(W+2) -> s; mfma m1x{n1,n0}.
//   Waits: @P0-end vmcnt(2GA+2GB); @P1-end vmcnt(GA+GB); tail GA then 0.
// STATS: exp+rowsums (tile index bx over gx m-tiles). SCALEN: *linv[n].
// OUT_MODE: 0 bf16, 1 f32+resid, 2 fp8 e4m3 k-interleaved.
// MODE0: bz=bid%8 per XCD; MODE1/2: XCD y/x-chunking.
template <int BM, int BIAS_MODE, int OUT_MODE, int STATS, int SCALEN, int MODE, int FP8, int P2,
          int WL = 0>
__global__ __launch_bounds__((BM == 256) ? 512 : 256, (WL && FP8) ? 3 : 2)
void gemm256(const void* __restrict__ A, long lda, long sAz,
             const void* __restrict__ B, long ldb, long sBz,
             void* __restrict__ Cp, long ldc, long sCz,
             const float* __restrict__ bias,
             const float* __restrict__ resid,
             float* __restrict__ rowsums,
             const float* __restrict__ linv,
             float alpha, int K, int gx, int gy) {
  constexpr int EB = FP8 ? 1 : 2;                    // element bytes
  constexpr int THREADS = (BM == 256) ? 512 : 256;
  constexpr int BN = WL ? 128 : 256;                 // n-tile
  constexpr int HBA = (BM / 2) * 64 * EB;            // bytes per A half
  constexpr int HBB = (BN / 2) * 64 * EB;            // bytes per B half
  constexpr int GA = HBA / (THREADS * 16);           // gll per A-half stage
  constexpr int GB = HBB / (THREADS * 16);           // gll per B-half stage
  constexpr int V0 = GB + 2 * GA, V3 = 2 * GB + GA, VP = GB + GA;
  constexpr int NSLOT = WL ? 8 : ((BM == 256) ? 8 : 4);
  constexpr int MR = WL ? 4 : 8;                     // acc M-frags per wave
  constexpr int FQ = WL ? 2 : 4;                     // A-frags per (mh) phase
  constexpr int PRIO = !P2;                          // setprio only on 1-block path
  __shared__ alignas(16) unsigned char As[2][2][HBA];
  __shared__ alignas(16) unsigned char Bs[2][2][HBB];
  using ABt2 = typename std::conditional<FP8, longx2, bf2frag>::type;

  const int tid = threadIdx.x;
  const int lane = tid & 63, wid = tid >> 6;
  const int wm = WL ? (wid >> 1) : ((BM == 256) ? (wid & 1) : 0);
  const int wn = WL ? (wid & 1) : ((BM == 256) ? (wid >> 1) : wid);
  int bx, by, bz;
  {
    const int g8 = blockIdx.x & 7, n = blockIdx.x >> 3;
    if (MODE == 0) { bz = g8; bx = n % gx; by = n / gx; }
    else if (MODE == 1) { bz = 0; bx = n % gx; by = g8 * gy + n / gx; }
    else { bz = 0; by = n % gy; bx = g8 * gx + n / gy; }
  }
  const unsigned char* Ab = (const unsigned char*)A + ((long)bz * sAz + (long)bx * BM * lda) * EB;
  const unsigned char* Bb = (const unsigned char*)B + ((long)bz * sBz + (long)by * BN * ldb) * EB;

  // ---- staging (global -> LDS, pre-swizzled source; fp8 global is k-interleaved) ----
  auto stageA = [&](int slot, int h, int k0) {
    if constexpr (!FP8) {
      const int ksw = ((tid & 7) << 3) ^ (((tid >> 3) & 7) << 3);
#pragma unroll
      for (int call = 0; call < GA; ++call) {
        const int r = call * (THREADS / 8) + (tid >> 3);
        const int grow = WL ? (((r >> 5) << 6) + h * 32 + (r & 31))
                            : (((r >> 6) << 7) + h * 64 + (r & 63));
        gll(Ab + ((long)grow * lda + k0) * 2 + ksw * 2, &As[slot][h][call * THREADS * 16 + tid * 16]);
      }
    } else {
#pragma unroll
      for (int call = 0; call < GA; ++call) {
        const int l = call * (THREADS / 4) + (tid >> 2);
        const int grow = WL ? (((l >> 5) << 6) + h * 32 + (l & 31))
                            : (((l >> 6) << 7) + h * 64 + (l & 63));
        const int x = (((l & 3) ^ ((l >> 2) & 3)) << 4);
        gll(Ab + (long)grow * lda + k0 + (((tid & 3) << 4) ^ x),
            &As[slot][h][call * THREADS * 16 + tid * 16]);
      }
    }
  };
  auto stageB = [&](int slot, int h, int k0) {
    if constexpr (!FP8) {
      const int ksw = ((tid & 7) << 3) ^ (((tid >> 3) & 7) << 3);
#pragma unroll
      for (int call = 0; call < GB; ++call) {
        const int r = call * (THREADS / 8) + (tid >> 3);
        const int grow = ((r >> 5) << 6) + h * 32 + (r & 31);
        gll(Bb + ((long)grow * ldb + k0) * 2 + ksw * 2, &Bs[slot][h][call * THREADS * 16 + tid * 16]);
      }
    } else {
#pragma unroll
      for (int call = 0; call < GB; ++call) {
        const int l = call * (THREADS / 4) + (tid >> 2);
        const int grow = ((l >> 5) << 6) + h * 32 + (l & 31);
        const int x = (((l & 3) ^ ((l >> 2) & 3)) << 4);
        gll(Bb + (long)grow * ldb + k0 + (((tid & 3) << 4) ^ x),
            &Bs[slot][h][call * THREADS * 16 + tid * 16]);
      }
    }
  };
  // ---- LDS -> fragment reads (same swizzle; fp8 = ONE b128 for both k2 slices) ----
  auto ldA = [&](int slot, int mh, int fq) -> ABt2 {
    const int r = (WL ? wm * 32 : wm * 64) + fq * 16 + (lane & 15);
    if constexpr (!FP8) {
      bf2frag f;
      const int kk0 = (((lane >> 4) << 3)) ^ ((r & 7) << 3);
      const int kk1 = (32 + ((lane >> 4) << 3)) ^ ((r & 7) << 3);
      f.k0 = *reinterpret_cast<const bf16x8*>(&As[slot][mh][r * 128 + kk0 * 2]);
      f.k1 = *reinterpret_cast<const bf16x8*>(&As[slot][mh][r * 128 + kk1 * 2]);
      return f;
    } else {
      const int x = (((r & 3) ^ ((r >> 2) & 3)) << 4);
      const int kk = ((lane >> 4) << 4) ^ x;
      return *reinterpret_cast<const longx2*>(&As[slot][mh][r * 64 + kk]);
    }
  };
  auto ldB = [&](int slot, int nh, int g) -> ABt2 {
    const int r = wn * 32 + g * 16 + (lane & 15);
    if constexpr (!FP8) {
      bf2frag f;
      const int kk0 = (((lane >> 4) << 3)) ^ ((r & 7) << 3);
      const int kk1 = (32 + ((lane >> 4) << 3)) ^ ((r & 7) << 3);
      f.k0 = *reinterpret_cast<const bf16x8*>(&Bs[slot][nh][r * 128 + kk0 * 2]);
      f.k1 = *reinterpret_cast<const bf16x8*>(&Bs[slot][nh][r * 128 + kk1 * 2]);
      return f;
    } else {
      const int x = (((r & 3) ^ ((r >> 2) & 3)) << 4);
      const int kk = ((lane >> 4) << 4) ^ x;
      return *reinterpret_cast<const longx2*>(&Bs[slot][nh][r * 64 + kk]);
    }
  };

  f32x4 acc[MR][4] = {};
  ABt2 a[4], b0[2], b1[2];

#define READ_A(SLOT, MH)                                                     \
  _Pragma("unroll") for (int fq = 0; fq < FQ; ++fq) a[fq] = ldA(SLOT, MH, fq);
#define READ_B(SLOT, NH, DST)                                                \
  _Pragma("unroll") for (int g = 0; g < 2; ++g) DST[g] = ldB(SLOT, NH, g);
#define MFMA_QUAD(MH, NH, BARR)                                              \
  if constexpr (PRIO) __builtin_amdgcn_s_setprio(1);                         \
  _Pragma("unroll") for (int fq = 0; fq < FQ; ++fq)                          \
    _Pragma("unroll") for (int g = 0; g < 2; ++g)                            \
      _Pragma("unroll") for (int k2 = 0; k2 < 2; ++k2)                       \
        acc[(MH) * FQ + fq][(NH) * 2 + g] =                                  \
            mmak(a[fq], BARR[g], acc[(MH) * FQ + fq][(NH) * 2 + g], k2);     \
  if constexpr (PRIO) __builtin_amdgcn_s_setprio(0);

  const int KT = K >> 6;
  // Prologue queue: [B0(0), A0(0), B1(0), A1(0), B0(1)] (+A1(1) for P2=0)
  stageB(0, 0, 0);
  stageA(0, 0, 0);
  stageB(0, 1, 0);
  stageA(0, 1, 0);
  stageB(1, 0, 64);
  if constexpr (!P2) stageA(1, 1, 64);
  vmw<VP>();
  bar();

  if constexpr (!P2) {
    for (int W = 0; W < KT; ++W) {
      const int s = W & 1;
      const int kn1 = (W + 1) << 6, kn2 = (W + 2) << 6;
      const bool st1 = (W + 1 < KT), st2 = (W + 2 < KT);
      // p0: (m0,n0)
      READ_A(s, 0)
      READ_B(s, 0, b0)
      if (st1) stageA(s ^ 1, 0, kn1);
      bar();
      MFMA_QUAD(0, 0, b0)
      if (st1) { vmw<V0>(); }
      bar();
      // p1: (m0,n1)
      READ_B(s, 1, b1)
      if (st1) stageB(s ^ 1, 1, kn1);
      bar();
      MFMA_QUAD(0, 1, b1)
      bar();
      // p2: (m1,n1)
      READ_A(s, 1)
      if (st2) stageB(s, 0, kn2);
      bar();
      MFMA_QUAD(1, 1, b1)
      bar();
      // p3: (m1,n0)
      if (st2) stageA(s, 1, kn2);
      bar();
      MFMA_QUAD(1, 0, b0)
      if (st2) { vmw<V3>(); } else { vmw<0>(); }
      bar();
    }
  } else {
    for (int W = 0; W < KT; ++W) {
      const int s = W & 1;
      const int kn1 = (W + 1) << 6, kn2 = (W + 2) << 6;
      const bool st1 = (W + 1 < KT), st2 = (W + 2 < KT);
      // P0: (m0 x n0,n1); stage next A-slot fully + B1(W+1). A1 issued LAST.
      READ_A(s, 0)
      READ_B(s, 0, b0)
      READ_B(s, 1, b1)
      if (st1) { stageA(s ^ 1, 0, kn1); stageB(s ^ 1, 1, kn1); stageA(s ^ 1, 1, kn1); }
      bar();
      MFMA_QUAD(0, 0, b0)
      MFMA_QUAD(0, 1, b1)
      if (st1) { vmw<2 * (GA + GB)>(); } else { vmw<0>(); }
      bar();
      // P1: (m1 x n1,n0); stage B0(W+2) into current slot (B0(W) consumed in P0).
      READ_A(s, 1)
      if (st2) stageB(s, 0, kn2);
      bar();
      MFMA_QUAD(1, 1, b1)
      MFMA_QUAD(1, 0, b0)
      if (st2) { vmw<GA + GB>(); } else if (st1) { vmw<GA>(); } else { vmw<0>(); }
      bar();
    }
  }

  // epilogue: acc[M][N].
  // WL=0: M = mh*4+fq, m-off = (M>>2)*64 + (M&3)*16, wave m-base wm*128.
  // WL=1: M = mh*2+fq, m-off = (M>>1)*32 + (M&1)*16, wave m-base wm*64.
  const int mg0 = bx * BM + (WL ? wm * 64 : wm * 128) + ((lane >> 4) << 2);
  const int ng0 = by * BN + wn * 64 + (lane & 15);
  float* red = (float*)&As[0][0][0];  // STATS scratch: BN rows x NSLOT f32
#pragma unroll
  for (int N = 0; N < 4; ++N) {
    const int n = ng0 + (N >> 1) * 32 + (N & 1) * 16;
    const float bn = (BIAS_MODE == 2) ? bias[n] : 0.f;
    const float sc = SCALEN ? linv[(long)bz * 2304 + n] : 1.0f;
    float eN = 0.f;
#pragma unroll
    for (int M = 0; M < MR; ++M) {
      const int m = mg0 + (WL ? ((M >> 1) * 32 + (M & 1) * 16) : ((M >> 2) * 64 + (M & 3) * 16));
      const f32x4 av = acc[M][N];
      float vals[4];
#pragma unroll
      for (int j = 0; j < 4; ++j) {
        vals[j] = av[j] * alpha + ((BIAS_MODE == 1) ? bias[m + j] : bn);
        if (SCALEN) vals[j] *= sc;
        if (STATS) { vals[j] = __expf(vals[j]); eN += vals[j]; }
      }
      if (OUT_MODE == 0) {
        ushort4 o; o.x = f2bf(vals[0]); o.y = f2bf(vals[1]); o.z = f2bf(vals[2]); o.w = f2bf(vals[3]);
        *(ushort4*)((unsigned short*)Cp + (long)bz * sCz + (long)n * ldc + m) = o;
      } else if (OUT_MODE == 2) {
        int pk = __builtin_amdgcn_cvt_pk_fp8_f32(vals[0], vals[1], 0, false);
        pk = __builtin_amdgcn_cvt_pk_fp8_f32(vals[2], vals[3], pk, true);
        *(int*)((unsigned char*)Cp + (long)bz * sCz + (long)n * ldc + perm64(m)) = pk;
      } else {
        const float* rp = resid + (long)n * ldc + m;
        float4 o; o.x = vals[0] + rp[0]; o.y = vals[1] + rp[1]; o.z = vals[2] + rp[2]; o.w = vals[3] + rp[3];
        *(float4*)((float*)Cp + (long)bz * sCz + (long)n * ldc + m) = o;
      }
    }
    if (STATS) {
      const int nloc = wn * 64 + (N >> 1) * 32 + (N & 1) * 16 + (lane & 15);
      const int slot = wm * 4 + (lane >> 4);
      red[nloc * NSLOT + slot] = eN;
    }
  }
  if (STATS) {
    bar();
    if (tid < BN) {
      float L = 0.f;
#pragma unroll
      for (int s2 = 0; s2 < NSLOT; ++s2) L += red[tid * NSLOT + s2];
      rowsums[((long)(bz * gx + bx)) * 2304 + by * BN + tid] = L;
    }
  }
#undef READ_A
#undef READ_B
#undef MFMA_QUAD
}

extern "C" void kernel_launch(void* const* d_in, const int* in_sizes, int n_in,
                              void* d_out, int out_size, void* d_ws, size_t ws_size,
                              hipStream_t stream) {
  const float* x = (const float*)d_in[0];
  const float* gamma = (const float*)d_in[1];
  const float* beta = (const float*)d_in[2];
  const float* wq = (const float*)d_in[3];
  const float* bq = (const float*)d_in[4];
  const float* wk = (const float*)d_in[5];
  const float* bk = (const float*)d_in[6];
  const float* wv = (const float*)d_in[7];
  const float* bv = (const float*)d_in[8];
  const float* wo = (const float*)d_in[9];
  const float* bo = (const float*)d_in[10];
  float* out = (float*)d_out;

  char* ws = (char*)d_ws;
  size_t off = 0;
  auto alloc = [&](size_t bytes) {
    char* p = ws + off;
    off = (off + bytes + 255) & ~(size_t)255;
    return p;
  };
  float* part = (float*)alloc(256 * 2 * sizeof(float));
  float* stats = (float*)alloc(32 * 2 * sizeof(float));
  unsigned short* wqkb = (unsigned short*)alloc((size_t)2 * 262144 * 2);
  unsigned short* wvb = (unsigned short*)alloc((size_t)262144 * 2);
  unsigned short* wob = (unsigned short*)alloc((size_t)262144 * 2);
  float* bqk = (float*)alloc(1024 * sizeof(float));
  float* rowsums = (float*)alloc((size_t)8 * 18 * 2304 * sizeof(float));
  float* linv = (float*)alloc((size_t)18432 * sizeof(float));
  unsigned short* hnT = (unsigned short*)alloc((size_t)18432 * 512 * 2);
  unsigned char* qkA = (unsigned char*)alloc((size_t)18432 * 1024);      // fp8 k-interleaved
  unsigned char* vT = (unsigned char*)alloc((size_t)512 * 18432);        // fp8 k-interleaved
  unsigned char* Sm = (unsigned char*)alloc((size_t)8 * 2304 * 2304);    // fp8 E k-interleaved
  unsigned short* Ob = hnT;  // alias: hnT fully consumed after qk/v GEMMs
  (void)ws_size; (void)in_sizes; (void)n_in; (void)out_size;

  stats_partial_k<<<dim3(256), dim3(256), 0, stream>>>(x, part);
  stats_final_k<<<dim3(1), dim3(64), 0, stream>>>(part, stats);
  gn_transpose_k<<<dim3(8, 288), dim3(256), 0, stream>>>(x, stats, gamma, beta, hnT);
  pack_bf16_k<<<dim3(256), dim3(256), 0, stream>>>(wq, wqkb);
  pack_bf16_k<<<dim3(256), dim3(256), 0, stream>>>(wk, wqkb + 262144);
  pack_bf16_k<<<dim3(256), dim3(256), 0, stream>>>(wv, wvb);
  pack_bf16_k<<<dim3(256), dim3(256), 0, stream>>>(wo, wob);
  pack_bias_k<<<dim3(1), dim3(1024), 0, stream>>>(bq, bk, bqk);

  // qk fused: A=[Wq;Wk] bf16, B=hnT bf16 -> q,k fp8 interleaved [sp][1024].
  // WL=1 bf16 (128x128, 2 blocks/CU): 8x144x(8 XCD) = 1152 blocks MODE1.
  gemm256<128, 1, 2, 0, 0, 1, 0, 1, 1><<<dim3(1152), dim3(256), 0, stream>>>(
      wqkb, 512, 0, hnT, 512, 0, (void*)qkA, 1024, 0, bqk, nullptr, nullptr, nullptr,
      1.0f, 512, 8, 18);
  // v: A=hnT bf16, B=Wv bf16 -> vT fp8 interleaved [co][18432]. MODE2: 144 blocks.
  gemm256<256, 2, 2, 0, 0, 2, 0, 0><<<dim3(144), dim3(512), 0, stream>>>(
      hnT, 512, 0, wvb, 512, 0, (void*)vT, 18432, 0, bv, nullptr, nullptr, nullptr,
      1.0f, 512, 9, 2);
  // S: per t: A=k fp8, B=q fp8 -> E=exp(alpha*S) fp8 interleaved + rowsums.
  // WL=1 128x128 tiles, 3 blocks/CU: 18x18x8 = 2592 blocks MODE0.
  gemm256<128, 0, 2, 1, 0, 0, 1, 1, 1><<<dim3(2592), dim3(256), 0, stream>>>(
      qkA + 512, 1024, (long)2304 * 1024, qkA, 1024, (long)2304 * 1024, (void*)Sm, 2304,
      (long)2304 * 2304, nullptr, nullptr, rowsums, nullptr,
      0.044194173824159216f, 512, 18, 18);
  combine_k<<<dim3(72), dim3(256), 0, stream>>>(rowsums, linv, 18);
  // PV: per t: A=vT fp8, B=E fp8 -> O bf16 [(t,i)*512+c], rows scaled by linv.
  // R15: WL=1 128x128 tiles, 3 blocks/CU: 4x18x8 = 576 blocks MODE0.
  gemm256<128, 0, 0, 0, 1, 0, 1, 1, 1><<<dim3(576), dim3(256), 0, stream>>>(
      vT, 18432, 2304, Sm, 2304, (long)2304 * 2304, (void*)Ob, 512, (long)2304 * 512,
      nullptr, nullptr, nullptr, linv, 1.0f, 2304, 4, 18);
  // final: A=O bf16, B=Wo bf16 -> out[co*18432+sp] = x + acc + bo[co]. MODE2: 144 blocks.
  gemm256<256, 2, 1, 0, 0, 2, 0, 0><<<dim3(144), dim3(512), 0, stream>>>(
      Ob, 512, 0, wob, 512, 0, (void*)out, 18432, 0, bo, x, nullptr, nullptr,
      1.0f, 512, 9, 2);
}

// Round 7
// 232.921 us; speedup vs baseline: 1.1454x; 1.0058x over previous
//
#include <hip/hip_runtime.h>
#include <hip/hip_bf16.h>
#include <cstdint>
#include <type_traits>

typedef __attribute__((ext_vector_type(8))) __bf16 bf16x8;
typedef __attribute__((ext_vector_type(4))) float f32x4;
typedef __attribute__((ext_vector_type(2))) long longx2;

struct bf2frag { bf16x8 k0, k1; };

__device__ __forceinline__ float bf2f(unsigned short u) {
  union { uint32_t i; float f; } v; v.i = (uint32_t)u << 16; return v.f;
}
__device__ __forceinline__ unsigned short f2bf(float f) {
  union { float f; uint32_t i; } v{f};
  uint32_t r = v.i + 0x7fffu + ((v.i >> 16) & 1u);
  return (unsigned short)(r >> 16);
}

__device__ __forceinline__ void gll(const void* g, void* l) {
  __builtin_amdgcn_global_load_lds(
      (const __attribute__((address_space(1))) uint32_t*)(uintptr_t)g,
      (__attribute__((address_space(3))) uint32_t*)(uint32_t)(uintptr_t)l,
      16, 0, 0);
}

__device__ __forceinline__ void bar() {
  asm volatile("" ::: "memory");
  __builtin_amdgcn_s_barrier();
  asm volatile("" ::: "memory");
}

#define VMCNT(n) asm volatile("s_waitcnt vmcnt(" #n ")" ::: "memory")

template <int N>
__device__ __forceinline__ void vmw() {
  if constexpr (N == 0) { VMCNT(0); }
  else if constexpr (N == 1) { VMCNT(1); }
  else if constexpr (N == 2) { VMCNT(2); }
  else if constexpr (N == 3) { VMCNT(3); }
  else if constexpr (N == 4) { VMCNT(4); }
  else if constexpr (N == 5) { VMCNT(5); }
  else if constexpr (N == 6) { VMCNT(6); }
  else if constexpr (N == 7) { VMCNT(7); }
  else if constexpr (N == 8) { VMCNT(8); }
  else if constexpr (N == 9) { VMCNT(9); }
  else if constexpr (N == 10) { VMCNT(10); }
  else { VMCNT(12); }
}

__device__ __forceinline__ f32x4 mma(bf16x8 a, bf16x8 b, f32x4 c) {
  return __builtin_amdgcn_mfma_f32_16x16x32_bf16(a, b, c, 0, 0, 0);
}
__device__ __forceinline__ f32x4 mma(long a, long b, f32x4 c) {
  return __builtin_amdgcn_mfma_f32_16x16x32_fp8_fp8(a, b, c, 0, 0, 0);
}
__device__ __forceinline__ f32x4 mmak(const bf2frag& a, const bf2frag& b, f32x4 c, int k2) {
  return k2 ? mma(a.k1, b.k1, c) : mma(a.k0, b.k0, c);
}
__device__ __forceinline__ f32x4 mmak(longx2 a, longx2 b, f32x4 c, int k2) {
  return mma(a[k2], b[k2], c);
}

// k-interleave store permutation for fp8 buffers (unit u=8B: slot p(u)=(u&3)*2+(u>>2))
__device__ __forceinline__ int perm64(int m) {
  return (m & ~63) | (((m >> 3) & 3) << 4) | (((m >> 5) & 1) << 3) | (m & 7);
}

// ---------------- GroupNorm stats ----------------
__global__ __launch_bounds__(256) void stats_partial_k(const float* __restrict__ x,
                                                       float* __restrict__ part) {
  const int g = blockIdx.x >> 3, p = blockIdx.x & 7;
  const float* base = x + (long)g * 16 * 18432 + (long)p * 2304;
  float s = 0.f, ss = 0.f;
  for (int idx = threadIdx.x; idx < 16 * 576; idx += 256) {
    const int c = idx / 576, i4 = idx % 576;
    const float4 v = *(const float4*)(base + (long)c * 18432 + i4 * 4);
    s += v.x + v.y + v.z + v.w;
    ss += v.x * v.x + v.y * v.y + v.z * v.z + v.w * v.w;
  }
  __shared__ float rs[256], rss[256];
  rs[threadIdx.x] = s; rss[threadIdx.x] = ss;
  __syncthreads();
  for (int o = 128; o > 0; o >>= 1) {
    if ((int)threadIdx.x < o) { rs[threadIdx.x] += rs[threadIdx.x + o]; rss[threadIdx.x] += rss[threadIdx.x + o]; }
    __syncthreads();
  }
  if (threadIdx.x == 0) { part[blockIdx.x * 2] = rs[0]; part[blockIdx.x * 2 + 1] = rss[0]; }
}

__global__ void stats_final_k(const float* __restrict__ part, float* __restrict__ stats) {
  const int g = threadIdx.x;
  if (g < 32) {
    float s = 0.f, ss = 0.f;
    for (int p = 0; p < 8; ++p) { s += part[(g * 8 + p) * 2]; ss += part[(g * 8 + p) * 2 + 1]; }
    const float mean = s / 294912.0f;
    const float var = ss / 294912.0f - mean * mean;
    stats[g * 2] = mean;
    stats[g * 2 + 1] = rsqrtf(var + 1e-6f);
  }
}

// ---------------- GN apply + transpose to (spatial, channel) bf16 ----------------
__global__ __launch_bounds__(256) void gn_transpose_k(const float* __restrict__ x,
                                                      const float* __restrict__ stats,
                                                      const float* __restrict__ gamma,
                                                      const float* __restrict__ beta,
                                                      unsigned short* __restrict__ hnT) {
  __shared__ float tile[64][65];
  const int c0 = blockIdx.x * 64, n0 = blockIdx.y * 64;
  const int tn = threadIdx.x & 63, tr = threadIdx.x >> 6;
  for (int cc = tr; cc < 64; cc += 4) {
    const int c = c0 + cc, g = c >> 4;
    const float mean = stats[g * 2], rstd = stats[g * 2 + 1];
    const float v = x[(long)c * 18432 + n0 + tn];
    tile[cc][tn] = (v - mean) * rstd * gamma[c] + beta[c];
  }
  __syncthreads();
  for (int nn = tr; nn < 64; nn += 4) {
    hnT[(long)(n0 + nn) * 512 + c0 + tn] = f2bf(tile[tn][nn]);
  }
}

// ---------------- fp32 -> bf16 weight pack ----------------
__global__ __launch_bounds__(256) void pack_bf16_k(const float* __restrict__ w,
                                                   unsigned short* __restrict__ o) {
  const int i = (blockIdx.x * 256 + threadIdx.x) * 4;
  const float4 v = *(const float4*)(w + i);
  ushort4 u; u.x = f2bf(v.x); u.y = f2bf(v.y); u.z = f2bf(v.z); u.w = f2bf(v.w);
  *(ushort4*)(o + i) = u;
}

__global__ void pack_bias_k(const float* __restrict__ bq, const float* __restrict__ bk,
                            float* __restrict__ bqk) {
  const int t = threadIdx.x;
  bqk[t] = (t < 512) ? bq[t] : bk[t - 512];
}

// ---------------- per-row 1/L combine from per-tile sums (NT tiles of rows) ----------------
__global__ __launch_bounds__(256) void combine_k(const float* __restrict__ rs,
                                                 float* __restrict__ linv, int ntile) {
  const int row = blockIdx.x * 256 + threadIdx.x;  // [0, 18432)
  const int t = row / 2304, r = row % 2304;
  float L = 0.f;
  for (int x = 0; x < ntile; ++x) L += rs[((long)(t * ntile + x)) * 2304 + r];
  linv[row] = 1.0f / L;
}

// ================= BMxBNx64 NT GEMM, XCD-swizzled, bf16/fp8 =================
// C[n*ldc+m] = alpha*sum_k A[m,k]*B[n,k] (+bias)(+resid)
// WL=0, BM=256: 512 thr, 8 waves (2m x 4n), 1 block/CU, P2=0, setprio ON.
// WL=0, BM=128: 256 thr, 4 waves (1m x 4n, BN=256), 2 blocks/CU, P2=1, no prio.
// WL=1: BM=128 x BN=128, 256 thr, 4 waves (2m x 2n, 64x64/wave).
//   fp8: 32KB LDS -> R16: 4 blocks/CU (launch_bounds(256,4), VGPR cap 128;
//   acc 64 + frags ~24 fits). R13 proved 2->3 blocks was +8us on S; S remains
//   overlap-limited (MfmaUtil 28.5, VALU 28.6, LDS ~34%, no pipe >40%,
//   generation wall 41k cy vs 17k cy perfect-overlap) -> 4th independent
//   block/SIMD continues the TLP ladder. bf16: 64KB LDS -> 2 blocks/CU (R14 qk).
//   A/B halves use 32-row stripe interleave: grow = (r>>5)*64 + h*32 + (r&31);
//   wave wm covers rows [wm*64, wm*64+64).
// P2=0 (8-phase snake): see prior rounds; vmcnt V0=GB+2GA, V3=2GB+GA, VP=GB+GA.
// P2=1 (2-phase): P0: read A0,B0,B1; stage [A0,B1,A1](W+1) -> s^1; mfma m0x{n0,n1}.
//   P1: read A1; stage B0(W+2) -> s; mfma m1x{n1,n0}.
//   Waits: @P0-end vmcnt(2GA+2GB); @P1-end vmcnt(GA+GB); tail GA then 0.
// STATS: exp+rowsums (tile index bx over gx m-tiles). SCALEN: *linv[n].
// OUT_MODE: 0 bf16, 1 f32+resid, 2 fp8 e4m3 k-interleaved.
// MODE0: bz=bid%8 per XCD; MODE1/2: XCD y/x-chunking.
template <int BM, int BIAS_MODE, int OUT_MODE, int STATS, int SCALEN, int MODE, int FP8, int P2,
          int WL = 0>
__global__ __launch_bounds__((BM == 256) ? 512 : 256, (WL && FP8) ? 4 : 2)
void gemm256(const void* __restrict__ A, long lda, long sAz,
             const void* __restrict__ B, long ldb, long sBz,
             void* __restrict__ Cp, long ldc, long sCz,
             const float* __restrict__ bias,
             const float* __restrict__ resid,
             float* __restrict__ rowsums,
             const float* __restrict__ linv,
             float alpha, int K, int gx, int gy) {
  constexpr int EB = FP8 ? 1 : 2;                    // element bytes
  constexpr int THREADS = (BM == 256) ? 512 : 256;
  constexpr int BN = WL ? 128 : 256;                 // n-tile
  constexpr int HBA = (BM / 2) * 64 * EB;            // bytes per A half
  constexpr int HBB = (BN / 2) * 64 * EB;            // bytes per B half
  constexpr int GA = HBA / (THREADS * 16);           // gll per A-half stage
  constexpr int GB = HBB / (THREADS * 16);           // gll per B-half stage
  constexpr int V0 = GB + 2 * GA, V3 = 2 * GB + GA, VP = GB + GA;
  constexpr int NSLOT = WL ? 8 : ((BM == 256) ? 8 : 4);
  constexpr int MR = WL ? 4 : 8;                     // acc M-frags per wave
  constexpr int FQ = WL ? 2 : 4;                     // A-frags per (mh) phase
  constexpr int PRIO = !P2;                          // setprio only on 1-block path
  __shared__ alignas(16) unsigned char As[2][2][HBA];
  __shared__ alignas(16) unsigned char Bs[2][2][HBB];
  using ABt2 = typename std::conditional<FP8, longx2, bf2frag>::type;

  const int tid = threadIdx.x;
  const int lane = tid & 63, wid = tid >> 6;
  const int wm = WL ? (wid >> 1) : ((BM == 256) ? (wid & 1) : 0);
  const int wn = WL ? (wid & 1) : ((BM == 256) ? (wid >> 1) : wid);
  int bx, by, bz;
  {
    const int g8 = blockIdx.x & 7, n = blockIdx.x >> 3;
    if (MODE == 0) { bz = g8; bx = n % gx; by = n / gx; }
    else if (MODE == 1) { bz = 0; bx = n % gx; by = g8 * gy + n / gx; }
    else { bz = 0; by = n % gy; bx = g8 * gx + n / gy; }
  }
  const unsigned char* Ab = (const unsigned char*)A + ((long)bz * sAz + (long)bx * BM * lda) * EB;
  const unsigned char* Bb = (const unsigned char*)B + ((long)bz * sBz + (long)by * BN * ldb) * EB;

  // ---- staging (global -> LDS, pre-swizzled source; fp8 global is k-interleaved) ----
  auto stageA = [&](int slot, int h, int k0) {
    if constexpr (!FP8) {
      const int ksw = ((tid & 7) << 3) ^ (((tid >> 3) & 7) << 3);
#pragma unroll
      for (int call = 0; call < GA; ++call) {
        const int r = call * (THREADS / 8) + (tid >> 3);
        const int grow = WL ? (((r >> 5) << 6) + h * 32 + (r & 31))
                            : (((r >> 6) << 7) + h * 64 + (r & 63));
        gll(Ab + ((long)grow * lda + k0) * 2 + ksw * 2, &As[slot][h][call * THREADS * 16 + tid * 16]);
      }
    } else {
#pragma unroll
      for (int call = 0; call < GA; ++call) {
        const int l = call * (THREADS / 4) + (tid >> 2);
        const int grow = WL ? (((l >> 5) << 6) + h * 32 + (l & 31))
                            : (((l >> 6) << 7) + h * 64 + (l & 63));
        const int x = (((l & 3) ^ ((l >> 2) & 3)) << 4);
        gll(Ab + (long)grow * lda + k0 + (((tid & 3) << 4) ^ x),
            &As[slot][h][call * THREADS * 16 + tid * 16]);
      }
    }
  };
  auto stageB = [&](int slot, int h, int k0) {
    if constexpr (!FP8) {
      const int ksw = ((tid & 7) << 3) ^ (((tid >> 3) & 7) << 3);
#pragma unroll
      for (int call = 0; call < GB; ++call) {
        const int r = call * (THREADS / 8) + (tid >> 3);
        const int grow = ((r >> 5) << 6) + h * 32 + (r & 31);
        gll(Bb + ((long)grow * ldb + k0) * 2 + ksw * 2, &Bs[slot][h][call * THREADS * 16 + tid * 16]);
      }
    } else {
#pragma unroll
      for (int call = 0; call < GB; ++call) {
        const int l = call * (THREADS / 4) + (tid >> 2);
        const int grow = ((l >> 5) << 6) + h * 32 + (l & 31);
        const int x = (((l & 3) ^ ((l >> 2) & 3)) << 4);
        gll(Bb + (long)grow * ldb + k0 + (((tid & 3) << 4) ^ x),
            &Bs[slot][h][call * THREADS * 16 + tid * 16]);
      }
    }
  };
  // ---- LDS -> fragment reads (same swizzle; fp8 = ONE b128 for both k2 slices) ----
  auto ldA = [&](int slot, int mh, int fq) -> ABt2 {
    const int r = (WL ? wm * 32 : wm * 64) + fq * 16 + (lane & 15);
    if constexpr (!FP8) {
      bf2frag f;
      const int kk0 = (((lane >> 4) << 3)) ^ ((r & 7) << 3);
      const int kk1 = (32 + ((lane >> 4) << 3)) ^ ((r & 7) << 3);
      f.k0 = *reinterpret_cast<const bf16x8*>(&As[slot][mh][r * 128 + kk0 * 2]);
      f.k1 = *reinterpret_cast<const bf16x8*>(&As[slot][mh][r * 128 + kk1 * 2]);
      return f;
    } else {
      const int x = (((r & 3) ^ ((r >> 2) & 3)) << 4);
      const int kk = ((lane >> 4) << 4) ^ x;
      return *reinterpret_cast<const longx2*>(&As[slot][mh][r * 64 + kk]);
    }
  };
  auto ldB = [&](int slot, int nh, int g) -> ABt2 {
    const int r = wn * 32 + g * 16 + (lane & 15);
    if constexpr (!FP8) {
      bf2frag f;
      const int kk0 = (((lane >> 4) << 3)) ^ ((r & 7) << 3);
      const int kk1 = (32 + ((lane >> 4) << 3)) ^ ((r & 7) << 3);
      f.k0 = *reinterpret_cast<const bf16x8*>(&Bs[slot][nh][r * 128 + kk0 * 2]);
      f.k1 = *reinterpret_cast<const bf16x8*>(&Bs[slot][nh][r * 128 + kk1 * 2]);
      return f;
    } else {
      const int x = (((r & 3) ^ ((r >> 2) & 3)) << 4);
      const int kk = ((lane >> 4) << 4) ^ x;
      return *reinterpret_cast<const longx2*>(&Bs[slot][nh][r * 64 + kk]);
    }
  };

  f32x4 acc[MR][4] = {};
  ABt2 a[4], b0[2], b1[2];

#define READ_A(SLOT, MH)                                                     \
  _Pragma("unroll") for (int fq = 0; fq < FQ; ++fq) a[fq] = ldA(SLOT, MH, fq);
#define READ_B(SLOT, NH, DST)                                                \
  _Pragma("unroll") for (int g = 0; g < 2; ++g) DST[g] = ldB(SLOT, NH, g);
#define MFMA_QUAD(MH, NH, BARR)                                              \
  if constexpr (PRIO) __builtin_amdgcn_s_setprio(1);                         \
  _Pragma("unroll") for (int fq = 0; fq < FQ; ++fq)                          \
    _Pragma("unroll") for (int g = 0; g < 2; ++g)                            \
      _Pragma("unroll") for (int k2 = 0; k2 < 2; ++k2)                       \
        acc[(MH) * FQ + fq][(NH) * 2 + g] =                                  \
            mmak(a[fq], BARR[g], acc[(MH) * FQ + fq][(NH) * 2 + g], k2);     \
  if constexpr (PRIO) __builtin_amdgcn_s_setprio(0);

  const int KT = K >> 6;
  // Prologue queue: [B0(0), A0(0), B1(0), A1(0), B0(1)] (+A1(1) for P2=0)
  stageB(0, 0, 0);
  stageA(0, 0, 0);
  stageB(0, 1, 0);
  stageA(0, 1, 0);
  stageB(1, 0, 64);
  if constexpr (!P2) stageA(1, 1, 64);
  vmw<VP>();
  bar();

  if constexpr (!P2) {
    for (int W = 0; W < KT; ++W) {
      const int s = W & 1;
      const int kn1 = (W + 1) << 6, kn2 = (W + 2) << 6;
      const bool st1 = (W + 1 < KT), st2 = (W + 2 < KT);
      // p0: (m0,n0)
      READ_A(s, 0)
      READ_B(s, 0, b0)
      if (st1) stageA(s ^ 1, 0, kn1);
      bar();
      MFMA_QUAD(0, 0, b0)
      if (st1) { vmw<V0>(); }
      bar();
      // p1: (m0,n1)
      READ_B(s, 1, b1)
      if (st1) stageB(s ^ 1, 1, kn1);
      bar();
      MFMA_QUAD(0, 1, b1)
      bar();
      // p2: (m1,n1)
      READ_A(s, 1)
      if (st2) stageB(s, 0, kn2);
      bar();
      MFMA_QUAD(1, 1, b1)
      bar();
      // p3: (m1,n0)
      if (st2) stageA(s, 1, kn2);
      bar();
      MFMA_QUAD(1, 0, b0)
      if (st2) { vmw<V3>(); } else { vmw<0>(); }
      bar();
    }
  } else {
    for (int W = 0; W < KT; ++W) {
      const int s = W & 1;
      const int kn1 = (W + 1) << 6, kn2 = (W + 2) << 6;
      const bool st1 = (W + 1 < KT), st2 = (W + 2 < KT);
      // P0: (m0 x n0,n1); stage next A-slot fully + B1(W+1). A1 issued LAST.
      READ_A(s, 0)
      READ_B(s, 0, b0)
      READ_B(s, 1, b1)
      if (st1) { stageA(s ^ 1, 0, kn1); stageB(s ^ 1, 1, kn1); stageA(s ^ 1, 1, kn1); }
      bar();
      MFMA_QUAD(0, 0, b0)
      MFMA_QUAD(0, 1, b1)
      if (st1) { vmw<2 * (GA + GB)>(); } else { vmw<0>(); }
      bar();
      // P1: (m1 x n1,n0); stage B0(W+2) into current slot (B0(W) consumed in P0).
      READ_A(s, 1)
      if (st2) stageB(s, 0, kn2);
      bar();
      MFMA_QUAD(1, 1, b1)
      MFMA_QUAD(1, 0, b0)
      if (st2) { vmw<GA + GB>(); } else if (st1) { vmw<GA>(); } else { vmw<0>(); }
      bar();
    }
  }

  // epilogue: acc[M][N].
  // WL=0: M = mh*4+fq, m-off = (M>>2)*64 + (M&3)*16, wave m-base wm*128.
  // WL=1: M = mh*2+fq, m-off = (M>>1)*32 + (M&1)*16, wave m-base wm*64.
  const int mg0 = bx * BM + (WL ? wm * 64 : wm * 128) + ((lane >> 4) << 2);
  const int ng0 = by * BN + wn * 64 + (lane & 15);
  float* red = (float*)&As[0][0][0];  // STATS scratch: BN rows x NSLOT f32
#pragma unroll
  for (int N = 0; N < 4; ++N) {
    const int n = ng0 + (N >> 1) * 32 + (N & 1) * 16;
    const float bn = (BIAS_MODE == 2) ? bias[n] : 0.f;
    const float sc = SCALEN ? linv[(long)bz * 2304 + n] : 1.0f;
    float eN = 0.f;
#pragma unroll
    for (int M = 0; M < MR; ++M) {
      const int m = mg0 + (WL ? ((M >> 1) * 32 + (M & 1) * 16) : ((M >> 2) * 64 + (M & 3) * 16));
      const f32x4 av = acc[M][N];
      float vals[4];
#pragma unroll
      for (int j = 0; j < 4; ++j) {
        vals[j] = av[j] * alpha + ((BIAS_MODE == 1) ? bias[m + j] : bn);
        if (SCALEN) vals[j] *= sc;
        if (STATS) { vals[j] = __expf(vals[j]); eN += vals[j]; }
      }
      if (OUT_MODE == 0) {
        ushort4 o; o.x = f2bf(vals[0]); o.y = f2bf(vals[1]); o.z = f2bf(vals[2]); o.w = f2bf(vals[3]);
        *(ushort4*)((unsigned short*)Cp + (long)bz * sCz + (long)n * ldc + m) = o;
      } else if (OUT_MODE == 2) {
        int pk = __builtin_amdgcn_cvt_pk_fp8_f32(vals[0], vals[1], 0, false);
        pk = __builtin_amdgcn_cvt_pk_fp8_f32(vals[2], vals[3], pk, true);
        *(int*)((unsigned char*)Cp + (long)bz * sCz + (long)n * ldc + perm64(m)) = pk;
      } else {
        const float* rp = resid + (long)n * ldc + m;
        float4 o; o.x = vals[0] + rp[0]; o.y = vals[1] + rp[1]; o.z = vals[2] + rp[2]; o.w = vals[3] + rp[3];
        *(float4*)((float*)Cp + (long)bz * sCz + (long)n * ldc + m) = o;
      }
    }
    if (STATS) {
      const int nloc = wn * 64 + (N >> 1) * 32 + (N & 1) * 16 + (lane & 15);
      const int slot = wm * 4 + (lane >> 4);
      red[nloc * NSLOT + slot] = eN;
    }
  }
  if (STATS) {
    bar();
    if (tid < BN) {
      float L = 0.f;
#pragma unroll
      for (int s2 = 0; s2 < NSLOT; ++s2) L += red[tid * NSLOT + s2];
      rowsums[((long)(bz * gx + bx)) * 2304 + by * BN + tid] = L;
    }
  }
#undef READ_A
#undef READ_B
#undef MFMA_QUAD
}

extern "C" void kernel_launch(void* const* d_in, const int* in_sizes, int n_in,
                              void* d_out, int out_size, void* d_ws, size_t ws_size,
                              hipStream_t stream) {
  const float* x = (const float*)d_in[0];
  const float* gamma = (const float*)d_in[1];
  const float* beta = (const float*)d_in[2];
  const float* wq = (const float*)d_in[3];
  const float* bq = (const float*)d_in[4];
  const float* wk = (const float*)d_in[5];
  const float* bk = (const float*)d_in[6];
  const float* wv = (const float*)d_in[7];
  const float* bv = (const float*)d_in[8];
  const float* wo = (const float*)d_in[9];
  const float* bo = (const float*)d_in[10];
  float* out = (float*)d_out;

  char* ws = (char*)d_ws;
  size_t off = 0;
  auto alloc = [&](size_t bytes) {
    char* p = ws + off;
    off = (off + bytes + 255) & ~(size_t)255;
    return p;
  };
  float* part = (float*)alloc(256 * 2 * sizeof(float));
  float* stats = (float*)alloc(32 * 2 * sizeof(float));
  unsigned short* wqkb = (unsigned short*)alloc((size_t)2 * 262144 * 2);
  unsigned short* wvb = (unsigned short*)alloc((size_t)262144 * 2);
  unsigned short* wob = (unsigned short*)alloc((size_t)262144 * 2);
  float* bqk = (float*)alloc(1024 * sizeof(float));
  float* rowsums = (float*)alloc((size_t)8 * 18 * 2304 * sizeof(float));
  float* linv = (float*)alloc((size_t)18432 * sizeof(float));
  unsigned short* hnT = (unsigned short*)alloc((size_t)18432 * 512 * 2);
  unsigned char* qkA = (unsigned char*)alloc((size_t)18432 * 1024);      // fp8 k-interleaved
  unsigned char* vT = (unsigned char*)alloc((size_t)512 * 18432);        // fp8 k-interleaved
  unsigned char* Sm = (unsigned char*)alloc((size_t)8 * 2304 * 2304);    // fp8 E k-interleaved
  unsigned short* Ob = hnT;  // alias: hnT fully consumed after qk/v GEMMs
  (void)ws_size; (void)in_sizes; (void)n_in; (void)out_size;

  stats_partial_k<<<dim3(256), dim3(256), 0, stream>>>(x, part);
  stats_final_k<<<dim3(1), dim3(64), 0, stream>>>(part, stats);
  gn_transpose_k<<<dim3(8, 288), dim3(256), 0, stream>>>(x, stats, gamma, beta, hnT);
  pack_bf16_k<<<dim3(256), dim3(256), 0, stream>>>(wq, wqkb);
  pack_bf16_k<<<dim3(256), dim3(256), 0, stream>>>(wk, wqkb + 262144);
  pack_bf16_k<<<dim3(256), dim3(256), 0, stream>>>(wv, wvb);
  pack_bf16_k<<<dim3(256), dim3(256), 0, stream>>>(wo, wob);
  pack_bias_k<<<dim3(1), dim3(1024), 0, stream>>>(bq, bk, bqk);

  // qk fused: A=[Wq;Wk] bf16, B=hnT bf16 -> q,k fp8 interleaved [sp][1024].
  // WL=1 bf16 (128x128, 2 blocks/CU): 8x144x(8 XCD) = 1152 blocks MODE1.
  gemm256<128, 1, 2, 0, 0, 1, 0, 1, 1><<<dim3(1152), dim3(256), 0, stream>>>(
      wqkb, 512, 0, hnT, 512, 0, (void*)qkA, 1024, 0, bqk, nullptr, nullptr, nullptr,
      1.0f, 512, 8, 18);
  // v: A=hnT bf16, B=Wv bf16 -> vT fp8 interleaved [co][18432]. MODE2: 144 blocks.
  gemm256<256, 2, 2, 0, 0, 2, 0, 0><<<dim3(144), dim3(512), 0, stream>>>(
      hnT, 512, 0, wvb, 512, 0, (void*)vT, 18432, 0, bv, nullptr, nullptr, nullptr,
      1.0f, 512, 9, 2);
  // S: per t: A=k fp8, B=q fp8 -> E=exp(alpha*S) fp8 interleaved + rowsums.
  // R16: WL=1 fp8, 4 blocks/CU: 18x18x8 = 2592 blocks MODE0.
  gemm256<128, 0, 2, 1, 0, 0, 1, 1, 1><<<dim3(2592), dim3(256), 0, stream>>>(
      qkA + 512, 1024, (long)2304 * 1024, qkA, 1024, (long)2304 * 1024, (void*)Sm, 2304,
      (long)2304 * 2304, nullptr, nullptr, rowsums, nullptr,
      0.044194173824159216f, 512, 18, 18);
  combine_k<<<dim3(72), dim3(256), 0, stream>>>(rowsums, linv, 18);
  // PV: per t: A=vT fp8, B=E fp8 -> O bf16 [(t,i)*512+c], rows scaled by linv.
  // R16: WL=1 fp8, 4 blocks/CU: 4x18x8 = 576 blocks MODE0.
  gemm256<128, 0, 0, 0, 1, 0, 1, 1, 1><<<dim3(576), dim3(256), 0, stream>>>(
      vT, 18432, 2304, Sm, 2304, (long)2304 * 2304, (void*)Ob, 512, (long)2304 * 512,
      nullptr, nullptr, nullptr, linv, 1.0f, 2304, 4, 18);
  // final: A=O bf16, B=Wo bf16 -> out[co*18432+sp] = x + acc + bo[co]. MODE2: 144 blocks.
  gemm256<256, 2, 1, 0, 0, 2, 0, 0><<<dim3(144), dim3(512), 0, stream>>>(
      Ob, 512, 0, wob, 512, 0, (void*)out, 18432, 0, bo, x, nullptr, nullptr,
      1.0f, 512, 9, 2);
}

// Round 8
// 228.468 us; speedup vs baseline: 1.1677x; 1.0195x over previous
//
#include <hip/hip_runtime.h>
#include <hip/hip_bf16.h>
#include <cstdint>
#include <type_traits>

typedef __attribute__((ext_vector_type(8))) __bf16 bf16x8;
typedef __attribute__((ext_vector_type(4))) float f32x4;
typedef __attribute__((ext_vector_type(2))) long longx2;

struct bf2frag { bf16x8 k0, k1; };

__device__ __forceinline__ float bf2f(unsigned short u) {
  union { uint32_t i; float f; } v; v.i = (uint32_t)u << 16; return v.f;
}
__device__ __forceinline__ unsigned short f2bf(float f) {
  union { float f; uint32_t i; } v{f};
  uint32_t r = v.i + 0x7fffu + ((v.i >> 16) & 1u);
  return (unsigned short)(r >> 16);
}

__device__ __forceinline__ void gll(const void* g, void* l) {
  __builtin_amdgcn_global_load_lds(
      (const __attribute__((address_space(1))) uint32_t*)(uintptr_t)g,
      (__attribute__((address_space(3))) uint32_t*)(uint32_t)(uintptr_t)l,
      16, 0, 0);
}

__device__ __forceinline__ void bar() {
  asm volatile("" ::: "memory");
  __builtin_amdgcn_s_barrier();
  asm volatile("" ::: "memory");
}

#define VMCNT(n) asm volatile("s_waitcnt vmcnt(" #n ")" ::: "memory")

template <int N>
__device__ __forceinline__ void vmw() {
  if constexpr (N == 0) { VMCNT(0); }
  else if constexpr (N == 1) { VMCNT(1); }
  else if constexpr (N == 2) { VMCNT(2); }
  else if constexpr (N == 3) { VMCNT(3); }
  else if constexpr (N == 4) { VMCNT(4); }
  else if constexpr (N == 5) { VMCNT(5); }
  else if constexpr (N == 6) { VMCNT(6); }
  else if constexpr (N == 7) { VMCNT(7); }
  else if constexpr (N == 8) { VMCNT(8); }
  else if constexpr (N == 9) { VMCNT(9); }
  else if constexpr (N == 10) { VMCNT(10); }
  else { VMCNT(12); }
}

__device__ __forceinline__ f32x4 mma(bf16x8 a, bf16x8 b, f32x4 c) {
  return __builtin_amdgcn_mfma_f32_16x16x32_bf16(a, b, c, 0, 0, 0);
}
__device__ __forceinline__ f32x4 mma(long a, long b, f32x4 c) {
  return __builtin_amdgcn_mfma_f32_16x16x32_fp8_fp8(a, b, c, 0, 0, 0);
}
__device__ __forceinline__ f32x4 mmak(const bf2frag& a, const bf2frag& b, f32x4 c, int k2) {
  return k2 ? mma(a.k1, b.k1, c) : mma(a.k0, b.k0, c);
}
__device__ __forceinline__ f32x4 mmak(longx2 a, longx2 b, f32x4 c, int k2) {
  return mma(a[k2], b[k2], c);
}

// k-interleave store permutation for fp8 buffers (unit u=8B: slot p(u)=(u&3)*2+(u>>2))
__device__ __forceinline__ int perm64(int m) {
  return (m & ~63) | (((m >> 3) & 3) << 4) | (((m >> 5) & 1) << 3) | (m & 7);
}

// ---------------- GroupNorm stats ----------------
__global__ __launch_bounds__(256) void stats_partial_k(const float* __restrict__ x,
                                                       float* __restrict__ part) {
  const int g = blockIdx.x >> 3, p = blockIdx.x & 7;
  const float* base = x + (long)g * 16 * 18432 + (long)p * 2304;
  float s = 0.f, ss = 0.f;
  for (int idx = threadIdx.x; idx < 16 * 576; idx += 256) {
    const int c = idx / 576, i4 = idx % 576;
    const float4 v = *(const float4*)(base + (long)c * 18432 + i4 * 4);
    s += v.x + v.y + v.z + v.w;
    ss += v.x * v.x + v.y * v.y + v.z * v.z + v.w * v.w;
  }
  __shared__ float rs[256], rss[256];
  rs[threadIdx.x] = s; rss[threadIdx.x] = ss;
  __syncthreads();
  for (int o = 128; o > 0; o >>= 1) {
    if ((int)threadIdx.x < o) { rs[threadIdx.x] += rs[threadIdx.x + o]; rss[threadIdx.x] += rss[threadIdx.x + o]; }
    __syncthreads();
  }
  if (threadIdx.x == 0) { part[blockIdx.x * 2] = rs[0]; part[blockIdx.x * 2 + 1] = rss[0]; }
}

__global__ void stats_final_k(const float* __restrict__ part, float* __restrict__ stats) {
  const int g = threadIdx.x;
  if (g < 32) {
    float s = 0.f, ss = 0.f;
    for (int p = 0; p < 8; ++p) { s += part[(g * 8 + p) * 2]; ss += part[(g * 8 + p) * 2 + 1]; }
    const float mean = s / 294912.0f;
    const float var = ss / 294912.0f - mean * mean;
    stats[g * 2] = mean;
    stats[g * 2 + 1] = rsqrtf(var + 1e-6f);
  }
}

// ---------------- GN apply + transpose to (spatial, channel) bf16 ----------------
__global__ __launch_bounds__(256) void gn_transpose_k(const float* __restrict__ x,
                                                      const float* __restrict__ stats,
                                                      const float* __restrict__ gamma,
                                                      const float* __restrict__ beta,
                                                      unsigned short* __restrict__ hnT) {
  __shared__ float tile[64][65];
  const int c0 = blockIdx.x * 64, n0 = blockIdx.y * 64;
  const int tn = threadIdx.x & 63, tr = threadIdx.x >> 6;
  for (int cc = tr; cc < 64; cc += 4) {
    const int c = c0 + cc, g = c >> 4;
    const float mean = stats[g * 2], rstd = stats[g * 2 + 1];
    const float v = x[(long)c * 18432 + n0 + tn];
    tile[cc][tn] = (v - mean) * rstd * gamma[c] + beta[c];
  }
  __syncthreads();
  for (int nn = tr; nn < 64; nn += 4) {
    hnT[(long)(n0 + nn) * 512 + c0 + tn] = f2bf(tile[tn][nn]);
  }
}

// ---------------- fp32 -> bf16 weight pack ----------------
__global__ __launch_bounds__(256) void pack_bf16_k(const float* __restrict__ w,
                                                   unsigned short* __restrict__ o) {
  const int i = (blockIdx.x * 256 + threadIdx.x) * 4;
  const float4 v = *(const float4*)(w + i);
  ushort4 u; u.x = f2bf(v.x); u.y = f2bf(v.y); u.z = f2bf(v.z); u.w = f2bf(v.w);
  *(ushort4*)(o + i) = u;
}

__global__ void pack_bias_k(const float* __restrict__ bq, const float* __restrict__ bk,
                            float* __restrict__ bqk) {
  const int t = threadIdx.x;
  bqk[t] = (t < 512) ? bq[t] : bk[t - 512];
}

// ---------------- per-row 1/L combine from per-tile sums (NT tiles of rows) ----------------
__global__ __launch_bounds__(256) void combine_k(const float* __restrict__ rs,
                                                 float* __restrict__ linv, int ntile) {
  const int row = blockIdx.x * 256 + threadIdx.x;  // [0, 18432)
  const int t = row / 2304, r = row % 2304;
  float L = 0.f;
  for (int x = 0; x < ntile; ++x) L += rs[((long)(t * ntile + x)) * 2304 + r];
  linv[row] = 1.0f / L;
}

// ================= BMxBNx64 NT GEMM, XCD-swizzled, bf16/fp8 =================
// C[n*ldc+m] = alpha*sum_k A[m,k]*B[n,k] (+bias)(+resid)
// WL=0, BM=256: 512 thr, 8 waves (2m x 4n), 1 block/CU, P2=0, setprio ON.
// WL=0, BM=128: 256 thr, 4 waves (1m x 4n, BN=256), 2 blocks/CU, P2=1, no prio.
// WL=1: BM=128 x BN=128, 256 thr, 4 waves (2m x 2n, 64x64/wave).
//   fp8: 32KB LDS, launch_bounds(256,4) (R16: occupancy saturated ~3 blocks;
//   4th is harmless). bf16: 64KB LDS -> 2 blocks/CU.
//   Ladder: R13 S 66->58 (TLP), R14 qk 59->~45 (makespan), R15 PV 58->~40,
//   R17: v + final 144 coarse blocks (44% CUs idle; final also memory-heavy,
//   idle CUs = idle HBM ports) -> 576 fine blocks on the qk-proven machine.
//   A/B halves use 32-row stripe interleave: grow = (r>>5)*64 + h*32 + (r&31);
//   wave wm covers rows [wm*64, wm*64+64).
// P2=0 (8-phase snake): see prior rounds; vmcnt V0=GB+2GA, V3=2GB+GA, VP=GB+GA.
// P2=1 (2-phase): P0: read A0,B0,B1; stage [A0,B1,A1](W+1) -> s^1; mfma m0x{n0,n1}.
//   P1: read A1; stage B0(W+2) -> s; mfma m1x{n1,n0}.
//   Waits: @P0-end vmcnt(2GA+2GB); @P1-end vmcnt(GA+GB); tail GA then 0.
// STATS: exp+rowsums (tile index bx over gx m-tiles). SCALEN: *linv[n].
// OUT_MODE: 0 bf16, 1 f32+resid, 2 fp8 e4m3 k-interleaved.
// MODE0: bz=bid%8 per XCD; MODE1/2: XCD y/x-chunking.
template <int BM, int BIAS_MODE, int OUT_MODE, int STATS, int SCALEN, int MODE, int FP8, int P2,
          int WL = 0>
__global__ __launch_bounds__((BM == 256) ? 512 : 256, (WL && FP8) ? 4 : 2)
void gemm256(const void* __restrict__ A, long lda, long sAz,
             const void* __restrict__ B, long ldb, long sBz,
             void* __restrict__ Cp, long ldc, long sCz,
             const float* __restrict__ bias,
             const float* __restrict__ resid,
             float* __restrict__ rowsums,
             const float* __restrict__ linv,
             float alpha, int K, int gx, int gy) {
  constexpr int EB = FP8 ? 1 : 2;                    // element bytes
  constexpr int THREADS = (BM == 256) ? 512 : 256;
  constexpr int BN = WL ? 128 : 256;                 // n-tile
  constexpr int HBA = (BM / 2) * 64 * EB;            // bytes per A half
  constexpr int HBB = (BN / 2) * 64 * EB;            // bytes per B half
  constexpr int GA = HBA / (THREADS * 16);           // gll per A-half stage
  constexpr int GB = HBB / (THREADS * 16);           // gll per B-half stage
  constexpr int V0 = GB + 2 * GA, V3 = 2 * GB + GA, VP = GB + GA;
  constexpr int NSLOT = WL ? 8 : ((BM == 256) ? 8 : 4);
  constexpr int MR = WL ? 4 : 8;                     // acc M-frags per wave
  constexpr int FQ = WL ? 2 : 4;                     // A-frags per (mh) phase
  constexpr int PRIO = !P2;                          // setprio only on 1-block path
  __shared__ alignas(16) unsigned char As[2][2][HBA];
  __shared__ alignas(16) unsigned char Bs[2][2][HBB];
  using ABt2 = typename std::conditional<FP8, longx2, bf2frag>::type;

  const int tid = threadIdx.x;
  const int lane = tid & 63, wid = tid >> 6;
  const int wm = WL ? (wid >> 1) : ((BM == 256) ? (wid & 1) : 0);
  const int wn = WL ? (wid & 1) : ((BM == 256) ? (wid >> 1) : wid);
  int bx, by, bz;
  {
    const int g8 = blockIdx.x & 7, n = blockIdx.x >> 3;
    if (MODE == 0) { bz = g8; bx = n % gx; by = n / gx; }
    else if (MODE == 1) { bz = 0; bx = n % gx; by = g8 * gy + n / gx; }
    else { bz = 0; by = n % gy; bx = g8 * gx + n / gy; }
  }
  const unsigned char* Ab = (const unsigned char*)A + ((long)bz * sAz + (long)bx * BM * lda) * EB;
  const unsigned char* Bb = (const unsigned char*)B + ((long)bz * sBz + (long)by * BN * ldb) * EB;

  // ---- staging (global -> LDS, pre-swizzled source; fp8 global is k-interleaved) ----
  auto stageA = [&](int slot, int h, int k0) {
    if constexpr (!FP8) {
      const int ksw = ((tid & 7) << 3) ^ (((tid >> 3) & 7) << 3);
#pragma unroll
      for (int call = 0; call < GA; ++call) {
        const int r = call * (THREADS / 8) + (tid >> 3);
        const int grow = WL ? (((r >> 5) << 6) + h * 32 + (r & 31))
                            : (((r >> 6) << 7) + h * 64 + (r & 63));
        gll(Ab + ((long)grow * lda + k0) * 2 + ksw * 2, &As[slot][h][call * THREADS * 16 + tid * 16]);
      }
    } else {
#pragma unroll
      for (int call = 0; call < GA; ++call) {
        const int l = call * (THREADS / 4) + (tid >> 2);
        const int grow = WL ? (((l >> 5) << 6) + h * 32 + (l & 31))
                            : (((l >> 6) << 7) + h * 64 + (l & 63));
        const int x = (((l & 3) ^ ((l >> 2) & 3)) << 4);
        gll(Ab + (long)grow * lda + k0 + (((tid & 3) << 4) ^ x),
            &As[slot][h][call * THREADS * 16 + tid * 16]);
      }
    }
  };
  auto stageB = [&](int slot, int h, int k0) {
    if constexpr (!FP8) {
      const int ksw = ((tid & 7) << 3) ^ (((tid >> 3) & 7) << 3);
#pragma unroll
      for (int call = 0; call < GB; ++call) {
        const int r = call * (THREADS / 8) + (tid >> 3);
        const int grow = ((r >> 5) << 6) + h * 32 + (r & 31);
        gll(Bb + ((long)grow * ldb + k0) * 2 + ksw * 2, &Bs[slot][h][call * THREADS * 16 + tid * 16]);
      }
    } else {
#pragma unroll
      for (int call = 0; call < GB; ++call) {
        const int l = call * (THREADS / 4) + (tid >> 2);
        const int grow = ((l >> 5) << 6) + h * 32 + (l & 31);
        const int x = (((l & 3) ^ ((l >> 2) & 3)) << 4);
        gll(Bb + (long)grow * ldb + k0 + (((tid & 3) << 4) ^ x),
            &Bs[slot][h][call * THREADS * 16 + tid * 16]);
      }
    }
  };
  // ---- LDS -> fragment reads (same swizzle; fp8 = ONE b128 for both k2 slices) ----
  auto ldA = [&](int slot, int mh, int fq) -> ABt2 {
    const int r = (WL ? wm * 32 : wm * 64) + fq * 16 + (lane & 15);
    if constexpr (!FP8) {
      bf2frag f;
      const int kk0 = (((lane >> 4) << 3)) ^ ((r & 7) << 3);
      const int kk1 = (32 + ((lane >> 4) << 3)) ^ ((r & 7) << 3);
      f.k0 = *reinterpret_cast<const bf16x8*>(&As[slot][mh][r * 128 + kk0 * 2]);
      f.k1 = *reinterpret_cast<const bf16x8*>(&As[slot][mh][r * 128 + kk1 * 2]);
      return f;
    } else {
      const int x = (((r & 3) ^ ((r >> 2) & 3)) << 4);
      const int kk = ((lane >> 4) << 4) ^ x;
      return *reinterpret_cast<const longx2*>(&As[slot][mh][r * 64 + kk]);
    }
  };
  auto ldB = [&](int slot, int nh, int g) -> ABt2 {
    const int r = wn * 32 + g * 16 + (lane & 15);
    if constexpr (!FP8) {
      bf2frag f;
      const int kk0 = (((lane >> 4) << 3)) ^ ((r & 7) << 3);
      const int kk1 = (32 + ((lane >> 4) << 3)) ^ ((r & 7) << 3);
      f.k0 = *reinterpret_cast<const bf16x8*>(&Bs[slot][nh][r * 128 + kk0 * 2]);
      f.k1 = *reinterpret_cast<const bf16x8*>(&Bs[slot][nh][r * 128 + kk1 * 2]);
      return f;
    } else {
      const int x = (((r & 3) ^ ((r >> 2) & 3)) << 4);
      const int kk = ((lane >> 4) << 4) ^ x;
      return *reinterpret_cast<const longx2*>(&Bs[slot][nh][r * 64 + kk]);
    }
  };

  f32x4 acc[MR][4] = {};
  ABt2 a[4], b0[2], b1[2];

#define READ_A(SLOT, MH)                                                     \
  _Pragma("unroll") for (int fq = 0; fq < FQ; ++fq) a[fq] = ldA(SLOT, MH, fq);
#define READ_B(SLOT, NH, DST)                                                \
  _Pragma("unroll") for (int g = 0; g < 2; ++g) DST[g] = ldB(SLOT, NH, g);
#define MFMA_QUAD(MH, NH, BARR)                                              \
  if constexpr (PRIO) __builtin_amdgcn_s_setprio(1);                         \
  _Pragma("unroll") for (int fq = 0; fq < FQ; ++fq)                          \
    _Pragma("unroll") for (int g = 0; g < 2; ++g)                            \
      _Pragma("unroll") for (int k2 = 0; k2 < 2; ++k2)                       \
        acc[(MH) * FQ + fq][(NH) * 2 + g] =                                  \
            mmak(a[fq], BARR[g], acc[(MH) * FQ + fq][(NH) * 2 + g], k2);     \
  if constexpr (PRIO) __builtin_amdgcn_s_setprio(0);

  const int KT = K >> 6;
  // Prologue queue: [B0(0), A0(0), B1(0), A1(0), B0(1)] (+A1(1) for P2=0)
  stageB(0, 0, 0);
  stageA(0, 0, 0);
  stageB(0, 1, 0);
  stageA(0, 1, 0);
  stageB(1, 0, 64);
  if constexpr (!P2) stageA(1, 1, 64);
  vmw<VP>();
  bar();

  if constexpr (!P2) {
    for (int W = 0; W < KT; ++W) {
      const int s = W & 1;
      const int kn1 = (W + 1) << 6, kn2 = (W + 2) << 6;
      const bool st1 = (W + 1 < KT), st2 = (W + 2 < KT);
      // p0: (m0,n0)
      READ_A(s, 0)
      READ_B(s, 0, b0)
      if (st1) stageA(s ^ 1, 0, kn1);
      bar();
      MFMA_QUAD(0, 0, b0)
      if (st1) { vmw<V0>(); }
      bar();
      // p1: (m0,n1)
      READ_B(s, 1, b1)
      if (st1) stageB(s ^ 1, 1, kn1);
      bar();
      MFMA_QUAD(0, 1, b1)
      bar();
      // p2: (m1,n1)
      READ_A(s, 1)
      if (st2) stageB(s, 0, kn2);
      bar();
      MFMA_QUAD(1, 1, b1)
      bar();
      // p3: (m1,n0)
      if (st2) stageA(s, 1, kn2);
      bar();
      MFMA_QUAD(1, 0, b0)
      if (st2) { vmw<V3>(); } else { vmw<0>(); }
      bar();
    }
  } else {
    for (int W = 0; W < KT; ++W) {
      const int s = W & 1;
      const int kn1 = (W + 1) << 6, kn2 = (W + 2) << 6;
      const bool st1 = (W + 1 < KT), st2 = (W + 2 < KT);
      // P0: (m0 x n0,n1); stage next A-slot fully + B1(W+1). A1 issued LAST.
      READ_A(s, 0)
      READ_B(s, 0, b0)
      READ_B(s, 1, b1)
      if (st1) { stageA(s ^ 1, 0, kn1); stageB(s ^ 1, 1, kn1); stageA(s ^ 1, 1, kn1); }
      bar();
      MFMA_QUAD(0, 0, b0)
      MFMA_QUAD(0, 1, b1)
      if (st1) { vmw<2 * (GA + GB)>(); } else { vmw<0>(); }
      bar();
      // P1: (m1 x n1,n0); stage B0(W+2) into current slot (B0(W) consumed in P0).
      READ_A(s, 1)
      if (st2) stageB(s, 0, kn2);
      bar();
      MFMA_QUAD(1, 1, b1)
      MFMA_QUAD(1, 0, b0)
      if (st2) { vmw<GA + GB>(); } else if (st1) { vmw<GA>(); } else { vmw<0>(); }
      bar();
    }
  }

  // epilogue: acc[M][N].
  // WL=0: M = mh*4+fq, m-off = (M>>2)*64 + (M&3)*16, wave m-base wm*128.
  // WL=1: M = mh*2+fq, m-off = (M>>1)*32 + (M&1)*16, wave m-base wm*64.
  const int mg0 = bx * BM + (WL ? wm * 64 : wm * 128) + ((lane >> 4) << 2);
  const int ng0 = by * BN + wn * 64 + (lane & 15);
  float* red = (float*)&As[0][0][0];  // STATS scratch: BN rows x NSLOT f32
#pragma unroll
  for (int N = 0; N < 4; ++N) {
    const int n = ng0 + (N >> 1) * 32 + (N & 1) * 16;
    const float bn = (BIAS_MODE == 2) ? bias[n] : 0.f;
    const float sc = SCALEN ? linv[(long)bz * 2304 + n] : 1.0f;
    float eN = 0.f;
#pragma unroll
    for (int M = 0; M < MR; ++M) {
      const int m = mg0 + (WL ? ((M >> 1) * 32 + (M & 1) * 16) : ((M >> 2) * 64 + (M & 3) * 16));
      const f32x4 av = acc[M][N];
      float vals[4];
#pragma unroll
      for (int j = 0; j < 4; ++j) {
        vals[j] = av[j] * alpha + ((BIAS_MODE == 1) ? bias[m + j] : bn);
        if (SCALEN) vals[j] *= sc;
        if (STATS) { vals[j] = __expf(vals[j]); eN += vals[j]; }
      }
      if (OUT_MODE == 0) {
        ushort4 o; o.x = f2bf(vals[0]); o.y = f2bf(vals[1]); o.z = f2bf(vals[2]); o.w = f2bf(vals[3]);
        *(ushort4*)((unsigned short*)Cp + (long)bz * sCz + (long)n * ldc + m) = o;
      } else if (OUT_MODE == 2) {
        int pk = __builtin_amdgcn_cvt_pk_fp8_f32(vals[0], vals[1], 0, false);
        pk = __builtin_amdgcn_cvt_pk_fp8_f32(vals[2], vals[3], pk, true);
        *(int*)((unsigned char*)Cp + (long)bz * sCz + (long)n * ldc + perm64(m)) = pk;
      } else {
        const float* rp = resid + (long)n * ldc + m;
        float4 o; o.x = vals[0] + rp[0]; o.y = vals[1] + rp[1]; o.z = vals[2] + rp[2]; o.w = vals[3] + rp[3];
        *(float4*)((float*)Cp + (long)bz * sCz + (long)n * ldc + m) = o;
      }
    }
    if (STATS) {
      const int nloc = wn * 64 + (N >> 1) * 32 + (N & 1) * 16 + (lane & 15);
      const int slot = wm * 4 + (lane >> 4);
      red[nloc * NSLOT + slot] = eN;
    }
  }
  if (STATS) {
    bar();
    if (tid < BN) {
      float L = 0.f;
#pragma unroll
      for (int s2 = 0; s2 < NSLOT; ++s2) L += red[tid * NSLOT + s2];
      rowsums[((long)(bz * gx + bx)) * 2304 + by * BN + tid] = L;
    }
  }
#undef READ_A
#undef READ_B
#undef MFMA_QUAD
}

extern "C" void kernel_launch(void* const* d_in, const int* in_sizes, int n_in,
                              void* d_out, int out_size, void* d_ws, size_t ws_size,
                              hipStream_t stream) {
  const float* x = (const float*)d_in[0];
  const float* gamma = (const float*)d_in[1];
  const float* beta = (const float*)d_in[2];
  const float* wq = (const float*)d_in[3];
  const float* bq = (const float*)d_in[4];
  const float* wk = (const float*)d_in[5];
  const float* bk = (const float*)d_in[6];
  const float* wv = (const float*)d_in[7];
  const float* bv = (const float*)d_in[8];
  const float* wo = (const float*)d_in[9];
  const float* bo = (const float*)d_in[10];
  float* out = (float*)d_out;

  char* ws = (char*)d_ws;
  size_t off = 0;
  auto alloc = [&](size_t bytes) {
    char* p = ws + off;
    off = (off + bytes + 255) & ~(size_t)255;
    return p;
  };
  float* part = (float*)alloc(256 * 2 * sizeof(float));
  float* stats = (float*)alloc(32 * 2 * sizeof(float));
  unsigned short* wqkb = (unsigned short*)alloc((size_t)2 * 262144 * 2);
  unsigned short* wvb = (unsigned short*)alloc((size_t)262144 * 2);
  unsigned short* wob = (unsigned short*)alloc((size_t)262144 * 2);
  float* bqk = (float*)alloc(1024 * sizeof(float));
  float* rowsums = (float*)alloc((size_t)8 * 18 * 2304 * sizeof(float));
  float* linv = (float*)alloc((size_t)18432 * sizeof(float));
  unsigned short* hnT = (unsigned short*)alloc((size_t)18432 * 512 * 2);
  unsigned char* qkA = (unsigned char*)alloc((size_t)18432 * 1024);      // fp8 k-interleaved
  unsigned char* vT = (unsigned char*)alloc((size_t)512 * 18432);        // fp8 k-interleaved
  unsigned char* Sm = (unsigned char*)alloc((size_t)8 * 2304 * 2304);    // fp8 E k-interleaved
  unsigned short* Ob = hnT;  // alias: hnT fully consumed after qk/v GEMMs
  (void)ws_size; (void)in_sizes; (void)n_in; (void)out_size;

  stats_partial_k<<<dim3(256), dim3(256), 0, stream>>>(x, part);
  stats_final_k<<<dim3(1), dim3(64), 0, stream>>>(part, stats);
  gn_transpose_k<<<dim3(8, 288), dim3(256), 0, stream>>>(x, stats, gamma, beta, hnT);
  pack_bf16_k<<<dim3(256), dim3(256), 0, stream>>>(wq, wqkb);
  pack_bf16_k<<<dim3(256), dim3(256), 0, stream>>>(wk, wqkb + 262144);
  pack_bf16_k<<<dim3(256), dim3(256), 0, stream>>>(wv, wvb);
  pack_bf16_k<<<dim3(256), dim3(256), 0, stream>>>(wo, wob);
  pack_bias_k<<<dim3(1), dim3(1024), 0, stream>>>(bq, bk, bqk);

  // qk fused: A=[Wq;Wk] bf16, B=hnT bf16 -> q,k fp8 interleaved [sp][1024].
  // WL=1 bf16 (128x128, 2 blocks/CU): 8x144x(8 XCD) = 1152 blocks MODE1.
  gemm256<128, 1, 2, 0, 0, 1, 0, 1, 1><<<dim3(1152), dim3(256), 0, stream>>>(
      wqkb, 512, 0, hnT, 512, 0, (void*)qkA, 1024, 0, bqk, nullptr, nullptr, nullptr,
      1.0f, 512, 8, 18);
  // v: A=hnT bf16, B=Wv bf16 -> vT fp8 interleaved [co][18432].
  // R17: WL=1 bf16, MODE2: 8 XCD x (gx=18 m-chunk) x (gy=4 n) = 576 blocks.
  gemm256<128, 2, 2, 0, 0, 2, 0, 1, 1><<<dim3(576), dim3(256), 0, stream>>>(
      hnT, 512, 0, wvb, 512, 0, (void*)vT, 18432, 0, bv, nullptr, nullptr, nullptr,
      1.0f, 512, 18, 4);
  // S: per t: A=k fp8, B=q fp8 -> E=exp(alpha*S) fp8 interleaved + rowsums.
  // WL=1 fp8: 18x18x8 = 2592 blocks MODE0.
  gemm256<128, 0, 2, 1, 0, 0, 1, 1, 1><<<dim3(2592), dim3(256), 0, stream>>>(
      qkA + 512, 1024, (long)2304 * 1024, qkA, 1024, (long)2304 * 1024, (void*)Sm, 2304,
      (long)2304 * 2304, nullptr, nullptr, rowsums, nullptr,
      0.044194173824159216f, 512, 18, 18);
  combine_k<<<dim3(72), dim3(256), 0, stream>>>(rowsums, linv, 18);
  // PV: per t: A=vT fp8, B=E fp8 -> O bf16 [(t,i)*512+c], rows scaled by linv.
  // WL=1 fp8: 4x18x8 = 576 blocks MODE0.
  gemm256<128, 0, 0, 0, 1, 0, 1, 1, 1><<<dim3(576), dim3(256), 0, stream>>>(
      vT, 18432, 2304, Sm, 2304, (long)2304 * 2304, (void*)Ob, 512, (long)2304 * 512,
      nullptr, nullptr, nullptr, linv, 1.0f, 2304, 4, 18);
  // final: A=O bf16, B=Wo bf16 -> out[co*18432+sp] = x + acc + bo[co].
  // R17: WL=1 bf16, MODE2: 8 x 18 x 4 = 576 blocks.
  gemm256<128, 2, 1, 0, 0, 2, 0, 1, 1><<<dim3(576), dim3(256), 0, stream>>>(
      Ob, 512, 0, wob, 512, 0, (void*)out, 18432, 0, bo, x, nullptr, nullptr,
      1.0f, 512, 18, 4);
}

// Round 9
// 228.307 us; speedup vs baseline: 1.1686x; 1.0007x over previous
//
#include <hip/hip_runtime.h>
#include <hip/hip_bf16.h>
#include <cstdint>
#include <type_traits>

typedef __attribute__((ext_vector_type(8))) __bf16 bf16x8;
typedef __attribute__((ext_vector_type(4))) float f32x4;
typedef __attribute__((ext_vector_type(2))) long longx2;

struct bf2frag { bf16x8 k0, k1; };

__device__ __forceinline__ float bf2f(unsigned short u) {
  union { uint32_t i; float f; } v; v.i = (uint32_t)u << 16; return v.f;
}
__device__ __forceinline__ unsigned short f2bf(float f) {
  union { float f; uint32_t i; } v{f};
  uint32_t r = v.i + 0x7fffu + ((v.i >> 16) & 1u);
  return (unsigned short)(r >> 16);
}

__device__ __forceinline__ void gll(const void* g, void* l) {
  __builtin_amdgcn_global_load_lds(
      (const __attribute__((address_space(1))) uint32_t*)(uintptr_t)g,
      (__attribute__((address_space(3))) uint32_t*)(uint32_t)(uintptr_t)l,
      16, 0, 0);
}

__device__ __forceinline__ void bar() {
  asm volatile("" ::: "memory");
  __builtin_amdgcn_s_barrier();
  asm volatile("" ::: "memory");
}

#define VMCNT(n) asm volatile("s_waitcnt vmcnt(" #n ")" ::: "memory")

template <int N>
__device__ __forceinline__ void vmw() {
  if constexpr (N == 0) { VMCNT(0); }
  else if constexpr (N == 1) { VMCNT(1); }
  else if constexpr (N == 2) { VMCNT(2); }
  else if constexpr (N == 3) { VMCNT(3); }
  else if constexpr (N == 4) { VMCNT(4); }
  else if constexpr (N == 5) { VMCNT(5); }
  else if constexpr (N == 6) { VMCNT(6); }
  else if constexpr (N == 7) { VMCNT(7); }
  else if constexpr (N == 8) { VMCNT(8); }
  else if constexpr (N == 9) { VMCNT(9); }
  else if constexpr (N == 10) { VMCNT(10); }
  else { VMCNT(12); }
}

__device__ __forceinline__ f32x4 mma(bf16x8 a, bf16x8 b, f32x4 c) {
  return __builtin_amdgcn_mfma_f32_16x16x32_bf16(a, b, c, 0, 0, 0);
}
__device__ __forceinline__ f32x4 mma(long a, long b, f32x4 c) {
  return __builtin_amdgcn_mfma_f32_16x16x32_fp8_fp8(a, b, c, 0, 0, 0);
}
__device__ __forceinline__ f32x4 mmak(const bf2frag& a, const bf2frag& b, f32x4 c, int k2) {
  return k2 ? mma(a.k1, b.k1, c) : mma(a.k0, b.k0, c);
}
__device__ __forceinline__ f32x4 mmak(longx2 a, longx2 b, f32x4 c, int k2) {
  return mma(a[k2], b[k2], c);
}

// k-interleave store permutation for fp8 buffers (unit u=8B: slot p(u)=(u&3)*2+(u>>2))
__device__ __forceinline__ int perm64(int m) {
  return (m & ~63) | (((m >> 3) & 3) << 4) | (((m >> 5) & 1) << 3) | (m & 7);
}

// ---------------- GroupNorm stats ----------------
__global__ __launch_bounds__(256) void stats_partial_k(const float* __restrict__ x,
                                                       float* __restrict__ part) {
  const int g = blockIdx.x >> 3, p = blockIdx.x & 7;
  const float* base = x + (long)g * 16 * 18432 + (long)p * 2304;
  float s = 0.f, ss = 0.f;
  for (int idx = threadIdx.x; idx < 16 * 576; idx += 256) {
    const int c = idx / 576, i4 = idx % 576;
    const float4 v = *(const float4*)(base + (long)c * 18432 + i4 * 4);
    s += v.x + v.y + v.z + v.w;
    ss += v.x * v.x + v.y * v.y + v.z * v.z + v.w * v.w;
  }
  __shared__ float rs[256], rss[256];
  rs[threadIdx.x] = s; rss[threadIdx.x] = ss;
  __syncthreads();
  for (int o = 128; o > 0; o >>= 1) {
    if ((int)threadIdx.x < o) { rs[threadIdx.x] += rs[threadIdx.x + o]; rss[threadIdx.x] += rss[threadIdx.x + o]; }
    __syncthreads();
  }
  if (threadIdx.x == 0) { part[blockIdx.x * 2] = rs[0]; part[blockIdx.x * 2 + 1] = rss[0]; }
}

__global__ void stats_final_k(const float* __restrict__ part, float* __restrict__ stats) {
  const int g = threadIdx.x;
  if (g < 32) {
    float s = 0.f, ss = 0.f;
    for (int p = 0; p < 8; ++p) { s += part[(g * 8 + p) * 2]; ss += part[(g * 8 + p) * 2 + 1]; }
    const float mean = s / 294912.0f;
    const float var = ss / 294912.0f - mean * mean;
    stats[g * 2] = mean;
    stats[g * 2 + 1] = rsqrtf(var + 1e-6f);
  }
}

// ---------------- GN apply + transpose to (spatial, channel) bf16 ----------------
__global__ __launch_bounds__(256) void gn_transpose_k(const float* __restrict__ x,
                                                      const float* __restrict__ stats,
                                                      const float* __restrict__ gamma,
                                                      const float* __restrict__ beta,
                                                      unsigned short* __restrict__ hnT) {
  __shared__ float tile[64][65];
  const int c0 = blockIdx.x * 64, n0 = blockIdx.y * 64;
  const int tn = threadIdx.x & 63, tr = threadIdx.x >> 6;
  for (int cc = tr; cc < 64; cc += 4) {
    const int c = c0 + cc, g = c >> 4;
    const float mean = stats[g * 2], rstd = stats[g * 2 + 1];
    const float v = x[(long)c * 18432 + n0 + tn];
    tile[cc][tn] = (v - mean) * rstd * gamma[c] + beta[c];
  }
  __syncthreads();
  for (int nn = tr; nn < 64; nn += 4) {
    hnT[(long)(n0 + nn) * 512 + c0 + tn] = f2bf(tile[tn][nn]);
  }
}

// ---------------- fp32 -> bf16 weight pack ----------------
__global__ __launch_bounds__(256) void pack_bf16_k(const float* __restrict__ w,
                                                   unsigned short* __restrict__ o) {
  const int i = (blockIdx.x * 256 + threadIdx.x) * 4;
  const float4 v = *(const float4*)(w + i);
  ushort4 u; u.x = f2bf(v.x); u.y = f2bf(v.y); u.z = f2bf(v.z); u.w = f2bf(v.w);
  *(ushort4*)(o + i) = u;
}

__global__ void pack_bias_k(const float* __restrict__ bq, const float* __restrict__ bk,
                            float* __restrict__ bqk) {
  const int t = threadIdx.x;
  bqk[t] = (t < 512) ? bq[t] : bk[t - 512];
}

// ---------------- per-row 1/L combine from per-tile sums (NT tiles of rows) ----------------
__global__ __launch_bounds__(256) void combine_k(const float* __restrict__ rs,
                                                 float* __restrict__ linv, int ntile) {
  const int row = blockIdx.x * 256 + threadIdx.x;  // [0, 18432)
  const int t = row / 2304, r = row % 2304;
  float L = 0.f;
  for (int x = 0; x < ntile; ++x) L += rs[((long)(t * ntile + x)) * 2304 + r];
  linv[row] = 1.0f / L;
}

// ================= BMxBNx64 NT GEMM, XCD-swizzled, bf16/fp8 =================
// C[n*ldc+m] = alpha*sum_k A[m,k]*B[n,k] (+bias)(+resid)
// WL=0, BM=256: 512 thr, 8 waves (2m x 4n), 1 block/CU, P2=0, setprio ON.
// WL=0, BM=128: 256 thr, 4 waves (1m x 4n, BN=256), 2 blocks/CU, P2=1, no prio.
// WL=1: BM=128 x BN=128, 256 thr, 4 waves (2m x 2n, 64x64/wave).
//   fp8: 32KB LDS, launch_bounds(256,4). bf16: 64KB LDS -> 2 blocks/CU.
//   Ladder: R13 S 66->58 (TLP), R14 qk (makespan), R15 PV, R17 v+final.
//   R18: STATS scratch stride NSLOT -> NSLOT+1. The 2.94M bank conflicts on S
//   are NOT in the main loop (fp8 ld swizzle is conflict-free per 8-lane group;
//   gll writes linear) -- they're the reduction read red[tid*8+s2]: lane i hits
//   bank 8i%32 = 4 banks = 16-way, behind a barrier (critical path), once per
//   block x 2592 blocks. Odd stride 9 spreads across all 32 banks (~2-way).
//   Scratch 128x9x4 = 4.6KB aliases As (16KB) -- safe, used post-loop only.
//   A/B halves use 32-row stripe interleave: grow = (r>>5)*64 + h*32 + (r&31).
// P2=0 (8-phase snake): see prior rounds; vmcnt V0=GB+2GA, V3=2GB+GA, VP=GB+GA.
// P2=1 (2-phase): P0: read A0,B0,B1; stage [A0,B1,A1](W+1) -> s^1; mfma m0x{n0,n1}.
//   P1: read A1; stage B0(W+2) -> s; mfma m1x{n1,n0}.
//   Waits: @P0-end vmcnt(2GA+2GB); @P1-end vmcnt(GA+GB); tail GA then 0.
// STATS: exp+rowsums (tile index bx over gx m-tiles). SCALEN: *linv[n].
// OUT_MODE: 0 bf16, 1 f32+resid, 2 fp8 e4m3 k-interleaved.
// MODE0: bz=bid%8 per XCD; MODE1/2: XCD y/x-chunking.
template <int BM, int BIAS_MODE, int OUT_MODE, int STATS, int SCALEN, int MODE, int FP8, int P2,
          int WL = 0>
__global__ __launch_bounds__((BM == 256) ? 512 : 256, (WL && FP8) ? 4 : 2)
void gemm256(const void* __restrict__ A, long lda, long sAz,
             const void* __restrict__ B, long ldb, long sBz,
             void* __restrict__ Cp, long ldc, long sCz,
             const float* __restrict__ bias,
             const float* __restrict__ resid,
             float* __restrict__ rowsums,
             const float* __restrict__ linv,
             float alpha, int K, int gx, int gy) {
  constexpr int EB = FP8 ? 1 : 2;                    // element bytes
  constexpr int THREADS = (BM == 256) ? 512 : 256;
  constexpr int BN = WL ? 128 : 256;                 // n-tile
  constexpr int HBA = (BM / 2) * 64 * EB;            // bytes per A half
  constexpr int HBB = (BN / 2) * 64 * EB;            // bytes per B half
  constexpr int GA = HBA / (THREADS * 16);           // gll per A-half stage
  constexpr int GB = HBB / (THREADS * 16);           // gll per B-half stage
  constexpr int V0 = GB + 2 * GA, V3 = 2 * GB + GA, VP = GB + GA;
  constexpr int NSLOT = WL ? 8 : ((BM == 256) ? 8 : 4);
  constexpr int NSLOTP = NSLOT + 1;                  // R18: odd stride, no 16-way conflict
  constexpr int MR = WL ? 4 : 8;                     // acc M-frags per wave
  constexpr int FQ = WL ? 2 : 4;                     // A-frags per (mh) phase
  constexpr int PRIO = !P2;                          // setprio only on 1-block path
  __shared__ alignas(16) unsigned char As[2][2][HBA];
  __shared__ alignas(16) unsigned char Bs[2][2][HBB];
  using ABt2 = typename std::conditional<FP8, longx2, bf2frag>::type;

  const int tid = threadIdx.x;
  const int lane = tid & 63, wid = tid >> 6;
  const int wm = WL ? (wid >> 1) : ((BM == 256) ? (wid & 1) : 0);
  const int wn = WL ? (wid & 1) : ((BM == 256) ? (wid >> 1) : wid);
  int bx, by, bz;
  {
    const int g8 = blockIdx.x & 7, n = blockIdx.x >> 3;
    if (MODE == 0) { bz = g8; bx = n % gx; by = n / gx; }
    else if (MODE == 1) { bz = 0; bx = n % gx; by = g8 * gy + n / gx; }
    else { bz = 0; by = n % gy; bx = g8 * gx + n / gy; }
  }
  const unsigned char* Ab = (const unsigned char*)A + ((long)bz * sAz + (long)bx * BM * lda) * EB;
  const unsigned char* Bb = (const unsigned char*)B + ((long)bz * sBz + (long)by * BN * ldb) * EB;

  // ---- staging (global -> LDS, pre-swizzled source; fp8 global is k-interleaved) ----
  auto stageA = [&](int slot, int h, int k0) {
    if constexpr (!FP8) {
      const int ksw = ((tid & 7) << 3) ^ (((tid >> 3) & 7) << 3);
#pragma unroll
      for (int call = 0; call < GA; ++call) {
        const int r = call * (THREADS / 8) + (tid >> 3);
        const int grow = WL ? (((r >> 5) << 6) + h * 32 + (r & 31))
                            : (((r >> 6) << 7) + h * 64 + (r & 63));
        gll(Ab + ((long)grow * lda + k0) * 2 + ksw * 2, &As[slot][h][call * THREADS * 16 + tid * 16]);
      }
    } else {
#pragma unroll
      for (int call = 0; call < GA; ++call) {
        const int l = call * (THREADS / 4) + (tid >> 2);
        const int grow = WL ? (((l >> 5) << 6) + h * 32 + (l & 31))
                            : (((l >> 6) << 7) + h * 64 + (l & 63));
        const int x = (((l & 3) ^ ((l >> 2) & 3)) << 4);
        gll(Ab + (long)grow * lda + k0 + (((tid & 3) << 4) ^ x),
            &As[slot][h][call * THREADS * 16 + tid * 16]);
      }
    }
  };
  auto stageB = [&](int slot, int h, int k0) {
    if constexpr (!FP8) {
      const int ksw = ((tid & 7) << 3) ^ (((tid >> 3) & 7) << 3);
#pragma unroll
      for (int call = 0; call < GB; ++call) {
        const int r = call * (THREADS / 8) + (tid >> 3);
        const int grow = ((r >> 5) << 6) + h * 32 + (r & 31);
        gll(Bb + ((long)grow * ldb + k0) * 2 + ksw * 2, &Bs[slot][h][call * THREADS * 16 + tid * 16]);
      }
    } else {
#pragma unroll
      for (int call = 0; call < GB; ++call) {
        const int l = call * (THREADS / 4) + (tid >> 2);
        const int grow = ((l >> 5) << 6) + h * 32 + (l & 31);
        const int x = (((l & 3) ^ ((l >> 2) & 3)) << 4);
        gll(Bb + (long)grow * ldb + k0 + (((tid & 3) << 4) ^ x),
            &Bs[slot][h][call * THREADS * 16 + tid * 16]);
      }
    }
  };
  // ---- LDS -> fragment reads (same swizzle; fp8 = ONE b128 for both k2 slices) ----
  auto ldA = [&](int slot, int mh, int fq) -> ABt2 {
    const int r = (WL ? wm * 32 : wm * 64) + fq * 16 + (lane & 15);
    if constexpr (!FP8) {
      bf2frag f;
      const int kk0 = (((lane >> 4) << 3)) ^ ((r & 7) << 3);
      const int kk1 = (32 + ((lane >> 4) << 3)) ^ ((r & 7) << 3);
      f.k0 = *reinterpret_cast<const bf16x8*>(&As[slot][mh][r * 128 + kk0 * 2]);
      f.k1 = *reinterpret_cast<const bf16x8*>(&As[slot][mh][r * 128 + kk1 * 2]);
      return f;
    } else {
      const int x = (((r & 3) ^ ((r >> 2) & 3)) << 4);
      const int kk = ((lane >> 4) << 4) ^ x;
      return *reinterpret_cast<const longx2*>(&As[slot][mh][r * 64 + kk]);
    }
  };
  auto ldB = [&](int slot, int nh, int g) -> ABt2 {
    const int r = wn * 32 + g * 16 + (lane & 15);
    if constexpr (!FP8) {
      bf2frag f;
      const int kk0 = (((lane >> 4) << 3)) ^ ((r & 7) << 3);
      const int kk1 = (32 + ((lane >> 4) << 3)) ^ ((r & 7) << 3);
      f.k0 = *reinterpret_cast<const bf16x8*>(&Bs[slot][nh][r * 128 + kk0 * 2]);
      f.k1 = *reinterpret_cast<const bf16x8*>(&Bs[slot][nh][r * 128 + kk1 * 2]);
      return f;
    } else {
      const int x = (((r & 3) ^ ((r >> 2) & 3)) << 4);
      const int kk = ((lane >> 4) << 4) ^ x;
      return *reinterpret_cast<const longx2*>(&Bs[slot][nh][r * 64 + kk]);
    }
  };

  f32x4 acc[MR][4] = {};
  ABt2 a[4], b0[2], b1[2];

#define READ_A(SLOT, MH)                                                     \
  _Pragma("unroll") for (int fq = 0; fq < FQ; ++fq) a[fq] = ldA(SLOT, MH, fq);
#define READ_B(SLOT, NH, DST)                                                \
  _Pragma("unroll") for (int g = 0; g < 2; ++g) DST[g] = ldB(SLOT, NH, g);
#define MFMA_QUAD(MH, NH, BARR)                                              \
  if constexpr (PRIO) __builtin_amdgcn_s_setprio(1);                         \
  _Pragma("unroll") for (int fq = 0; fq < FQ; ++fq)                          \
    _Pragma("unroll") for (int g = 0; g < 2; ++g)                            \
      _Pragma("unroll") for (int k2 = 0; k2 < 2; ++k2)                       \
        acc[(MH) * FQ + fq][(NH) * 2 + g] =                                  \
            mmak(a[fq], BARR[g], acc[(MH) * FQ + fq][(NH) * 2 + g], k2);     \
  if constexpr (PRIO) __builtin_amdgcn_s_setprio(0);

  const int KT = K >> 6;
  // Prologue queue: [B0(0), A0(0), B1(0), A1(0), B0(1)] (+A1(1) for P2=0)
  stageB(0, 0, 0);
  stageA(0, 0, 0);
  stageB(0, 1, 0);
  stageA(0, 1, 0);
  stageB(1, 0, 64);
  if constexpr (!P2) stageA(1, 1, 64);
  vmw<VP>();
  bar();

  if constexpr (!P2) {
    for (int W = 0; W < KT; ++W) {
      const int s = W & 1;
      const int kn1 = (W + 1) << 6, kn2 = (W + 2) << 6;
      const bool st1 = (W + 1 < KT), st2 = (W + 2 < KT);
      // p0: (m0,n0)
      READ_A(s, 0)
      READ_B(s, 0, b0)
      if (st1) stageA(s ^ 1, 0, kn1);
      bar();
      MFMA_QUAD(0, 0, b0)
      if (st1) { vmw<V0>(); }
      bar();
      // p1: (m0,n1)
      READ_B(s, 1, b1)
      if (st1) stageB(s ^ 1, 1, kn1);
      bar();
      MFMA_QUAD(0, 1, b1)
      bar();
      // p2: (m1,n1)
      READ_A(s, 1)
      if (st2) stageB(s, 0, kn2);
      bar();
      MFMA_QUAD(1, 1, b1)
      bar();
      // p3: (m1,n0)
      if (st2) stageA(s, 1, kn2);
      bar();
      MFMA_QUAD(1, 0, b0)
      if (st2) { vmw<V3>(); } else { vmw<0>(); }
      bar();
    }
  } else {
    for (int W = 0; W < KT; ++W) {
      const int s = W & 1;
      const int kn1 = (W + 1) << 6, kn2 = (W + 2) << 6;
      const bool st1 = (W + 1 < KT), st2 = (W + 2 < KT);
      // P0: (m0 x n0,n1); stage next A-slot fully + B1(W+1). A1 issued LAST.
      READ_A(s, 0)
      READ_B(s, 0, b0)
      READ_B(s, 1, b1)
      if (st1) { stageA(s ^ 1, 0, kn1); stageB(s ^ 1, 1, kn1); stageA(s ^ 1, 1, kn1); }
      bar();
      MFMA_QUAD(0, 0, b0)
      MFMA_QUAD(0, 1, b1)
      if (st1) { vmw<2 * (GA + GB)>(); } else { vmw<0>(); }
      bar();
      // P1: (m1 x n1,n0); stage B0(W+2) into current slot (B0(W) consumed in P0).
      READ_A(s, 1)
      if (st2) stageB(s, 0, kn2);
      bar();
      MFMA_QUAD(1, 1, b1)
      MFMA_QUAD(1, 0, b0)
      if (st2) { vmw<GA + GB>(); } else if (st1) { vmw<GA>(); } else { vmw<0>(); }
      bar();
    }
  }

  // epilogue: acc[M][N].
  // WL=0: M = mh*4+fq, m-off = (M>>2)*64 + (M&3)*16, wave m-base wm*128.
  // WL=1: M = mh*2+fq, m-off = (M>>1)*32 + (M&1)*16, wave m-base wm*64.
  const int mg0 = bx * BM + (WL ? wm * 64 : wm * 128) + ((lane >> 4) << 2);
  const int ng0 = by * BN + wn * 64 + (lane & 15);
  float* red = (float*)&As[0][0][0];  // STATS scratch: BN rows x NSLOTP f32
#pragma unroll
  for (int N = 0; N < 4; ++N) {
    const int n = ng0 + (N >> 1) * 32 + (N & 1) * 16;
    const float bn = (BIAS_MODE == 2) ? bias[n] : 0.f;
    const float sc = SCALEN ? linv[(long)bz * 2304 + n] : 1.0f;
    float eN = 0.f;
#pragma unroll
    for (int M = 0; M < MR; ++M) {
      const int m = mg0 + (WL ? ((M >> 1) * 32 + (M & 1) * 16) : ((M >> 2) * 64 + (M & 3) * 16));
      const f32x4 av = acc[M][N];
      float vals[4];
#pragma unroll
      for (int j = 0; j < 4; ++j) {
        vals[j] = av[j] * alpha + ((BIAS_MODE == 1) ? bias[m + j] : bn);
        if (SCALEN) vals[j] *= sc;
        if (STATS) { vals[j] = __expf(vals[j]); eN += vals[j]; }
      }
      if (OUT_MODE == 0) {
        ushort4 o; o.x = f2bf(vals[0]); o.y = f2bf(vals[1]); o.z = f2bf(vals[2]); o.w = f2bf(vals[3]);
        *(ushort4*)((unsigned short*)Cp + (long)bz * sCz + (long)n * ldc + m) = o;
      } else if (OUT_MODE == 2) {
        int pk = __builtin_amdgcn_cvt_pk_fp8_f32(vals[0], vals[1], 0, false);
        pk = __builtin_amdgcn_cvt_pk_fp8_f32(vals[2], vals[3], pk, true);
        *(int*)((unsigned char*)Cp + (long)bz * sCz + (long)n * ldc + perm64(m)) = pk;
      } else {
        const float* rp = resid + (long)n * ldc + m;
        float4 o; o.x = vals[0] + rp[0]; o.y = vals[1] + rp[1]; o.z = vals[2] + rp[2]; o.w = vals[3] + rp[3];
        *(float4*)((float*)Cp + (long)bz * sCz + (long)n * ldc + m) = o;
      }
    }
    if (STATS) {
      const int nloc = wn * 64 + (N >> 1) * 32 + (N & 1) * 16 + (lane & 15);
      const int slot = wm * 4 + (lane >> 4);
      red[nloc * NSLOTP + slot] = eN;
    }
  }
  if (STATS) {
    bar();
    if (tid < BN) {
      float L = 0.f;
#pragma unroll
      for (int s2 = 0; s2 < NSLOT; ++s2) L += red[tid * NSLOTP + s2];
      rowsums[((long)(bz * gx + bx)) * 2304 + by * BN + tid] = L;
    }
  }
#undef READ_A
#undef READ_B
#undef MFMA_QUAD
}

extern "C" void kernel_launch(void* const* d_in, const int* in_sizes, int n_in,
                              void* d_out, int out_size, void* d_ws, size_t ws_size,
                              hipStream_t stream) {
  const float* x = (const float*)d_in[0];
  const float* gamma = (const float*)d_in[1];
  const float* beta = (const float*)d_in[2];
  const float* wq = (const float*)d_in[3];
  const float* bq = (const float*)d_in[4];
  const float* wk = (const float*)d_in[5];
  const float* bk = (const float*)d_in[6];
  const float* wv = (const float*)d_in[7];
  const float* bv = (const float*)d_in[8];
  const float* wo = (const float*)d_in[9];
  const float* bo = (const float*)d_in[10];
  float* out = (float*)d_out;

  char* ws = (char*)d_ws;
  size_t off = 0;
  auto alloc = [&](size_t bytes) {
    char* p = ws + off;
    off = (off + bytes + 255) & ~(size_t)255;
    return p;
  };
  float* part = (float*)alloc(256 * 2 * sizeof(float));
  float* stats = (float*)alloc(32 * 2 * sizeof(float));
  unsigned short* wqkb = (unsigned short*)alloc((size_t)2 * 262144 * 2);
  unsigned short* wvb = (unsigned short*)alloc((size_t)262144 * 2);
  unsigned short* wob = (unsigned short*)alloc((size_t)262144 * 2);
  float* bqk = (float*)alloc(1024 * sizeof(float));
  float* rowsums = (float*)alloc((size_t)8 * 18 * 2304 * sizeof(float));
  float* linv = (float*)alloc((size_t)18432 * sizeof(float));
  unsigned short* hnT = (unsigned short*)alloc((size_t)18432 * 512 * 2);
  unsigned char* qkA = (unsigned char*)alloc((size_t)18432 * 1024);      // fp8 k-interleaved
  unsigned char* vT = (unsigned char*)alloc((size_t)512 * 18432);        // fp8 k-interleaved
  unsigned char* Sm = (unsigned char*)alloc((size_t)8 * 2304 * 2304);    // fp8 E k-interleaved
  unsigned short* Ob = hnT;  // alias: hnT fully consumed after qk/v GEMMs
  (void)ws_size; (void)in_sizes; (void)n_in; (void)out_size;

  stats_partial_k<<<dim3(256), dim3(256), 0, stream>>>(x, part);
  stats_final_k<<<dim3(1), dim3(64), 0, stream>>>(part, stats);
  gn_transpose_k<<<dim3(8, 288), dim3(256), 0, stream>>>(x, stats, gamma, beta, hnT);
  pack_bf16_k<<<dim3(256), dim3(256), 0, stream>>>(wq, wqkb);
  pack_bf16_k<<<dim3(256), dim3(256), 0, stream>>>(wk, wqkb + 262144);
  pack_bf16_k<<<dim3(256), dim3(256), 0, stream>>>(wv, wvb);
  pack_bf16_k<<<dim3(256), dim3(256), 0, stream>>>(wo, wob);
  pack_bias_k<<<dim3(1), dim3(1024), 0, stream>>>(bq, bk, bqk);

  // qk fused: A=[Wq;Wk] bf16, B=hnT bf16 -> q,k fp8 interleaved [sp][1024].
  // WL=1 bf16 (128x128, 2 blocks/CU): 8x144x(8 XCD) = 1152 blocks MODE1.
  gemm256<128, 1, 2, 0, 0, 1, 0, 1, 1><<<dim3(1152), dim3(256), 0, stream>>>(
      wqkb, 512, 0, hnT, 512, 0, (void*)qkA, 1024, 0, bqk, nullptr, nullptr, nullptr,
      1.0f, 512, 8, 18);
  // v: A=hnT bf16, B=Wv bf16 -> vT fp8 interleaved [co][18432].
  // WL=1 bf16, MODE2: 8 XCD x (gx=18 m-chunk) x (gy=4 n) = 576 blocks.
  gemm256<128, 2, 2, 0, 0, 2, 0, 1, 1><<<dim3(576), dim3(256), 0, stream>>>(
      hnT, 512, 0, wvb, 512, 0, (void*)vT, 18432, 0, bv, nullptr, nullptr, nullptr,
      1.0f, 512, 18, 4);
  // S: per t: A=k fp8, B=q fp8 -> E=exp(alpha*S) fp8 interleaved + rowsums.
  // WL=1 fp8: 18x18x8 = 2592 blocks MODE0.
  gemm256<128, 0, 2, 1, 0, 0, 1, 1, 1><<<dim3(2592), dim3(256), 0, stream>>>(
      qkA + 512, 1024, (long)2304 * 1024, qkA, 1024, (long)2304 * 1024, (void*)Sm, 2304,
      (long)2304 * 2304, nullptr, nullptr, rowsums, nullptr,
      0.044194173824159216f, 512, 18, 18);
  combine_k<<<dim3(72), dim3(256), 0, stream>>>(rowsums, linv, 18);
  // PV: per t: A=vT fp8, B=E fp8 -> O bf16 [(t,i)*512+c], rows scaled by linv.
  // WL=1 fp8: 4x18x8 = 576 blocks MODE0.
  gemm256<128, 0, 0, 0, 1, 0, 1, 1, 1><<<dim3(576), dim3(256), 0, stream>>>(
      vT, 18432, 2304, Sm, 2304, (long)2304 * 2304, (void*)Ob, 512, (long)2304 * 512,
      nullptr, nullptr, nullptr, linv, 1.0f, 2304, 4, 18);
  // final: A=O bf16, B=Wo bf16 -> out[co*18432+sp] = x + acc + bo[co].
  // WL=1 bf16, MODE2: 8 x 18 x 4 = 576 blocks.
  gemm256<128, 2, 1, 0, 0, 2, 0, 1, 1><<<dim3(576), dim3(256), 0, stream>>>(
      Ob, 512, 0, wob, 512, 0, (void*)out, 18432, 0, bo, x, nullptr, nullptr,
      1.0f, 512, 18, 4);
}

// Round 10
// 228.241 us; speedup vs baseline: 1.1689x; 1.0003x over previous
//
#include <hip/hip_runtime.h>
#include <hip/hip_bf16.h>
#include <cstdint>
#include <type_traits>

typedef __attribute__((ext_vector_type(8))) __bf16 bf16x8;
typedef __attribute__((ext_vector_type(4))) float f32x4;
typedef __attribute__((ext_vector_type(2))) long longx2;

struct bf2frag { bf16x8 k0, k1; };

__device__ __forceinline__ float bf2f(unsigned short u) {
  union { uint32_t i; float f; } v; v.i = (uint32_t)u << 16; return v.f;
}
__device__ __forceinline__ unsigned short f2bf(float f) {
  union { float f; uint32_t i; } v{f};
  uint32_t r = v.i + 0x7fffu + ((v.i >> 16) & 1u);
  return (unsigned short)(r >> 16);
}

__device__ __forceinline__ void gll(const void* g, void* l) {
  __builtin_amdgcn_global_load_lds(
      (const __attribute__((address_space(1))) uint32_t*)(uintptr_t)g,
      (__attribute__((address_space(3))) uint32_t*)(uint32_t)(uintptr_t)l,
      16, 0, 0);
}

__device__ __forceinline__ void bar() {
  asm volatile("" ::: "memory");
  __builtin_amdgcn_s_barrier();
  asm volatile("" ::: "memory");
}

#define VMCNT(n) asm volatile("s_waitcnt vmcnt(" #n ")" ::: "memory")

template <int N>
__device__ __forceinline__ void vmw() {
  if constexpr (N == 0) { VMCNT(0); }
  else if constexpr (N == 1) { VMCNT(1); }
  else if constexpr (N == 2) { VMCNT(2); }
  else if constexpr (N == 3) { VMCNT(3); }
  else if constexpr (N == 4) { VMCNT(4); }
  else if constexpr (N == 5) { VMCNT(5); }
  else if constexpr (N == 6) { VMCNT(6); }
  else if constexpr (N == 7) { VMCNT(7); }
  else if constexpr (N == 8) { VMCNT(8); }
  else if constexpr (N == 9) { VMCNT(9); }
  else if constexpr (N == 10) { VMCNT(10); }
  else { VMCNT(12); }
}

__device__ __forceinline__ f32x4 mma(bf16x8 a, bf16x8 b, f32x4 c) {
  return __builtin_amdgcn_mfma_f32_16x16x32_bf16(a, b, c, 0, 0, 0);
}
__device__ __forceinline__ f32x4 mma(long a, long b, f32x4 c) {
  return __builtin_amdgcn_mfma_f32_16x16x32_fp8_fp8(a, b, c, 0, 0, 0);
}
__device__ __forceinline__ f32x4 mmak(const bf2frag& a, const bf2frag& b, f32x4 c, int k2) {
  return k2 ? mma(a.k1, b.k1, c) : mma(a.k0, b.k0, c);
}
__device__ __forceinline__ f32x4 mmak(longx2 a, longx2 b, f32x4 c, int k2) {
  return mma(a[k2], b[k2], c);
}

// k-interleave store permutation for fp8 buffers (unit u=8B: slot p(u)=(u&3)*2+(u>>2))
__device__ __forceinline__ int perm64(int m) {
  return (m & ~63) | (((m >> 3) & 3) << 4) | (((m >> 5) & 1) << 3) | (m & 7);
}

// ---------------- GroupNorm stats ----------------
__global__ __launch_bounds__(256) void stats_partial_k(const float* __restrict__ x,
                                                       float* __restrict__ part) {
  const int g = blockIdx.x >> 3, p = blockIdx.x & 7;
  const float* base = x + (long)g * 16 * 18432 + (long)p * 2304;
  float s = 0.f, ss = 0.f;
  for (int idx = threadIdx.x; idx < 16 * 576; idx += 256) {
    const int c = idx / 576, i4 = idx % 576;
    const float4 v = *(const float4*)(base + (long)c * 18432 + i4 * 4);
    s += v.x + v.y + v.z + v.w;
    ss += v.x * v.x + v.y * v.y + v.z * v.z + v.w * v.w;
  }
  __shared__ float rs[256], rss[256];
  rs[threadIdx.x] = s; rss[threadIdx.x] = ss;
  __syncthreads();
  for (int o = 128; o > 0; o >>= 1) {
    if ((int)threadIdx.x < o) { rs[threadIdx.x] += rs[threadIdx.x + o]; rss[threadIdx.x] += rss[threadIdx.x + o]; }
    __syncthreads();
  }
  if (threadIdx.x == 0) { part[blockIdx.x * 2] = rs[0]; part[blockIdx.x * 2 + 1] = rss[0]; }
}

__global__ void stats_final_k(const float* __restrict__ part, float* __restrict__ stats) {
  const int g = threadIdx.x;
  if (g < 32) {
    float s = 0.f, ss = 0.f;
    for (int p = 0; p < 8; ++p) { s += part[(g * 8 + p) * 2]; ss += part[(g * 8 + p) * 2 + 1]; }
    const float mean = s / 294912.0f;
    const float var = ss / 294912.0f - mean * mean;
    stats[g * 2] = mean;
    stats[g * 2 + 1] = rsqrtf(var + 1e-6f);
  }
}

// ---------------- GN apply + transpose to (spatial, channel) bf16 ----------------
__global__ __launch_bounds__(256) void gn_transpose_k(const float* __restrict__ x,
                                                      const float* __restrict__ stats,
                                                      const float* __restrict__ gamma,
                                                      const float* __restrict__ beta,
                                                      unsigned short* __restrict__ hnT) {
  __shared__ float tile[64][65];
  const int c0 = blockIdx.x * 64, n0 = blockIdx.y * 64;
  const int tn = threadIdx.x & 63, tr = threadIdx.x >> 6;
  for (int cc = tr; cc < 64; cc += 4) {
    const int c = c0 + cc, g = c >> 4;
    const float mean = stats[g * 2], rstd = stats[g * 2 + 1];
    const float v = x[(long)c * 18432 + n0 + tn];
    tile[cc][tn] = (v - mean) * rstd * gamma[c] + beta[c];
  }
  __syncthreads();
  for (int nn = tr; nn < 64; nn += 4) {
    hnT[(long)(n0 + nn) * 512 + c0 + tn] = f2bf(tile[tn][nn]);
  }
}

// ---------------- fp32 -> bf16 weight pack (4 weights in one launch) ----------------
__global__ __launch_bounds__(256) void pack4_bf16_k(const float* __restrict__ w0,
                                                    const float* __restrict__ w1,
                                                    const float* __restrict__ w2,
                                                    const float* __restrict__ w3,
                                                    unsigned short* __restrict__ o0,
                                                    unsigned short* __restrict__ o1,
                                                    unsigned short* __restrict__ o2,
                                                    unsigned short* __restrict__ o3) {
  const int y = blockIdx.y;
  const float* w = (y == 0) ? w0 : (y == 1) ? w1 : (y == 2) ? w2 : w3;
  unsigned short* o = (y == 0) ? o0 : (y == 1) ? o1 : (y == 2) ? o2 : o3;
  const int i = (blockIdx.x * 256 + threadIdx.x) * 4;
  const float4 v = *(const float4*)(w + i);
  ushort4 u; u.x = f2bf(v.x); u.y = f2bf(v.y); u.z = f2bf(v.z); u.w = f2bf(v.w);
  *(ushort4*)(o + i) = u;
}

__global__ void pack_bias_k(const float* __restrict__ bq, const float* __restrict__ bk,
                            float* __restrict__ bqk) {
  const int t = threadIdx.x;
  bqk[t] = (t < 512) ? bq[t] : bk[t - 512];
}

// ---------------- per-row 1/L combine from per-tile sums (NT tiles of rows) ----------------
__global__ __launch_bounds__(256) void combine_k(const float* __restrict__ rs,
                                                 float* __restrict__ linv, int ntile) {
  const int row = blockIdx.x * 256 + threadIdx.x;  // [0, 18432)
  const int t = row / 2304, r = row % 2304;
  float L = 0.f;
  for (int x = 0; x < ntile; ++x) L += rs[((long)(t * ntile + x)) * 2304 + r];
  linv[row] = 1.0f / L;
}

// ================= BMxBNxBK NT GEMM, XCD-swizzled, bf16/fp8 =================
// C[n*ldc+m] = alpha*sum_k A[m,k]*B[n,k] (+bias)(+resid)
// WL=0, BM=256: 512 thr, 8 waves (2m x 4n), 1 block/CU, P2=0, setprio ON.
// WL=1: BM=128 x BN=128, 256 thr, 4 waves (2m x 2n, 64x64/wave).
//   fp8 KU=1: 32KB LDS, bounds(256,4). bf16: 64KB, 2 blocks/CU.
//   KU=2 (R19, S only): BK=128, LDS 64KB -> 2 blocks/CU, KT 8->4.
//   Theory: per-K-step wall ~1700cy with only ~400cy MFMA; the ~1300cy/step
//   fixed cost survived barrier-halving (R10), prio (R11), TLP (R13/R16) --
//   so halve the STEP COUNT. S has 5+ block generations (tail washes out);
//   PV stays KU=1 (576 blocks all-co-resident at 4-deep; 2/CU cap would add a
//   makespan generation). Sub-k-major LDS: stage call=sub*GA0+c0 writes linear;
//   reads at sub*HBA0 + r*64 + kk (per-64k swizzle + k-interleave self-contained
//   per 64-block, so k0+64 staging valid). vmcnt formulas scale with GA=GB=2
//   (FIFO re-derived incl. prologue VP=4 and KT=4 tail).
//   A/B halves use 32-row stripe interleave: grow = (r>>5)*64 + h*32 + (r&31).
// P2=1 (2-phase): P0: read A0,B0,B1; stage [A0,B1,A1](W+1) -> s^1; mfma m0x{n0,n1}.
//   P1: read A1; stage B0(W+2) -> s; mfma m1x{n1,n0}.
//   Waits: @P0-end vmcnt(2(GA+GB)); @P1-end vmcnt(GA+GB); tail GA then 0.
// STATS: exp+rowsums, scratch stride NSLOT+1 (R18). SCALEN: *linv[n].
// OUT_MODE: 0 bf16, 1 f32+resid, 2 fp8 e4m3 k-interleaved.
// MODE0: bz=bid%8 per XCD; MODE1/2: XCD y/x-chunking.
template <int BM, int BIAS_MODE, int OUT_MODE, int STATS, int SCALEN, int MODE, int FP8, int P2,
          int WL = 0, int KU = 1>
__global__ __launch_bounds__((BM == 256) ? 512 : 256, (WL && FP8) ? (KU == 2 ? 2 : 4) : 2)
void gemm256(const void* __restrict__ A, long lda, long sAz,
             const void* __restrict__ B, long ldb, long sBz,
             void* __restrict__ Cp, long ldc, long sCz,
             const float* __restrict__ bias,
             const float* __restrict__ resid,
             float* __restrict__ rowsums,
             const float* __restrict__ linv,
             float alpha, int K, int gx, int gy) {
  static_assert(KU == 1 || FP8, "KU=2 only on fp8 path");
  constexpr int EB = FP8 ? 1 : 2;                    // element bytes
  constexpr int THREADS = (BM == 256) ? 512 : 256;
  constexpr int BN = WL ? 128 : 256;                 // n-tile
  constexpr int BK = 64 * KU;                        // k-step
  constexpr int HBA = (BM / 2) * BK * EB;            // bytes per A half
  constexpr int HBB = (BN / 2) * BK * EB;            // bytes per B half
  constexpr int HBA0 = HBA / KU, HBB0 = HBB / KU;    // per 64-k sub-block
  constexpr int GA = HBA / (THREADS * 16);           // gll per A-half stage
  constexpr int GB = HBB / (THREADS * 16);           // gll per B-half stage
  constexpr int GA0 = GA / KU, GB0 = GB / KU;        // gll per 64-k sub-stage
  constexpr int V0 = GB + 2 * GA, V3 = 2 * GB + GA, VP = GB + GA;
  constexpr int NSLOT = WL ? 8 : ((BM == 256) ? 8 : 4);
  constexpr int NSLOTP = NSLOT + 1;                  // R18: odd stride
  constexpr int MR = WL ? 4 : 8;                     // acc M-frags per wave
  constexpr int FQ = WL ? 2 : 4;                     // A-frags per (mh) phase
  constexpr int PRIO = !P2;                          // setprio only on 1-block path
  __shared__ alignas(16) unsigned char As[2][2][HBA];
  __shared__ alignas(16) unsigned char Bs[2][2][HBB];
  using ABt2 = typename std::conditional<FP8, longx2, bf2frag>::type;

  const int tid = threadIdx.x;
  const int lane = tid & 63, wid = tid >> 6;
  const int wm = WL ? (wid >> 1) : ((BM == 256) ? (wid & 1) : 0);
  const int wn = WL ? (wid & 1) : ((BM == 256) ? (wid >> 1) : wid);
  int bx, by, bz;
  {
    const int g8 = blockIdx.x & 7, n = blockIdx.x >> 3;
    if (MODE == 0) { bz = g8; bx = n % gx; by = n / gx; }
    else if (MODE == 1) { bz = 0; bx = n % gx; by = g8 * gy + n / gx; }
    else { bz = 0; by = n % gy; bx = g8 * gx + n / gy; }
  }
  const unsigned char* Ab = (const unsigned char*)A + ((long)bz * sAz + (long)bx * BM * lda) * EB;
  const unsigned char* Bb = (const unsigned char*)B + ((long)bz * sBz + (long)by * BN * ldb) * EB;

  // ---- staging (global -> LDS, pre-swizzled source; fp8 global is k-interleaved) ----
  auto stageA = [&](int slot, int h, int k0) {
    if constexpr (!FP8) {
      const int ksw = ((tid & 7) << 3) ^ (((tid >> 3) & 7) << 3);
#pragma unroll
      for (int call = 0; call < GA; ++call) {
        const int r = call * (THREADS / 8) + (tid >> 3);
        const int grow = WL ? (((r >> 5) << 6) + h * 32 + (r & 31))
                            : (((r >> 6) << 7) + h * 64 + (r & 63));
        gll(Ab + ((long)grow * lda + k0) * 2 + ksw * 2, &As[slot][h][call * THREADS * 16 + tid * 16]);
      }
    } else {
#pragma unroll
      for (int call = 0; call < GA; ++call) {
        const int sub = call / GA0, c0 = call % GA0;
        const int l = c0 * (THREADS / 4) + (tid >> 2);
        const int grow = WL ? (((l >> 5) << 6) + h * 32 + (l & 31))
                            : (((l >> 6) << 7) + h * 64 + (l & 63));
        const int x = (((l & 3) ^ ((l >> 2) & 3)) << 4);
        gll(Ab + (long)grow * lda + k0 + sub * 64 + (((tid & 3) << 4) ^ x),
            &As[slot][h][call * THREADS * 16 + tid * 16]);
      }
    }
  };
  auto stageB = [&](int slot, int h, int k0) {
    if constexpr (!FP8) {
      const int ksw = ((tid & 7) << 3) ^ (((tid >> 3) & 7) << 3);
#pragma unroll
      for (int call = 0; call < GB; ++call) {
        const int r = call * (THREADS / 8) + (tid >> 3);
        const int grow = ((r >> 5) << 6) + h * 32 + (r & 31);
        gll(Bb + ((long)grow * ldb + k0) * 2 + ksw * 2, &Bs[slot][h][call * THREADS * 16 + tid * 16]);
      }
    } else {
#pragma unroll
      for (int call = 0; call < GB; ++call) {
        const int sub = call / GB0, c0 = call % GB0;
        const int l = c0 * (THREADS / 4) + (tid >> 2);
        const int grow = ((l >> 5) << 6) + h * 32 + (l & 31);
        const int x = (((l & 3) ^ ((l >> 2) & 3)) << 4);
        gll(Bb + (long)grow * ldb + k0 + sub * 64 + (((tid & 3) << 4) ^ x),
            &Bs[slot][h][call * THREADS * 16 + tid * 16]);
      }
    }
  };
  // ---- LDS -> fragment reads (same swizzle; fp8 = ONE b128 for both k2 slices) ----
  auto ldA = [&](int slot, int mh, int fq, int sub) -> ABt2 {
    const int r = (WL ? wm * 32 : wm * 64) + fq * 16 + (lane & 15);
    if constexpr (!FP8) {
      bf2frag f;
      const int kk0 = (((lane >> 4) << 3)) ^ ((r & 7) << 3);
      const int kk1 = (32 + ((lane >> 4) << 3)) ^ ((r & 7) << 3);
      f.k0 = *reinterpret_cast<const bf16x8*>(&As[slot][mh][r * 128 + kk0 * 2]);
      f.k1 = *reinterpret_cast<const bf16x8*>(&As[slot][mh][r * 128 + kk1 * 2]);
      return f;
    } else {
      const int x = (((r & 3) ^ ((r >> 2) & 3)) << 4);
      const int kk = ((lane >> 4) << 4) ^ x;
      return *reinterpret_cast<const longx2*>(&As[slot][mh][sub * HBA0 + r * 64 + kk]);
    }
  };
  auto ldB = [&](int slot, int nh, int g, int sub) -> ABt2 {
    const int r = wn * 32 + g * 16 + (lane & 15);
    if constexpr (!FP8) {
      bf2frag f;
      const int kk0 = (((lane >> 4) << 3)) ^ ((r & 7) << 3);
      const int kk1 = (32 + ((lane >> 4) << 3)) ^ ((r & 7) << 3);
      f.k0 = *reinterpret_cast<const bf16x8*>(&Bs[slot][nh][r * 128 + kk0 * 2]);
      f.k1 = *reinterpret_cast<const bf16x8*>(&Bs[slot][nh][r * 128 + kk1 * 2]);
      return f;
    } else {
      const int x = (((r & 3) ^ ((r >> 2) & 3)) << 4);
      const int kk = ((lane >> 4) << 4) ^ x;
      return *reinterpret_cast<const longx2*>(&Bs[slot][nh][sub * HBB0 + r * 64 + kk]);
    }
  };

  f32x4 acc[MR][4] = {};
  ABt2 a[FQ * KU], b0[2 * KU], b1[2 * KU];

#define READ_A(SLOT, MH)                                                       \
  _Pragma("unroll") for (int fq = 0; fq < FQ; ++fq)                            \
    _Pragma("unroll") for (int sub = 0; sub < KU; ++sub)                       \
      a[fq * KU + sub] = ldA(SLOT, MH, fq, sub);
#define READ_B(SLOT, NH, DST)                                                  \
  _Pragma("unroll") for (int g = 0; g < 2; ++g)                                \
    _Pragma("unroll") for (int sub = 0; sub < KU; ++sub)                       \
      DST[g * KU + sub] = ldB(SLOT, NH, g, sub);
#define MFMA_QUAD(MH, NH, BARR)                                                \
  if constexpr (PRIO) __builtin_amdgcn_s_setprio(1);                           \
  _Pragma("unroll") for (int fq = 0; fq < FQ; ++fq)                            \
    _Pragma("unroll") for (int g = 0; g < 2; ++g)                              \
      _Pragma("unroll") for (int sub = 0; sub < KU; ++sub)                     \
        _Pragma("unroll") for (int k2 = 0; k2 < 2; ++k2)                       \
          acc[(MH) * FQ + fq][(NH) * 2 + g] =                                  \
              mmak(a[fq * KU + sub], BARR[g * KU + sub],                       \
                   acc[(MH) * FQ + fq][(NH) * 2 + g], k2);                     \
  if constexpr (PRIO) __builtin_amdgcn_s_setprio(0);

  const int KT = K / BK;
  // Prologue queue: [B0(0), A0(0), B1(0), A1(0), B0(1)] (+A1(1) for P2=0)
  stageB(0, 0, 0);
  stageA(0, 0, 0);
  stageB(0, 1, 0);
  stageA(0, 1, 0);
  stageB(1, 0, BK);
  if constexpr (!P2) stageA(1, 1, BK);
  vmw<VP>();
  bar();

  if constexpr (!P2) {
    for (int W = 0; W < KT; ++W) {
      const int s = W & 1;
      const int kn1 = (W + 1) * BK, kn2 = (W + 2) * BK;
      const bool st1 = (W + 1 < KT), st2 = (W + 2 < KT);
      // p0: (m0,n0)
      READ_A(s, 0)
      READ_B(s, 0, b0)
      if (st1) stageA(s ^ 1, 0, kn1);
      bar();
      MFMA_QUAD(0, 0, b0)
      if (st1) { vmw<V0>(); }
      bar();
      // p1: (m0,n1)
      READ_B(s, 1, b1)
      if (st1) stageB(s ^ 1, 1, kn1);
      bar();
      MFMA_QUAD(0, 1, b1)
      bar();
      // p2: (m1,n1)
      READ_A(s, 1)
      if (st2) stageB(s, 0, kn2);
      bar();
      MFMA_QUAD(1, 1, b1)
      bar();
      // p3: (m1,n0)
      if (st2) stageA(s, 1, kn2);
      bar();
      MFMA_QUAD(1, 0, b0)
      if (st2) { vmw<V3>(); } else { vmw<0>(); }
      bar();
    }
  } else {
    for (int W = 0; W < KT; ++W) {
      const int s = W & 1;
      const int kn1 = (W + 1) * BK, kn2 = (W + 2) * BK;
      const bool st1 = (W + 1 < KT), st2 = (W + 2 < KT);
      // P0: (m0 x n0,n1); stage next A-slot fully + B1(W+1). A1 issued LAST.
      READ_A(s, 0)
      READ_B(s, 0, b0)
      READ_B(s, 1, b1)
      if (st1) { stageA(s ^ 1, 0, kn1); stageB(s ^ 1, 1, kn1); stageA(s ^ 1, 1, kn1); }
      bar();
      MFMA_QUAD(0, 0, b0)
      MFMA_QUAD(0, 1, b1)
      if (st1) { vmw<2 * (GA + GB)>(); } else { vmw<0>(); }
      bar();
      // P1: (m1 x n1,n0); stage B0(W+2) into current slot (B0(W) consumed in P0).
      READ_A(s, 1)
      if (st2) stageB(s, 0, kn2);
      bar();
      MFMA_QUAD(1, 1, b1)
      MFMA_QUAD(1, 0, b0)
      if (st2) { vmw<GA + GB>(); } else if (st1) { vmw<GA>(); } else { vmw<0>(); }
      bar();
    }
  }

  // epilogue: acc[M][N].
  // WL=0: M = mh*4+fq, m-off = (M>>2)*64 + (M&3)*16, wave m-base wm*128.
  // WL=1: M = mh*2+fq, m-off = (M>>1)*32 + (M&1)*16, wave m-base wm*64.
  const int mg0 = bx * BM + (WL ? wm * 64 : wm * 128) + ((lane >> 4) << 2);
  const int ng0 = by * BN + wn * 64 + (lane & 15);
  float* red = (float*)&As[0][0][0];  // STATS scratch: BN rows x NSLOTP f32
#pragma unroll
  for (int N = 0; N < 4; ++N) {
    const int n = ng0 + (N >> 1) * 32 + (N & 1) * 16;
    const float bn = (BIAS_MODE == 2) ? bias[n] : 0.f;
    const float sc = SCALEN ? linv[(long)bz * 2304 + n] : 1.0f;
    float eN = 0.f;
#pragma unroll
    for (int M = 0; M < MR; ++M) {
      const int m = mg0 + (WL ? ((M >> 1) * 32 + (M & 1) * 16) : ((M >> 2) * 64 + (M & 3) * 16));
      const f32x4 av = acc[M][N];
      float vals[4];
#pragma unroll
      for (int j = 0; j < 4; ++j) {
        vals[j] = av[j] * alpha + ((BIAS_MODE == 1) ? bias[m + j] : bn);
        if (SCALEN) vals[j] *= sc;
        if (STATS) { vals[j] = __expf(vals[j]); eN += vals[j]; }
      }
      if (OUT_MODE == 0) {
        ushort4 o; o.x = f2bf(vals[0]); o.y = f2bf(vals[1]); o.z = f2bf(vals[2]); o.w = f2bf(vals[3]);
        *(ushort4*)((unsigned short*)Cp + (long)bz * sCz + (long)n * ldc + m) = o;
      } else if (OUT_MODE == 2) {
        int pk = __builtin_amdgcn_cvt_pk_fp8_f32(vals[0], vals[1], 0, false);
        pk = __builtin_amdgcn_cvt_pk_fp8_f32(vals[2], vals[3], pk, true);
        *(int*)((unsigned char*)Cp + (long)bz * sCz + (long)n * ldc + perm64(m)) = pk;
      } else {
        const float* rp = resid + (long)n * ldc + m;
        float4 o; o.x = vals[0] + rp[0]; o.y = vals[1] + rp[1]; o.z = vals[2] + rp[2]; o.w = vals[3] + rp[3];
        *(float4*)((float*)Cp + (long)bz * sCz + (long)n * ldc + m) = o;
      }
    }
    if (STATS) {
      const int nloc = wn * 64 + (N >> 1) * 32 + (N & 1) * 16 + (lane & 15);
      const int slot = wm * 4 + (lane >> 4);
      red[nloc * NSLOTP + slot] = eN;
    }
  }
  if (STATS) {
    bar();
    if (tid < BN) {
      float L = 0.f;
#pragma unroll
      for (int s2 = 0; s2 < NSLOT; ++s2) L += red[tid * NSLOTP + s2];
      rowsums[((long)(bz * gx + bx)) * 2304 + by * BN + tid] = L;
    }
  }
#undef READ_A
#undef READ_B
#undef MFMA_QUAD
}

extern "C" void kernel_launch(void* const* d_in, const int* in_sizes, int n_in,
                              void* d_out, int out_size, void* d_ws, size_t ws_size,
                              hipStream_t stream) {
  const float* x = (const float*)d_in[0];
  const float* gamma = (const float*)d_in[1];
  const float* beta = (const float*)d_in[2];
  const float* wq = (const float*)d_in[3];
  const float* bq = (const float*)d_in[4];
  const float* wk = (const float*)d_in[5];
  const float* bk = (const float*)d_in[6];
  const float* wv = (const float*)d_in[7];
  const float* bv = (const float*)d_in[8];
  const float* wo = (const float*)d_in[9];
  const float* bo = (const float*)d_in[10];
  float* out = (float*)d_out;

  char* ws = (char*)d_ws;
  size_t off = 0;
  auto alloc = [&](size_t bytes) {
    char* p = ws + off;
    off = (off + bytes + 255) & ~(size_t)255;
    return p;
  };
  float* part = (float*)alloc(256 * 2 * sizeof(float));
  float* stats = (float*)alloc(32 * 2 * sizeof(float));
  unsigned short* wqkb = (unsigned short*)alloc((size_t)2 * 262144 * 2);
  unsigned short* wvb = (unsigned short*)alloc((size_t)262144 * 2);
  unsigned short* wob = (unsigned short*)alloc((size_t)262144 * 2);
  float* bqk = (float*)alloc(1024 * sizeof(float));
  float* rowsums = (float*)alloc((size_t)8 * 18 * 2304 * sizeof(float));
  float* linv = (float*)alloc((size_t)18432 * sizeof(float));
  unsigned short* hnT = (unsigned short*)alloc((size_t)18432 * 512 * 2);
  unsigned char* qkA = (unsigned char*)alloc((size_t)18432 * 1024);      // fp8 k-interleaved
  unsigned char* vT = (unsigned char*)alloc((size_t)512 * 18432);        // fp8 k-interleaved
  unsigned char* Sm = (unsigned char*)alloc((size_t)8 * 2304 * 2304);    // fp8 E k-interleaved
  unsigned short* Ob = hnT;  // alias: hnT fully consumed after qk/v GEMMs
  (void)ws_size; (void)in_sizes; (void)n_in; (void)out_size;

  stats_partial_k<<<dim3(256), dim3(256), 0, stream>>>(x, part);
  stats_final_k<<<dim3(1), dim3(64), 0, stream>>>(part, stats);
  gn_transpose_k<<<dim3(8, 288), dim3(256), 0, stream>>>(x, stats, gamma, beta, hnT);
  pack4_bf16_k<<<dim3(256, 4), dim3(256), 0, stream>>>(wq, wk, wv, wo,
                                                       wqkb, wqkb + 262144, wvb, wob);
  pack_bias_k<<<dim3(1), dim3(1024), 0, stream>>>(bq, bk, bqk);

  // qk fused: A=[Wq;Wk] bf16, B=hnT bf16 -> q,k fp8 interleaved [sp][1024].
  // WL=1 bf16 (128x128, 2 blocks/CU): 8x144x(8 XCD) = 1152 blocks MODE1.
  gemm256<128, 1, 2, 0, 0, 1, 0, 1, 1><<<dim3(1152), dim3(256), 0, stream>>>(
      wqkb, 512, 0, hnT, 512, 0, (void*)qkA, 1024, 0, bqk, nullptr, nullptr, nullptr,
      1.0f, 512, 8, 18);
  // v: A=hnT bf16, B=Wv bf16 -> vT fp8 interleaved [co][18432].
  // WL=1 bf16, MODE2: 8 XCD x (gx=18 m-chunk) x (gy=4 n) = 576 blocks.
  gemm256<128, 2, 2, 0, 0, 2, 0, 1, 1><<<dim3(576), dim3(256), 0, stream>>>(
      hnT, 512, 0, wvb, 512, 0, (void*)vT, 18432, 0, bv, nullptr, nullptr, nullptr,
      1.0f, 512, 18, 4);
  // S: per t: A=k fp8, B=q fp8 -> E=exp(alpha*S) fp8 interleaved + rowsums.
  // R19: WL=1 fp8 KU=2 (BK=128, KT=4, 64KB LDS, 2 blocks/CU): 2592 blocks MODE0.
  gemm256<128, 0, 2, 1, 0, 0, 1, 1, 1, 2><<<dim3(2592), dim3(256), 0, stream>>>(
      qkA + 512, 1024, (long)2304 * 1024, qkA, 1024, (long)2304 * 1024, (void*)Sm, 2304,
      (long)2304 * 2304, nullptr, nullptr, rowsums, nullptr,
      0.044194173824159216f, 512, 18, 18);
  combine_k<<<dim3(72), dim3(256), 0, stream>>>(rowsums, linv, 18);
  // PV: per t: A=vT fp8, B=E fp8 -> O bf16 [(t,i)*512+c], rows scaled by linv.
  // WL=1 fp8 KU=1: 4x18x8 = 576 blocks MODE0 (all co-resident; KU=2 would cap
  // 2 blocks/CU -> extra makespan generation, so PV stays KU=1).
  gemm256<128, 0, 0, 0, 1, 0, 1, 1, 1><<<dim3(576), dim3(256), 0, stream>>>(
      vT, 18432, 2304, Sm, 2304, (long)2304 * 2304, (void*)Ob, 512, (long)2304 * 512,
      nullptr, nullptr, nullptr, linv, 1.0f, 2304, 4, 18);
  // final: A=O bf16, B=Wo bf16 -> out[co*18432+sp] = x + acc + bo[co].
  // WL=1 bf16, MODE2: 8 x 18 x 4 = 576 blocks.
  gemm256<128, 2, 1, 0, 0, 2, 0, 1, 1><<<dim3(576), dim3(256), 0, stream>>>(
      Ob, 512, 0, wob, 512, 0, (void*)out, 18432, 0, bo, x, nullptr, nullptr,
      1.0f, 512, 18, 4);
}

// Round 11
// 225.188 us; speedup vs baseline: 1.1847x; 1.0136x over previous
//
#include <hip/hip_runtime.h>
#include <hip/hip_bf16.h>
#include <cstdint>
#include <type_traits>

typedef __attribute__((ext_vector_type(8))) __bf16 bf16x8;
typedef __attribute__((ext_vector_type(4))) float f32x4;
typedef __attribute__((ext_vector_type(2))) long longx2;

struct bf2frag { bf16x8 k0, k1; };

__device__ __forceinline__ float bf2f(unsigned short u) {
  union { uint32_t i; float f; } v; v.i = (uint32_t)u << 16; return v.f;
}
__device__ __forceinline__ unsigned short f2bf(float f) {
  union { float f; uint32_t i; } v{f};
  uint32_t r = v.i + 0x7fffu + ((v.i >> 16) & 1u);
  return (unsigned short)(r >> 16);
}

__device__ __forceinline__ void gll(const void* g, void* l) {
  __builtin_amdgcn_global_load_lds(
      (const __attribute__((address_space(1))) uint32_t*)(uintptr_t)g,
      (__attribute__((address_space(3))) uint32_t*)(uint32_t)(uintptr_t)l,
      16, 0, 0);
}

__device__ __forceinline__ void bar() {
  asm volatile("" ::: "memory");
  __builtin_amdgcn_s_barrier();
  asm volatile("" ::: "memory");
}

#define VMCNT(n) asm volatile("s_waitcnt vmcnt(" #n ")" ::: "memory")

template <int N>
__device__ __forceinline__ void vmw() {
  if constexpr (N == 0) { VMCNT(0); }
  else if constexpr (N == 1) { VMCNT(1); }
  else if constexpr (N == 2) { VMCNT(2); }
  else if constexpr (N == 3) { VMCNT(3); }
  else if constexpr (N == 4) { VMCNT(4); }
  else if constexpr (N == 5) { VMCNT(5); }
  else if constexpr (N == 6) { VMCNT(6); }
  else if constexpr (N == 7) { VMCNT(7); }
  else if constexpr (N == 8) { VMCNT(8); }
  else if constexpr (N == 9) { VMCNT(9); }
  else if constexpr (N == 10) { VMCNT(10); }
  else { VMCNT(12); }
}

__device__ __forceinline__ f32x4 mma(bf16x8 a, bf16x8 b, f32x4 c) {
  return __builtin_amdgcn_mfma_f32_16x16x32_bf16(a, b, c, 0, 0, 0);
}
__device__ __forceinline__ f32x4 mma(long a, long b, f32x4 c) {
  return __builtin_amdgcn_mfma_f32_16x16x32_fp8_fp8(a, b, c, 0, 0, 0);
}
__device__ __forceinline__ f32x4 mmak(const bf2frag& a, const bf2frag& b, f32x4 c, int k2) {
  return k2 ? mma(a.k1, b.k1, c) : mma(a.k0, b.k0, c);
}
__device__ __forceinline__ f32x4 mmak(longx2 a, longx2 b, f32x4 c, int k2) {
  return mma(a[k2], b[k2], c);
}

// k-interleave store permutation for fp8 buffers (unit u=8B: slot p(u)=(u&3)*2+(u>>2))
__device__ __forceinline__ int perm64(int m) {
  return (m & ~63) | (((m >> 3) & 3) << 4) | (((m >> 5) & 1) << 3) | (m & 7);
}

// ---------------- GroupNorm stats ----------------
__global__ __launch_bounds__(256) void stats_partial_k(const float* __restrict__ x,
                                                       float* __restrict__ part) {
  const int g = blockIdx.x >> 3, p = blockIdx.x & 7;
  const float* base = x + (long)g * 16 * 18432 + (long)p * 2304;
  float s = 0.f, ss = 0.f;
  for (int idx = threadIdx.x; idx < 16 * 576; idx += 256) {
    const int c = idx / 576, i4 = idx % 576;
    const float4 v = *(const float4*)(base + (long)c * 18432 + i4 * 4);
    s += v.x + v.y + v.z + v.w;
    ss += v.x * v.x + v.y * v.y + v.z * v.z + v.w * v.w;
  }
  __shared__ float rs[256], rss[256];
  rs[threadIdx.x] = s; rss[threadIdx.x] = ss;
  __syncthreads();
  for (int o = 128; o > 0; o >>= 1) {
    if ((int)threadIdx.x < o) { rs[threadIdx.x] += rs[threadIdx.x + o]; rss[threadIdx.x] += rss[threadIdx.x + o]; }
    __syncthreads();
  }
  if (threadIdx.x == 0) { part[blockIdx.x * 2] = rs[0]; part[blockIdx.x * 2 + 1] = rss[0]; }
}

__global__ void stats_final_k(const float* __restrict__ part, float* __restrict__ stats) {
  const int g = threadIdx.x;
  if (g < 32) {
    float s = 0.f, ss = 0.f;
    for (int p = 0; p < 8; ++p) { s += part[(g * 8 + p) * 2]; ss += part[(g * 8 + p) * 2 + 1]; }
    const float mean = s / 294912.0f;
    const float var = ss / 294912.0f - mean * mean;
    stats[g * 2] = mean;
    stats[g * 2 + 1] = rsqrtf(var + 1e-6f);
  }
}

// ---------------- GN apply + transpose to (spatial, channel) bf16 ----------------
__global__ __launch_bounds__(256) void gn_transpose_k(const float* __restrict__ x,
                                                      const float* __restrict__ stats,
                                                      const float* __restrict__ gamma,
                                                      const float* __restrict__ beta,
                                                      unsigned short* __restrict__ hnT) {
  __shared__ float tile[64][65];
  const int c0 = blockIdx.x * 64, n0 = blockIdx.y * 64;
  const int tn = threadIdx.x & 63, tr = threadIdx.x >> 6;
  for (int cc = tr; cc < 64; cc += 4) {
    const int c = c0 + cc, g = c >> 4;
    const float mean = stats[g * 2], rstd = stats[g * 2 + 1];
    const float v = x[(long)c * 18432 + n0 + tn];
    tile[cc][tn] = (v - mean) * rstd * gamma[c] + beta[c];
  }
  __syncthreads();
  for (int nn = tr; nn < 64; nn += 4) {
    hnT[(long)(n0 + nn) * 512 + c0 + tn] = f2bf(tile[tn][nn]);
  }
}

// ---------------- fp32 -> bf16 weight pack (4 weights in one launch) ----------------
__global__ __launch_bounds__(256) void pack4_bf16_k(const float* __restrict__ w0,
                                                    const float* __restrict__ w1,
                                                    const float* __restrict__ w2,
                                                    const float* __restrict__ w3,
                                                    unsigned short* __restrict__ o0,
                                                    unsigned short* __restrict__ o1,
                                                    unsigned short* __restrict__ o2,
                                                    unsigned short* __restrict__ o3) {
  const int y = blockIdx.y;
  const float* w = (y == 0) ? w0 : (y == 1) ? w1 : (y == 2) ? w2 : w3;
  unsigned short* o = (y == 0) ? o0 : (y == 1) ? o1 : (y == 2) ? o2 : o3;
  const int i = (blockIdx.x * 256 + threadIdx.x) * 4;
  const float4 v = *(const float4*)(w + i);
  ushort4 u; u.x = f2bf(v.x); u.y = f2bf(v.y); u.z = f2bf(v.z); u.w = f2bf(v.w);
  *(ushort4*)(o + i) = u;
}

__global__ void pack_bias_k(const float* __restrict__ bq, const float* __restrict__ bk,
                            float* __restrict__ bqk) {
  const int t = threadIdx.x;
  bqk[t] = (t < 512) ? bq[t] : bk[t - 512];
}

// ---------------- per-row 1/L combine from per-tile sums (NT tiles of rows) ----------------
__global__ __launch_bounds__(256) void combine_k(const float* __restrict__ rs,
                                                 float* __restrict__ linv, int ntile) {
  const int row = blockIdx.x * 256 + threadIdx.x;  // [0, 18432)
  const int t = row / 2304, r = row % 2304;
  float L = 0.f;
  for (int x = 0; x < ntile; ++x) L += rs[((long)(t * ntile + x)) * 2304 + r];
  linv[row] = 1.0f / L;
}

// ================= BMxBNxBK NT GEMM, XCD-swizzled, bf16/fp8 =================
// C[n*ldc+m] = alpha*sum_k A[m,k]*B[n,k] (+bias)(+resid)
// WL=0, BM=256: 512 thr, 8 waves (2m x 4n), 1 block/CU, P2=0, setprio ON.
// WL=1: BM=128 x BN=128, 256 thr, 4 waves (2m x 2n, 64x64/wave).
//   fp8 KU=1: 32KB LDS, bounds(256,4). bf16: 64KB, 2 blocks/CU.
//   R19/R20: KU=2 (BK=128) on S FALSIFIED -- 64KB LDS halves blocks/CU 4->2,
//   S 57.5->64.8us, Occupancy 32->18%. Per-step cost scales with staged bytes,
//   NOT fixed per step; TLP (blocks/CU) is the binding constraint. S reverted
//   to KU=1; KU machinery kept (inert at KU=1), pack4 merge kept (it bought
//   ~7us of launch overhead in R19).
//   Ladder: R13 S 66->58 (TLP), R14 qk (makespan), R15 PV, R17 v+final.
//   A/B halves use 32-row stripe interleave: grow = (r>>5)*64 + h*32 + (r&31).
// P2=1 (2-phase): P0: read A0,B0,B1; stage [A0,B1,A1](W+1) -> s^1; mfma m0x{n0,n1}.
//   P1: read A1; stage B0(W+2) -> s; mfma m1x{n1,n0}.
//   Waits: @P0-end vmcnt(2(GA+GB)); @P1-end vmcnt(GA+GB); tail GA then 0.
// STATS: exp+rowsums, scratch stride NSLOT+1 (R18). SCALEN: *linv[n].
// OUT_MODE: 0 bf16, 1 f32+resid, 2 fp8 e4m3 k-interleaved.
// MODE0: bz=bid%8 per XCD; MODE1/2: XCD y/x-chunking.
template <int BM, int BIAS_MODE, int OUT_MODE, int STATS, int SCALEN, int MODE, int FP8, int P2,
          int WL = 0, int KU = 1>
__global__ __launch_bounds__((BM == 256) ? 512 : 256, (WL && FP8) ? (KU == 2 ? 2 : 4) : 2)
void gemm256(const void* __restrict__ A, long lda, long sAz,
             const void* __restrict__ B, long ldb, long sBz,
             void* __restrict__ Cp, long ldc, long sCz,
             const float* __restrict__ bias,
             const float* __restrict__ resid,
             float* __restrict__ rowsums,
             const float* __restrict__ linv,
             float alpha, int K, int gx, int gy) {
  static_assert(KU == 1 || FP8, "KU=2 only on fp8 path");
  constexpr int EB = FP8 ? 1 : 2;                    // element bytes
  constexpr int THREADS = (BM == 256) ? 512 : 256;
  constexpr int BN = WL ? 128 : 256;                 // n-tile
  constexpr int BK = 64 * KU;                        // k-step
  constexpr int HBA = (BM / 2) * BK * EB;            // bytes per A half
  constexpr int HBB = (BN / 2) * BK * EB;            // bytes per B half
  constexpr int HBA0 = HBA / KU, HBB0 = HBB / KU;    // per 64-k sub-block
  constexpr int GA = HBA / (THREADS * 16);           // gll per A-half stage
  constexpr int GB = HBB / (THREADS * 16);           // gll per B-half stage
  constexpr int GA0 = GA / KU, GB0 = GB / KU;        // gll per 64-k sub-stage
  constexpr int V0 = GB + 2 * GA, V3 = 2 * GB + GA, VP = GB + GA;
  constexpr int NSLOT = WL ? 8 : ((BM == 256) ? 8 : 4);
  constexpr int NSLOTP = NSLOT + 1;                  // R18: odd stride
  constexpr int MR = WL ? 4 : 8;                     // acc M-frags per wave
  constexpr int FQ = WL ? 2 : 4;                     // A-frags per (mh) phase
  constexpr int PRIO = !P2;                          // setprio only on 1-block path
  __shared__ alignas(16) unsigned char As[2][2][HBA];
  __shared__ alignas(16) unsigned char Bs[2][2][HBB];
  using ABt2 = typename std::conditional<FP8, longx2, bf2frag>::type;

  const int tid = threadIdx.x;
  const int lane = tid & 63, wid = tid >> 6;
  const int wm = WL ? (wid >> 1) : ((BM == 256) ? (wid & 1) : 0);
  const int wn = WL ? (wid & 1) : ((BM == 256) ? (wid >> 1) : wid);
  int bx, by, bz;
  {
    const int g8 = blockIdx.x & 7, n = blockIdx.x >> 3;
    if (MODE == 0) { bz = g8; bx = n % gx; by = n / gx; }
    else if (MODE == 1) { bz = 0; bx = n % gx; by = g8 * gy + n / gx; }
    else { bz = 0; by = n % gy; bx = g8 * gx + n / gy; }
  }
  const unsigned char* Ab = (const unsigned char*)A + ((long)bz * sAz + (long)bx * BM * lda) * EB;
  const unsigned char* Bb = (const unsigned char*)B + ((long)bz * sBz + (long)by * BN * ldb) * EB;

  // ---- staging (global -> LDS, pre-swizzled source; fp8 global is k-interleaved) ----
  auto stageA = [&](int slot, int h, int k0) {
    if constexpr (!FP8) {
      const int ksw = ((tid & 7) << 3) ^ (((tid >> 3) & 7) << 3);
#pragma unroll
      for (int call = 0; call < GA; ++call) {
        const int r = call * (THREADS / 8) + (tid >> 3);
        const int grow = WL ? (((r >> 5) << 6) + h * 32 + (r & 31))
                            : (((r >> 6) << 7) + h * 64 + (r & 63));
        gll(Ab + ((long)grow * lda + k0) * 2 + ksw * 2, &As[slot][h][call * THREADS * 16 + tid * 16]);
      }
    } else {
#pragma unroll
      for (int call = 0; call < GA; ++call) {
        const int sub = call / GA0, c0 = call % GA0;
        const int l = c0 * (THREADS / 4) + (tid >> 2);
        const int grow = WL ? (((l >> 5) << 6) + h * 32 + (l & 31))
                            : (((l >> 6) << 7) + h * 64 + (l & 63));
        const int x = (((l & 3) ^ ((l >> 2) & 3)) << 4);
        gll(Ab + (long)grow * lda + k0 + sub * 64 + (((tid & 3) << 4) ^ x),
            &As[slot][h][call * THREADS * 16 + tid * 16]);
      }
    }
  };
  auto stageB = [&](int slot, int h, int k0) {
    if constexpr (!FP8) {
      const int ksw = ((tid & 7) << 3) ^ (((tid >> 3) & 7) << 3);
#pragma unroll
      for (int call = 0; call < GB; ++call) {
        const int r = call * (THREADS / 8) + (tid >> 3);
        const int grow = ((r >> 5) << 6) + h * 32 + (r & 31);
        gll(Bb + ((long)grow * ldb + k0) * 2 + ksw * 2, &Bs[slot][h][call * THREADS * 16 + tid * 16]);
      }
    } else {
#pragma unroll
      for (int call = 0; call < GB; ++call) {
        const int sub = call / GB0, c0 = call % GB0;
        const int l = c0 * (THREADS / 4) + (tid >> 2);
        const int grow = ((l >> 5) << 6) + h * 32 + (l & 31);
        const int x = (((l & 3) ^ ((l >> 2) & 3)) << 4);
        gll(Bb + (long)grow * ldb + k0 + sub * 64 + (((tid & 3) << 4) ^ x),
            &Bs[slot][h][call * THREADS * 16 + tid * 16]);
      }
    }
  };
  // ---- LDS -> fragment reads (same swizzle; fp8 = ONE b128 for both k2 slices) ----
  auto ldA = [&](int slot, int mh, int fq, int sub) -> ABt2 {
    const int r = (WL ? wm * 32 : wm * 64) + fq * 16 + (lane & 15);
    if constexpr (!FP8) {
      bf2frag f;
      const int kk0 = (((lane >> 4) << 3)) ^ ((r & 7) << 3);
      const int kk1 = (32 + ((lane >> 4) << 3)) ^ ((r & 7) << 3);
      f.k0 = *reinterpret_cast<const bf16x8*>(&As[slot][mh][r * 128 + kk0 * 2]);
      f.k1 = *reinterpret_cast<const bf16x8*>(&As[slot][mh][r * 128 + kk1 * 2]);
      return f;
    } else {
      const int x = (((r & 3) ^ ((r >> 2) & 3)) << 4);
      const int kk = ((lane >> 4) << 4) ^ x;
      return *reinterpret_cast<const longx2*>(&As[slot][mh][sub * HBA0 + r * 64 + kk]);
    }
  };
  auto ldB = [&](int slot, int nh, int g, int sub) -> ABt2 {
    const int r = wn * 32 + g * 16 + (lane & 15);
    if constexpr (!FP8) {
      bf2frag f;
      const int kk0 = (((lane >> 4) << 3)) ^ ((r & 7) << 3);
      const int kk1 = (32 + ((lane >> 4) << 3)) ^ ((r & 7) << 3);
      f.k0 = *reinterpret_cast<const bf16x8*>(&Bs[slot][nh][r * 128 + kk0 * 2]);
      f.k1 = *reinterpret_cast<const bf16x8*>(&Bs[slot][nh][r * 128 + kk1 * 2]);
      return f;
    } else {
      const int x = (((r & 3) ^ ((r >> 2) & 3)) << 4);
      const int kk = ((lane >> 4) << 4) ^ x;
      return *reinterpret_cast<const longx2*>(&Bs[slot][nh][sub * HBB0 + r * 64 + kk]);
    }
  };

  f32x4 acc[MR][4] = {};
  ABt2 a[FQ * KU], b0[2 * KU], b1[2 * KU];

#define READ_A(SLOT, MH)                                                       \
  _Pragma("unroll") for (int fq = 0; fq < FQ; ++fq)                            \
    _Pragma("unroll") for (int sub = 0; sub < KU; ++sub)                       \
      a[fq * KU + sub] = ldA(SLOT, MH, fq, sub);
#define READ_B(SLOT, NH, DST)                                                  \
  _Pragma("unroll") for (int g = 0; g < 2; ++g)                                \
    _Pragma("unroll") for (int sub = 0; sub < KU; ++sub)                       \
      DST[g * KU + sub] = ldB(SLOT, NH, g, sub);
#define MFMA_QUAD(MH, NH, BARR)                                                \
  if constexpr (PRIO) __builtin_amdgcn_s_setprio(1);                           \
  _Pragma("unroll") for (int fq = 0; fq < FQ; ++fq)                            \
    _Pragma("unroll") for (int g = 0; g < 2; ++g)                              \
      _Pragma("unroll") for (int sub = 0; sub < KU; ++sub)                     \
        _Pragma("unroll") for (int k2 = 0; k2 < 2; ++k2)                       \
          acc[(MH) * FQ + fq][(NH) * 2 + g] =                                  \
              mmak(a[fq * KU + sub], BARR[g * KU + sub],                       \
                   acc[(MH) * FQ + fq][(NH) * 2 + g], k2);                     \
  if constexpr (PRIO) __builtin_amdgcn_s_setprio(0);

  const int KT = K / BK;
  // Prologue queue: [B0(0), A0(0), B1(0), A1(0), B0(1)] (+A1(1) for P2=0)
  stageB(0, 0, 0);
  stageA(0, 0, 0);
  stageB(0, 1, 0);
  stageA(0, 1, 0);
  stageB(1, 0, BK);
  if constexpr (!P2) stageA(1, 1, BK);
  vmw<VP>();
  bar();

  if constexpr (!P2) {
    for (int W = 0; W < KT; ++W) {
      const int s = W & 1;
      const int kn1 = (W + 1) * BK, kn2 = (W + 2) * BK;
      const bool st1 = (W + 1 < KT), st2 = (W + 2 < KT);
      // p0: (m0,n0)
      READ_A(s, 0)
      READ_B(s, 0, b0)
      if (st1) stageA(s ^ 1, 0, kn1);
      bar();
      MFMA_QUAD(0, 0, b0)
      if (st1) { vmw<V0>(); }
      bar();
      // p1: (m0,n1)
      READ_B(s, 1, b1)
      if (st1) stageB(s ^ 1, 1, kn1);
      bar();
      MFMA_QUAD(0, 1, b1)
      bar();
      // p2: (m1,n1)
      READ_A(s, 1)
      if (st2) stageB(s, 0, kn2);
      bar();
      MFMA_QUAD(1, 1, b1)
      bar();
      // p3: (m1,n0)
      if (st2) stageA(s, 1, kn2);
      bar();
      MFMA_QUAD(1, 0, b0)
      if (st2) { vmw<V3>(); } else { vmw<0>(); }
      bar();
    }
  } else {
    for (int W = 0; W < KT; ++W) {
      const int s = W & 1;
      const int kn1 = (W + 1) * BK, kn2 = (W + 2) * BK;
      const bool st1 = (W + 1 < KT), st2 = (W + 2 < KT);
      // P0: (m0 x n0,n1); stage next A-slot fully + B1(W+1). A1 issued LAST.
      READ_A(s, 0)
      READ_B(s, 0, b0)
      READ_B(s, 1, b1)
      if (st1) { stageA(s ^ 1, 0, kn1); stageB(s ^ 1, 1, kn1); stageA(s ^ 1, 1, kn1); }
      bar();
      MFMA_QUAD(0, 0, b0)
      MFMA_QUAD(0, 1, b1)
      if (st1) { vmw<2 * (GA + GB)>(); } else { vmw<0>(); }
      bar();
      // P1: (m1 x n1,n0); stage B0(W+2) into current slot (B0(W) consumed in P0).
      READ_A(s, 1)
      if (st2) stageB(s, 0, kn2);
      bar();
      MFMA_QUAD(1, 1, b1)
      MFMA_QUAD(1, 0, b0)
      if (st2) { vmw<GA + GB>(); } else if (st1) { vmw<GA>(); } else { vmw<0>(); }
      bar();
    }
  }

  // epilogue: acc[M][N].
  // WL=0: M = mh*4+fq, m-off = (M>>2)*64 + (M&3)*16, wave m-base wm*128.
  // WL=1: M = mh*2+fq, m-off = (M>>1)*32 + (M&1)*16, wave m-base wm*64.
  const int mg0 = bx * BM + (WL ? wm * 64 : wm * 128) + ((lane >> 4) << 2);
  const int ng0 = by * BN + wn * 64 + (lane & 15);
  float* red = (float*)&As[0][0][0];  // STATS scratch: BN rows x NSLOTP f32
#pragma unroll
  for (int N = 0; N < 4; ++N) {
    const int n = ng0 + (N >> 1) * 32 + (N & 1) * 16;
    const float bn = (BIAS_MODE == 2) ? bias[n] : 0.f;
    const float sc = SCALEN ? linv[(long)bz * 2304 + n] : 1.0f;
    float eN = 0.f;
#pragma unroll
    for (int M = 0; M < MR; ++M) {
      const int m = mg0 + (WL ? ((M >> 1) * 32 + (M & 1) * 16) : ((M >> 2) * 64 + (M & 3) * 16));
      const f32x4 av = acc[M][N];
      float vals[4];
#pragma unroll
      for (int j = 0; j < 4; ++j) {
        vals[j] = av[j] * alpha + ((BIAS_MODE == 1) ? bias[m + j] : bn);
        if (SCALEN) vals[j] *= sc;
        if (STATS) { vals[j] = __expf(vals[j]); eN += vals[j]; }
      }
      if (OUT_MODE == 0) {
        ushort4 o; o.x = f2bf(vals[0]); o.y = f2bf(vals[1]); o.z = f2bf(vals[2]); o.w = f2bf(vals[3]);
        *(ushort4*)((unsigned short*)Cp + (long)bz * sCz + (long)n * ldc + m) = o;
      } else if (OUT_MODE == 2) {
        int pk = __builtin_amdgcn_cvt_pk_fp8_f32(vals[0], vals[1], 0, false);
        pk = __builtin_amdgcn_cvt_pk_fp8_f32(vals[2], vals[3], pk, true);
        *(int*)((unsigned char*)Cp + (long)bz * sCz + (long)n * ldc + perm64(m)) = pk;
      } else {
        const float* rp = resid + (long)n * ldc + m;
        float4 o; o.x = vals[0] + rp[0]; o.y = vals[1] + rp[1]; o.z = vals[2] + rp[2]; o.w = vals[3] + rp[3];
        *(float4*)((float*)Cp + (long)bz * sCz + (long)n * ldc + m) = o;
      }
    }
    if (STATS) {
      const int nloc = wn * 64 + (N >> 1) * 32 + (N & 1) * 16 + (lane & 15);
      const int slot = wm * 4 + (lane >> 4);
      red[nloc * NSLOTP + slot] = eN;
    }
  }
  if (STATS) {
    bar();
    if (tid < BN) {
      float L = 0.f;
#pragma unroll
      for (int s2 = 0; s2 < NSLOT; ++s2) L += red[tid * NSLOTP + s2];
      rowsums[((long)(bz * gx + bx)) * 2304 + by * BN + tid] = L;
    }
  }
#undef READ_A
#undef READ_B
#undef MFMA_QUAD
}

extern "C" void kernel_launch(void* const* d_in, const int* in_sizes, int n_in,
                              void* d_out, int out_size, void* d_ws, size_t ws_size,
                              hipStream_t stream) {
  const float* x = (const float*)d_in[0];
  const float* gamma = (const float*)d_in[1];
  const float* beta = (const float*)d_in[2];
  const float* wq = (const float*)d_in[3];
  const float* bq = (const float*)d_in[4];
  const float* wk = (const float*)d_in[5];
  const float* bk = (const float*)d_in[6];
  const float* wv = (const float*)d_in[7];
  const float* bv = (const float*)d_in[8];
  const float* wo = (const float*)d_in[9];
  const float* bo = (const float*)d_in[10];
  float* out = (float*)d_out;

  char* ws = (char*)d_ws;
  size_t off = 0;
  auto alloc = [&](size_t bytes) {
    char* p = ws + off;
    off = (off + bytes + 255) & ~(size_t)255;
    return p;
  };
  float* part = (float*)alloc(256 * 2 * sizeof(float));
  float* stats = (float*)alloc(32 * 2 * sizeof(float));
  unsigned short* wqkb = (unsigned short*)alloc((size_t)2 * 262144 * 2);
  unsigned short* wvb = (unsigned short*)alloc((size_t)262144 * 2);
  unsigned short* wob = (unsigned short*)alloc((size_t)262144 * 2);
  float* bqk = (float*)alloc(1024 * sizeof(float));
  float* rowsums = (float*)alloc((size_t)8 * 18 * 2304 * sizeof(float));
  float* linv = (float*)alloc((size_t)18432 * sizeof(float));
  unsigned short* hnT = (unsigned short*)alloc((size_t)18432 * 512 * 2);
  unsigned char* qkA = (unsigned char*)alloc((size_t)18432 * 1024);      // fp8 k-interleaved
  unsigned char* vT = (unsigned char*)alloc((size_t)512 * 18432);        // fp8 k-interleaved
  unsigned char* Sm = (unsigned char*)alloc((size_t)8 * 2304 * 2304);    // fp8 E k-interleaved
  unsigned short* Ob = hnT;  // alias: hnT fully consumed after qk/v GEMMs
  (void)ws_size; (void)in_sizes; (void)n_in; (void)out_size;

  stats_partial_k<<<dim3(256), dim3(256), 0, stream>>>(x, part);
  stats_final_k<<<dim3(1), dim3(64), 0, stream>>>(part, stats);
  gn_transpose_k<<<dim3(8, 288), dim3(256), 0, stream>>>(x, stats, gamma, beta, hnT);
  pack4_bf16_k<<<dim3(256, 4), dim3(256), 0, stream>>>(wq, wk, wv, wo,
                                                       wqkb, wqkb + 262144, wvb, wob);
  pack_bias_k<<<dim3(1), dim3(1024), 0, stream>>>(bq, bk, bqk);

  // qk fused: A=[Wq;Wk] bf16, B=hnT bf16 -> q,k fp8 interleaved [sp][1024].
  // WL=1 bf16 (128x128, 2 blocks/CU): 8x144x(8 XCD) = 1152 blocks MODE1.
  gemm256<128, 1, 2, 0, 0, 1, 0, 1, 1><<<dim3(1152), dim3(256), 0, stream>>>(
      wqkb, 512, 0, hnT, 512, 0, (void*)qkA, 1024, 0, bqk, nullptr, nullptr, nullptr,
      1.0f, 512, 8, 18);
  // v: A=hnT bf16, B=Wv bf16 -> vT fp8 interleaved [co][18432].
  // WL=1 bf16, MODE2: 8 XCD x (gx=18 m-chunk) x (gy=4 n) = 576 blocks.
  gemm256<128, 2, 2, 0, 0, 2, 0, 1, 1><<<dim3(576), dim3(256), 0, stream>>>(
      hnT, 512, 0, wvb, 512, 0, (void*)vT, 18432, 0, bv, nullptr, nullptr, nullptr,
      1.0f, 512, 18, 4);
  // S: per t: A=k fp8, B=q fp8 -> E=exp(alpha*S) fp8 interleaved + rowsums.
  // R20: back to WL=1 fp8 KU=1 (32KB LDS, 4 blocks/CU): 2592 blocks MODE0.
  gemm256<128, 0, 2, 1, 0, 0, 1, 1, 1><<<dim3(2592), dim3(256), 0, stream>>>(
      qkA + 512, 1024, (long)2304 * 1024, qkA, 1024, (long)2304 * 1024, (void*)Sm, 2304,
      (long)2304 * 2304, nullptr, nullptr, rowsums, nullptr,
      0.044194173824159216f, 512, 18, 18);
  combine_k<<<dim3(72), dim3(256), 0, stream>>>(rowsums, linv, 18);
  // PV: per t: A=vT fp8, B=E fp8 -> O bf16 [(t,i)*512+c], rows scaled by linv.
  // WL=1 fp8 KU=1: 4x18x8 = 576 blocks MODE0.
  gemm256<128, 0, 0, 0, 1, 0, 1, 1, 1><<<dim3(576), dim3(256), 0, stream>>>(
      vT, 18432, 2304, Sm, 2304, (long)2304 * 2304, (void*)Ob, 512, (long)2304 * 512,
      nullptr, nullptr, nullptr, linv, 1.0f, 2304, 4, 18);
  // final: A=O bf16, B=Wo bf16 -> out[co*18432+sp] = x + acc + bo[co].
  // WL=1 bf16, MODE2: 8 x 18 x 4 = 576 blocks.
  gemm256<128, 2, 1, 0, 0, 2, 0, 1, 1><<<dim3(576), dim3(256), 0, stream>>>(
      Ob, 512, 0, wob, 512, 0, (void*)out, 18432, 0, bo, x, nullptr, nullptr,
      1.0f, 512, 18, 4);
}

// Round 12
// 220.608 us; speedup vs baseline: 1.2093x; 1.0208x over previous
//
#include <hip/hip_runtime.h>
#include <hip/hip_bf16.h>
#include <cstdint>
#include <type_traits>

typedef __attribute__((ext_vector_type(8))) __bf16 bf16x8;
typedef __attribute__((ext_vector_type(4))) float f32x4;
typedef __attribute__((ext_vector_type(2))) long longx2;

struct bf2frag { bf16x8 k0, k1; };

__device__ __forceinline__ float bf2f(unsigned short u) {
  union { uint32_t i; float f; } v; v.i = (uint32_t)u << 16; return v.f;
}
__device__ __forceinline__ unsigned short f2bf(float f) {
  union { float f; uint32_t i; } v{f};
  uint32_t r = v.i + 0x7fffu + ((v.i >> 16) & 1u);
  return (unsigned short)(r >> 16);
}

__device__ __forceinline__ void gll(const void* g, void* l) {
  __builtin_amdgcn_global_load_lds(
      (const __attribute__((address_space(1))) uint32_t*)(uintptr_t)g,
      (__attribute__((address_space(3))) uint32_t*)(uint32_t)(uintptr_t)l,
      16, 0, 0);
}

__device__ __forceinline__ void bar() {
  asm volatile("" ::: "memory");
  __builtin_amdgcn_s_barrier();
  asm volatile("" ::: "memory");
}

#define VMCNT(n) asm volatile("s_waitcnt vmcnt(" #n ")" ::: "memory")

template <int N>
__device__ __forceinline__ void vmw() {
  if constexpr (N == 0) { VMCNT(0); }
  else if constexpr (N == 1) { VMCNT(1); }
  else if constexpr (N == 2) { VMCNT(2); }
  else if constexpr (N == 3) { VMCNT(3); }
  else if constexpr (N == 4) { VMCNT(4); }
  else if constexpr (N == 5) { VMCNT(5); }
  else if constexpr (N == 6) { VMCNT(6); }
  else if constexpr (N == 7) { VMCNT(7); }
  else if constexpr (N == 8) { VMCNT(8); }
  else if constexpr (N == 9) { VMCNT(9); }
  else if constexpr (N == 10) { VMCNT(10); }
  else { VMCNT(12); }
}

__device__ __forceinline__ f32x4 mma(bf16x8 a, bf16x8 b, f32x4 c) {
  return __builtin_amdgcn_mfma_f32_16x16x32_bf16(a, b, c, 0, 0, 0);
}
__device__ __forceinline__ f32x4 mma(long a, long b, f32x4 c) {
  return __builtin_amdgcn_mfma_f32_16x16x32_fp8_fp8(a, b, c, 0, 0, 0);
}
__device__ __forceinline__ f32x4 mmak(const bf2frag& a, const bf2frag& b, f32x4 c, int k2) {
  return k2 ? mma(a.k1, b.k1, c) : mma(a.k0, b.k0, c);
}
__device__ __forceinline__ f32x4 mmak(longx2 a, longx2 b, f32x4 c, int k2) {
  return mma(a[k2], b[k2], c);
}

// k-interleave store permutation for fp8 buffers (unit u=8B: slot p(u)=(u&3)*2+(u>>2))
__device__ __forceinline__ int perm64(int m) {
  return (m & ~63) | (((m >> 3) & 3) << 4) | (((m >> 5) & 1) << 3) | (m & 7);
}

// ---------------- GroupNorm stats ----------------
__global__ __launch_bounds__(256) void stats_partial_k(const float* __restrict__ x,
                                                       float* __restrict__ part) {
  const int g = blockIdx.x >> 3, p = blockIdx.x & 7;
  const float* base = x + (long)g * 16 * 18432 + (long)p * 2304;
  float s = 0.f, ss = 0.f;
  for (int idx = threadIdx.x; idx < 16 * 576; idx += 256) {
    const int c = idx / 576, i4 = idx % 576;
    const float4 v = *(const float4*)(base + (long)c * 18432 + i4 * 4);
    s += v.x + v.y + v.z + v.w;
    ss += v.x * v.x + v.y * v.y + v.z * v.z + v.w * v.w;
  }
  __shared__ float rs[256], rss[256];
  rs[threadIdx.x] = s; rss[threadIdx.x] = ss;
  __syncthreads();
  for (int o = 128; o > 0; o >>= 1) {
    if ((int)threadIdx.x < o) { rs[threadIdx.x] += rs[threadIdx.x + o]; rss[threadIdx.x] += rss[threadIdx.x + o]; }
    __syncthreads();
  }
  if (threadIdx.x == 0) { part[blockIdx.x * 2] = rs[0]; part[blockIdx.x * 2 + 1] = rss[0]; }
}

// ---------------- GN apply + transpose to (spatial, channel) bf16 ----------------
// R21: stats_final folded in -- each block reduces part[] for its own 4 groups.
__global__ __launch_bounds__(256) void gn_transpose_k(const float* __restrict__ x,
                                                      const float* __restrict__ part,
                                                      const float* __restrict__ gamma,
                                                      const float* __restrict__ beta,
                                                      unsigned short* __restrict__ hnT) {
  __shared__ float tile[64][65];
  __shared__ float sm[4], sr[4];
  const int c0 = blockIdx.x * 64, n0 = blockIdx.y * 64;
  const int tn = threadIdx.x & 63, tr = threadIdx.x >> 6;
  if (threadIdx.x < 4) {
    const int g = (c0 >> 4) + threadIdx.x;
    float s = 0.f, ss = 0.f;
    for (int p = 0; p < 8; ++p) { s += part[(g * 8 + p) * 2]; ss += part[(g * 8 + p) * 2 + 1]; }
    const float mean = s / 294912.0f;
    const float var = ss / 294912.0f - mean * mean;
    sm[threadIdx.x] = mean;
    sr[threadIdx.x] = rsqrtf(var + 1e-6f);
  }
  __syncthreads();
  for (int cc = tr; cc < 64; cc += 4) {
    const int c = c0 + cc;
    const float mean = sm[cc >> 4], rstd = sr[cc >> 4];
    const float v = x[(long)c * 18432 + n0 + tn];
    tile[cc][tn] = (v - mean) * rstd * gamma[c] + beta[c];
  }
  __syncthreads();
  for (int nn = tr; nn < 64; nn += 4) {
    hnT[(long)(n0 + nn) * 512 + c0 + tn] = f2bf(tile[tn][nn]);
  }
}

// ---------------- fp32 -> bf16 weight pack (4 weights + qk-bias in one launch) ----------------
__global__ __launch_bounds__(256) void pack4_bf16_k(const float* __restrict__ w0,
                                                    const float* __restrict__ w1,
                                                    const float* __restrict__ w2,
                                                    const float* __restrict__ w3,
                                                    unsigned short* __restrict__ o0,
                                                    unsigned short* __restrict__ o1,
                                                    unsigned short* __restrict__ o2,
                                                    unsigned short* __restrict__ o3,
                                                    const float* __restrict__ bq,
                                                    const float* __restrict__ bk,
                                                    float* __restrict__ bqk) {
  const int y = blockIdx.y;
  if (y == 4) {  // R21: pack_bias folded in (block 0 only)
    if (blockIdx.x == 0) {
      const int i = threadIdx.x * 4;
#pragma unroll
      for (int j = 0; j < 4; ++j) {
        const int t = i + j;
        bqk[t] = (t < 512) ? bq[t] : bk[t - 512];
      }
    }
    return;
  }
  const float* w = (y == 0) ? w0 : (y == 1) ? w1 : (y == 2) ? w2 : w3;
  unsigned short* o = (y == 0) ? o0 : (y == 1) ? o1 : (y == 2) ? o2 : o3;
  const int i = (blockIdx.x * 256 + threadIdx.x) * 4;
  const float4 v = *(const float4*)(w + i);
  ushort4 u; u.x = f2bf(v.x); u.y = f2bf(v.y); u.z = f2bf(v.z); u.w = f2bf(v.w);
  *(ushort4*)(o + i) = u;
}

// ================= BMxBNxBK NT GEMM, XCD-swizzled, bf16/fp8 =================
// C[n*ldc+m] = alpha*sum_k A[m,k]*B[n,k] (+bias)(+resid)
// WL=0, BM=256: 512 thr, 8 waves (2m x 4n), 1 block/CU, P2=0, setprio ON.
// WL=1: BM=128 x BN=128, 256 thr, 4 waves (2m x 2n, 64x64/wave).
//   fp8 KU=1: 32KB LDS, bounds(256,4). bf16: 64KB, 2 blocks/CU.
//   R19/R20: KU=2 on S FALSIFIED (LDS halves blocks/CU, TLP is binding).
//   Ladder: R13 S (TLP), R14 qk (makespan), R15 PV, R17 v+final, R18 scratch
//   pad, R20 KU revert + pack4 (launch overhead ~2.3us each).
//   A/B halves use 32-row stripe interleave: grow = (r>>5)*64 + h*32 + (r&31).
// P2=1 (2-phase): P0: read A0,B0,B1; stage [A0,B1,A1](W+1) -> s^1; mfma m0x{n0,n1}.
//   P1: read A1; stage B0(W+2) -> s; mfma m1x{n1,n0}.
//   Waits: @P0-end vmcnt(2(GA+GB)); @P1-end vmcnt(GA+GB); tail GA then 0.
// STATS: exp+rowsums, scratch stride NSLOT+1 (R18).
// SCALEN: 1 = *linv[n] from global; 2 (R21) = combine folded in -- prologue
//   computes 1/L for this block's BN rows from rowsums (ntile=K/BN, stride=K)
//   into linvs[] LDS BEFORE staging (scalar loads drain before gll FIFO).
// OUT_MODE: 0 bf16, 1 f32+resid, 2 fp8 e4m3 k-interleaved.
// MODE0: bz=bid%8 per XCD; MODE1/2: XCD y/x-chunking.
template <int BM, int BIAS_MODE, int OUT_MODE, int STATS, int SCALEN, int MODE, int FP8, int P2,
          int WL = 0, int KU = 1>
__global__ __launch_bounds__((BM == 256) ? 512 : 256, (WL && FP8) ? (KU == 2 ? 2 : 4) : 2)
void gemm256(const void* __restrict__ A, long lda, long sAz,
             const void* __restrict__ B, long ldb, long sBz,
             void* __restrict__ Cp, long ldc, long sCz,
             const float* __restrict__ bias,
             const float* __restrict__ resid,
             float* __restrict__ rowsums,
             const float* __restrict__ linv,
             float alpha, int K, int gx, int gy) {
  static_assert(KU == 1 || FP8, "KU=2 only on fp8 path");
  constexpr int EB = FP8 ? 1 : 2;                    // element bytes
  constexpr int THREADS = (BM == 256) ? 512 : 256;
  constexpr int BN = WL ? 128 : 256;                 // n-tile
  constexpr int BK = 64 * KU;                        // k-step
  constexpr int HBA = (BM / 2) * BK * EB;            // bytes per A half
  constexpr int HBB = (BN / 2) * BK * EB;            // bytes per B half
  constexpr int HBA0 = HBA / KU, HBB0 = HBB / KU;    // per 64-k sub-block
  constexpr int GA = HBA / (THREADS * 16);           // gll per A-half stage
  constexpr int GB = HBB / (THREADS * 16);           // gll per B-half stage
  constexpr int GA0 = GA / KU, GB0 = GB / KU;        // gll per 64-k sub-stage
  constexpr int V0 = GB + 2 * GA, V3 = 2 * GB + GA, VP = GB + GA;
  constexpr int NSLOT = WL ? 8 : ((BM == 256) ? 8 : 4);
  constexpr int NSLOTP = NSLOT + 1;                  // R18: odd stride
  constexpr int MR = WL ? 4 : 8;                     // acc M-frags per wave
  constexpr int FQ = WL ? 2 : 4;                     // A-frags per (mh) phase
  constexpr int PRIO = !P2;                          // setprio only on 1-block path
  __shared__ alignas(16) unsigned char As[2][2][HBA];
  __shared__ alignas(16) unsigned char Bs[2][2][HBB];
  __shared__ float linvs[SCALEN == 2 ? BN : 1];
  using ABt2 = typename std::conditional<FP8, longx2, bf2frag>::type;

  const int tid = threadIdx.x;
  const int lane = tid & 63, wid = tid >> 6;
  const int wm = WL ? (wid >> 1) : ((BM == 256) ? (wid & 1) : 0);
  const int wn = WL ? (wid & 1) : ((BM == 256) ? (wid >> 1) : wid);
  int bx, by, bz;
  {
    const int g8 = blockIdx.x & 7, n = blockIdx.x >> 3;
    if (MODE == 0) { bz = g8; bx = n % gx; by = n / gx; }
    else if (MODE == 1) { bz = 0; bx = n % gx; by = g8 * gy + n / gx; }
    else { bz = 0; by = n % gy; bx = g8 * gx + n / gy; }
  }
  const unsigned char* Ab = (const unsigned char*)A + ((long)bz * sAz + (long)bx * BM * lda) * EB;
  const unsigned char* Bb = (const unsigned char*)B + ((long)bz * sBz + (long)by * BN * ldb) * EB;

  // R21 (SCALEN==2): fold combine -- compute 1/L for this block's rows first,
  // so the scalar loads retire before any gll enters the vmcnt FIFO.
  if constexpr (SCALEN == 2) {
    if (tid < BN) {
      const int ntile = K / BN;
      float L = 0.f;
      for (int xx = 0; xx < ntile; ++xx)
        L += rowsums[((long)(bz * ntile + xx)) * K + by * BN + tid];
      linvs[tid] = 1.0f / L;
    }
  }

  // ---- staging (global -> LDS, pre-swizzled source; fp8 global is k-interleaved) ----
  auto stageA = [&](int slot, int h, int k0) {
    if constexpr (!FP8) {
      const int ksw = ((tid & 7) << 3) ^ (((tid >> 3) & 7) << 3);
#pragma unroll
      for (int call = 0; call < GA; ++call) {
        const int r = call * (THREADS / 8) + (tid >> 3);
        const int grow = WL ? (((r >> 5) << 6) + h * 32 + (r & 31))
                            : (((r >> 6) << 7) + h * 64 + (r & 63));
        gll(Ab + ((long)grow * lda + k0) * 2 + ksw * 2, &As[slot][h][call * THREADS * 16 + tid * 16]);
      }
    } else {
#pragma unroll
      for (int call = 0; call < GA; ++call) {
        const int sub = call / GA0, c0 = call % GA0;
        const int l = c0 * (THREADS / 4) + (tid >> 2);
        const int grow = WL ? (((l >> 5) << 6) + h * 32 + (l & 31))
                            : (((l >> 6) << 7) + h * 64 + (l & 63));
        const int x = (((l & 3) ^ ((l >> 2) & 3)) << 4);
        gll(Ab + (long)grow * lda + k0 + sub * 64 + (((tid & 3) << 4) ^ x),
            &As[slot][h][call * THREADS * 16 + tid * 16]);
      }
    }
  };
  auto stageB = [&](int slot, int h, int k0) {
    if constexpr (!FP8) {
      const int ksw = ((tid & 7) << 3) ^ (((tid >> 3) & 7) << 3);
#pragma unroll
      for (int call = 0; call < GB; ++call) {
        const int r = call * (THREADS / 8) + (tid >> 3);
        const int grow = ((r >> 5) << 6) + h * 32 + (r & 31);
        gll(Bb + ((long)grow * ldb + k0) * 2 + ksw * 2, &Bs[slot][h][call * THREADS * 16 + tid * 16]);
      }
    } else {
#pragma unroll
      for (int call = 0; call < GB; ++call) {
        const int sub = call / GB0, c0 = call % GB0;
        const int l = c0 * (THREADS / 4) + (tid >> 2);
        const int grow = ((l >> 5) << 6) + h * 32 + (l & 31);
        const int x = (((l & 3) ^ ((l >> 2) & 3)) << 4);
        gll(Bb + (long)grow * ldb + k0 + sub * 64 + (((tid & 3) << 4) ^ x),
            &Bs[slot][h][call * THREADS * 16 + tid * 16]);
      }
    }
  };
  // ---- LDS -> fragment reads (same swizzle; fp8 = ONE b128 for both k2 slices) ----
  auto ldA = [&](int slot, int mh, int fq, int sub) -> ABt2 {
    const int r = (WL ? wm * 32 : wm * 64) + fq * 16 + (lane & 15);
    if constexpr (!FP8) {
      bf2frag f;
      const int kk0 = (((lane >> 4) << 3)) ^ ((r & 7) << 3);
      const int kk1 = (32 + ((lane >> 4) << 3)) ^ ((r & 7) << 3);
      f.k0 = *reinterpret_cast<const bf16x8*>(&As[slot][mh][r * 128 + kk0 * 2]);
      f.k1 = *reinterpret_cast<const bf16x8*>(&As[slot][mh][r * 128 + kk1 * 2]);
      return f;
    } else {
      const int x = (((r & 3) ^ ((r >> 2) & 3)) << 4);
      const int kk = ((lane >> 4) << 4) ^ x;
      return *reinterpret_cast<const longx2*>(&As[slot][mh][sub * HBA0 + r * 64 + kk]);
    }
  };
  auto ldB = [&](int slot, int nh, int g, int sub) -> ABt2 {
    const int r = wn * 32 + g * 16 + (lane & 15);
    if constexpr (!FP8) {
      bf2frag f;
      const int kk0 = (((lane >> 4) << 3)) ^ ((r & 7) << 3);
      const int kk1 = (32 + ((lane >> 4) << 3)) ^ ((r & 7) << 3);
      f.k0 = *reinterpret_cast<const bf16x8*>(&Bs[slot][nh][r * 128 + kk0 * 2]);
      f.k1 = *reinterpret_cast<const bf16x8*>(&Bs[slot][nh][r * 128 + kk1 * 2]);
      return f;
    } else {
      const int x = (((r & 3) ^ ((r >> 2) & 3)) << 4);
      const int kk = ((lane >> 4) << 4) ^ x;
      return *reinterpret_cast<const longx2*>(&Bs[slot][nh][sub * HBB0 + r * 64 + kk]);
    }
  };

  f32x4 acc[MR][4] = {};
  ABt2 a[FQ * KU], b0[2 * KU], b1[2 * KU];

#define READ_A(SLOT, MH)                                                       \
  _Pragma("unroll") for (int fq = 0; fq < FQ; ++fq)                            \
    _Pragma("unroll") for (int sub = 0; sub < KU; ++sub)                       \
      a[fq * KU + sub] = ldA(SLOT, MH, fq, sub);
#define READ_B(SLOT, NH, DST)                                                  \
  _Pragma("unroll") for (int g = 0; g < 2; ++g)                                \
    _Pragma("unroll") for (int sub = 0; sub < KU; ++sub)                       \
      DST[g * KU + sub] = ldB(SLOT, NH, g, sub);
#define MFMA_QUAD(MH, NH, BARR)                                                \
  if constexpr (PRIO) __builtin_amdgcn_s_setprio(1);                           \
  _Pragma("unroll") for (int fq = 0; fq < FQ; ++fq)                            \
    _Pragma("unroll") for (int g = 0; g < 2; ++g)                              \
      _Pragma("unroll") for (int sub = 0; sub < KU; ++sub)                     \
        _Pragma("unroll") for (int k2 = 0; k2 < 2; ++k2)                       \
          acc[(MH) * FQ + fq][(NH) * 2 + g] =                                  \
              mmak(a[fq * KU + sub], BARR[g * KU + sub],                       \
                   acc[(MH) * FQ + fq][(NH) * 2 + g], k2);                     \
  if constexpr (PRIO) __builtin_amdgcn_s_setprio(0);

  const int KT = K / BK;
  // Prologue queue: [B0(0), A0(0), B1(0), A1(0), B0(1)] (+A1(1) for P2=0)
  stageB(0, 0, 0);
  stageA(0, 0, 0);
  stageB(0, 1, 0);
  stageA(0, 1, 0);
  stageB(1, 0, BK);
  if constexpr (!P2) stageA(1, 1, BK);
  vmw<VP>();
  bar();

  if constexpr (!P2) {
    for (int W = 0; W < KT; ++W) {
      const int s = W & 1;
      const int kn1 = (W + 1) * BK, kn2 = (W + 2) * BK;
      const bool st1 = (W + 1 < KT), st2 = (W + 2 < KT);
      // p0: (m0,n0)
      READ_A(s, 0)
      READ_B(s, 0, b0)
      if (st1) stageA(s ^ 1, 0, kn1);
      bar();
      MFMA_QUAD(0, 0, b0)
      if (st1) { vmw<V0>(); }
      bar();
      // p1: (m0,n1)
      READ_B(s, 1, b1)
      if (st1) stageB(s ^ 1, 1, kn1);
      bar();
      MFMA_QUAD(0, 1, b1)
      bar();
      // p2: (m1,n1)
      READ_A(s, 1)
      if (st2) stageB(s, 0, kn2);
      bar();
      MFMA_QUAD(1, 1, b1)
      bar();
      // p3: (m1,n0)
      if (st2) stageA(s, 1, kn2);
      bar();
      MFMA_QUAD(1, 0, b0)
      if (st2) { vmw<V3>(); } else { vmw<0>(); }
      bar();
    }
  } else {
    for (int W = 0; W < KT; ++W) {
      const int s = W & 1;
      const int kn1 = (W + 1) * BK, kn2 = (W + 2) * BK;
      const bool st1 = (W + 1 < KT), st2 = (W + 2 < KT);
      // P0: (m0 x n0,n1); stage next A-slot fully + B1(W+1). A1 issued LAST.
      READ_A(s, 0)
      READ_B(s, 0, b0)
      READ_B(s, 1, b1)
      if (st1) { stageA(s ^ 1, 0, kn1); stageB(s ^ 1, 1, kn1); stageA(s ^ 1, 1, kn1); }
      bar();
      MFMA_QUAD(0, 0, b0)
      MFMA_QUAD(0, 1, b1)
      if (st1) { vmw<2 * (GA + GB)>(); } else { vmw<0>(); }
      bar();
      // P1: (m1 x n1,n0); stage B0(W+2) into current slot (B0(W) consumed in P0).
      READ_A(s, 1)
      if (st2) stageB(s, 0, kn2);
      bar();
      MFMA_QUAD(1, 1, b1)
      MFMA_QUAD(1, 0, b0)
      if (st2) { vmw<GA + GB>(); } else if (st1) { vmw<GA>(); } else { vmw<0>(); }
      bar();
    }
  }

  // epilogue: acc[M][N].
  // WL=0: M = mh*4+fq, m-off = (M>>2)*64 + (M&3)*16, wave m-base wm*128.
  // WL=1: M = mh*2+fq, m-off = (M>>1)*32 + (M&1)*16, wave m-base wm*64.
  const int mg0 = bx * BM + (WL ? wm * 64 : wm * 128) + ((lane >> 4) << 2);
  const int ng0 = by * BN + wn * 64 + (lane & 15);
  float* red = (float*)&As[0][0][0];  // STATS scratch: BN rows x NSLOTP f32
#pragma unroll
  for (int N = 0; N < 4; ++N) {
    const int n = ng0 + (N >> 1) * 32 + (N & 1) * 16;
    const float bn = (BIAS_MODE == 2) ? bias[n] : 0.f;
    const float sc = (SCALEN == 1) ? linv[(long)bz * 2304 + n]
                   : (SCALEN == 2) ? linvs[n - by * BN] : 1.0f;
    float eN = 0.f;
#pragma unroll
    for (int M = 0; M < MR; ++M) {
      const int m = mg0 + (WL ? ((M >> 1) * 32 + (M & 1) * 16) : ((M >> 2) * 64 + (M & 3) * 16));
      const f32x4 av = acc[M][N];
      float vals[4];
#pragma unroll
      for (int j = 0; j < 4; ++j) {
        vals[j] = av[j] * alpha + ((BIAS_MODE == 1) ? bias[m + j] : bn);
        if (SCALEN) vals[j] *= sc;
        if (STATS) { vals[j] = __expf(vals[j]); eN += vals[j]; }
      }
      if (OUT_MODE == 0) {
        ushort4 o; o.x = f2bf(vals[0]); o.y = f2bf(vals[1]); o.z = f2bf(vals[2]); o.w = f2bf(vals[3]);
        *(ushort4*)((unsigned short*)Cp + (long)bz * sCz + (long)n * ldc + m) = o;
      } else if (OUT_MODE == 2) {
        int pk = __builtin_amdgcn_cvt_pk_fp8_f32(vals[0], vals[1], 0, false);
        pk = __builtin_amdgcn_cvt_pk_fp8_f32(vals[2], vals[3], pk, true);
        *(int*)((unsigned char*)Cp + (long)bz * sCz + (long)n * ldc + perm64(m)) = pk;
      } else {
        const float* rp = resid + (long)n * ldc + m;
        float4 o; o.x = vals[0] + rp[0]; o.y = vals[1] + rp[1]; o.z = vals[2] + rp[2]; o.w = vals[3] + rp[3];
        *(float4*)((float*)Cp + (long)bz * sCz + (long)n * ldc + m) = o;
      }
    }
    if (STATS) {
      const int nloc = wn * 64 + (N >> 1) * 32 + (N & 1) * 16 + (lane & 15);
      const int slot = wm * 4 + (lane >> 4);
      red[nloc * NSLOTP + slot] = eN;
    }
  }
  if (STATS) {
    bar();
    if (tid < BN) {
      float L = 0.f;
#pragma unroll
      for (int s2 = 0; s2 < NSLOT; ++s2) L += red[tid * NSLOTP + s2];
      rowsums[((long)(bz * gx + bx)) * 2304 + by * BN + tid] = L;
    }
  }
#undef READ_A
#undef READ_B
#undef MFMA_QUAD
}

extern "C" void kernel_launch(void* const* d_in, const int* in_sizes, int n_in,
                              void* d_out, int out_size, void* d_ws, size_t ws_size,
                              hipStream_t stream) {
  const float* x = (const float*)d_in[0];
  const float* gamma = (const float*)d_in[1];
  const float* beta = (const float*)d_in[2];
  const float* wq = (const float*)d_in[3];
  const float* bq = (const float*)d_in[4];
  const float* wk = (const float*)d_in[5];
  const float* bk = (const float*)d_in[6];
  const float* wv = (const float*)d_in[7];
  const float* bv = (const float*)d_in[8];
  const float* wo = (const float*)d_in[9];
  const float* bo = (const float*)d_in[10];
  float* out = (float*)d_out;

  char* ws = (char*)d_ws;
  size_t off = 0;
  auto alloc = [&](size_t bytes) {
    char* p = ws + off;
    off = (off + bytes + 255) & ~(size_t)255;
    return p;
  };
  float* part = (float*)alloc(256 * 2 * sizeof(float));
  unsigned short* wqkb = (unsigned short*)alloc((size_t)2 * 262144 * 2);
  unsigned short* wvb = (unsigned short*)alloc((size_t)262144 * 2);
  unsigned short* wob = (unsigned short*)alloc((size_t)262144 * 2);
  float* bqk = (float*)alloc(1024 * sizeof(float));
  float* rowsums = (float*)alloc((size_t)8 * 18 * 2304 * sizeof(float));
  unsigned short* hnT = (unsigned short*)alloc((size_t)18432 * 512 * 2);
  unsigned char* qkA = (unsigned char*)alloc((size_t)18432 * 1024);      // fp8 k-interleaved
  unsigned char* vT = (unsigned char*)alloc((size_t)512 * 18432);        // fp8 k-interleaved
  unsigned char* Sm = (unsigned char*)alloc((size_t)8 * 2304 * 2304);    // fp8 E k-interleaved
  unsigned short* Ob = hnT;  // alias: hnT fully consumed after qk/v GEMMs
  (void)ws_size; (void)in_sizes; (void)n_in; (void)out_size;

  stats_partial_k<<<dim3(256), dim3(256), 0, stream>>>(x, part);
  // R21: stats_final folded into gn_transpose; pack_bias folded into pack4.
  gn_transpose_k<<<dim3(8, 288), dim3(256), 0, stream>>>(x, part, gamma, beta, hnT);
  pack4_bf16_k<<<dim3(256, 5), dim3(256), 0, stream>>>(wq, wk, wv, wo,
                                                       wqkb, wqkb + 262144, wvb, wob,
                                                       bq, bk, bqk);

  // qk fused: A=[Wq;Wk] bf16, B=hnT bf16 -> q,k fp8 interleaved [sp][1024].
  // WL=1 bf16 (128x128, 2 blocks/CU): 8x144x(8 XCD) = 1152 blocks MODE1.
  gemm256<128, 1, 2, 0, 0, 1, 0, 1, 1><<<dim3(1152), dim3(256), 0, stream>>>(
      wqkb, 512, 0, hnT, 512, 0, (void*)qkA, 1024, 0, bqk, nullptr, nullptr, nullptr,
      1.0f, 512, 8, 18);
  // v: A=hnT bf16, B=Wv bf16 -> vT fp8 interleaved [co][18432].
  // WL=1 bf16, MODE2: 8 XCD x (gx=18 m-chunk) x (gy=4 n) = 576 blocks.
  gemm256<128, 2, 2, 0, 0, 2, 0, 1, 1><<<dim3(576), dim3(256), 0, stream>>>(
      hnT, 512, 0, wvb, 512, 0, (void*)vT, 18432, 0, bv, nullptr, nullptr, nullptr,
      1.0f, 512, 18, 4);
  // S: per t: A=k fp8, B=q fp8 -> E=exp(alpha*S) fp8 interleaved + rowsums.
  // WL=1 fp8 KU=1 (32KB LDS, 4 blocks/CU): 2592 blocks MODE0.
  gemm256<128, 0, 2, 1, 0, 0, 1, 1, 1><<<dim3(2592), dim3(256), 0, stream>>>(
      qkA + 512, 1024, (long)2304 * 1024, qkA, 1024, (long)2304 * 1024, (void*)Sm, 2304,
      (long)2304 * 2304, nullptr, nullptr, rowsums, nullptr,
      0.044194173824159216f, 512, 18, 18);
  // PV: per t: A=vT fp8, B=E fp8 -> O bf16 [(t,i)*512+c], rows scaled by 1/L.
  // R21: SCALEN=2 -- combine folded into PV prologue (reads rowsums directly).
  // WL=1 fp8 KU=1: 4x18x8 = 576 blocks MODE0.
  gemm256<128, 0, 0, 0, 2, 0, 1, 1, 1><<<dim3(576), dim3(256), 0, stream>>>(
      vT, 18432, 2304, Sm, 2304, (long)2304 * 2304, (void*)Ob, 512, (long)2304 * 512,
      nullptr, nullptr, rowsums, nullptr, 1.0f, 2304, 4, 18);
  // final: A=O bf16, B=Wo bf16 -> out[co*18432+sp] = x + acc + bo[co].
  // WL=1 bf16, MODE2: 8 x 18 x 4 = 576 blocks.
  gemm256<128, 2, 1, 0, 0, 2, 0, 1, 1><<<dim3(576), dim3(256), 0, stream>>>(
      Ob, 512, 0, wob, 512, 0, (void*)out, 18432, 0, bo, x, nullptr, nullptr,
      1.0f, 512, 18, 4);
}

// Round 13
// 214.855 us; speedup vs baseline: 1.2417x; 1.0268x over previous
//
#include <hip/hip_runtime.h>
#include <hip/hip_bf16.h>
#include <cstdint>
#include <type_traits>

typedef __attribute__((ext_vector_type(8))) __bf16 bf16x8;
typedef __attribute__((ext_vector_type(4))) float f32x4;
typedef __attribute__((ext_vector_type(2))) long longx2;

struct bf2frag { bf16x8 k0, k1; };

__device__ __forceinline__ float bf2f(unsigned short u) {
  union { uint32_t i; float f; } v; v.i = (uint32_t)u << 16; return v.f;
}
__device__ __forceinline__ unsigned short f2bf(float f) {
  union { float f; uint32_t i; } v{f};
  uint32_t r = v.i + 0x7fffu + ((v.i >> 16) & 1u);
  return (unsigned short)(r >> 16);
}

__device__ __forceinline__ void gll(const void* g, void* l) {
  __builtin_amdgcn_global_load_lds(
      (const __attribute__((address_space(1))) uint32_t*)(uintptr_t)g,
      (__attribute__((address_space(3))) uint32_t*)(uint32_t)(uintptr_t)l,
      16, 0, 0);
}

__device__ __forceinline__ void bar() {
  asm volatile("" ::: "memory");
  __builtin_amdgcn_s_barrier();
  asm volatile("" ::: "memory");
}

#define VMCNT(n) asm volatile("s_waitcnt vmcnt(" #n ")" ::: "memory")

template <int N>
__device__ __forceinline__ void vmw() {
  if constexpr (N == 0) { VMCNT(0); }
  else if constexpr (N == 1) { VMCNT(1); }
  else if constexpr (N == 2) { VMCNT(2); }
  else if constexpr (N == 3) { VMCNT(3); }
  else if constexpr (N == 4) { VMCNT(4); }
  else if constexpr (N == 5) { VMCNT(5); }
  else if constexpr (N == 6) { VMCNT(6); }
  else if constexpr (N == 7) { VMCNT(7); }
  else if constexpr (N == 8) { VMCNT(8); }
  else if constexpr (N == 9) { VMCNT(9); }
  else if constexpr (N == 10) { VMCNT(10); }
  else { VMCNT(12); }
}

__device__ __forceinline__ f32x4 mma(bf16x8 a, bf16x8 b, f32x4 c) {
  return __builtin_amdgcn_mfma_f32_16x16x32_bf16(a, b, c, 0, 0, 0);
}
__device__ __forceinline__ f32x4 mma(long a, long b, f32x4 c) {
  return __builtin_amdgcn_mfma_f32_16x16x32_fp8_fp8(a, b, c, 0, 0, 0);
}
__device__ __forceinline__ f32x4 mmak(const bf2frag& a, const bf2frag& b, f32x4 c, int k2) {
  return k2 ? mma(a.k1, b.k1, c) : mma(a.k0, b.k0, c);
}
__device__ __forceinline__ f32x4 mmak(longx2 a, longx2 b, f32x4 c, int k2) {
  return mma(a[k2], b[k2], c);
}

// k-interleave store permutation for fp8 buffers (unit u=8B: slot p(u)=(u&3)*2+(u>>2))
__device__ __forceinline__ int perm64(int m) {
  return (m & ~63) | (((m >> 3) & 3) << 4) | (((m >> 5) & 1) << 3) | (m & 7);
}

// ---------------- GroupNorm stats ----------------
__global__ __launch_bounds__(256) void stats_partial_k(const float* __restrict__ x,
                                                       float* __restrict__ part) {
  const int g = blockIdx.x >> 3, p = blockIdx.x & 7;
  const float* base = x + (long)g * 16 * 18432 + (long)p * 2304;
  float s = 0.f, ss = 0.f;
  for (int idx = threadIdx.x; idx < 16 * 576; idx += 256) {
    const int c = idx / 576, i4 = idx % 576;
    const float4 v = *(const float4*)(base + (long)c * 18432 + i4 * 4);
    s += v.x + v.y + v.z + v.w;
    ss += v.x * v.x + v.y * v.y + v.z * v.z + v.w * v.w;
  }
  __shared__ float rs[256], rss[256];
  rs[threadIdx.x] = s; rss[threadIdx.x] = ss;
  __syncthreads();
  for (int o = 128; o > 0; o >>= 1) {
    if ((int)threadIdx.x < o) { rs[threadIdx.x] += rs[threadIdx.x + o]; rss[threadIdx.x] += rss[threadIdx.x + o]; }
    __syncthreads();
  }
  if (threadIdx.x == 0) { part[blockIdx.x * 2] = rs[0]; part[blockIdx.x * 2 + 1] = rss[0]; }
}

// ---------------- GN apply + transpose to (spatial, channel) bf16 ----------------
// R21: stats_final folded in -- each block reduces part[] for its own 4 groups.
__global__ __launch_bounds__(256) void gn_transpose_k(const float* __restrict__ x,
                                                      const float* __restrict__ part,
                                                      const float* __restrict__ gamma,
                                                      const float* __restrict__ beta,
                                                      unsigned short* __restrict__ hnT) {
  __shared__ float tile[64][65];
  __shared__ float sm[4], sr[4];
  const int c0 = blockIdx.x * 64, n0 = blockIdx.y * 64;
  const int tn = threadIdx.x & 63, tr = threadIdx.x >> 6;
  if (threadIdx.x < 4) {
    const int g = (c0 >> 4) + threadIdx.x;
    float s = 0.f, ss = 0.f;
    for (int p = 0; p < 8; ++p) { s += part[(g * 8 + p) * 2]; ss += part[(g * 8 + p) * 2 + 1]; }
    const float mean = s / 294912.0f;
    const float var = ss / 294912.0f - mean * mean;
    sm[threadIdx.x] = mean;
    sr[threadIdx.x] = rsqrtf(var + 1e-6f);
  }
  __syncthreads();
  for (int cc = tr; cc < 64; cc += 4) {
    const int c = c0 + cc;
    const float mean = sm[cc >> 4], rstd = sr[cc >> 4];
    const float v = x[(long)c * 18432 + n0 + tn];
    tile[cc][tn] = (v - mean) * rstd * gamma[c] + beta[c];
  }
  __syncthreads();
  for (int nn = tr; nn < 64; nn += 4) {
    hnT[(long)(n0 + nn) * 512 + c0 + tn] = f2bf(tile[tn][nn]);
  }
}

// ---------------- fp32 -> bf16 weight pack (4 weights + qk-bias in one launch) ----------------
__global__ __launch_bounds__(256) void pack4_bf16_k(const float* __restrict__ w0,
                                                    const float* __restrict__ w1,
                                                    const float* __restrict__ w2,
                                                    const float* __restrict__ w3,
                                                    unsigned short* __restrict__ o0,
                                                    unsigned short* __restrict__ o1,
                                                    unsigned short* __restrict__ o2,
                                                    unsigned short* __restrict__ o3,
                                                    const float* __restrict__ bq,
                                                    const float* __restrict__ bk,
                                                    float* __restrict__ bqk) {
  const int y = blockIdx.y;
  if (y == 4) {  // R21: pack_bias folded in (block 0 only)
    if (blockIdx.x == 0) {
      const int i = threadIdx.x * 4;
#pragma unroll
      for (int j = 0; j < 4; ++j) {
        const int t = i + j;
        bqk[t] = (t < 512) ? bq[t] : bk[t - 512];
      }
    }
    return;
  }
  const float* w = (y == 0) ? w0 : (y == 1) ? w1 : (y == 2) ? w2 : w3;
  unsigned short* o = (y == 0) ? o0 : (y == 1) ? o1 : (y == 2) ? o2 : o3;
  const int i = (blockIdx.x * 256 + threadIdx.x) * 4;
  const float4 v = *(const float4*)(w + i);
  ushort4 u; u.x = f2bf(v.x); u.y = f2bf(v.y); u.z = f2bf(v.z); u.w = f2bf(v.w);
  *(ushort4*)(o + i) = u;
}

// ================= BMxBNxBK NT GEMM, XCD-swizzled, bf16/fp8 =================
// C[n*ldc+m] = alpha*sum_k A[m,k]*B[n,k] (+bias)(+resid)
// WL=0, BM=256: 512 thr, 8 waves (2m x 4n), 1 block/CU, P2=0, setprio ON.
// WL=1: BM=128 x BN=128, 256 thr, 4 waves (2m x 2n, 64x64/wave).
//   fp8 KU=1: 32KB LDS, bounds(256,4). bf16: 64KB, 2 blocks/CU.
//   R19/R20: KU=2 on S FALSIFIED (LDS halves blocks/CU, TLP is binding).
//   Ladder: R13 S (TLP), R14 qk (makespan), R15 PV, R17 v+final, R18 scratch
//   pad, R20 KU revert + pack4, R21 launch folds (~2.3us/launch).
//   A/B halves use 32-row stripe interleave: grow = (r>>5)*64 + h*32 + (r&31).
// P2=1 (2-phase): P0: read A0,B0,B1; stage [A0,B1,A1](W+1) -> s^1; mfma m0x{n0,n1}.
//   P1: read A1; stage B0(W+2) -> s; mfma m1x{n1,n0}.
//   Waits: @P0-end vmcnt(2(GA+GB)); @P1-end vmcnt(GA+GB); tail GA then 0.
// STATS: exp+rowsums, scratch stride NSLOT+1 (R18).
// SCALEN: 1 = *linv[n] from global; 2 (R21) = combine folded in -- prologue
//   computes 1/L for this block's BN rows from rowsums into linvs[] LDS.
// OUT_MODE: 0 bf16, 1 f32+resid, 2 fp8 e4m3 k-interleaved.
// MODE0: bz=bid%8 per XCD; MODE1/2: XCD y/x-chunking.
// MODE3 (R22): fused qk+v single dispatch -- both are the same WL=1 bf16 P2=1
//   machine (lda=ldb=512, K=512, OUT_MODE=2, alpha=1); only pointers/ldc/grid
//   map/bias-indexing differ. Blocks < gx(=1152) run the qk mapping (MODE1,
//   gx=8,gy=18; C=Cp ldc=1024, bias[m]); the rest run the v mapping (MODE2,
//   gx=18,gy=4; A=B(hnT), B=resid(wvb), C=rowsums(vT) ldc=18432, bias=linv(bv),
//   bias[n]). Saves one launch gap + packs the two ragged tails (2.25g + 1.125g
//   -> 3.375g). resid/rowsums/linv args are free in this instantiation.
template <int BM, int BIAS_MODE, int OUT_MODE, int STATS, int SCALEN, int MODE, int FP8, int P2,
          int WL = 0, int KU = 1>
__global__ __launch_bounds__((BM == 256) ? 512 : 256, (WL && FP8) ? (KU == 2 ? 2 : 4) : 2)
void gemm256(const void* __restrict__ A, long lda, long sAz,
             const void* __restrict__ B, long ldb, long sBz,
             void* __restrict__ Cp, long ldc, long sCz,
             const float* __restrict__ bias,
             const float* __restrict__ resid,
             float* __restrict__ rowsums,
             const float* __restrict__ linv,
             float alpha, int K, int gx, int gy) {
  static_assert(KU == 1 || FP8, "KU=2 only on fp8 path");
  constexpr int EB = FP8 ? 1 : 2;                    // element bytes
  constexpr int THREADS = (BM == 256) ? 512 : 256;
  constexpr int BN = WL ? 128 : 256;                 // n-tile
  constexpr int BK = 64 * KU;                        // k-step
  constexpr int HBA = (BM / 2) * BK * EB;            // bytes per A half
  constexpr int HBB = (BN / 2) * BK * EB;            // bytes per B half
  constexpr int HBA0 = HBA / KU, HBB0 = HBB / KU;    // per 64-k sub-block
  constexpr int GA = HBA / (THREADS * 16);           // gll per A-half stage
  constexpr int GB = HBB / (THREADS * 16);           // gll per B-half stage
  constexpr int GA0 = GA / KU, GB0 = GB / KU;        // gll per 64-k sub-stage
  constexpr int V0 = GB + 2 * GA, V3 = 2 * GB + GA, VP = GB + GA;
  constexpr int NSLOT = WL ? 8 : ((BM == 256) ? 8 : 4);
  constexpr int NSLOTP = NSLOT + 1;                  // R18: odd stride
  constexpr int MR = WL ? 4 : 8;                     // acc M-frags per wave
  constexpr int FQ = WL ? 2 : 4;                     // A-frags per (mh) phase
  constexpr int PRIO = !P2;                          // setprio only on 1-block path
  __shared__ alignas(16) unsigned char As[2][2][HBA];
  __shared__ alignas(16) unsigned char Bs[2][2][HBB];
  __shared__ float linvs[SCALEN == 2 ? BN : 1];
  using ABt2 = typename std::conditional<FP8, longx2, bf2frag>::type;

  const int tid = threadIdx.x;
  const int lane = tid & 63, wid = tid >> 6;
  const int wm = WL ? (wid >> 1) : ((BM == 256) ? (wid & 1) : 0);
  const int wn = WL ? (wid & 1) : ((BM == 256) ? (wid >> 1) : wid);
  int bx, by, bz;
  const void* Asel = A;
  const void* Bsel = B;
  void* Csel = Cp;
  const float* biasSel = bias;
  long ldcSel = ldc;
  bool bias_m = (BIAS_MODE == 1);
  {
    const int g8 = blockIdx.x & 7, n = blockIdx.x >> 3;
    if (MODE == 0) { bz = g8; bx = n % gx; by = n / gx; }
    else if (MODE == 1) { bz = 0; bx = n % gx; by = g8 * gy + n / gx; }
    else if (MODE == 2) { bz = 0; by = n % gy; bx = g8 * gx + n / gy; }
    else {  // MODE 3: fused qk+v; gx = number of qk blocks
      bz = 0;
      if ((int)blockIdx.x < gx) {
        bx = n % 8; by = g8 * 18 + n / 8;          // qk: MODE1 gx=8, gy=18
      } else {
        const int b2 = (int)blockIdx.x - gx;
        const int g82 = b2 & 7, n2 = b2 >> 3;
        by = n2 % 4; bx = g82 * 18 + n2 / 4;       // v: MODE2 gx=18, gy=4
        Asel = B;                                   // hnT
        Bsel = (const void*)resid;                  // wvb
        Csel = (void*)rowsums;                      // vT
        biasSel = linv;                             // bv
        ldcSel = 18432;
        bias_m = false;
      }
    }
  }
  const unsigned char* Ab = (const unsigned char*)Asel + ((long)bz * sAz + (long)bx * BM * lda) * EB;
  const unsigned char* Bb = (const unsigned char*)Bsel + ((long)bz * sBz + (long)by * BN * ldb) * EB;

  // R21 (SCALEN==2): fold combine -- compute 1/L for this block's rows first,
  // so the scalar loads retire before any gll enters the vmcnt FIFO.
  if constexpr (SCALEN == 2) {
    if (tid < BN) {
      const int ntile = K / BN;
      float L = 0.f;
      for (int xx = 0; xx < ntile; ++xx)
        L += rowsums[((long)(bz * ntile + xx)) * K + by * BN + tid];
      linvs[tid] = 1.0f / L;
    }
  }

  // ---- staging (global -> LDS, pre-swizzled source; fp8 global is k-interleaved) ----
  auto stageA = [&](int slot, int h, int k0) {
    if constexpr (!FP8) {
      const int ksw = ((tid & 7) << 3) ^ (((tid >> 3) & 7) << 3);
#pragma unroll
      for (int call = 0; call < GA; ++call) {
        const int r = call * (THREADS / 8) + (tid >> 3);
        const int grow = WL ? (((r >> 5) << 6) + h * 32 + (r & 31))
                            : (((r >> 6) << 7) + h * 64 + (r & 63));
        gll(Ab + ((long)grow * lda + k0) * 2 + ksw * 2, &As[slot][h][call * THREADS * 16 + tid * 16]);
      }
    } else {
#pragma unroll
      for (int call = 0; call < GA; ++call) {
        const int sub = call / GA0, c0 = call % GA0;
        const int l = c0 * (THREADS / 4) + (tid >> 2);
        const int grow = WL ? (((l >> 5) << 6) + h * 32 + (l & 31))
                            : (((l >> 6) << 7) + h * 64 + (l & 63));
        const int x = (((l & 3) ^ ((l >> 2) & 3)) << 4);
        gll(Ab + (long)grow * lda + k0 + sub * 64 + (((tid & 3) << 4) ^ x),
            &As[slot][h][call * THREADS * 16 + tid * 16]);
      }
    }
  };
  auto stageB = [&](int slot, int h, int k0) {
    if constexpr (!FP8) {
      const int ksw = ((tid & 7) << 3) ^ (((tid >> 3) & 7) << 3);
#pragma unroll
      for (int call = 0; call < GB; ++call) {
        const int r = call * (THREADS / 8) + (tid >> 3);
        const int grow = ((r >> 5) << 6) + h * 32 + (r & 31);
        gll(Bb + ((long)grow * ldb + k0) * 2 + ksw * 2, &Bs[slot][h][call * THREADS * 16 + tid * 16]);
      }
    } else {
#pragma unroll
      for (int call = 0; call < GB; ++call) {
        const int sub = call / GB0, c0 = call % GB0;
        const int l = c0 * (THREADS / 4) + (tid >> 2);
        const int grow = ((l >> 5) << 6) + h * 32 + (l & 31);
        const int x = (((l & 3) ^ ((l >> 2) & 3)) << 4);
        gll(Bb + (long)grow * ldb + k0 + sub * 64 + (((tid & 3) << 4) ^ x),
            &Bs[slot][h][call * THREADS * 16 + tid * 16]);
      }
    }
  };
  // ---- LDS -> fragment reads (same swizzle; fp8 = ONE b128 for both k2 slices) ----
  auto ldA = [&](int slot, int mh, int fq, int sub) -> ABt2 {
    const int r = (WL ? wm * 32 : wm * 64) + fq * 16 + (lane & 15);
    if constexpr (!FP8) {
      bf2frag f;
      const int kk0 = (((lane >> 4) << 3)) ^ ((r & 7) << 3);
      const int kk1 = (32 + ((lane >> 4) << 3)) ^ ((r & 7) << 3);
      f.k0 = *reinterpret_cast<const bf16x8*>(&As[slot][mh][r * 128 + kk0 * 2]);
      f.k1 = *reinterpret_cast<const bf16x8*>(&As[slot][mh][r * 128 + kk1 * 2]);
      return f;
    } else {
      const int x = (((r & 3) ^ ((r >> 2) & 3)) << 4);
      const int kk = ((lane >> 4) << 4) ^ x;
      return *reinterpret_cast<const longx2*>(&As[slot][mh][sub * HBA0 + r * 64 + kk]);
    }
  };
  auto ldB = [&](int slot, int nh, int g, int sub) -> ABt2 {
    const int r = wn * 32 + g * 16 + (lane & 15);
    if constexpr (!FP8) {
      bf2frag f;
      const int kk0 = (((lane >> 4) << 3)) ^ ((r & 7) << 3);
      const int kk1 = (32 + ((lane >> 4) << 3)) ^ ((r & 7) << 3);
      f.k0 = *reinterpret_cast<const bf16x8*>(&Bs[slot][nh][r * 128 + kk0 * 2]);
      f.k1 = *reinterpret_cast<const bf16x8*>(&Bs[slot][nh][r * 128 + kk1 * 2]);
      return f;
    } else {
      const int x = (((r & 3) ^ ((r >> 2) & 3)) << 4);
      const int kk = ((lane >> 4) << 4) ^ x;
      return *reinterpret_cast<const longx2*>(&Bs[slot][nh][sub * HBB0 + r * 64 + kk]);
    }
  };

  f32x4 acc[MR][4] = {};
  ABt2 a[FQ * KU], b0[2 * KU], b1[2 * KU];

#define READ_A(SLOT, MH)                                                       \
  _Pragma("unroll") for (int fq = 0; fq < FQ; ++fq)                            \
    _Pragma("unroll") for (int sub = 0; sub < KU; ++sub)                       \
      a[fq * KU + sub] = ldA(SLOT, MH, fq, sub);
#define READ_B(SLOT, NH, DST)                                                  \
  _Pragma("unroll") for (int g = 0; g < 2; ++g)                                \
    _Pragma("unroll") for (int sub = 0; sub < KU; ++sub)                       \
      DST[g * KU + sub] = ldB(SLOT, NH, g, sub);
#define MFMA_QUAD(MH, NH, BARR)                                                \
  if constexpr (PRIO) __builtin_amdgcn_s_setprio(1);                           \
  _Pragma("unroll") for (int fq = 0; fq < FQ; ++fq)                            \
    _Pragma("unroll") for (int g = 0; g < 2; ++g)                              \
      _Pragma("unroll") for (int sub = 0; sub < KU; ++sub)                     \
        _Pragma("unroll") for (int k2 = 0; k2 < 2; ++k2)                       \
          acc[(MH) * FQ + fq][(NH) * 2 + g] =                                  \
              mmak(a[fq * KU + sub], BARR[g * KU + sub],                       \
                   acc[(MH) * FQ + fq][(NH) * 2 + g], k2);                     \
  if constexpr (PRIO) __builtin_amdgcn_s_setprio(0);

  const int KT = K / BK;
  // Prologue queue: [B0(0), A0(0), B1(0), A1(0), B0(1)] (+A1(1) for P2=0)
  stageB(0, 0, 0);
  stageA(0, 0, 0);
  stageB(0, 1, 0);
  stageA(0, 1, 0);
  stageB(1, 0, BK);
  if constexpr (!P2) stageA(1, 1, BK);
  vmw<VP>();
  bar();

  if constexpr (!P2) {
    for (int W = 0; W < KT; ++W) {
      const int s = W & 1;
      const int kn1 = (W + 1) * BK, kn2 = (W + 2) * BK;
      const bool st1 = (W + 1 < KT), st2 = (W + 2 < KT);
      // p0: (m0,n0)
      READ_A(s, 0)
      READ_B(s, 0, b0)
      if (st1) stageA(s ^ 1, 0, kn1);
      bar();
      MFMA_QUAD(0, 0, b0)
      if (st1) { vmw<V0>(); }
      bar();
      // p1: (m0,n1)
      READ_B(s, 1, b1)
      if (st1) stageB(s ^ 1, 1, kn1);
      bar();
      MFMA_QUAD(0, 1, b1)
      bar();
      // p2: (m1,n1)
      READ_A(s, 1)
      if (st2) stageB(s, 0, kn2);
      bar();
      MFMA_QUAD(1, 1, b1)
      bar();
      // p3: (m1,n0)
      if (st2) stageA(s, 1, kn2);
      bar();
      MFMA_QUAD(1, 0, b0)
      if (st2) { vmw<V3>(); } else { vmw<0>(); }
      bar();
    }
  } else {
    for (int W = 0; W < KT; ++W) {
      const int s = W & 1;
      const int kn1 = (W + 1) * BK, kn2 = (W + 2) * BK;
      const bool st1 = (W + 1 < KT), st2 = (W + 2 < KT);
      // P0: (m0 x n0,n1); stage next A-slot fully + B1(W+1). A1 issued LAST.
      READ_A(s, 0)
      READ_B(s, 0, b0)
      READ_B(s, 1, b1)
      if (st1) { stageA(s ^ 1, 0, kn1); stageB(s ^ 1, 1, kn1); stageA(s ^ 1, 1, kn1); }
      bar();
      MFMA_QUAD(0, 0, b0)
      MFMA_QUAD(0, 1, b1)
      if (st1) { vmw<2 * (GA + GB)>(); } else { vmw<0>(); }
      bar();
      // P1: (m1 x n1,n0); stage B0(W+2) into current slot (B0(W) consumed in P0).
      READ_A(s, 1)
      if (st2) stageB(s, 0, kn2);
      bar();
      MFMA_QUAD(1, 1, b1)
      MFMA_QUAD(1, 0, b0)
      if (st2) { vmw<GA + GB>(); } else if (st1) { vmw<GA>(); } else { vmw<0>(); }
      bar();
    }
  }

  // epilogue: acc[M][N].
  // WL=0: M = mh*4+fq, m-off = (M>>2)*64 + (M&3)*16, wave m-base wm*128.
  // WL=1: M = mh*2+fq, m-off = (M>>1)*32 + (M&1)*16, wave m-base wm*64.
  const int mg0 = bx * BM + (WL ? wm * 64 : wm * 128) + ((lane >> 4) << 2);
  const int ng0 = by * BN + wn * 64 + (lane & 15);
  float* red = (float*)&As[0][0][0];  // STATS scratch: BN rows x NSLOTP f32
#pragma unroll
  for (int N = 0; N < 4; ++N) {
    const int n = ng0 + (N >> 1) * 32 + (N & 1) * 16;
    float bn;
    if constexpr (MODE == 3) bn = bias_m ? 0.f : biasSel[n];
    else bn = (BIAS_MODE == 2) ? bias[n] : 0.f;
    const float sc = (SCALEN == 1) ? linv[(long)bz * 2304 + n]
                   : (SCALEN == 2) ? linvs[n - by * BN] : 1.0f;
    float eN = 0.f;
#pragma unroll
    for (int M = 0; M < MR; ++M) {
      const int m = mg0 + (WL ? ((M >> 1) * 32 + (M & 1) * 16) : ((M >> 2) * 64 + (M & 3) * 16));
      const f32x4 av = acc[M][N];
      float vals[4];
#pragma unroll
      for (int j = 0; j < 4; ++j) {
        float addv;
        if constexpr (MODE == 3) addv = bias_m ? biasSel[m + j] : bn;
        else if constexpr (BIAS_MODE == 1) addv = bias[m + j];
        else addv = bn;
        vals[j] = av[j] * alpha + addv;
        if (SCALEN) vals[j] *= sc;
        if (STATS) { vals[j] = __expf(vals[j]); eN += vals[j]; }
      }
      if (OUT_MODE == 0) {
        ushort4 o; o.x = f2bf(vals[0]); o.y = f2bf(vals[1]); o.z = f2bf(vals[2]); o.w = f2bf(vals[3]);
        *(ushort4*)((unsigned short*)Csel + (long)bz * sCz + (long)n * ldcSel + m) = o;
      } else if (OUT_MODE == 2) {
        int pk = __builtin_amdgcn_cvt_pk_fp8_f32(vals[0], vals[1], 0, false);
        pk = __builtin_amdgcn_cvt_pk_fp8_f32(vals[2], vals[3], pk, true);
        *(int*)((unsigned char*)Csel + (long)bz * sCz + (long)n * ldcSel + perm64(m)) = pk;
      } else {
        const float* rp = resid + (long)n * ldcSel + m;
        float4 o; o.x = vals[0] + rp[0]; o.y = vals[1] + rp[1]; o.z = vals[2] + rp[2]; o.w = vals[3] + rp[3];
        *(float4*)((float*)Csel + (long)bz * sCz + (long)n * ldcSel + m) = o;
      }
    }
    if (STATS) {
      const int nloc = wn * 64 + (N >> 1) * 32 + (N & 1) * 16 + (lane & 15);
      const int slot = wm * 4 + (lane >> 4);
      red[nloc * NSLOTP + slot] = eN;
    }
  }
  if (STATS) {
    bar();
    if (tid < BN) {
      float L = 0.f;
#pragma unroll
      for (int s2 = 0; s2 < NSLOT; ++s2) L += red[tid * NSLOTP + s2];
      rowsums[((long)(bz * gx + bx)) * 2304 + by * BN + tid] = L;
    }
  }
#undef READ_A
#undef READ_B
#undef MFMA_QUAD
}

extern "C" void kernel_launch(void* const* d_in, const int* in_sizes, int n_in,
                              void* d_out, int out_size, void* d_ws, size_t ws_size,
                              hipStream_t stream) {
  const float* x = (const float*)d_in[0];
  const float* gamma = (const float*)d_in[1];
  const float* beta = (const float*)d_in[2];
  const float* wq = (const float*)d_in[3];
  const float* bq = (const float*)d_in[4];
  const float* wk = (const float*)d_in[5];
  const float* bk = (const float*)d_in[6];
  const float* wv = (const float*)d_in[7];
  const float* bv = (const float*)d_in[8];
  const float* wo = (const float*)d_in[9];
  const float* bo = (const float*)d_in[10];
  float* out = (float*)d_out;

  char* ws = (char*)d_ws;
  size_t off = 0;
  auto alloc = [&](size_t bytes) {
    char* p = ws + off;
    off = (off + bytes + 255) & ~(size_t)255;
    return p;
  };
  float* part = (float*)alloc(256 * 2 * sizeof(float));
  unsigned short* wqkb = (unsigned short*)alloc((size_t)2 * 262144 * 2);
  unsigned short* wvb = (unsigned short*)alloc((size_t)262144 * 2);
  unsigned short* wob = (unsigned short*)alloc((size_t)262144 * 2);
  float* bqk = (float*)alloc(1024 * sizeof(float));
  float* rowsums = (float*)alloc((size_t)8 * 18 * 2304 * sizeof(float));
  unsigned short* hnT = (unsigned short*)alloc((size_t)18432 * 512 * 2);
  unsigned char* qkA = (unsigned char*)alloc((size_t)18432 * 1024);      // fp8 k-interleaved
  unsigned char* vT = (unsigned char*)alloc((size_t)512 * 18432);        // fp8 k-interleaved
  unsigned char* Sm = (unsigned char*)alloc((size_t)8 * 2304 * 2304);    // fp8 E k-interleaved
  unsigned short* Ob = hnT;  // alias: hnT fully consumed after qk/v GEMMs
  (void)ws_size; (void)in_sizes; (void)n_in; (void)out_size;

  stats_partial_k<<<dim3(256), dim3(256), 0, stream>>>(x, part);
  gn_transpose_k<<<dim3(8, 288), dim3(256), 0, stream>>>(x, part, gamma, beta, hnT);
  pack4_bf16_k<<<dim3(256, 5), dim3(256), 0, stream>>>(wq, wk, wv, wo,
                                                       wqkb, wqkb + 262144, wvb, wob,
                                                       bq, bk, bqk);

  // R22: fused qk+v (MODE3). Blocks [0,1152): qk -- A=[Wq;Wk] bf16, B=hnT ->
  // qkA fp8 interleaved [sp][1024], bias bqk by m. Blocks [1152,1728): v --
  // A=hnT, B=wvb -> vT fp8 interleaved [co][18432], bias bv by n.
  // Second param set via resid/rowsums/linv (free at OUT_MODE=2/STATS=0/SCALEN=0).
  gemm256<128, 1, 2, 0, 0, 3, 0, 1, 1><<<dim3(1728), dim3(256), 0, stream>>>(
      wqkb, 512, 0, hnT, 512, 0, (void*)qkA, 1024, 0, bqk,
      (const float*)wvb, (float*)vT, bv, 1.0f, 512, 1152, 0);
  // S: per t: A=k fp8, B=q fp8 -> E=exp(alpha*S) fp8 interleaved + rowsums.
  // WL=1 fp8 KU=1 (32KB LDS, 4 blocks/CU): 2592 blocks MODE0.
  gemm256<128, 0, 2, 1, 0, 0, 1, 1, 1><<<dim3(2592), dim3(256), 0, stream>>>(
      qkA + 512, 1024, (long)2304 * 1024, qkA, 1024, (long)2304 * 1024, (void*)Sm, 2304,
      (long)2304 * 2304, nullptr, nullptr, rowsums, nullptr,
      0.044194173824159216f, 512, 18, 18);
  // PV: per t: A=vT fp8, B=E fp8 -> O bf16 [(t,i)*512+c], rows scaled by 1/L.
  // SCALEN=2 -- combine folded into PV prologue (reads rowsums directly).
  // WL=1 fp8 KU=1: 4x18x8 = 576 blocks MODE0.
  gemm256<128, 0, 0, 0, 2, 0, 1, 1, 1><<<dim3(576), dim3(256), 0, stream>>>(
      vT, 18432, 2304, Sm, 2304, (long)2304 * 2304, (void*)Ob, 512, (long)2304 * 512,
      nullptr, nullptr, rowsums, nullptr, 1.0f, 2304, 4, 18);
  // final: A=O bf16, B=Wo bf16 -> out[co*18432+sp] = x + acc + bo[co].
  // WL=1 bf16, MODE2: 8 x 18 x 4 = 576 blocks.
  gemm256<128, 2, 1, 0, 0, 2, 0, 1, 1><<<dim3(576), dim3(256), 0, stream>>>(
      Ob, 512, 0, wob, 512, 0, (void*)out, 18432, 0, bo, x, nullptr, nullptr,
      1.0f, 512, 18, 4);
}

// Round 14
// 210.560 us; speedup vs baseline: 1.2670x; 1.0204x over previous
//
#include <hip/hip_runtime.h>
#include <hip/hip_bf16.h>
#include <cstdint>
#include <type_traits>

typedef __attribute__((ext_vector_type(8))) __bf16 bf16x8;
typedef __attribute__((ext_vector_type(4))) float f32x4;
typedef __attribute__((ext_vector_type(2))) long longx2;

struct bf2frag { bf16x8 k0, k1; };

__device__ __forceinline__ float bf2f(unsigned short u) {
  union { uint32_t i; float f; } v; v.i = (uint32_t)u << 16; return v.f;
}
__device__ __forceinline__ unsigned short f2bf(float f) {
  union { float f; uint32_t i; } v{f};
  uint32_t r = v.i + 0x7fffu + ((v.i >> 16) & 1u);
  return (unsigned short)(r >> 16);
}

__device__ __forceinline__ void gll(const void* g, void* l) {
  __builtin_amdgcn_global_load_lds(
      (const __attribute__((address_space(1))) uint32_t*)(uintptr_t)g,
      (__attribute__((address_space(3))) uint32_t*)(uint32_t)(uintptr_t)l,
      16, 0, 0);
}

__device__ __forceinline__ void bar() {
  asm volatile("" ::: "memory");
  __builtin_amdgcn_s_barrier();
  asm volatile("" ::: "memory");
}

#define VMCNT(n) asm volatile("s_waitcnt vmcnt(" #n ")" ::: "memory")

template <int N>
__device__ __forceinline__ void vmw() {
  if constexpr (N == 0) { VMCNT(0); }
  else if constexpr (N == 1) { VMCNT(1); }
  else if constexpr (N == 2) { VMCNT(2); }
  else if constexpr (N == 3) { VMCNT(3); }
  else if constexpr (N == 4) { VMCNT(4); }
  else if constexpr (N == 5) { VMCNT(5); }
  else if constexpr (N == 6) { VMCNT(6); }
  else if constexpr (N == 7) { VMCNT(7); }
  else if constexpr (N == 8) { VMCNT(8); }
  else if constexpr (N == 9) { VMCNT(9); }
  else if constexpr (N == 10) { VMCNT(10); }
  else { VMCNT(12); }
}

__device__ __forceinline__ f32x4 mma(bf16x8 a, bf16x8 b, f32x4 c) {
  return __builtin_amdgcn_mfma_f32_16x16x32_bf16(a, b, c, 0, 0, 0);
}
__device__ __forceinline__ f32x4 mma(long a, long b, f32x4 c) {
  return __builtin_amdgcn_mfma_f32_16x16x32_fp8_fp8(a, b, c, 0, 0, 0);
}
__device__ __forceinline__ f32x4 mmak(const bf2frag& a, const bf2frag& b, f32x4 c, int k2) {
  return k2 ? mma(a.k1, b.k1, c) : mma(a.k0, b.k0, c);
}
__device__ __forceinline__ f32x4 mmak(longx2 a, longx2 b, f32x4 c, int k2) {
  return mma(a[k2], b[k2], c);
}

// k-interleave store permutation for fp8 buffers (unit u=8B: slot p(u)=(u&3)*2+(u>>2))
__device__ __forceinline__ int perm64(int m) {
  return (m & ~63) | (((m >> 3) & 3) << 4) | (((m >> 5) & 1) << 3) | (m & 7);
}

// ---------------- GroupNorm stats ----------------
__global__ __launch_bounds__(256) void stats_partial_k(const float* __restrict__ x,
                                                       float* __restrict__ part) {
  const int g = blockIdx.x >> 3, p = blockIdx.x & 7;
  const float* base = x + (long)g * 16 * 18432 + (long)p * 2304;
  float s = 0.f, ss = 0.f;
  for (int idx = threadIdx.x; idx < 16 * 576; idx += 256) {
    const int c = idx / 576, i4 = idx % 576;
    const float4 v = *(const float4*)(base + (long)c * 18432 + i4 * 4);
    s += v.x + v.y + v.z + v.w;
    ss += v.x * v.x + v.y * v.y + v.z * v.z + v.w * v.w;
  }
  __shared__ float rs[256], rss[256];
  rs[threadIdx.x] = s; rss[threadIdx.x] = ss;
  __syncthreads();
  for (int o = 128; o > 0; o >>= 1) {
    if ((int)threadIdx.x < o) { rs[threadIdx.x] += rs[threadIdx.x + o]; rss[threadIdx.x] += rss[threadIdx.x + o]; }
    __syncthreads();
  }
  if (threadIdx.x == 0) { part[blockIdx.x * 2] = rs[0]; part[blockIdx.x * 2 + 1] = rss[0]; }
}

// ---------------- GN apply + transpose to (spatial, channel) bf16 ----------------
// R21: stats_final folded in -- each block reduces part[] for its own 4 groups.
__global__ __launch_bounds__(256) void gn_transpose_k(const float* __restrict__ x,
                                                      const float* __restrict__ part,
                                                      const float* __restrict__ gamma,
                                                      const float* __restrict__ beta,
                                                      unsigned short* __restrict__ hnT) {
  __shared__ float tile[64][65];
  __shared__ float sm[4], sr[4];
  const int c0 = blockIdx.x * 64, n0 = blockIdx.y * 64;
  const int tn = threadIdx.x & 63, tr = threadIdx.x >> 6;
  if (threadIdx.x < 4) {
    const int g = (c0 >> 4) + threadIdx.x;
    float s = 0.f, ss = 0.f;
    for (int p = 0; p < 8; ++p) { s += part[(g * 8 + p) * 2]; ss += part[(g * 8 + p) * 2 + 1]; }
    const float mean = s / 294912.0f;
    const float var = ss / 294912.0f - mean * mean;
    sm[threadIdx.x] = mean;
    sr[threadIdx.x] = rsqrtf(var + 1e-6f);
  }
  __syncthreads();
  for (int cc = tr; cc < 64; cc += 4) {
    const int c = c0 + cc;
    const float mean = sm[cc >> 4], rstd = sr[cc >> 4];
    const float v = x[(long)c * 18432 + n0 + tn];
    tile[cc][tn] = (v - mean) * rstd * gamma[c] + beta[c];
  }
  __syncthreads();
  for (int nn = tr; nn < 64; nn += 4) {
    hnT[(long)(n0 + nn) * 512 + c0 + tn] = f2bf(tile[tn][nn]);
  }
}

// ---------------- fp32 -> bf16 weight pack (4 weights + qk-bias in one launch) ----------------
__global__ __launch_bounds__(256) void pack4_bf16_k(const float* __restrict__ w0,
                                                    const float* __restrict__ w1,
                                                    const float* __restrict__ w2,
                                                    const float* __restrict__ w3,
                                                    unsigned short* __restrict__ o0,
                                                    unsigned short* __restrict__ o1,
                                                    unsigned short* __restrict__ o2,
                                                    unsigned short* __restrict__ o3,
                                                    const float* __restrict__ bq,
                                                    const float* __restrict__ bk,
                                                    float* __restrict__ bqk) {
  const int y = blockIdx.y;
  if (y == 4) {  // R21: pack_bias folded in (block 0 only)
    if (blockIdx.x == 0) {
      const int i = threadIdx.x * 4;
#pragma unroll
      for (int j = 0; j < 4; ++j) {
        const int t = i + j;
        bqk[t] = (t < 512) ? bq[t] : bk[t - 512];
      }
    }
    return;
  }
  const float* w = (y == 0) ? w0 : (y == 1) ? w1 : (y == 2) ? w2 : w3;
  unsigned short* o = (y == 0) ? o0 : (y == 1) ? o1 : (y == 2) ? o2 : o3;
  const int i = (blockIdx.x * 256 + threadIdx.x) * 4;
  const float4 v = *(const float4*)(w + i);
  ushort4 u; u.x = f2bf(v.x); u.y = f2bf(v.y); u.z = f2bf(v.z); u.w = f2bf(v.w);
  *(ushort4*)(o + i) = u;
}

// ================= BMxBNxBK NT GEMM, XCD-swizzled, bf16/fp8 =================
// C[n*ldc+m] = alpha*sum_k A[m,k]*B[n,k] (+bias)(+resid)
// WL=0, BM=256: 512 thr, 8 waves (2m x 4n), 1 block/CU, P2=0, setprio ON.
// WL=1: BM=128 x BN=128, 256 thr, 4 waves (2m x 2n, 64x64/wave).
//   fp8 KU=1: 32KB LDS, bounds(256,4). bf16: 64KB, 2 blocks/CU.
// WL=2 (R23): BM=128 x BN=128, 512 thr, 8 waves (2m x 4n, 64x32/wave), bf16.
//   Same 64KB LDS / 2 blocks/CU but 16 waves/CU = 4 waves/SIMD (2x TLP of
//   WL=1 bf16). qv was perfectly packed (measured == makespan lower bound) yet
//   MfmaUtil 17 / Occupancy 18 -- per-block latency at 2 waves/SIMD was the
//   bound (R13/R16: waves/SIMD is THE lever). Block-level code (staging,
//   swizzle, vmcnt -- GA/GB halve, formulas auto-derive) unchanged; per-wave:
//   wn in 0..3 owns B stripe chunk wn>>1 half wn&1 (32 global n-rows), one
//   8-mfma quad per phase, acc[4][2] (32 VGPR), n = by*128+wn*32+N*16+ln.
//   R19/R20: KU=2 on S FALSIFIED (LDS halves blocks/CU, TLP is binding).
//   Ladder: R13 S (TLP), R14 qk (makespan), R15 PV, R17 v+final, R21/22 folds.
//   A/B halves use 32-row stripe interleave: grow = (r>>5)*64 + h*32 + (r&31).
// P2=1 (2-phase): P0: read A0,B(own); stage [A0,B1,A1](W+1) -> s^1; mfma m0.
//   P1: read A1; stage B0(W+2) -> s; mfma m1.
//   Waits: @P0-end vmcnt(2(GA+GB)); @P1-end vmcnt(GA+GB); tail GA then 0.
// STATS: exp+rowsums, scratch stride NSLOT+1 (R18).
// SCALEN: 1 = *linv[n]; 2 = combine folded into prologue (R21).
// OUT_MODE: 0 bf16, 1 f32+resid, 2 fp8 e4m3 k-interleaved.
// MODE0: bz=bid%8 per XCD; MODE1/2: XCD y/x-chunking.
// MODE3 (R22): fused qk+v single dispatch; blocks < gx run qk (MODE1 8x18),
//   rest run v (MODE2 18x4) with params via resid/rowsums/linv.
template <int BM, int BIAS_MODE, int OUT_MODE, int STATS, int SCALEN, int MODE, int FP8, int P2,
          int WL = 0, int KU = 1>
__global__ __launch_bounds__((BM == 256 || WL == 2) ? 512 : 256, (WL == 1 && FP8) ? (KU == 2 ? 2 : 4) : 2)
void gemm256(const void* __restrict__ A, long lda, long sAz,
             const void* __restrict__ B, long ldb, long sBz,
             void* __restrict__ Cp, long ldc, long sCz,
             const float* __restrict__ bias,
             const float* __restrict__ resid,
             float* __restrict__ rowsums,
             const float* __restrict__ linv,
             float alpha, int K, int gx, int gy) {
  static_assert(KU == 1 || FP8, "KU=2 only on fp8 path");
  constexpr int EB = FP8 ? 1 : 2;                    // element bytes
  constexpr int THREADS = (BM == 256 || WL == 2) ? 512 : 256;
  constexpr int BN = WL ? 128 : 256;                 // n-tile
  constexpr int BK = 64 * KU;                        // k-step
  constexpr int HBA = (BM / 2) * BK * EB;            // bytes per A half
  constexpr int HBB = (BN / 2) * BK * EB;            // bytes per B half
  constexpr int HBA0 = HBA / KU, HBB0 = HBB / KU;    // per 64-k sub-block
  constexpr int GA = HBA / (THREADS * 16);           // gll per A-half stage
  constexpr int GB = HBB / (THREADS * 16);           // gll per B-half stage
  constexpr int GA0 = GA / KU, GB0 = GB / KU;        // gll per 64-k sub-stage
  constexpr int V0 = GB + 2 * GA, V3 = 2 * GB + GA, VP = GB + GA;
  constexpr int NSLOT = WL ? 8 : ((BM == 256) ? 8 : 4);
  constexpr int NSLOTP = NSLOT + 1;                  // R18: odd stride
  constexpr int MR = WL ? 4 : 8;                     // acc M-frags per wave
  constexpr int NR = (WL == 2) ? 2 : 4;              // acc N-frags per wave
  constexpr int FQ = WL ? 2 : 4;                     // A-frags per (mh) phase
  constexpr int PRIO = !P2;                          // setprio only on 1-block path
  __shared__ alignas(16) unsigned char As[2][2][HBA];
  __shared__ alignas(16) unsigned char Bs[2][2][HBB];
  __shared__ float linvs[SCALEN == 2 ? BN : 1];
  using ABt2 = typename std::conditional<FP8, longx2, bf2frag>::type;

  const int tid = threadIdx.x;
  const int lane = tid & 63, wid = tid >> 6;
  const int wm = (WL == 2) ? (wid >> 2) : (WL ? (wid >> 1) : ((BM == 256) ? (wid & 1) : 0));
  const int wn = (WL == 2) ? (wid & 3) : (WL ? (wid & 1) : ((BM == 256) ? (wid >> 1) : wid));
  int bx, by, bz;
  const void* Asel = A;
  const void* Bsel = B;
  void* Csel = Cp;
  const float* biasSel = bias;
  long ldcSel = ldc;
  bool bias_m = (BIAS_MODE == 1);
  {
    const int g8 = blockIdx.x & 7, n = blockIdx.x >> 3;
    if (MODE == 0) { bz = g8; bx = n % gx; by = n / gx; }
    else if (MODE == 1) { bz = 0; bx = n % gx; by = g8 * gy + n / gx; }
    else if (MODE == 2) { bz = 0; by = n % gy; bx = g8 * gx + n / gy; }
    else {  // MODE 3: fused qk+v; gx = number of qk blocks
      bz = 0;
      if ((int)blockIdx.x < gx) {
        bx = n % 8; by = g8 * 18 + n / 8;          // qk: MODE1 gx=8, gy=18
      } else {
        const int b2 = (int)blockIdx.x - gx;
        const int g82 = b2 & 7, n2 = b2 >> 3;
        by = n2 % 4; bx = g82 * 18 + n2 / 4;       // v: MODE2 gx=18, gy=4
        Asel = B;                                   // hnT
        Bsel = (const void*)resid;                  // wvb
        Csel = (void*)rowsums;                      // vT
        biasSel = linv;                             // bv
        ldcSel = 18432;
        bias_m = false;
      }
    }
  }
  const unsigned char* Ab = (const unsigned char*)Asel + ((long)bz * sAz + (long)bx * BM * lda) * EB;
  const unsigned char* Bb = (const unsigned char*)Bsel + ((long)bz * sBz + (long)by * BN * ldb) * EB;

  // R21 (SCALEN==2): fold combine -- compute 1/L for this block's rows first,
  // so the scalar loads retire before any gll enters the vmcnt FIFO.
  if constexpr (SCALEN == 2) {
    if (tid < BN) {
      const int ntile = K / BN;
      float L = 0.f;
      for (int xx = 0; xx < ntile; ++xx)
        L += rowsums[((long)(bz * ntile + xx)) * K + by * BN + tid];
      linvs[tid] = 1.0f / L;
    }
  }

  // ---- staging (global -> LDS, pre-swizzled source; fp8 global is k-interleaved) ----
  auto stageA = [&](int slot, int h, int k0) {
    if constexpr (!FP8) {
      const int ksw = ((tid & 7) << 3) ^ (((tid >> 3) & 7) << 3);
#pragma unroll
      for (int call = 0; call < GA; ++call) {
        const int r = call * (THREADS / 8) + (tid >> 3);
        const int grow = WL ? (((r >> 5) << 6) + h * 32 + (r & 31))
                            : (((r >> 6) << 7) + h * 64 + (r & 63));
        gll(Ab + ((long)grow * lda + k0) * 2 + ksw * 2, &As[slot][h][call * THREADS * 16 + tid * 16]);
      }
    } else {
#pragma unroll
      for (int call = 0; call < GA; ++call) {
        const int sub = call / GA0, c0 = call % GA0;
        const int l = c0 * (THREADS / 4) + (tid >> 2);
        const int grow = WL ? (((l >> 5) << 6) + h * 32 + (l & 31))
                            : (((l >> 6) << 7) + h * 64 + (l & 63));
        const int x = (((l & 3) ^ ((l >> 2) & 3)) << 4);
        gll(Ab + (long)grow * lda + k0 + sub * 64 + (((tid & 3) << 4) ^ x),
            &As[slot][h][call * THREADS * 16 + tid * 16]);
      }
    }
  };
  auto stageB = [&](int slot, int h, int k0) {
    if constexpr (!FP8) {
      const int ksw = ((tid & 7) << 3) ^ (((tid >> 3) & 7) << 3);
#pragma unroll
      for (int call = 0; call < GB; ++call) {
        const int r = call * (THREADS / 8) + (tid >> 3);
        const int grow = ((r >> 5) << 6) + h * 32 + (r & 31);
        gll(Bb + ((long)grow * ldb + k0) * 2 + ksw * 2, &Bs[slot][h][call * THREADS * 16 + tid * 16]);
      }
    } else {
#pragma unroll
      for (int call = 0; call < GB; ++call) {
        const int sub = call / GB0, c0 = call % GB0;
        const int l = c0 * (THREADS / 4) + (tid >> 2);
        const int grow = ((l >> 5) << 6) + h * 32 + (l & 31);
        const int x = (((l & 3) ^ ((l >> 2) & 3)) << 4);
        gll(Bb + (long)grow * ldb + k0 + sub * 64 + (((tid & 3) << 4) ^ x),
            &Bs[slot][h][call * THREADS * 16 + tid * 16]);
      }
    }
  };
  // ---- LDS -> fragment reads (same swizzle; fp8 = ONE b128 for both k2 slices) ----
  auto ldA = [&](int slot, int mh, int fq, int sub) -> ABt2 {
    const int r = (WL ? wm * 32 : wm * 64) + fq * 16 + (lane & 15);
    if constexpr (!FP8) {
      bf2frag f;
      const int kk0 = (((lane >> 4) << 3)) ^ ((r & 7) << 3);
      const int kk1 = (32 + ((lane >> 4) << 3)) ^ ((r & 7) << 3);
      f.k0 = *reinterpret_cast<const bf16x8*>(&As[slot][mh][r * 128 + kk0 * 2]);
      f.k1 = *reinterpret_cast<const bf16x8*>(&As[slot][mh][r * 128 + kk1 * 2]);
      return f;
    } else {
      const int x = (((r & 3) ^ ((r >> 2) & 3)) << 4);
      const int kk = ((lane >> 4) << 4) ^ x;
      return *reinterpret_cast<const longx2*>(&As[slot][mh][sub * HBA0 + r * 64 + kk]);
    }
  };
  auto ldB = [&](int slot, int nh, int g, int sub) -> ABt2 {
    // WL=2: wave owns 32 global n-rows = stripe chunk wn>>1, half wn&1.
    const int half = (WL == 2) ? (wn & 1) : nh;
    const int r = ((WL == 2) ? (wn >> 1) : wn) * 32 + g * 16 + (lane & 15);
    if constexpr (!FP8) {
      bf2frag f;
      const int kk0 = (((lane >> 4) << 3)) ^ ((r & 7) << 3);
      const int kk1 = (32 + ((lane >> 4) << 3)) ^ ((r & 7) << 3);
      f.k0 = *reinterpret_cast<const bf16x8*>(&Bs[slot][half][r * 128 + kk0 * 2]);
      f.k1 = *reinterpret_cast<const bf16x8*>(&Bs[slot][half][r * 128 + kk1 * 2]);
      return f;
    } else {
      const int x = (((r & 3) ^ ((r >> 2) & 3)) << 4);
      const int kk = ((lane >> 4) << 4) ^ x;
      return *reinterpret_cast<const longx2*>(&Bs[slot][half][sub * HBB0 + r * 64 + kk]);
    }
  };

  f32x4 acc[MR][NR] = {};
  ABt2 a[FQ * KU], b0[2 * KU], b1[2 * KU];

#define READ_A(SLOT, MH)                                                       \
  _Pragma("unroll") for (int fq = 0; fq < FQ; ++fq)                            \
    _Pragma("unroll") for (int sub = 0; sub < KU; ++sub)                       \
      a[fq * KU + sub] = ldA(SLOT, MH, fq, sub);
#define READ_B(SLOT, NH, DST)                                                  \
  _Pragma("unroll") for (int g = 0; g < 2; ++g)                                \
    _Pragma("unroll") for (int sub = 0; sub < KU; ++sub)                       \
      DST[g * KU + sub] = ldB(SLOT, NH, g, sub);
#define MFMA_QUAD(MH, NH, BARR)                                                \
  if constexpr (PRIO) __builtin_amdgcn_s_setprio(1);                           \
  _Pragma("unroll") for (int fq = 0; fq < FQ; ++fq)                            \
    _Pragma("unroll") for (int g = 0; g < 2; ++g)                              \
      _Pragma("unroll") for (int sub = 0; sub < KU; ++sub)                     \
        _Pragma("unroll") for (int k2 = 0; k2 < 2; ++k2)                       \
          acc[(MH) * FQ + fq][(NH) * 2 + g] =                                  \
              mmak(a[fq * KU + sub], BARR[g * KU + sub],                       \
                   acc[(MH) * FQ + fq][(NH) * 2 + g], k2);                     \
  if constexpr (PRIO) __builtin_amdgcn_s_setprio(0);

  const int KT = K / BK;
  // Prologue queue: [B0(0), A0(0), B1(0), A1(0), B0(1)] (+A1(1) for P2=0)
  stageB(0, 0, 0);
  stageA(0, 0, 0);
  stageB(0, 1, 0);
  stageA(0, 1, 0);
  stageB(1, 0, BK);
  if constexpr (!P2) stageA(1, 1, BK);
  vmw<VP>();
  bar();

  if constexpr (!P2) {
    for (int W = 0; W < KT; ++W) {
      const int s = W & 1;
      const int kn1 = (W + 1) * BK, kn2 = (W + 2) * BK;
      const bool st1 = (W + 1 < KT), st2 = (W + 2 < KT);
      // p0: (m0,n0)
      READ_A(s, 0)
      READ_B(s, 0, b0)
      if (st1) stageA(s ^ 1, 0, kn1);
      bar();
      MFMA_QUAD(0, 0, b0)
      if (st1) { vmw<V0>(); }
      bar();
      // p1: (m0,n1)
      READ_B(s, 1, b1)
      if (st1) stageB(s ^ 1, 1, kn1);
      bar();
      MFMA_QUAD(0, 1, b1)
      bar();
      // p2: (m1,n1)
      READ_A(s, 1)
      if (st2) stageB(s, 0, kn2);
      bar();
      MFMA_QUAD(1, 1, b1)
      bar();
      // p3: (m1,n0)
      if (st2) stageA(s, 1, kn2);
      bar();
      MFMA_QUAD(1, 0, b0)
      if (st2) { vmw<V3>(); } else { vmw<0>(); }
      bar();
    }
  } else {
    for (int W = 0; W < KT; ++W) {
      const int s = W & 1;
      const int kn1 = (W + 1) * BK, kn2 = (W + 2) * BK;
      const bool st1 = (W + 1 < KT), st2 = (W + 2 < KT);
      // P0: m0 x (WL=2: own B-half | else: n0,n1); stage trio (A1 LAST).
      READ_A(s, 0)
      READ_B(s, 0, b0)
      if constexpr (WL != 2) { READ_B(s, 1, b1) }
      if (st1) { stageA(s ^ 1, 0, kn1); stageB(s ^ 1, 1, kn1); stageA(s ^ 1, 1, kn1); }
      bar();
      MFMA_QUAD(0, 0, b0)
      if constexpr (WL != 2) { MFMA_QUAD(0, 1, b1) }
      if (st1) { vmw<2 * (GA + GB)>(); } else { vmw<0>(); }
      bar();
      // P1: m1; stage B0(W+2) into current slot (B0(W) consumed in P0).
      READ_A(s, 1)
      if (st2) stageB(s, 0, kn2);
      bar();
      if constexpr (WL != 2) { MFMA_QUAD(1, 1, b1) }
      MFMA_QUAD(1, 0, b0)
      if (st2) { vmw<GA + GB>(); } else if (st1) { vmw<GA>(); } else { vmw<0>(); }
      bar();
    }
  }

  // epilogue: acc[M][N].
  // WL=0: M = mh*4+fq, m-off = (M>>2)*64 + (M&3)*16, wave m-base wm*128.
  // WL>=1: M = mh*2+fq, m-off = (M>>1)*32 + (M&1)*16, wave m-base wm*64.
  // WL=2: N in {0,1}, n = by*128 + wn*32 + N*16 + (lane&15).
  const int mg0 = bx * BM + (WL ? wm * 64 : wm * 128) + ((lane >> 4) << 2);
  const int ng0 = by * BN + ((WL == 2) ? wn * 32 : wn * 64) + (lane & 15);
  float* red = (float*)&As[0][0][0];  // STATS scratch: BN rows x NSLOTP f32
#pragma unroll
  for (int N = 0; N < NR; ++N) {
    const int n = ng0 + ((WL == 2) ? N * 16 : ((N >> 1) * 32 + (N & 1) * 16));
    float bn;
    if constexpr (MODE == 3) bn = bias_m ? 0.f : biasSel[n];
    else bn = (BIAS_MODE == 2) ? bias[n] : 0.f;
    const float sc = (SCALEN == 1) ? linv[(long)bz * 2304 + n]
                   : (SCALEN == 2) ? linvs[n - by * BN] : 1.0f;
    float eN = 0.f;
#pragma unroll
    for (int M = 0; M < MR; ++M) {
      const int m = mg0 + (WL ? ((M >> 1) * 32 + (M & 1) * 16) : ((M >> 2) * 64 + (M & 3) * 16));
      const f32x4 av = acc[M][N];
      float vals[4];
#pragma unroll
      for (int j = 0; j < 4; ++j) {
        float addv;
        if constexpr (MODE == 3) addv = bias_m ? biasSel[m + j] : bn;
        else if constexpr (BIAS_MODE == 1) addv = bias[m + j];
        else addv = bn;
        vals[j] = av[j] * alpha + addv;
        if (SCALEN) vals[j] *= sc;
        if (STATS) { vals[j] = __expf(vals[j]); eN += vals[j]; }
      }
      if (OUT_MODE == 0) {
        ushort4 o; o.x = f2bf(vals[0]); o.y = f2bf(vals[1]); o.z = f2bf(vals[2]); o.w = f2bf(vals[3]);
        *(ushort4*)((unsigned short*)Csel + (long)bz * sCz + (long)n * ldcSel + m) = o;
      } else if (OUT_MODE == 2) {
        int pk = __builtin_amdgcn_cvt_pk_fp8_f32(vals[0], vals[1], 0, false);
        pk = __builtin_amdgcn_cvt_pk_fp8_f32(vals[2], vals[3], pk, true);
        *(int*)((unsigned char*)Csel + (long)bz * sCz + (long)n * ldcSel + perm64(m)) = pk;
      } else {
        const float* rp = resid + (long)n * ldcSel + m;
        float4 o; o.x = vals[0] + rp[0]; o.y = vals[1] + rp[1]; o.z = vals[2] + rp[2]; o.w = vals[3] + rp[3];
        *(float4*)((float*)Csel + (long)bz * sCz + (long)n * ldcSel + m) = o;
      }
    }
    if (STATS) {
      const int nloc = n - by * BN;
      const int slot = wm * 4 + (lane >> 4);
      red[nloc * NSLOTP + slot] = eN;
    }
  }
  if (STATS) {
    bar();
    if (tid < BN) {
      float L = 0.f;
#pragma unroll
      for (int s2 = 0; s2 < NSLOT; ++s2) L += red[tid * NSLOTP + s2];
      rowsums[((long)(bz * gx + bx)) * 2304 + by * BN + tid] = L;
    }
  }
#undef READ_A
#undef READ_B
#undef MFMA_QUAD
}

extern "C" void kernel_launch(void* const* d_in, const int* in_sizes, int n_in,
                              void* d_out, int out_size, void* d_ws, size_t ws_size,
                              hipStream_t stream) {
  const float* x = (const float*)d_in[0];
  const float* gamma = (const float*)d_in[1];
  const float* beta = (const float*)d_in[2];
  const float* wq = (const float*)d_in[3];
  const float* bq = (const float*)d_in[4];
  const float* wk = (const float*)d_in[5];
  const float* bk = (const float*)d_in[6];
  const float* wv = (const float*)d_in[7];
  const float* bv = (const float*)d_in[8];
  const float* wo = (const float*)d_in[9];
  const float* bo = (const float*)d_in[10];
  float* out = (float*)d_out;

  char* ws = (char*)d_ws;
  size_t off = 0;
  auto alloc = [&](size_t bytes) {
    char* p = ws + off;
    off = (off + bytes + 255) & ~(size_t)255;
    return p;
  };
  float* part = (float*)alloc(256 * 2 * sizeof(float));
  unsigned short* wqkb = (unsigned short*)alloc((size_t)2 * 262144 * 2);
  unsigned short* wvb = (unsigned short*)alloc((size_t)262144 * 2);
  unsigned short* wob = (unsigned short*)alloc((size_t)262144 * 2);
  float* bqk = (float*)alloc(1024 * sizeof(float));
  float* rowsums = (float*)alloc((size_t)8 * 18 * 2304 * sizeof(float));
  unsigned short* hnT = (unsigned short*)alloc((size_t)18432 * 512 * 2);
  unsigned char* qkA = (unsigned char*)alloc((size_t)18432 * 1024);      // fp8 k-interleaved
  unsigned char* vT = (unsigned char*)alloc((size_t)512 * 18432);        // fp8 k-interleaved
  unsigned char* Sm = (unsigned char*)alloc((size_t)8 * 2304 * 2304);    // fp8 E k-interleaved
  unsigned short* Ob = hnT;  // alias: hnT fully consumed after qk/v GEMMs
  (void)ws_size; (void)in_sizes; (void)n_in; (void)out_size;

  stats_partial_k<<<dim3(256), dim3(256), 0, stream>>>(x, part);
  gn_transpose_k<<<dim3(8, 288), dim3(256), 0, stream>>>(x, part, gamma, beta, hnT);
  pack4_bf16_k<<<dim3(256, 5), dim3(256), 0, stream>>>(wq, wk, wv, wo,
                                                       wqkb, wqkb + 262144, wvb, wob,
                                                       bq, bk, bqk);

  // R23: fused qk+v (MODE3) on WL=2 (512 thr, 8 waves, 4 waves/SIMD).
  // Blocks [0,1152): qk -- A=[Wq;Wk] bf16, B=hnT -> qkA fp8 [sp][1024].
  // Blocks [1152,1728): v -- A=hnT, B=wvb -> vT fp8 [co][18432].
  gemm256<128, 1, 2, 0, 0, 3, 0, 1, 2><<<dim3(1728), dim3(512), 0, stream>>>(
      wqkb, 512, 0, hnT, 512, 0, (void*)qkA, 1024, 0, bqk,
      (const float*)wvb, (float*)vT, bv, 1.0f, 512, 1152, 0);
  // S: per t: A=k fp8, B=q fp8 -> E=exp(alpha*S) fp8 interleaved + rowsums.
  // WL=1 fp8 KU=1 (32KB LDS, 4 blocks/CU): 2592 blocks MODE0.
  gemm256<128, 0, 2, 1, 0, 0, 1, 1, 1><<<dim3(2592), dim3(256), 0, stream>>>(
      qkA + 512, 1024, (long)2304 * 1024, qkA, 1024, (long)2304 * 1024, (void*)Sm, 2304,
      (long)2304 * 2304, nullptr, nullptr, rowsums, nullptr,
      0.044194173824159216f, 512, 18, 18);
  // PV: per t: A=vT fp8, B=E fp8 -> O bf16 [(t,i)*512+c], rows scaled by 1/L.
  // SCALEN=2 -- combine folded into PV prologue (reads rowsums directly).
  // WL=1 fp8 KU=1: 4x18x8 = 576 blocks MODE0.
  gemm256<128, 0, 0, 0, 2, 0, 1, 1, 1><<<dim3(576), dim3(256), 0, stream>>>(
      vT, 18432, 2304, Sm, 2304, (long)2304 * 2304, (void*)Ob, 512, (long)2304 * 512,
      nullptr, nullptr, rowsums, nullptr, 1.0f, 2304, 4, 18);
  // final: A=O bf16, B=Wo bf16 -> out[co*18432+sp] = x + acc + bo[co].
  // WL=1 bf16, MODE2: 8 x 18 x 4 = 576 blocks.
  gemm256<128, 2, 1, 0, 0, 2, 0, 1, 1><<<dim3(576), dim3(256), 0, stream>>>(
      Ob, 512, 0, wob, 512, 0, (void*)out, 18432, 0, bo, x, nullptr, nullptr,
      1.0f, 512, 18, 4);
}

// Round 15
// 209.869 us; speedup vs baseline: 1.2712x; 1.0033x over previous
//
#include <hip/hip_runtime.h>
#include <hip/hip_bf16.h>
#include <cstdint>
#include <type_traits>

typedef __attribute__((ext_vector_type(8))) __bf16 bf16x8;
typedef __attribute__((ext_vector_type(4))) float f32x4;
typedef __attribute__((ext_vector_type(2))) long longx2;

struct bf2frag { bf16x8 k0, k1; };

__device__ __forceinline__ float bf2f(unsigned short u) {
  union { uint32_t i; float f; } v; v.i = (uint32_t)u << 16; return v.f;
}
__device__ __forceinline__ unsigned short f2bf(float f) {
  union { float f; uint32_t i; } v{f};
  uint32_t r = v.i + 0x7fffu + ((v.i >> 16) & 1u);
  return (unsigned short)(r >> 16);
}

__device__ __forceinline__ void gll(const void* g, void* l) {
  __builtin_amdgcn_global_load_lds(
      (const __attribute__((address_space(1))) uint32_t*)(uintptr_t)g,
      (__attribute__((address_space(3))) uint32_t*)(uint32_t)(uintptr_t)l,
      16, 0, 0);
}

__device__ __forceinline__ void bar() {
  asm volatile("" ::: "memory");
  __builtin_amdgcn_s_barrier();
  asm volatile("" ::: "memory");
}

#define VMCNT(n) asm volatile("s_waitcnt vmcnt(" #n ")" ::: "memory")

template <int N>
__device__ __forceinline__ void vmw() {
  if constexpr (N == 0) { VMCNT(0); }
  else if constexpr (N == 1) { VMCNT(1); }
  else if constexpr (N == 2) { VMCNT(2); }
  else if constexpr (N == 3) { VMCNT(3); }
  else if constexpr (N == 4) { VMCNT(4); }
  else if constexpr (N == 5) { VMCNT(5); }
  else if constexpr (N == 6) { VMCNT(6); }
  else if constexpr (N == 7) { VMCNT(7); }
  else if constexpr (N == 8) { VMCNT(8); }
  else if constexpr (N == 9) { VMCNT(9); }
  else if constexpr (N == 10) { VMCNT(10); }
  else { VMCNT(12); }
}

__device__ __forceinline__ f32x4 mma(bf16x8 a, bf16x8 b, f32x4 c) {
  return __builtin_amdgcn_mfma_f32_16x16x32_bf16(a, b, c, 0, 0, 0);
}
__device__ __forceinline__ f32x4 mma(long a, long b, f32x4 c) {
  return __builtin_amdgcn_mfma_f32_16x16x32_fp8_fp8(a, b, c, 0, 0, 0);
}
__device__ __forceinline__ f32x4 mmak(const bf2frag& a, const bf2frag& b, f32x4 c, int k2) {
  return k2 ? mma(a.k1, b.k1, c) : mma(a.k0, b.k0, c);
}
__device__ __forceinline__ f32x4 mmak(longx2 a, longx2 b, f32x4 c, int k2) {
  return mma(a[k2], b[k2], c);
}

// k-interleave store permutation for fp8 buffers (unit u=8B: slot p(u)=(u&3)*2+(u>>2))
__device__ __forceinline__ int perm64(int m) {
  return (m & ~63) | (((m >> 3) & 3) << 4) | (((m >> 5) & 1) << 3) | (m & 7);
}

// ---------------- GroupNorm stats ----------------
__global__ __launch_bounds__(256) void stats_partial_k(const float* __restrict__ x,
                                                       float* __restrict__ part) {
  const int g = blockIdx.x >> 3, p = blockIdx.x & 7;
  const float* base = x + (long)g * 16 * 18432 + (long)p * 2304;
  float s = 0.f, ss = 0.f;
  for (int idx = threadIdx.x; idx < 16 * 576; idx += 256) {
    const int c = idx / 576, i4 = idx % 576;
    const float4 v = *(const float4*)(base + (long)c * 18432 + i4 * 4);
    s += v.x + v.y + v.z + v.w;
    ss += v.x * v.x + v.y * v.y + v.z * v.z + v.w * v.w;
  }
  __shared__ float rs[256], rss[256];
  rs[threadIdx.x] = s; rss[threadIdx.x] = ss;
  __syncthreads();
  for (int o = 128; o > 0; o >>= 1) {
    if ((int)threadIdx.x < o) { rs[threadIdx.x] += rs[threadIdx.x + o]; rss[threadIdx.x] += rss[threadIdx.x + o]; }
    __syncthreads();
  }
  if (threadIdx.x == 0) { part[blockIdx.x * 2] = rs[0]; part[blockIdx.x * 2 + 1] = rss[0]; }
}

// ---------------- GN apply + transpose to (spatial, channel) bf16 ----------------
// R21: stats_final folded in -- each block reduces part[] for its own 4 groups.
__global__ __launch_bounds__(256) void gn_transpose_k(const float* __restrict__ x,
                                                      const float* __restrict__ part,
                                                      const float* __restrict__ gamma,
                                                      const float* __restrict__ beta,
                                                      unsigned short* __restrict__ hnT) {
  __shared__ float tile[64][65];
  __shared__ float sm[4], sr[4];
  const int c0 = blockIdx.x * 64, n0 = blockIdx.y * 64;
  const int tn = threadIdx.x & 63, tr = threadIdx.x >> 6;
  if (threadIdx.x < 4) {
    const int g = (c0 >> 4) + threadIdx.x;
    float s = 0.f, ss = 0.f;
    for (int p = 0; p < 8; ++p) { s += part[(g * 8 + p) * 2]; ss += part[(g * 8 + p) * 2 + 1]; }
    const float mean = s / 294912.0f;
    const float var = ss / 294912.0f - mean * mean;
    sm[threadIdx.x] = mean;
    sr[threadIdx.x] = rsqrtf(var + 1e-6f);
  }
  __syncthreads();
  for (int cc = tr; cc < 64; cc += 4) {
    const int c = c0 + cc;
    const float mean = sm[cc >> 4], rstd = sr[cc >> 4];
    const float v = x[(long)c * 18432 + n0 + tn];
    tile[cc][tn] = (v - mean) * rstd * gamma[c] + beta[c];
  }
  __syncthreads();
  for (int nn = tr; nn < 64; nn += 4) {
    hnT[(long)(n0 + nn) * 512 + c0 + tn] = f2bf(tile[tn][nn]);
  }
}

// ---------------- fp32 -> bf16 weight pack (4 weights + qk-bias in one launch) ----------------
__global__ __launch_bounds__(256) void pack4_bf16_k(const float* __restrict__ w0,
                                                    const float* __restrict__ w1,
                                                    const float* __restrict__ w2,
                                                    const float* __restrict__ w3,
                                                    unsigned short* __restrict__ o0,
                                                    unsigned short* __restrict__ o1,
                                                    unsigned short* __restrict__ o2,
                                                    unsigned short* __restrict__ o3,
                                                    const float* __restrict__ bq,
                                                    const float* __restrict__ bk,
                                                    float* __restrict__ bqk) {
  const int y = blockIdx.y;
  if (y == 4) {  // R21: pack_bias folded in (block 0 only)
    if (blockIdx.x == 0) {
      const int i = threadIdx.x * 4;
#pragma unroll
      for (int j = 0; j < 4; ++j) {
        const int t = i + j;
        bqk[t] = (t < 512) ? bq[t] : bk[t - 512];
      }
    }
    return;
  }
  const float* w = (y == 0) ? w0 : (y == 1) ? w1 : (y == 2) ? w2 : w3;
  unsigned short* o = (y == 0) ? o0 : (y == 1) ? o1 : (y == 2) ? o2 : o3;
  const int i = (blockIdx.x * 256 + threadIdx.x) * 4;
  const float4 v = *(const float4*)(w + i);
  ushort4 u; u.x = f2bf(v.x); u.y = f2bf(v.y); u.z = f2bf(v.z); u.w = f2bf(v.w);
  *(ushort4*)(o + i) = u;
}

// ================= BMxBNxBK NT GEMM, XCD-swizzled, bf16/fp8 =================
// C[n*ldc+m] = alpha*sum_k A[m,k]*B[n,k] (+bias)(+resid)
// WL=0, BM=256: 512 thr, 8 waves (2m x 4n), 1 block/CU, P2=0, setprio ON.
// WL=1: BM=128 x BN=128, 256 thr, 4 waves (2m x 2n, 64x64/wave).
//   fp8 KU=1: 32KB LDS, bounds(256,4). bf16: 64KB, 2 blocks/CU.
// WL=2: BM=128 x BN=128, 512 thr, 8 waves (2m x 4n, 64x32/wave).
//   bf16 (R23, qv-proven; R24 final): 64KB LDS, 2 blocks/CU, 4 waves/SIMD.
//   fp8 (R24, S): 32KB LDS, bounds(512,8) -> 4 blocks/CU, 32 waves/CU =
//   8 waves/SIMD (2x the WL=1-fp8 TLP; intra-block waves -- guaranteed
//   co-resident, unlike R16's extra-blocks null). Per-half stage = 4096B <
//   one 512-thr gll round -> FULL-TILE stages (8192B = 1 gll/thread; LDS
//   dest linear: As[slot][0..1] contiguous, tid*16 spans halves).
//   WL2-fp8 schedule (FIFO re-derived): prologue [Afull(0),Bfull(0),Bfull(1)],
//   vmcnt(1); P0: read A0+ownB, stage Afull(W+1)->s^1 (A of s^1 dead since
//   W-1 P1-end bar), mfma m0, NO vmcnt; P1: read A1, stage Bfull(W+2)->s
//   (all B reads of s were in P0, bar passed), mfma m1, vmcnt(st2?1:0)
//   (drain {B,A}(W+1), keep B(W+2) in flight). Tail OK at KT=8.
//   R19/R20: KU=2 on S FALSIFIED (LDS halves blocks/CU, TLP is binding).
//   Ladder: R13 S (TLP), R14 qk, R15 PV, R17 v+final, R21/22 folds, R23 qv WL2.
//   A/B halves use 32-row stripe interleave: grow = (r>>5)*64 + h*32 + (r&31).
// P2=1 (2-phase, WL<2 or bf16): P0: read A0,B; stage [A0,B1,A1](W+1) -> s^1;
//   mfma m0. P1: read A1; stage B0(W+2) -> s; mfma m1.
//   Waits: @P0-end vmcnt(2(GA+GB)); @P1-end vmcnt(GA+GB); tail GA then 0.
// STATS: exp+rowsums, scratch stride NSLOT+1 (R18).
// SCALEN: 1 = *linv[n]; 2 = combine folded into prologue (R21).
// OUT_MODE: 0 bf16, 1 f32+resid, 2 fp8 e4m3 k-interleaved.
// MODE0: bz=bid%8 per XCD; MODE1/2: XCD y/x-chunking.
// MODE3 (R22): fused qk+v single dispatch; blocks < gx run qk (MODE1 8x18),
//   rest run v (MODE2 18x4) with params via resid/rowsums/linv.
template <int BM, int BIAS_MODE, int OUT_MODE, int STATS, int SCALEN, int MODE, int FP8, int P2,
          int WL = 0, int KU = 1>
__global__ __launch_bounds__((BM == 256 || WL == 2) ? 512 : 256,
                             (WL == 1 && FP8) ? (KU == 2 ? 2 : 4) : ((WL == 2 && FP8) ? 8 : 2))
void gemm256(const void* __restrict__ A, long lda, long sAz,
             const void* __restrict__ B, long ldb, long sBz,
             void* __restrict__ Cp, long ldc, long sCz,
             const float* __restrict__ bias,
             const float* __restrict__ resid,
             float* __restrict__ rowsums,
             const float* __restrict__ linv,
             float alpha, int K, int gx, int gy) {
  static_assert(KU == 1 || FP8, "KU=2 only on fp8 path");
  constexpr int EB = FP8 ? 1 : 2;                    // element bytes
  constexpr int THREADS = (BM == 256 || WL == 2) ? 512 : 256;
  constexpr int BN = WL ? 128 : 256;                 // n-tile
  constexpr int BK = 64 * KU;                        // k-step
  constexpr int HBA = (BM / 2) * BK * EB;            // bytes per A half
  constexpr int HBB = (BN / 2) * BK * EB;            // bytes per B half
  constexpr int HBA0 = HBA / KU, HBB0 = HBB / KU;    // per 64-k sub-block
  constexpr bool FT = (WL == 2 && FP8);              // full-tile staging path
  constexpr int GA = FT ? 1 : HBA / (THREADS * 16);  // gll per A stage unit
  constexpr int GB = FT ? 1 : HBB / (THREADS * 16);  // gll per B stage unit
  constexpr int GA0 = FT ? 1 : GA / KU, GB0 = FT ? 1 : GB / KU;
  constexpr int V0 = GB + 2 * GA, V3 = 2 * GB + GA, VP = GB + GA;
  constexpr int NSLOT = WL ? 8 : ((BM == 256) ? 8 : 4);
  constexpr int NSLOTP = NSLOT + 1;                  // R18: odd stride
  constexpr int MR = WL ? 4 : 8;                     // acc M-frags per wave
  constexpr int NR = (WL == 2) ? 2 : 4;              // acc N-frags per wave
  constexpr int FQ = WL ? 2 : 4;                     // A-frags per (mh) phase
  constexpr int PRIO = !P2;                          // setprio only on 1-block path
  __shared__ alignas(16) unsigned char As[2][2][HBA];
  __shared__ alignas(16) unsigned char Bs[2][2][HBB];
  __shared__ float linvs[SCALEN == 2 ? BN : 1];
  using ABt2 = typename std::conditional<FP8, longx2, bf2frag>::type;

  const int tid = threadIdx.x;
  const int lane = tid & 63, wid = tid >> 6;
  const int wm = (WL == 2) ? (wid >> 2) : (WL ? (wid >> 1) : ((BM == 256) ? (wid & 1) : 0));
  const int wn = (WL == 2) ? (wid & 3) : (WL ? (wid & 1) : ((BM == 256) ? (wid >> 1) : wid));
  int bx, by, bz;
  const void* Asel = A;
  const void* Bsel = B;
  void* Csel = Cp;
  const float* biasSel = bias;
  long ldcSel = ldc;
  bool bias_m = (BIAS_MODE == 1);
  {
    const int g8 = blockIdx.x & 7, n = blockIdx.x >> 3;
    if (MODE == 0) { bz = g8; bx = n % gx; by = n / gx; }
    else if (MODE == 1) { bz = 0; bx = n % gx; by = g8 * gy + n / gx; }
    else if (MODE == 2) { bz = 0; by = n % gy; bx = g8 * gx + n / gy; }
    else {  // MODE 3: fused qk+v; gx = number of qk blocks
      bz = 0;
      if ((int)blockIdx.x < gx) {
        bx = n % 8; by = g8 * 18 + n / 8;          // qk: MODE1 gx=8, gy=18
      } else {
        const int b2 = (int)blockIdx.x - gx;
        const int g82 = b2 & 7, n2 = b2 >> 3;
        by = n2 % 4; bx = g82 * 18 + n2 / 4;       // v: MODE2 gx=18, gy=4
        Asel = B;                                   // hnT
        Bsel = (const void*)resid;                  // wvb
        Csel = (void*)rowsums;                      // vT
        biasSel = linv;                             // bv
        ldcSel = 18432;
        bias_m = false;
      }
    }
  }
  const unsigned char* Ab = (const unsigned char*)Asel + ((long)bz * sAz + (long)bx * BM * lda) * EB;
  const unsigned char* Bb = (const unsigned char*)Bsel + ((long)bz * sBz + (long)by * BN * ldb) * EB;

  // R21 (SCALEN==2): fold combine -- compute 1/L for this block's rows first,
  // so the scalar loads retire before any gll enters the vmcnt FIFO.
  if constexpr (SCALEN == 2) {
    if (tid < BN) {
      const int ntile = K / BN;
      float L = 0.f;
      for (int xx = 0; xx < ntile; ++xx)
        L += rowsums[((long)(bz * ntile + xx)) * K + by * BN + tid];
      linvs[tid] = 1.0f / L;
    }
  }

  // ---- staging (global -> LDS, pre-swizzled source; fp8 global is k-interleaved) ----
  auto stageA = [&](int slot, int h, int k0) {
    if constexpr (!FP8) {
      const int ksw = ((tid & 7) << 3) ^ (((tid >> 3) & 7) << 3);
#pragma unroll
      for (int call = 0; call < GA; ++call) {
        const int r = call * (THREADS / 8) + (tid >> 3);
        const int grow = WL ? (((r >> 5) << 6) + h * 32 + (r & 31))
                            : (((r >> 6) << 7) + h * 64 + (r & 63));
        gll(Ab + ((long)grow * lda + k0) * 2 + ksw * 2, &As[slot][h][call * THREADS * 16 + tid * 16]);
      }
    } else {
#pragma unroll
      for (int call = 0; call < GA; ++call) {
        const int sub = call / GA0, c0 = call % GA0;
        const int l = c0 * (THREADS / 4) + (tid >> 2);
        const int grow = WL ? (((l >> 5) << 6) + h * 32 + (l & 31))
                            : (((l >> 6) << 7) + h * 64 + (l & 63));
        const int x = (((l & 3) ^ ((l >> 2) & 3)) << 4);
        gll(Ab + (long)grow * lda + k0 + sub * 64 + (((tid & 3) << 4) ^ x),
            &As[slot][h][call * THREADS * 16 + tid * 16]);
      }
    }
  };
  auto stageB = [&](int slot, int h, int k0) {
    if constexpr (!FP8) {
      const int ksw = ((tid & 7) << 3) ^ (((tid >> 3) & 7) << 3);
#pragma unroll
      for (int call = 0; call < GB; ++call) {
        const int r = call * (THREADS / 8) + (tid >> 3);
        const int grow = ((r >> 5) << 6) + h * 32 + (r & 31);
        gll(Bb + ((long)grow * ldb + k0) * 2 + ksw * 2, &Bs[slot][h][call * THREADS * 16 + tid * 16]);
      }
    } else {
#pragma unroll
      for (int call = 0; call < GB; ++call) {
        const int sub = call / GB0, c0 = call % GB0;
        const int l = c0 * (THREADS / 4) + (tid >> 2);
        const int grow = ((l >> 5) << 6) + h * 32 + (l & 31);
        const int x = (((l & 3) ^ ((l >> 2) & 3)) << 4);
        gll(Bb + (long)grow * ldb + k0 + sub * 64 + (((tid & 3) << 4) ^ x),
            &Bs[slot][h][call * THREADS * 16 + tid * 16]);
      }
    }
  };
  // WL2-fp8 full-tile stages: 1 gll/thread covers both halves (8192B).
  // tid = hh*256 + tl; per-half mapping identical to WL=1 fp8 (THREADS=256, GA=1).
  auto stageAF = [&](int slot, int k0) {
    const int hh = tid >> 8, tl = tid & 255;
    const int l = tl >> 2;
    const int grow = ((l >> 5) << 6) + hh * 32 + (l & 31);
    const int x = (((l & 3) ^ ((l >> 2) & 3)) << 4);
    gll(Ab + (long)grow * lda + k0 + (((tid & 3) << 4) ^ x),
        &As[slot][0][0] + tid * 16);
  };
  auto stageBF = [&](int slot, int k0) {
    const int hh = tid >> 8, tl = tid & 255;
    const int l = tl >> 2;
    const int grow = ((l >> 5) << 6) + hh * 32 + (l & 31);
    const int x = (((l & 3) ^ ((l >> 2) & 3)) << 4);
    gll(Bb + (long)grow * ldb + k0 + (((tid & 3) << 4) ^ x),
        &Bs[slot][0][0] + tid * 16);
  };
  // ---- LDS -> fragment reads (same swizzle; fp8 = ONE b128 for both k2 slices) ----
  auto ldA = [&](int slot, int mh, int fq, int sub) -> ABt2 {
    const int r = (WL ? wm * 32 : wm * 64) + fq * 16 + (lane & 15);
    if constexpr (!FP8) {
      bf2frag f;
      const int kk0 = (((lane >> 4) << 3)) ^ ((r & 7) << 3);
      const int kk1 = (32 + ((lane >> 4) << 3)) ^ ((r & 7) << 3);
      f.k0 = *reinterpret_cast<const bf16x8*>(&As[slot][mh][r * 128 + kk0 * 2]);
      f.k1 = *reinterpret_cast<const bf16x8*>(&As[slot][mh][r * 128 + kk1 * 2]);
      return f;
    } else {
      const int x = (((r & 3) ^ ((r >> 2) & 3)) << 4);
      const int kk = ((lane >> 4) << 4) ^ x;
      return *reinterpret_cast<const longx2*>(&As[slot][mh][sub * HBA0 + r * 64 + kk]);
    }
  };
  auto ldB = [&](int slot, int nh, int g, int sub) -> ABt2 {
    // WL=2: wave owns 32 global n-rows = stripe chunk wn>>1, half wn&1.
    const int half = (WL == 2) ? (wn & 1) : nh;
    const int r = ((WL == 2) ? (wn >> 1) : wn) * 32 + g * 16 + (lane & 15);
    if constexpr (!FP8) {
      bf2frag f;
      const int kk0 = (((lane >> 4) << 3)) ^ ((r & 7) << 3);
      const int kk1 = (32 + ((lane >> 4) << 3)) ^ ((r & 7) << 3);
      f.k0 = *reinterpret_cast<const bf16x8*>(&Bs[slot][half][r * 128 + kk0 * 2]);
      f.k1 = *reinterpret_cast<const bf16x8*>(&Bs[slot][half][r * 128 + kk1 * 2]);
      return f;
    } else {
      const int x = (((r & 3) ^ ((r >> 2) & 3)) << 4);
      const int kk = ((lane >> 4) << 4) ^ x;
      return *reinterpret_cast<const longx2*>(&Bs[slot][half][sub * HBB0 + r * 64 + kk]);
    }
  };

  f32x4 acc[MR][NR] = {};
  ABt2 a[FQ * KU], b0[2 * KU], b1[2 * KU];

#define READ_A(SLOT, MH)                                                       \
  _Pragma("unroll") for (int fq = 0; fq < FQ; ++fq)                            \
    _Pragma("unroll") for (int sub = 0; sub < KU; ++sub)                       \
      a[fq * KU + sub] = ldA(SLOT, MH, fq, sub);
#define READ_B(SLOT, NH, DST)                                                  \
  _Pragma("unroll") for (int g = 0; g < 2; ++g)                                \
    _Pragma("unroll") for (int sub = 0; sub < KU; ++sub)                       \
      DST[g * KU + sub] = ldB(SLOT, NH, g, sub);
#define MFMA_QUAD(MH, NH, BARR)                                                \
  if constexpr (PRIO) __builtin_amdgcn_s_setprio(1);                           \
  _Pragma("unroll") for (int fq = 0; fq < FQ; ++fq)                            \
    _Pragma("unroll") for (int g = 0; g < 2; ++g)                              \
      _Pragma("unroll") for (int sub = 0; sub < KU; ++sub)                     \
        _Pragma("unroll") for (int k2 = 0; k2 < 2; ++k2)                       \
          acc[(MH) * FQ + fq][(NH) * 2 + g] =                                  \
              mmak(a[fq * KU + sub], BARR[g * KU + sub],                       \
                   acc[(MH) * FQ + fq][(NH) * 2 + g], k2);                     \
  if constexpr (PRIO) __builtin_amdgcn_s_setprio(0);

  const int KT = K / BK;
  if constexpr (FT) {
    // ---- WL2-fp8: full-tile staging schedule ----
    stageAF(0, 0);
    stageBF(0, 0);
    stageBF(1, BK);
    vmw<1>();
    bar();
    for (int W = 0; W < KT; ++W) {
      const int s = W & 1;
      const int kn1 = (W + 1) * BK, kn2 = (W + 2) * BK;
      const bool st1 = (W + 1 < KT), st2 = (W + 2 < KT);
      // P0: read A0 + own B; stage A-full(W+1) -> s^1.
      READ_A(s, 0)
      READ_B(s, 0, b0)
      if (st1) stageAF(s ^ 1, kn1);
      bar();
      MFMA_QUAD(0, 0, b0)
      bar();
      // P1: read A1; stage B-full(W+2) -> s (all B reads of s done in P0).
      READ_A(s, 1)
      if (st2) stageBF(s, kn2);
      bar();
      MFMA_QUAD(1, 0, b0)
      if (st2) { vmw<1>(); } else { vmw<0>(); }
      bar();
    }
  } else {
    // Prologue queue: [B0(0), A0(0), B1(0), A1(0), B0(1)] (+A1(1) for P2=0)
    stageB(0, 0, 0);
    stageA(0, 0, 0);
    stageB(0, 1, 0);
    stageA(0, 1, 0);
    stageB(1, 0, BK);
    if constexpr (!P2) stageA(1, 1, BK);
    vmw<VP>();
    bar();

    if constexpr (!P2) {
      for (int W = 0; W < KT; ++W) {
        const int s = W & 1;
        const int kn1 = (W + 1) * BK, kn2 = (W + 2) * BK;
        const bool st1 = (W + 1 < KT), st2 = (W + 2 < KT);
        // p0: (m0,n0)
        READ_A(s, 0)
        READ_B(s, 0, b0)
        if (st1) stageA(s ^ 1, 0, kn1);
        bar();
        MFMA_QUAD(0, 0, b0)
        if (st1) { vmw<V0>(); }
        bar();
        // p1: (m0,n1)
        READ_B(s, 1, b1)
        if (st1) stageB(s ^ 1, 1, kn1);
        bar();
        MFMA_QUAD(0, 1, b1)
        bar();
        // p2: (m1,n1)
        READ_A(s, 1)
        if (st2) stageB(s, 0, kn2);
        bar();
        MFMA_QUAD(1, 1, b1)
        bar();
        // p3: (m1,n0)
        if (st2) stageA(s, 1, kn2);
        bar();
        MFMA_QUAD(1, 0, b0)
        if (st2) { vmw<V3>(); } else { vmw<0>(); }
        bar();
      }
    } else {
      for (int W = 0; W < KT; ++W) {
        const int s = W & 1;
        const int kn1 = (W + 1) * BK, kn2 = (W + 2) * BK;
        const bool st1 = (W + 1 < KT), st2 = (W + 2 < KT);
        // P0: m0 x (WL=2: own B-half | else: n0,n1); stage trio (A1 LAST).
        READ_A(s, 0)
        READ_B(s, 0, b0)
        if constexpr (WL != 2) { READ_B(s, 1, b1) }
        if (st1) { stageA(s ^ 1, 0, kn1); stageB(s ^ 1, 1, kn1); stageA(s ^ 1, 1, kn1); }
        bar();
        MFMA_QUAD(0, 0, b0)
        if constexpr (WL != 2) { MFMA_QUAD(0, 1, b1) }
        if (st1) { vmw<2 * (GA + GB)>(); } else { vmw<0>(); }
        bar();
        // P1: m1; stage B0(W+2) into current slot (B0(W) consumed in P0).
        READ_A(s, 1)
        if (st2) stageB(s, 0, kn2);
        bar();
        if constexpr (WL != 2) { MFMA_QUAD(1, 1, b1) }
        MFMA_QUAD(1, 0, b0)
        if (st2) { vmw<GA + GB>(); } else if (st1) { vmw<GA>(); } else { vmw<0>(); }
        bar();
      }
    }
  }

  // epilogue: acc[M][N].
  // WL=0: M = mh*4+fq, m-off = (M>>2)*64 + (M&3)*16, wave m-base wm*128.
  // WL>=1: M = mh*2+fq, m-off = (M>>1)*32 + (M&1)*16, wave m-base wm*64.
  // WL=2: N in {0,1}, n = by*128 + wn*32 + N*16 + (lane&15).
  const int mg0 = bx * BM + (WL ? wm * 64 : wm * 128) + ((lane >> 4) << 2);
  const int ng0 = by * BN + ((WL == 2) ? wn * 32 : wn * 64) + (lane & 15);
  float* red = (float*)&As[0][0][0];  // STATS scratch: BN rows x NSLOTP f32
#pragma unroll
  for (int N = 0; N < NR; ++N) {
    const int n = ng0 + ((WL == 2) ? N * 16 : ((N >> 1) * 32 + (N & 1) * 16));
    float bn;
    if constexpr (MODE == 3) bn = bias_m ? 0.f : biasSel[n];
    else bn = (BIAS_MODE == 2) ? bias[n] : 0.f;
    const float sc = (SCALEN == 1) ? linv[(long)bz * 2304 + n]
                   : (SCALEN == 2) ? linvs[n - by * BN] : 1.0f;
    float eN = 0.f;
#pragma unroll
    for (int M = 0; M < MR; ++M) {
      const int m = mg0 + (WL ? ((M >> 1) * 32 + (M & 1) * 16) : ((M >> 2) * 64 + (M & 3) * 16));
      const f32x4 av = acc[M][N];
      float vals[4];
#pragma unroll
      for (int j = 0; j < 4; ++j) {
        float addv;
        if constexpr (MODE == 3) addv = bias_m ? biasSel[m + j] : bn;
        else if constexpr (BIAS_MODE == 1) addv = bias[m + j];
        else addv = bn;
        vals[j] = av[j] * alpha + addv;
        if (SCALEN) vals[j] *= sc;
        if (STATS) { vals[j] = __expf(vals[j]); eN += vals[j]; }
      }
      if (OUT_MODE == 0) {
        ushort4 o; o.x = f2bf(vals[0]); o.y = f2bf(vals[1]); o.z = f2bf(vals[2]); o.w = f2bf(vals[3]);
        *(ushort4*)((unsigned short*)Csel + (long)bz * sCz + (long)n * ldcSel + m) = o;
      } else if (OUT_MODE == 2) {
        int pk = __builtin_amdgcn_cvt_pk_fp8_f32(vals[0], vals[1], 0, false);
        pk = __builtin_amdgcn_cvt_pk_fp8_f32(vals[2], vals[3], pk, true);
        *(int*)((unsigned char*)Csel + (long)bz * sCz + (long)n * ldcSel + perm64(m)) = pk;
      } else {
        const float* rp = resid + (long)n * ldcSel + m;
        float4 o; o.x = vals[0] + rp[0]; o.y = vals[1] + rp[1]; o.z = vals[2] + rp[2]; o.w = vals[3] + rp[3];
        *(float4*)((float*)Csel + (long)bz * sCz + (long)n * ldcSel + m) = o;
      }
    }
    if (STATS) {
      const int nloc = n - by * BN;
      const int slot = wm * 4 + (lane >> 4);
      red[nloc * NSLOTP + slot] = eN;
    }
  }
  if (STATS) {
    bar();
    if (tid < BN) {
      float L = 0.f;
#pragma unroll
      for (int s2 = 0; s2 < NSLOT; ++s2) L += red[tid * NSLOTP + s2];
      rowsums[((long)(bz * gx + bx)) * 2304 + by * BN + tid] = L;
    }
  }
#undef READ_A
#undef READ_B
#undef MFMA_QUAD
}

extern "C" void kernel_launch(void* const* d_in, const int* in_sizes, int n_in,
                              void* d_out, int out_size, void* d_ws, size_t ws_size,
                              hipStream_t stream) {
  const float* x = (const float*)d_in[0];
  const float* gamma = (const float*)d_in[1];
  const float* beta = (const float*)d_in[2];
  const float* wq = (const float*)d_in[3];
  const float* bq = (const float*)d_in[4];
  const float* wk = (const float*)d_in[5];
  const float* bk = (const float*)d_in[6];
  const float* wv = (const float*)d_in[7];
  const float* bv = (const float*)d_in[8];
  const float* wo = (const float*)d_in[9];
  const float* bo = (const float*)d_in[10];
  float* out = (float*)d_out;

  char* ws = (char*)d_ws;
  size_t off = 0;
  auto alloc = [&](size_t bytes) {
    char* p = ws + off;
    off = (off + bytes + 255) & ~(size_t)255;
    return p;
  };
  float* part = (float*)alloc(256 * 2 * sizeof(float));
  unsigned short* wqkb = (unsigned short*)alloc((size_t)2 * 262144 * 2);
  unsigned short* wvb = (unsigned short*)alloc((size_t)262144 * 2);
  unsigned short* wob = (unsigned short*)alloc((size_t)262144 * 2);
  float* bqk = (float*)alloc(1024 * sizeof(float));
  float* rowsums = (float*)alloc((size_t)8 * 18 * 2304 * sizeof(float));
  unsigned short* hnT = (unsigned short*)alloc((size_t)18432 * 512 * 2);
  unsigned char* qkA = (unsigned char*)alloc((size_t)18432 * 1024);      // fp8 k-interleaved
  unsigned char* vT = (unsigned char*)alloc((size_t)512 * 18432);        // fp8 k-interleaved
  unsigned char* Sm = (unsigned char*)alloc((size_t)8 * 2304 * 2304);    // fp8 E k-interleaved
  unsigned short* Ob = hnT;  // alias: hnT fully consumed after qk/v GEMMs
  (void)ws_size; (void)in_sizes; (void)n_in; (void)out_size;

  stats_partial_k<<<dim3(256), dim3(256), 0, stream>>>(x, part);
  gn_transpose_k<<<dim3(8, 288), dim3(256), 0, stream>>>(x, part, gamma, beta, hnT);
  pack4_bf16_k<<<dim3(256, 5), dim3(256), 0, stream>>>(wq, wk, wv, wo,
                                                       wqkb, wqkb + 262144, wvb, wob,
                                                       bq, bk, bqk);

  // Fused qk+v (MODE3) on WL=2 bf16 (512 thr, 8 waves, 4 waves/SIMD).
  // Blocks [0,1152): qk -- A=[Wq;Wk] bf16, B=hnT -> qkA fp8 [sp][1024].
  // Blocks [1152,1728): v -- A=hnT, B=wvb -> vT fp8 [co][18432].
  gemm256<128, 1, 2, 0, 0, 3, 0, 1, 2><<<dim3(1728), dim3(512), 0, stream>>>(
      wqkb, 512, 0, hnT, 512, 0, (void*)qkA, 1024, 0, bqk,
      (const float*)wvb, (float*)vT, bv, 1.0f, 512, 1152, 0);
  // S: per t: A=k fp8, B=q fp8 -> E=exp(alpha*S) fp8 interleaved + rowsums.
  // R24: WL=2 fp8 (512 thr, 8 waves, 4 blocks/CU -> 8 waves/SIMD): 2592 MODE0.
  gemm256<128, 0, 2, 1, 0, 0, 1, 1, 2><<<dim3(2592), dim3(512), 0, stream>>>(
      qkA + 512, 1024, (long)2304 * 1024, qkA, 1024, (long)2304 * 1024, (void*)Sm, 2304,
      (long)2304 * 2304, nullptr, nullptr, rowsums, nullptr,
      0.044194173824159216f, 512, 18, 18);
  // PV: per t: A=vT fp8, B=E fp8 -> O bf16 [(t,i)*512+c], rows scaled by 1/L.
  // SCALEN=2 -- combine folded into PV prologue. WL=1 fp8: 576 blocks MODE0.
  gemm256<128, 0, 0, 0, 2, 0, 1, 1, 1><<<dim3(576), dim3(256), 0, stream>>>(
      vT, 18432, 2304, Sm, 2304, (long)2304 * 2304, (void*)Ob, 512, (long)2304 * 512,
      nullptr, nullptr, rowsums, nullptr, 1.0f, 2304, 4, 18);
  // final: A=O bf16, B=Wo bf16 -> out[co*18432+sp] = x + acc + bo[co].
  // R24: WL=2 bf16 (qv-proven machine), MODE2: 8 x 18 x 4 = 576 blocks.
  gemm256<128, 2, 1, 0, 0, 2, 0, 1, 2><<<dim3(576), dim3(512), 0, stream>>>(
      Ob, 512, 0, wob, 512, 0, (void*)out, 18432, 0, bo, x, nullptr, nullptr,
      1.0f, 512, 18, 4);
}

// Round 16
// 209.453 us; speedup vs baseline: 1.2737x; 1.0020x over previous
//
#include <hip/hip_runtime.h>
#include <hip/hip_bf16.h>
#include <cstdint>
#include <type_traits>

typedef __attribute__((ext_vector_type(8))) __bf16 bf16x8;
typedef __attribute__((ext_vector_type(4))) float f32x4;
typedef __attribute__((ext_vector_type(2))) long longx2;

struct bf2frag { bf16x8 k0, k1; };

__device__ __forceinline__ float bf2f(unsigned short u) {
  union { uint32_t i; float f; } v; v.i = (uint32_t)u << 16; return v.f;
}
__device__ __forceinline__ unsigned short f2bf(float f) {
  union { float f; uint32_t i; } v{f};
  uint32_t r = v.i + 0x7fffu + ((v.i >> 16) & 1u);
  return (unsigned short)(r >> 16);
}

__device__ __forceinline__ void gll(const void* g, void* l) {
  __builtin_amdgcn_global_load_lds(
      (const __attribute__((address_space(1))) uint32_t*)(uintptr_t)g,
      (__attribute__((address_space(3))) uint32_t*)(uint32_t)(uintptr_t)l,
      16, 0, 0);
}

__device__ __forceinline__ void bar() {
  asm volatile("" ::: "memory");
  __builtin_amdgcn_s_barrier();
  asm volatile("" ::: "memory");
}

#define VMCNT(n) asm volatile("s_waitcnt vmcnt(" #n ")" ::: "memory")

template <int N>
__device__ __forceinline__ void vmw() {
  if constexpr (N == 0) { VMCNT(0); }
  else if constexpr (N == 1) { VMCNT(1); }
  else if constexpr (N == 2) { VMCNT(2); }
  else if constexpr (N == 3) { VMCNT(3); }
  else if constexpr (N == 4) { VMCNT(4); }
  else if constexpr (N == 5) { VMCNT(5); }
  else if constexpr (N == 6) { VMCNT(6); }
  else if constexpr (N == 7) { VMCNT(7); }
  else if constexpr (N == 8) { VMCNT(8); }
  else if constexpr (N == 9) { VMCNT(9); }
  else if constexpr (N == 10) { VMCNT(10); }
  else { VMCNT(12); }
}

__device__ __forceinline__ f32x4 mma(bf16x8 a, bf16x8 b, f32x4 c) {
  return __builtin_amdgcn_mfma_f32_16x16x32_bf16(a, b, c, 0, 0, 0);
}
__device__ __forceinline__ f32x4 mma(long a, long b, f32x4 c) {
  return __builtin_amdgcn_mfma_f32_16x16x32_fp8_fp8(a, b, c, 0, 0, 0);
}
__device__ __forceinline__ f32x4 mmak(const bf2frag& a, const bf2frag& b, f32x4 c, int k2) {
  return k2 ? mma(a.k1, b.k1, c) : mma(a.k0, b.k0, c);
}
__device__ __forceinline__ f32x4 mmak(longx2 a, longx2 b, f32x4 c, int k2) {
  return mma(a[k2], b[k2], c);
}

// k-interleave store permutation for fp8 buffers (unit u=8B: slot p(u)=(u&3)*2+(u>>2))
__device__ __forceinline__ int perm64(int m) {
  return (m & ~63) | (((m >> 3) & 3) << 4) | (((m >> 5) & 1) << 3) | (m & 7);
}

// ---------------- GroupNorm stats ----------------
__global__ __launch_bounds__(256) void stats_partial_k(const float* __restrict__ x,
                                                       float* __restrict__ part) {
  const int g = blockIdx.x >> 3, p = blockIdx.x & 7;
  const float* base = x + (long)g * 16 * 18432 + (long)p * 2304;
  float s = 0.f, ss = 0.f;
  for (int idx = threadIdx.x; idx < 16 * 576; idx += 256) {
    const int c = idx / 576, i4 = idx % 576;
    const float4 v = *(const float4*)(base + (long)c * 18432 + i4 * 4);
    s += v.x + v.y + v.z + v.w;
    ss += v.x * v.x + v.y * v.y + v.z * v.z + v.w * v.w;
  }
  __shared__ float rs[256], rss[256];
  rs[threadIdx.x] = s; rss[threadIdx.x] = ss;
  __syncthreads();
  for (int o = 128; o > 0; o >>= 1) {
    if ((int)threadIdx.x < o) { rs[threadIdx.x] += rs[threadIdx.x + o]; rss[threadIdx.x] += rss[threadIdx.x + o]; }
    __syncthreads();
  }
  if (threadIdx.x == 0) { part[blockIdx.x * 2] = rs[0]; part[blockIdx.x * 2 + 1] = rss[0]; }
}

// ---------------- GN apply + transpose to (spatial, channel) bf16 ----------------
// R21: stats_final folded in -- each block reduces part[] for its own 4 groups.
__global__ __launch_bounds__(256) void gn_transpose_k(const float* __restrict__ x,
                                                      const float* __restrict__ part,
                                                      const float* __restrict__ gamma,
                                                      const float* __restrict__ beta,
                                                      unsigned short* __restrict__ hnT) {
  __shared__ float tile[64][65];
  __shared__ float sm[4], sr[4];
  const int c0 = blockIdx.x * 64, n0 = blockIdx.y * 64;
  const int tn = threadIdx.x & 63, tr = threadIdx.x >> 6;
  if (threadIdx.x < 4) {
    const int g = (c0 >> 4) + threadIdx.x;
    float s = 0.f, ss = 0.f;
    for (int p = 0; p < 8; ++p) { s += part[(g * 8 + p) * 2]; ss += part[(g * 8 + p) * 2 + 1]; }
    const float mean = s / 294912.0f;
    const float var = ss / 294912.0f - mean * mean;
    sm[threadIdx.x] = mean;
    sr[threadIdx.x] = rsqrtf(var + 1e-6f);
  }
  __syncthreads();
  for (int cc = tr; cc < 64; cc += 4) {
    const int c = c0 + cc;
    const float mean = sm[cc >> 4], rstd = sr[cc >> 4];
    const float v = x[(long)c * 18432 + n0 + tn];
    tile[cc][tn] = (v - mean) * rstd * gamma[c] + beta[c];
  }
  __syncthreads();
  for (int nn = tr; nn < 64; nn += 4) {
    hnT[(long)(n0 + nn) * 512 + c0 + tn] = f2bf(tile[tn][nn]);
  }
}

// ---------------- fp32 -> bf16 weight pack (4 weights + qk-bias in one launch) ----------------
__global__ __launch_bounds__(256) void pack4_bf16_k(const float* __restrict__ w0,
                                                    const float* __restrict__ w1,
                                                    const float* __restrict__ w2,
                                                    const float* __restrict__ w3,
                                                    unsigned short* __restrict__ o0,
                                                    unsigned short* __restrict__ o1,
                                                    unsigned short* __restrict__ o2,
                                                    unsigned short* __restrict__ o3,
                                                    const float* __restrict__ bq,
                                                    const float* __restrict__ bk,
                                                    float* __restrict__ bqk) {
  const int y = blockIdx.y;
  if (y == 4) {  // R21: pack_bias folded in (block 0 only)
    if (blockIdx.x == 0) {
      const int i = threadIdx.x * 4;
#pragma unroll
      for (int j = 0; j < 4; ++j) {
        const int t = i + j;
        bqk[t] = (t < 512) ? bq[t] : bk[t - 512];
      }
    }
    return;
  }
  const float* w = (y == 0) ? w0 : (y == 1) ? w1 : (y == 2) ? w2 : w3;
  unsigned short* o = (y == 0) ? o0 : (y == 1) ? o1 : (y == 2) ? o2 : o3;
  const int i = (blockIdx.x * 256 + threadIdx.x) * 4;
  const float4 v = *(const float4*)(w + i);
  ushort4 u; u.x = f2bf(v.x); u.y = f2bf(v.y); u.z = f2bf(v.z); u.w = f2bf(v.w);
  *(ushort4*)(o + i) = u;
}

// ================= BMxBNxBK NT GEMM, XCD-swizzled, bf16/fp8 =================
// C[n*ldc+m] = alpha*sum_k A[m,k]*B[n,k] (+bias)(+resid)
// WL=0, BM=256: 512 thr, 8 waves (2m x 4n), 1 block/CU, P2=0, setprio ON.
// WL=1: BM=128 x BN=128, 256 thr, 4 waves (2m x 2n, 64x64/wave).
//   fp8 KU=1: 32KB LDS, bounds(256,4). bf16: 64KB, 2 blocks/CU.
// WL=2: BM=128 x BN=128, 512 thr, 8 waves (2m x 4n, 64x32/wave).
//   bf16 (R23 qv, R24 final): 64KB LDS, 2 blocks/CU, 4 waves/SIMD.
//   fp8 (R24 S; R25 PV): 32KB LDS, bounds(512,8), FULL-TILE stages (8192B =
//   1 gll/thread; LDS dest linear, As[slot][0..1] contiguous).
//   WL2-fp8 schedule: prologue [Afull(0),Bfull(0),Bfull(1)], vmcnt(1);
//   P0: read A0+ownB, stage Afull(W+1)->s^1, mfma m0; P1: read A1, stage
//   Bfull(W+2)->s, mfma m1, vmcnt(st2?1:0). Verified on S (R24, VGPR 32).
//   R24 verdict on S: Occupancy 33->62% with MfmaUtil FLAT at 28.6 -- TLP
//   exonerated; S's ~29% wall is structural (8 probes, no movement). STOP.
//   R25: transfer the verified WL2-fp8 machine to PV (576 blocks, was WL=1 at
//   ~2.25 waves/SIMD -- the worst TLP left; KT=36 latency-sensitive like R15).
//   Ladder: R13 S TLP, R14 qk, R15 PV, R17 v+final, R21/22 folds, R23 qv WL2.
//   A/B halves use 32-row stripe interleave: grow = (r>>5)*64 + h*32 + (r&31).
// P2=1 (2-phase, WL<2 or bf16): P0: read A0,B; stage [A0,B1,A1](W+1) -> s^1;
//   mfma m0. P1: read A1; stage B0(W+2) -> s; mfma m1.
//   Waits: @P0-end vmcnt(2(GA+GB)); @P1-end vmcnt(GA+GB); tail GA then 0.
// STATS: exp+rowsums, scratch stride NSLOT+1 (R18).
// SCALEN: 1 = *linv[n]; 2 = combine folded into prologue (R21).
// OUT_MODE: 0 bf16, 1 f32+resid, 2 fp8 e4m3 k-interleaved.
// MODE0: bz=bid%8 per XCD; MODE1/2: XCD y/x-chunking.
// MODE3 (R22): fused qk+v single dispatch; blocks < gx run qk (MODE1 8x18),
//   rest run v (MODE2 18x4) with params via resid/rowsums/linv.
template <int BM, int BIAS_MODE, int OUT_MODE, int STATS, int SCALEN, int MODE, int FP8, int P2,
          int WL = 0, int KU = 1>
__global__ __launch_bounds__((BM == 256 || WL == 2) ? 512 : 256,
                             (WL == 1 && FP8) ? (KU == 2 ? 2 : 4) : ((WL == 2 && FP8) ? 8 : 2))
void gemm256(const void* __restrict__ A, long lda, long sAz,
             const void* __restrict__ B, long ldb, long sBz,
             void* __restrict__ Cp, long ldc, long sCz,
             const float* __restrict__ bias,
             const float* __restrict__ resid,
             float* __restrict__ rowsums,
             const float* __restrict__ linv,
             float alpha, int K, int gx, int gy) {
  static_assert(KU == 1 || FP8, "KU=2 only on fp8 path");
  constexpr int EB = FP8 ? 1 : 2;                    // element bytes
  constexpr int THREADS = (BM == 256 || WL == 2) ? 512 : 256;
  constexpr int BN = WL ? 128 : 256;                 // n-tile
  constexpr int BK = 64 * KU;                        // k-step
  constexpr int HBA = (BM / 2) * BK * EB;            // bytes per A half
  constexpr int HBB = (BN / 2) * BK * EB;            // bytes per B half
  constexpr int HBA0 = HBA / KU, HBB0 = HBB / KU;    // per 64-k sub-block
  constexpr bool FT = (WL == 2 && FP8);              // full-tile staging path
  constexpr int GA = FT ? 1 : HBA / (THREADS * 16);  // gll per A stage unit
  constexpr int GB = FT ? 1 : HBB / (THREADS * 16);  // gll per B stage unit
  constexpr int GA0 = FT ? 1 : GA / KU, GB0 = FT ? 1 : GB / KU;
  constexpr int V0 = GB + 2 * GA, V3 = 2 * GB + GA, VP = GB + GA;
  constexpr int NSLOT = WL ? 8 : ((BM == 256) ? 8 : 4);
  constexpr int NSLOTP = NSLOT + 1;                  // R18: odd stride
  constexpr int MR = WL ? 4 : 8;                     // acc M-frags per wave
  constexpr int NR = (WL == 2) ? 2 : 4;              // acc N-frags per wave
  constexpr int FQ = WL ? 2 : 4;                     // A-frags per (mh) phase
  constexpr int PRIO = !P2;                          // setprio only on 1-block path
  __shared__ alignas(16) unsigned char As[2][2][HBA];
  __shared__ alignas(16) unsigned char Bs[2][2][HBB];
  __shared__ float linvs[SCALEN == 2 ? BN : 1];
  using ABt2 = typename std::conditional<FP8, longx2, bf2frag>::type;

  const int tid = threadIdx.x;
  const int lane = tid & 63, wid = tid >> 6;
  const int wm = (WL == 2) ? (wid >> 2) : (WL ? (wid >> 1) : ((BM == 256) ? (wid & 1) : 0));
  const int wn = (WL == 2) ? (wid & 3) : (WL ? (wid & 1) : ((BM == 256) ? (wid >> 1) : wid));
  int bx, by, bz;
  const void* Asel = A;
  const void* Bsel = B;
  void* Csel = Cp;
  const float* biasSel = bias;
  long ldcSel = ldc;
  bool bias_m = (BIAS_MODE == 1);
  {
    const int g8 = blockIdx.x & 7, n = blockIdx.x >> 3;
    if (MODE == 0) { bz = g8; bx = n % gx; by = n / gx; }
    else if (MODE == 1) { bz = 0; bx = n % gx; by = g8 * gy + n / gx; }
    else if (MODE == 2) { bz = 0; by = n % gy; bx = g8 * gx + n / gy; }
    else {  // MODE 3: fused qk+v; gx = number of qk blocks
      bz = 0;
      if ((int)blockIdx.x < gx) {
        bx = n % 8; by = g8 * 18 + n / 8;          // qk: MODE1 gx=8, gy=18
      } else {
        const int b2 = (int)blockIdx.x - gx;
        const int g82 = b2 & 7, n2 = b2 >> 3;
        by = n2 % 4; bx = g82 * 18 + n2 / 4;       // v: MODE2 gx=18, gy=4
        Asel = B;                                   // hnT
        Bsel = (const void*)resid;                  // wvb
        Csel = (void*)rowsums;                      // vT
        biasSel = linv;                             // bv
        ldcSel = 18432;
        bias_m = false;
      }
    }
  }
  const unsigned char* Ab = (const unsigned char*)Asel + ((long)bz * sAz + (long)bx * BM * lda) * EB;
  const unsigned char* Bb = (const unsigned char*)Bsel + ((long)bz * sBz + (long)by * BN * ldb) * EB;

  // R21 (SCALEN==2): fold combine -- compute 1/L for this block's rows first,
  // so the scalar loads retire before any gll enters the vmcnt FIFO.
  if constexpr (SCALEN == 2) {
    if (tid < BN) {
      const int ntile = K / BN;
      float L = 0.f;
      for (int xx = 0; xx < ntile; ++xx)
        L += rowsums[((long)(bz * ntile + xx)) * K + by * BN + tid];
      linvs[tid] = 1.0f / L;
    }
  }

  // ---- staging (global -> LDS, pre-swizzled source; fp8 global is k-interleaved) ----
  auto stageA = [&](int slot, int h, int k0) {
    if constexpr (!FP8) {
      const int ksw = ((tid & 7) << 3) ^ (((tid >> 3) & 7) << 3);
#pragma unroll
      for (int call = 0; call < GA; ++call) {
        const int r = call * (THREADS / 8) + (tid >> 3);
        const int grow = WL ? (((r >> 5) << 6) + h * 32 + (r & 31))
                            : (((r >> 6) << 7) + h * 64 + (r & 63));
        gll(Ab + ((long)grow * lda + k0) * 2 + ksw * 2, &As[slot][h][call * THREADS * 16 + tid * 16]);
      }
    } else {
#pragma unroll
      for (int call = 0; call < GA; ++call) {
        const int sub = call / GA0, c0 = call % GA0;
        const int l = c0 * (THREADS / 4) + (tid >> 2);
        const int grow = WL ? (((l >> 5) << 6) + h * 32 + (l & 31))
                            : (((l >> 6) << 7) + h * 64 + (l & 63));
        const int x = (((l & 3) ^ ((l >> 2) & 3)) << 4);
        gll(Ab + (long)grow * lda + k0 + sub * 64 + (((tid & 3) << 4) ^ x),
            &As[slot][h][call * THREADS * 16 + tid * 16]);
      }
    }
  };
  auto stageB = [&](int slot, int h, int k0) {
    if constexpr (!FP8) {
      const int ksw = ((tid & 7) << 3) ^ (((tid >> 3) & 7) << 3);
#pragma unroll
      for (int call = 0; call < GB; ++call) {
        const int r = call * (THREADS / 8) + (tid >> 3);
        const int grow = ((r >> 5) << 6) + h * 32 + (r & 31);
        gll(Bb + ((long)grow * ldb + k0) * 2 + ksw * 2, &Bs[slot][h][call * THREADS * 16 + tid * 16]);
      }
    } else {
#pragma unroll
      for (int call = 0; call < GB; ++call) {
        const int sub = call / GB0, c0 = call % GB0;
        const int l = c0 * (THREADS / 4) + (tid >> 2);
        const int grow = ((l >> 5) << 6) + h * 32 + (l & 31);
        const int x = (((l & 3) ^ ((l >> 2) & 3)) << 4);
        gll(Bb + (long)grow * ldb + k0 + sub * 64 + (((tid & 3) << 4) ^ x),
            &Bs[slot][h][call * THREADS * 16 + tid * 16]);
      }
    }
  };
  // WL2-fp8 full-tile stages: 1 gll/thread covers both halves (8192B).
  // tid = hh*256 + tl; per-half mapping identical to WL=1 fp8 (THREADS=256, GA=1).
  auto stageAF = [&](int slot, int k0) {
    const int hh = tid >> 8, tl = tid & 255;
    const int l = tl >> 2;
    const int grow = ((l >> 5) << 6) + hh * 32 + (l & 31);
    const int x = (((l & 3) ^ ((l >> 2) & 3)) << 4);
    gll(Ab + (long)grow * lda + k0 + (((tid & 3) << 4) ^ x),
        &As[slot][0][0] + tid * 16);
  };
  auto stageBF = [&](int slot, int k0) {
    const int hh = tid >> 8, tl = tid & 255;
    const int l = tl >> 2;
    const int grow = ((l >> 5) << 6) + hh * 32 + (l & 31);
    const int x = (((l & 3) ^ ((l >> 2) & 3)) << 4);
    gll(Bb + (long)grow * ldb + k0 + (((tid & 3) << 4) ^ x),
        &Bs[slot][0][0] + tid * 16);
  };
  // ---- LDS -> fragment reads (same swizzle; fp8 = ONE b128 for both k2 slices) ----
  auto ldA = [&](int slot, int mh, int fq, int sub) -> ABt2 {
    const int r = (WL ? wm * 32 : wm * 64) + fq * 16 + (lane & 15);
    if constexpr (!FP8) {
      bf2frag f;
      const int kk0 = (((lane >> 4) << 3)) ^ ((r & 7) << 3);
      const int kk1 = (32 + ((lane >> 4) << 3)) ^ ((r & 7) << 3);
      f.k0 = *reinterpret_cast<const bf16x8*>(&As[slot][mh][r * 128 + kk0 * 2]);
      f.k1 = *reinterpret_cast<const bf16x8*>(&As[slot][mh][r * 128 + kk1 * 2]);
      return f;
    } else {
      const int x = (((r & 3) ^ ((r >> 2) & 3)) << 4);
      const int kk = ((lane >> 4) << 4) ^ x;
      return *reinterpret_cast<const longx2*>(&As[slot][mh][sub * HBA0 + r * 64 + kk]);
    }
  };
  auto ldB = [&](int slot, int nh, int g, int sub) -> ABt2 {
    // WL=2: wave owns 32 global n-rows = stripe chunk wn>>1, half wn&1.
    const int half = (WL == 2) ? (wn & 1) : nh;
    const int r = ((WL == 2) ? (wn >> 1) : wn) * 32 + g * 16 + (lane & 15);
    if constexpr (!FP8) {
      bf2frag f;
      const int kk0 = (((lane >> 4) << 3)) ^ ((r & 7) << 3);
      const int kk1 = (32 + ((lane >> 4) << 3)) ^ ((r & 7) << 3);
      f.k0 = *reinterpret_cast<const bf16x8*>(&Bs[slot][half][r * 128 + kk0 * 2]);
      f.k1 = *reinterpret_cast<const bf16x8*>(&Bs[slot][half][r * 128 + kk1 * 2]);
      return f;
    } else {
      const int x = (((r & 3) ^ ((r >> 2) & 3)) << 4);
      const int kk = ((lane >> 4) << 4) ^ x;
      return *reinterpret_cast<const longx2*>(&Bs[slot][half][sub * HBB0 + r * 64 + kk]);
    }
  };

  f32x4 acc[MR][NR] = {};
  ABt2 a[FQ * KU], b0[2 * KU], b1[2 * KU];

#define READ_A(SLOT, MH)                                                       \
  _Pragma("unroll") for (int fq = 0; fq < FQ; ++fq)                            \
    _Pragma("unroll") for (int sub = 0; sub < KU; ++sub)                       \
      a[fq * KU + sub] = ldA(SLOT, MH, fq, sub);
#define READ_B(SLOT, NH, DST)                                                  \
  _Pragma("unroll") for (int g = 0; g < 2; ++g)                                \
    _Pragma("unroll") for (int sub = 0; sub < KU; ++sub)                       \
      DST[g * KU + sub] = ldB(SLOT, NH, g, sub);
#define MFMA_QUAD(MH, NH, BARR)                                                \
  if constexpr (PRIO) __builtin_amdgcn_s_setprio(1);                           \
  _Pragma("unroll") for (int fq = 0; fq < FQ; ++fq)                            \
    _Pragma("unroll") for (int g = 0; g < 2; ++g)                              \
      _Pragma("unroll") for (int sub = 0; sub < KU; ++sub)                     \
        _Pragma("unroll") for (int k2 = 0; k2 < 2; ++k2)                       \
          acc[(MH) * FQ + fq][(NH) * 2 + g] =                                  \
              mmak(a[fq * KU + sub], BARR[g * KU + sub],                       \
                   acc[(MH) * FQ + fq][(NH) * 2 + g], k2);                     \
  if constexpr (PRIO) __builtin_amdgcn_s_setprio(0);

  const int KT = K / BK;
  if constexpr (FT) {
    // ---- WL2-fp8: full-tile staging schedule ----
    stageAF(0, 0);
    stageBF(0, 0);
    stageBF(1, BK);
    vmw<1>();
    bar();
    for (int W = 0; W < KT; ++W) {
      const int s = W & 1;
      const int kn1 = (W + 1) * BK, kn2 = (W + 2) * BK;
      const bool st1 = (W + 1 < KT), st2 = (W + 2 < KT);
      // P0: read A0 + own B; stage A-full(W+1) -> s^1.
      READ_A(s, 0)
      READ_B(s, 0, b0)
      if (st1) stageAF(s ^ 1, kn1);
      bar();
      MFMA_QUAD(0, 0, b0)
      bar();
      // P1: read A1; stage B-full(W+2) -> s (all B reads of s done in P0).
      READ_A(s, 1)
      if (st2) stageBF(s, kn2);
      bar();
      MFMA_QUAD(1, 0, b0)
      if (st2) { vmw<1>(); } else { vmw<0>(); }
      bar();
    }
  } else {
    // Prologue queue: [B0(0), A0(0), B1(0), A1(0), B0(1)] (+A1(1) for P2=0)
    stageB(0, 0, 0);
    stageA(0, 0, 0);
    stageB(0, 1, 0);
    stageA(0, 1, 0);
    stageB(1, 0, BK);
    if constexpr (!P2) stageA(1, 1, BK);
    vmw<VP>();
    bar();

    if constexpr (!P2) {
      for (int W = 0; W < KT; ++W) {
        const int s = W & 1;
        const int kn1 = (W + 1) * BK, kn2 = (W + 2) * BK;
        const bool st1 = (W + 1 < KT), st2 = (W + 2 < KT);
        // p0: (m0,n0)
        READ_A(s, 0)
        READ_B(s, 0, b0)
        if (st1) stageA(s ^ 1, 0, kn1);
        bar();
        MFMA_QUAD(0, 0, b0)
        if (st1) { vmw<V0>(); }
        bar();
        // p1: (m0,n1)
        READ_B(s, 1, b1)
        if (st1) stageB(s ^ 1, 1, kn1);
        bar();
        MFMA_QUAD(0, 1, b1)
        bar();
        // p2: (m1,n1)
        READ_A(s, 1)
        if (st2) stageB(s, 0, kn2);
        bar();
        MFMA_QUAD(1, 1, b1)
        bar();
        // p3: (m1,n0)
        if (st2) stageA(s, 1, kn2);
        bar();
        MFMA_QUAD(1, 0, b0)
        if (st2) { vmw<V3>(); } else { vmw<0>(); }
        bar();
      }
    } else {
      for (int W = 0; W < KT; ++W) {
        const int s = W & 1;
        const int kn1 = (W + 1) * BK, kn2 = (W + 2) * BK;
        const bool st1 = (W + 1 < KT), st2 = (W + 2 < KT);
        // P0: m0 x (WL=2: own B-half | else: n0,n1); stage trio (A1 LAST).
        READ_A(s, 0)
        READ_B(s, 0, b0)
        if constexpr (WL != 2) { READ_B(s, 1, b1) }
        if (st1) { stageA(s ^ 1, 0, kn1); stageB(s ^ 1, 1, kn1); stageA(s ^ 1, 1, kn1); }
        bar();
        MFMA_QUAD(0, 0, b0)
        if constexpr (WL != 2) { MFMA_QUAD(0, 1, b1) }
        if (st1) { vmw<2 * (GA + GB)>(); } else { vmw<0>(); }
        bar();
        // P1: m1; stage B0(W+2) into current slot (B0(W) consumed in P0).
        READ_A(s, 1)
        if (st2) stageB(s, 0, kn2);
        bar();
        if constexpr (WL != 2) { MFMA_QUAD(1, 1, b1) }
        MFMA_QUAD(1, 0, b0)
        if (st2) { vmw<GA + GB>(); } else if (st1) { vmw<GA>(); } else { vmw<0>(); }
        bar();
      }
    }
  }

  // epilogue: acc[M][N].
  // WL=0: M = mh*4+fq, m-off = (M>>2)*64 + (M&3)*16, wave m-base wm*128.
  // WL>=1: M = mh*2+fq, m-off = (M>>1)*32 + (M&1)*16, wave m-base wm*64.
  // WL=2: N in {0,1}, n = by*128 + wn*32 + N*16 + (lane&15).
  const int mg0 = bx * BM + (WL ? wm * 64 : wm * 128) + ((lane >> 4) << 2);
  const int ng0 = by * BN + ((WL == 2) ? wn * 32 : wn * 64) + (lane & 15);
  float* red = (float*)&As[0][0][0];  // STATS scratch: BN rows x NSLOTP f32
#pragma unroll
  for (int N = 0; N < NR; ++N) {
    const int n = ng0 + ((WL == 2) ? N * 16 : ((N >> 1) * 32 + (N & 1) * 16));
    float bn;
    if constexpr (MODE == 3) bn = bias_m ? 0.f : biasSel[n];
    else bn = (BIAS_MODE == 2) ? bias[n] : 0.f;
    const float sc = (SCALEN == 1) ? linv[(long)bz * 2304 + n]
                   : (SCALEN == 2) ? linvs[n - by * BN] : 1.0f;
    float eN = 0.f;
#pragma unroll
    for (int M = 0; M < MR; ++M) {
      const int m = mg0 + (WL ? ((M >> 1) * 32 + (M & 1) * 16) : ((M >> 2) * 64 + (M & 3) * 16));
      const f32x4 av = acc[M][N];
      float vals[4];
#pragma unroll
      for (int j = 0; j < 4; ++j) {
        float addv;
        if constexpr (MODE == 3) addv = bias_m ? biasSel[m + j] : bn;
        else if constexpr (BIAS_MODE == 1) addv = bias[m + j];
        else addv = bn;
        vals[j] = av[j] * alpha + addv;
        if (SCALEN) vals[j] *= sc;
        if (STATS) { vals[j] = __expf(vals[j]); eN += vals[j]; }
      }
      if (OUT_MODE == 0) {
        ushort4 o; o.x = f2bf(vals[0]); o.y = f2bf(vals[1]); o.z = f2bf(vals[2]); o.w = f2bf(vals[3]);
        *(ushort4*)((unsigned short*)Csel + (long)bz * sCz + (long)n * ldcSel + m) = o;
      } else if (OUT_MODE == 2) {
        int pk = __builtin_amdgcn_cvt_pk_fp8_f32(vals[0], vals[1], 0, false);
        pk = __builtin_amdgcn_cvt_pk_fp8_f32(vals[2], vals[3], pk, true);
        *(int*)((unsigned char*)Csel + (long)bz * sCz + (long)n * ldcSel + perm64(m)) = pk;
      } else {
        const float* rp = resid + (long)n * ldcSel + m;
        float4 o; o.x = vals[0] + rp[0]; o.y = vals[1] + rp[1]; o.z = vals[2] + rp[2]; o.w = vals[3] + rp[3];
        *(float4*)((float*)Csel + (long)bz * sCz + (long)n * ldcSel + m) = o;
      }
    }
    if (STATS) {
      const int nloc = n - by * BN;
      const int slot = wm * 4 + (lane >> 4);
      red[nloc * NSLOTP + slot] = eN;
    }
  }
  if (STATS) {
    bar();
    if (tid < BN) {
      float L = 0.f;
#pragma unroll
      for (int s2 = 0; s2 < NSLOT; ++s2) L += red[tid * NSLOTP + s2];
      rowsums[((long)(bz * gx + bx)) * 2304 + by * BN + tid] = L;
    }
  }
#undef READ_A
#undef READ_B
#undef MFMA_QUAD
}

extern "C" void kernel_launch(void* const* d_in, const int* in_sizes, int n_in,
                              void* d_out, int out_size, void* d_ws, size_t ws_size,
                              hipStream_t stream) {
  const float* x = (const float*)d_in[0];
  const float* gamma = (const float*)d_in[1];
  const float* beta = (const float*)d_in[2];
  const float* wq = (const float*)d_in[3];
  const float* bq = (const float*)d_in[4];
  const float* wk = (const float*)d_in[5];
  const float* bk = (const float*)d_in[6];
  const float* wv = (const float*)d_in[7];
  const float* bv = (const float*)d_in[8];
  const float* wo = (const float*)d_in[9];
  const float* bo = (const float*)d_in[10];
  float* out = (float*)d_out;

  char* ws = (char*)d_ws;
  size_t off = 0;
  auto alloc = [&](size_t bytes) {
    char* p = ws + off;
    off = (off + bytes + 255) & ~(size_t)255;
    return p;
  };
  float* part = (float*)alloc(256 * 2 * sizeof(float));
  unsigned short* wqkb = (unsigned short*)alloc((size_t)2 * 262144 * 2);
  unsigned short* wvb = (unsigned short*)alloc((size_t)262144 * 2);
  unsigned short* wob = (unsigned short*)alloc((size_t)262144 * 2);
  float* bqk = (float*)alloc(1024 * sizeof(float));
  float* rowsums = (float*)alloc((size_t)8 * 18 * 2304 * sizeof(float));
  unsigned short* hnT = (unsigned short*)alloc((size_t)18432 * 512 * 2);
  unsigned char* qkA = (unsigned char*)alloc((size_t)18432 * 1024);      // fp8 k-interleaved
  unsigned char* vT = (unsigned char*)alloc((size_t)512 * 18432);        // fp8 k-interleaved
  unsigned char* Sm = (unsigned char*)alloc((size_t)8 * 2304 * 2304);    // fp8 E k-interleaved
  unsigned short* Ob = hnT;  // alias: hnT fully consumed after qk/v GEMMs
  (void)ws_size; (void)in_sizes; (void)n_in; (void)out_size;

  stats_partial_k<<<dim3(256), dim3(256), 0, stream>>>(x, part);
  gn_transpose_k<<<dim3(8, 288), dim3(256), 0, stream>>>(x, part, gamma, beta, hnT);
  pack4_bf16_k<<<dim3(256, 5), dim3(256), 0, stream>>>(wq, wk, wv, wo,
                                                       wqkb, wqkb + 262144, wvb, wob,
                                                       bq, bk, bqk);

  // Fused qk+v (MODE3) on WL=2 bf16 (512 thr, 8 waves, 4 waves/SIMD).
  // Blocks [0,1152): qk -- A=[Wq;Wk] bf16, B=hnT -> qkA fp8 [sp][1024].
  // Blocks [1152,1728): v -- A=hnT, B=wvb -> vT fp8 [co][18432].
  gemm256<128, 1, 2, 0, 0, 3, 0, 1, 2><<<dim3(1728), dim3(512), 0, stream>>>(
      wqkb, 512, 0, hnT, 512, 0, (void*)qkA, 1024, 0, bqk,
      (const float*)wvb, (float*)vT, bv, 1.0f, 512, 1152, 0);
  // S: per t: A=k fp8, B=q fp8 -> E=exp(alpha*S) fp8 interleaved + rowsums.
  // WL=2 fp8 (512 thr, 8 waves, 4 blocks/CU): 2592 blocks MODE0.
  gemm256<128, 0, 2, 1, 0, 0, 1, 1, 2><<<dim3(2592), dim3(512), 0, stream>>>(
      qkA + 512, 1024, (long)2304 * 1024, qkA, 1024, (long)2304 * 1024, (void*)Sm, 2304,
      (long)2304 * 2304, nullptr, nullptr, rowsums, nullptr,
      0.044194173824159216f, 512, 18, 18);
  // PV: per t: A=vT fp8, B=E fp8 -> O bf16 [(t,i)*512+c], rows scaled by 1/L.
  // R25: WL=2 fp8 (512 thr, 8 waves -- verified machine from R24 S), SCALEN=2.
  // 576 blocks MODE0: was ~2.25 waves/SIMD at WL=1, now ~4.5.
  gemm256<128, 0, 0, 0, 2, 0, 1, 1, 2><<<dim3(576), dim3(512), 0, stream>>>(
      vT, 18432, 2304, Sm, 2304, (long)2304 * 2304, (void*)Ob, 512, (long)2304 * 512,
      nullptr, nullptr, rowsums, nullptr, 1.0f, 2304, 4, 18);
  // final: A=O bf16, B=Wo bf16 -> out[co*18432+sp] = x + acc + bo[co].
  // WL=2 bf16 (qv-proven machine), MODE2: 8 x 18 x 4 = 576 blocks.
  gemm256<128, 2, 1, 0, 0, 2, 0, 1, 2><<<dim3(576), dim3(512), 0, stream>>>(
      Ob, 512, 0, wob, 512, 0, (void*)out, 18432, 0, bo, x, nullptr, nullptr,
      1.0f, 512, 18, 4);
}

// Round 17
// 201.744 us; speedup vs baseline: 1.3224x; 1.0382x over previous
//
#include <hip/hip_runtime.h>
#include <hip/hip_bf16.h>
#include <cstdint>
#include <type_traits>

typedef __attribute__((ext_vector_type(8))) __bf16 bf16x8;
typedef __attribute__((ext_vector_type(4))) float f32x4;
typedef __attribute__((ext_vector_type(2))) long longx2;

struct bf2frag { bf16x8 k0, k1; };

__device__ __forceinline__ float bf2f(unsigned short u) {
  union { uint32_t i; float f; } v; v.i = (uint32_t)u << 16; return v.f;
}
__device__ __forceinline__ unsigned short f2bf(float f) {
  union { float f; uint32_t i; } v{f};
  uint32_t r = v.i + 0x7fffu + ((v.i >> 16) & 1u);
  return (unsigned short)(r >> 16);
}

__device__ __forceinline__ void gll(const void* g, void* l) {
  __builtin_amdgcn_global_load_lds(
      (const __attribute__((address_space(1))) uint32_t*)(uintptr_t)g,
      (__attribute__((address_space(3))) uint32_t*)(uint32_t)(uintptr_t)l,
      16, 0, 0);
}

__device__ __forceinline__ void bar() {
  asm volatile("" ::: "memory");
  __builtin_amdgcn_s_barrier();
  asm volatile("" ::: "memory");
}

#define VMCNT(n) asm volatile("s_waitcnt vmcnt(" #n ")" ::: "memory")

template <int N>
__device__ __forceinline__ void vmw() {
  if constexpr (N == 0) { VMCNT(0); }
  else if constexpr (N == 1) { VMCNT(1); }
  else if constexpr (N == 2) { VMCNT(2); }
  else if constexpr (N == 3) { VMCNT(3); }
  else if constexpr (N == 4) { VMCNT(4); }
  else if constexpr (N == 5) { VMCNT(5); }
  else if constexpr (N == 6) { VMCNT(6); }
  else if constexpr (N == 7) { VMCNT(7); }
  else if constexpr (N == 8) { VMCNT(8); }
  else if constexpr (N == 9) { VMCNT(9); }
  else if constexpr (N == 10) { VMCNT(10); }
  else { VMCNT(12); }
}

__device__ __forceinline__ f32x4 mma(bf16x8 a, bf16x8 b, f32x4 c) {
  return __builtin_amdgcn_mfma_f32_16x16x32_bf16(a, b, c, 0, 0, 0);
}
__device__ __forceinline__ f32x4 mma(long a, long b, f32x4 c) {
  return __builtin_amdgcn_mfma_f32_16x16x32_fp8_fp8(a, b, c, 0, 0, 0);
}
__device__ __forceinline__ f32x4 mmak(const bf2frag& a, const bf2frag& b, f32x4 c, int k2) {
  return k2 ? mma(a.k1, b.k1, c) : mma(a.k0, b.k0, c);
}
__device__ __forceinline__ f32x4 mmak(longx2 a, longx2 b, f32x4 c, int k2) {
  return mma(a[k2], b[k2], c);
}

// k-interleave store permutation for fp8 buffers (unit u=8B: slot p(u)=(u&3)*2+(u>>2))
__device__ __forceinline__ int perm64(int m) {
  return (m & ~63) | (((m >> 3) & 3) << 4) | (((m >> 5) & 1) << 3) | (m & 7);
}

// ---------------- GroupNorm stats ----------------
// R26: 1024 blocks (32 spatial parts/group, 4 blocks/CU) for streaming TLP.
__global__ __launch_bounds__(256) void stats_partial_k(const float* __restrict__ x,
                                                       float* __restrict__ part) {
  const int g = blockIdx.x >> 5, p = blockIdx.x & 31;
  const float* base = x + (long)g * 16 * 18432 + (long)p * 576;
  float s = 0.f, ss = 0.f;
  for (int idx = threadIdx.x; idx < 16 * 144; idx += 256) {
    const int c = idx / 144, i4 = idx % 144;
    const float4 v = *(const float4*)(base + (long)c * 18432 + i4 * 4);
    s += v.x + v.y + v.z + v.w;
    ss += v.x * v.x + v.y * v.y + v.z * v.z + v.w * v.w;
  }
  __shared__ float rs[256], rss[256];
  rs[threadIdx.x] = s; rss[threadIdx.x] = ss;
  __syncthreads();
  for (int o = 128; o > 0; o >>= 1) {
    if ((int)threadIdx.x < o) { rs[threadIdx.x] += rs[threadIdx.x + o]; rss[threadIdx.x] += rss[threadIdx.x + o]; }
    __syncthreads();
  }
  if (threadIdx.x == 0) { part[blockIdx.x * 2] = rs[0]; part[blockIdx.x * 2 + 1] = rss[0]; }
}

// ---------------- GN apply + transpose to (spatial, channel) bf16 ----------------
// R21: stats_final folded in. R26: float4 loads + ushort4 transposed stores
// (was scalar f32 load / scalar ushort store -- G13 violation on a 94MB kernel).
__global__ __launch_bounds__(256) void gn_transpose_k(const float* __restrict__ x,
                                                      const float* __restrict__ part,
                                                      const float* __restrict__ gamma,
                                                      const float* __restrict__ beta,
                                                      unsigned short* __restrict__ hnT) {
  __shared__ float tile[64][65];
  __shared__ float sm[4], sr[4];
  const int c0 = blockIdx.x * 64, n0 = blockIdx.y * 64;
  const int tid = threadIdx.x;
  if (tid < 4) {
    const int g = (c0 >> 4) + tid;
    float s = 0.f, ss = 0.f;
    for (int p = 0; p < 32; ++p) { s += part[(g * 32 + p) * 2]; ss += part[(g * 32 + p) * 2 + 1]; }
    const float mean = s / 294912.0f;
    const float var = ss / 294912.0f - mean * mean;
    sm[tid] = mean;
    sr[tid] = rsqrtf(var + 1e-6f);
  }
  __syncthreads();
  const int rl = tid >> 4, cl4 = (tid & 15) * 4;
#pragma unroll
  for (int pass = 0; pass < 4; ++pass) {
    const int cc = rl + pass * 16;
    const int c = c0 + cc;
    const float mean = sm[cc >> 4], rstd = sr[cc >> 4];
    const float ga = gamma[c], be = beta[c];
    const float4 v = *(const float4*)(x + (long)c * 18432 + n0 + cl4);
    tile[cc][cl4 + 0] = (v.x - mean) * rstd * ga + be;
    tile[cc][cl4 + 1] = (v.y - mean) * rstd * ga + be;
    tile[cc][cl4 + 2] = (v.z - mean) * rstd * ga + be;
    tile[cc][cl4 + 3] = (v.w - mean) * rstd * ga + be;
  }
  __syncthreads();
#pragma unroll
  for (int pass = 0; pass < 4; ++pass) {
    const int nn = rl + pass * 16;
    ushort4 u;
    u.x = f2bf(tile[cl4 + 0][nn]);
    u.y = f2bf(tile[cl4 + 1][nn]);
    u.z = f2bf(tile[cl4 + 2][nn]);
    u.w = f2bf(tile[cl4 + 3][nn]);
    *(ushort4*)(hnT + (long)(n0 + nn) * 512 + c0 + cl4) = u;
  }
}

// ---------------- fp32 -> bf16 weight pack (4 weights + qk-bias in one launch) ----------------
__global__ __launch_bounds__(256) void pack4_bf16_k(const float* __restrict__ w0,
                                                    const float* __restrict__ w1,
                                                    const float* __restrict__ w2,
                                                    const float* __restrict__ w3,
                                                    unsigned short* __restrict__ o0,
                                                    unsigned short* __restrict__ o1,
                                                    unsigned short* __restrict__ o2,
                                                    unsigned short* __restrict__ o3,
                                                    const float* __restrict__ bq,
                                                    const float* __restrict__ bk,
                                                    float* __restrict__ bqk) {
  const int y = blockIdx.y;
  if (y == 4) {  // R21: pack_bias folded in (block 0 only)
    if (blockIdx.x == 0) {
      const int i = threadIdx.x * 4;
#pragma unroll
      for (int j = 0; j < 4; ++j) {
        const int t = i + j;
        bqk[t] = (t < 512) ? bq[t] : bk[t - 512];
      }
    }
    return;
  }
  const float* w = (y == 0) ? w0 : (y == 1) ? w1 : (y == 2) ? w2 : w3;
  unsigned short* o = (y == 0) ? o0 : (y == 1) ? o1 : (y == 2) ? o2 : o3;
  const int i = (blockIdx.x * 256 + threadIdx.x) * 4;
  const float4 v = *(const float4*)(w + i);
  ushort4 u; u.x = f2bf(v.x); u.y = f2bf(v.y); u.z = f2bf(v.z); u.w = f2bf(v.w);
  *(ushort4*)(o + i) = u;
}

// ================= BMxBNxBK NT GEMM, XCD-swizzled, bf16/fp8 =================
// C[n*ldc+m] = alpha*sum_k A[m,k]*B[n,k] (+bias)(+resid)
// WL=0, BM=256: 512 thr, 8 waves (2m x 4n), 1 block/CU, P2=0, setprio ON.
// WL=1: BM=128 x BN=128, 256 thr, 4 waves (2m x 2n, 64x64/wave).
//   fp8 KU=1: 32KB LDS, bounds(256,4). bf16: 64KB, 2 blocks/CU.
// WL=2: BM=128 x BN=128, 512 thr, 8 waves (2m x 4n, 64x32/wave).
//   bf16 (R23 qv, R24 final): 64KB LDS, 2 blocks/CU, 4 waves/SIMD.
//   fp8 (R24 S; R25 PV): 32KB LDS, bounds(512,8), FULL-TILE stages (8192B =
//   1 gll/thread; LDS dest linear, As[slot][0..1] contiguous).
//   WL2-fp8 schedule: prologue [Afull(0),Bfull(0),Bfull(1)], vmcnt(1);
//   P0: read A0+ownB, stage Afull(W+1)->s^1, mfma m0; P1: read A1, stage
//   Bfull(W+2)->s, mfma m1, vmcnt(st2?1:0). Verified on S (R24, VGPR 32).
//   R24/R25 verdict: TLP exonerated (Occupancy 62%, MfmaUtil flat 29);
//   the fp8 GEMM ~5000cy/K-step wall is structural after 9 probes. STOP.
//   Ladder: R13 S TLP, R14 qk, R15 PV, R17 v+final, R21/22 folds, R23 qv WL2.
//   A/B halves use 32-row stripe interleave: grow = (r>>5)*64 + h*32 + (r&31).
// P2=1 (2-phase, WL<2 or bf16): P0: read A0,B; stage [A0,B1,A1](W+1) -> s^1;
//   mfma m0. P1: read A1; stage B0(W+2) -> s; mfma m1.
//   Waits: @P0-end vmcnt(2(GA+GB)); @P1-end vmcnt(GA+GB); tail GA then 0.
// STATS: exp+rowsums, scratch stride NSLOT+1 (R18).
// SCALEN: 1 = *linv[n]; 2 = combine folded into prologue (R21).
// OUT_MODE: 0 bf16, 1 f32+resid, 2 fp8 e4m3 k-interleaved.
// MODE0: bz=bid%8 per XCD; MODE1/2: XCD y/x-chunking.
// MODE3 (R22): fused qk+v single dispatch; blocks < gx run qk (MODE1 8x18),
//   rest run v (MODE2 18x4) with params via resid/rowsums/linv.
template <int BM, int BIAS_MODE, int OUT_MODE, int STATS, int SCALEN, int MODE, int FP8, int P2,
          int WL = 0, int KU = 1>
__global__ __launch_bounds__((BM == 256 || WL == 2) ? 512 : 256,
                             (WL == 1 && FP8) ? (KU == 2 ? 2 : 4) : ((WL == 2 && FP8) ? 8 : 2))
void gemm256(const void* __restrict__ A, long lda, long sAz,
             const void* __restrict__ B, long ldb, long sBz,
             void* __restrict__ Cp, long ldc, long sCz,
             const float* __restrict__ bias,
             const float* __restrict__ resid,
             float* __restrict__ rowsums,
             const float* __restrict__ linv,
             float alpha, int K, int gx, int gy) {
  static_assert(KU == 1 || FP8, "KU=2 only on fp8 path");
  constexpr int EB = FP8 ? 1 : 2;                    // element bytes
  constexpr int THREADS = (BM == 256 || WL == 2) ? 512 : 256;
  constexpr int BN = WL ? 128 : 256;                 // n-tile
  constexpr int BK = 64 * KU;                        // k-step
  constexpr int HBA = (BM / 2) * BK * EB;            // bytes per A half
  constexpr int HBB = (BN / 2) * BK * EB;            // bytes per B half
  constexpr int HBA0 = HBA / KU, HBB0 = HBB / KU;    // per 64-k sub-block
  constexpr bool FT = (WL == 2 && FP8);              // full-tile staging path
  constexpr int GA = FT ? 1 : HBA / (THREADS * 16);  // gll per A stage unit
  constexpr int GB = FT ? 1 : HBB / (THREADS * 16);  // gll per B stage unit
  constexpr int GA0 = FT ? 1 : GA / KU, GB0 = FT ? 1 : GB / KU;
  constexpr int V0 = GB + 2 * GA, V3 = 2 * GB + GA, VP = GB + GA;
  constexpr int NSLOT = WL ? 8 : ((BM == 256) ? 8 : 4);
  constexpr int NSLOTP = NSLOT + 1;                  // R18: odd stride
  constexpr int MR = WL ? 4 : 8;                     // acc M-frags per wave
  constexpr int NR = (WL == 2) ? 2 : 4;              // acc N-frags per wave
  constexpr int FQ = WL ? 2 : 4;                     // A-frags per (mh) phase
  constexpr int PRIO = !P2;                          // setprio only on 1-block path
  __shared__ alignas(16) unsigned char As[2][2][HBA];
  __shared__ alignas(16) unsigned char Bs[2][2][HBB];
  __shared__ float linvs[SCALEN == 2 ? BN : 1];
  using ABt2 = typename std::conditional<FP8, longx2, bf2frag>::type;

  const int tid = threadIdx.x;
  const int lane = tid & 63, wid = tid >> 6;
  const int wm = (WL == 2) ? (wid >> 2) : (WL ? (wid >> 1) : ((BM == 256) ? (wid & 1) : 0));
  const int wn = (WL == 2) ? (wid & 3) : (WL ? (wid & 1) : ((BM == 256) ? (wid >> 1) : wid));
  int bx, by, bz;
  const void* Asel = A;
  const void* Bsel = B;
  void* Csel = Cp;
  const float* biasSel = bias;
  long ldcSel = ldc;
  bool bias_m = (BIAS_MODE == 1);
  {
    const int g8 = blockIdx.x & 7, n = blockIdx.x >> 3;
    if (MODE == 0) { bz = g8; bx = n % gx; by = n / gx; }
    else if (MODE == 1) { bz = 0; bx = n % gx; by = g8 * gy + n / gx; }
    else if (MODE == 2) { bz = 0; by = n % gy; bx = g8 * gx + n / gy; }
    else {  // MODE 3: fused qk+v; gx = number of qk blocks
      bz = 0;
      if ((int)blockIdx.x < gx) {
        bx = n % 8; by = g8 * 18 + n / 8;          // qk: MODE1 gx=8, gy=18
      } else {
        const int b2 = (int)blockIdx.x - gx;
        const int g82 = b2 & 7, n2 = b2 >> 3;
        by = n2 % 4; bx = g82 * 18 + n2 / 4;       // v: MODE2 gx=18, gy=4
        Asel = B;                                   // hnT
        Bsel = (const void*)resid;                  // wvb
        Csel = (void*)rowsums;                      // vT
        biasSel = linv;                             // bv
        ldcSel = 18432;
        bias_m = false;
      }
    }
  }
  const unsigned char* Ab = (const unsigned char*)Asel + ((long)bz * sAz + (long)bx * BM * lda) * EB;
  const unsigned char* Bb = (const unsigned char*)Bsel + ((long)bz * sBz + (long)by * BN * ldb) * EB;

  // R21 (SCALEN==2): fold combine -- compute 1/L for this block's rows first,
  // so the scalar loads retire before any gll enters the vmcnt FIFO.
  if constexpr (SCALEN == 2) {
    if (tid < BN) {
      const int ntile = K / BN;
      float L = 0.f;
      for (int xx = 0; xx < ntile; ++xx)
        L += rowsums[((long)(bz * ntile + xx)) * K + by * BN + tid];
      linvs[tid] = 1.0f / L;
    }
  }

  // ---- staging (global -> LDS, pre-swizzled source; fp8 global is k-interleaved) ----
  auto stageA = [&](int slot, int h, int k0) {
    if constexpr (!FP8) {
      const int ksw = ((tid & 7) << 3) ^ (((tid >> 3) & 7) << 3);
#pragma unroll
      for (int call = 0; call < GA; ++call) {
        const int r = call * (THREADS / 8) + (tid >> 3);
        const int grow = WL ? (((r >> 5) << 6) + h * 32 + (r & 31))
                            : (((r >> 6) << 7) + h * 64 + (r & 63));
        gll(Ab + ((long)grow * lda + k0) * 2 + ksw * 2, &As[slot][h][call * THREADS * 16 + tid * 16]);
      }
    } else {
#pragma unroll
      for (int call = 0; call < GA; ++call) {
        const int sub = call / GA0, c0 = call % GA0;
        const int l = c0 * (THREADS / 4) + (tid >> 2);
        const int grow = WL ? (((l >> 5) << 6) + h * 32 + (l & 31))
                            : (((l >> 6) << 7) + h * 64 + (l & 63));
        const int x = (((l & 3) ^ ((l >> 2) & 3)) << 4);
        gll(Ab + (long)grow * lda + k0 + sub * 64 + (((tid & 3) << 4) ^ x),
            &As[slot][h][call * THREADS * 16 + tid * 16]);
      }
    }
  };
  auto stageB = [&](int slot, int h, int k0) {
    if constexpr (!FP8) {
      const int ksw = ((tid & 7) << 3) ^ (((tid >> 3) & 7) << 3);
#pragma unroll
      for (int call = 0; call < GB; ++call) {
        const int r = call * (THREADS / 8) + (tid >> 3);
        const int grow = ((r >> 5) << 6) + h * 32 + (r & 31);
        gll(Bb + ((long)grow * ldb + k0) * 2 + ksw * 2, &Bs[slot][h][call * THREADS * 16 + tid * 16]);
      }
    } else {
#pragma unroll
      for (int call = 0; call < GB; ++call) {
        const int sub = call / GB0, c0 = call % GB0;
        const int l = c0 * (THREADS / 4) + (tid >> 2);
        const int grow = ((l >> 5) << 6) + h * 32 + (l & 31);
        const int x = (((l & 3) ^ ((l >> 2) & 3)) << 4);
        gll(Bb + (long)grow * ldb + k0 + sub * 64 + (((tid & 3) << 4) ^ x),
            &Bs[slot][h][call * THREADS * 16 + tid * 16]);
      }
    }
  };
  // WL2-fp8 full-tile stages: 1 gll/thread covers both halves (8192B).
  // tid = hh*256 + tl; per-half mapping identical to WL=1 fp8 (THREADS=256, GA=1).
  auto stageAF = [&](int slot, int k0) {
    const int hh = tid >> 8, tl = tid & 255;
    const int l = tl >> 2;
    const int grow = ((l >> 5) << 6) + hh * 32 + (l & 31);
    const int x = (((l & 3) ^ ((l >> 2) & 3)) << 4);
    gll(Ab + (long)grow * lda + k0 + (((tid & 3) << 4) ^ x),
        &As[slot][0][0] + tid * 16);
  };
  auto stageBF = [&](int slot, int k0) {
    const int hh = tid >> 8, tl = tid & 255;
    const int l = tl >> 2;
    const int grow = ((l >> 5) << 6) + hh * 32 + (l & 31);
    const int x = (((l & 3) ^ ((l >> 2) & 3)) << 4);
    gll(Bb + (long)grow * ldb + k0 + (((tid & 3) << 4) ^ x),
        &Bs[slot][0][0] + tid * 16);
  };
  // ---- LDS -> fragment reads (same swizzle; fp8 = ONE b128 for both k2 slices) ----
  auto ldA = [&](int slot, int mh, int fq, int sub) -> ABt2 {
    const int r = (WL ? wm * 32 : wm * 64) + fq * 16 + (lane & 15);
    if constexpr (!FP8) {
      bf2frag f;
      const int kk0 = (((lane >> 4) << 3)) ^ ((r & 7) << 3);
      const int kk1 = (32 + ((lane >> 4) << 3)) ^ ((r & 7) << 3);
      f.k0 = *reinterpret_cast<const bf16x8*>(&As[slot][mh][r * 128 + kk0 * 2]);
      f.k1 = *reinterpret_cast<const bf16x8*>(&As[slot][mh][r * 128 + kk1 * 2]);
      return f;
    } else {
      const int x = (((r & 3) ^ ((r >> 2) & 3)) << 4);
      const int kk = ((lane >> 4) << 4) ^ x;
      return *reinterpret_cast<const longx2*>(&As[slot][mh][sub * HBA0 + r * 64 + kk]);
    }
  };
  auto ldB = [&](int slot, int nh, int g, int sub) -> ABt2 {
    // WL=2: wave owns 32 global n-rows = stripe chunk wn>>1, half wn&1.
    const int half = (WL == 2) ? (wn & 1) : nh;
    const int r = ((WL == 2) ? (wn >> 1) : wn) * 32 + g * 16 + (lane & 15);
    if constexpr (!FP8) {
      bf2frag f;
      const int kk0 = (((lane >> 4) << 3)) ^ ((r & 7) << 3);
      const int kk1 = (32 + ((lane >> 4) << 3)) ^ ((r & 7) << 3);
      f.k0 = *reinterpret_cast<const bf16x8*>(&Bs[slot][half][r * 128 + kk0 * 2]);
      f.k1 = *reinterpret_cast<const bf16x8*>(&Bs[slot][half][r * 128 + kk1 * 2]);
      return f;
    } else {
      const int x = (((r & 3) ^ ((r >> 2) & 3)) << 4);
      const int kk = ((lane >> 4) << 4) ^ x;
      return *reinterpret_cast<const longx2*>(&Bs[slot][half][sub * HBB0 + r * 64 + kk]);
    }
  };

  f32x4 acc[MR][NR] = {};
  ABt2 a[FQ * KU], b0[2 * KU], b1[2 * KU];

#define READ_A(SLOT, MH)                                                       \
  _Pragma("unroll") for (int fq = 0; fq < FQ; ++fq)                            \
    _Pragma("unroll") for (int sub = 0; sub < KU; ++sub)                       \
      a[fq * KU + sub] = ldA(SLOT, MH, fq, sub);
#define READ_B(SLOT, NH, DST)                                                  \
  _Pragma("unroll") for (int g = 0; g < 2; ++g)                                \
    _Pragma("unroll") for (int sub = 0; sub < KU; ++sub)                       \
      DST[g * KU + sub] = ldB(SLOT, NH, g, sub);
#define MFMA_QUAD(MH, NH, BARR)                                                \
  if constexpr (PRIO) __builtin_amdgcn_s_setprio(1);                           \
  _Pragma("unroll") for (int fq = 0; fq < FQ; ++fq)                            \
    _Pragma("unroll") for (int g = 0; g < 2; ++g)                              \
      _Pragma("unroll") for (int sub = 0; sub < KU; ++sub)                     \
        _Pragma("unroll") for (int k2 = 0; k2 < 2; ++k2)                       \
          acc[(MH) * FQ + fq][(NH) * 2 + g] =                                  \
              mmak(a[fq * KU + sub], BARR[g * KU + sub],                       \
                   acc[(MH) * FQ + fq][(NH) * 2 + g], k2);                     \
  if constexpr (PRIO) __builtin_amdgcn_s_setprio(0);

  const int KT = K / BK;
  if constexpr (FT) {
    // ---- WL2-fp8: full-tile staging schedule ----
    stageAF(0, 0);
    stageBF(0, 0);
    stageBF(1, BK);
    vmw<1>();
    bar();
    for (int W = 0; W < KT; ++W) {
      const int s = W & 1;
      const int kn1 = (W + 1) * BK, kn2 = (W + 2) * BK;
      const bool st1 = (W + 1 < KT), st2 = (W + 2 < KT);
      // P0: read A0 + own B; stage A-full(W+1) -> s^1.
      READ_A(s, 0)
      READ_B(s, 0, b0)
      if (st1) stageAF(s ^ 1, kn1);
      bar();
      MFMA_QUAD(0, 0, b0)
      bar();
      // P1: read A1; stage B-full(W+2) -> s (all B reads of s done in P0).
      READ_A(s, 1)
      if (st2) stageBF(s, kn2);
      bar();
      MFMA_QUAD(1, 0, b0)
      if (st2) { vmw<1>(); } else { vmw<0>(); }
      bar();
    }
  } else {
    // Prologue queue: [B0(0), A0(0), B1(0), A1(0), B0(1)] (+A1(1) for P2=0)
    stageB(0, 0, 0);
    stageA(0, 0, 0);
    stageB(0, 1, 0);
    stageA(0, 1, 0);
    stageB(1, 0, BK);
    if constexpr (!P2) stageA(1, 1, BK);
    vmw<VP>();
    bar();

    if constexpr (!P2) {
      for (int W = 0; W < KT; ++W) {
        const int s = W & 1;
        const int kn1 = (W + 1) * BK, kn2 = (W + 2) * BK;
        const bool st1 = (W + 1 < KT), st2 = (W + 2 < KT);
        // p0: (m0,n0)
        READ_A(s, 0)
        READ_B(s, 0, b0)
        if (st1) stageA(s ^ 1, 0, kn1);
        bar();
        MFMA_QUAD(0, 0, b0)
        if (st1) { vmw<V0>(); }
        bar();
        // p1: (m0,n1)
        READ_B(s, 1, b1)
        if (st1) stageB(s ^ 1, 1, kn1);
        bar();
        MFMA_QUAD(0, 1, b1)
        bar();
        // p2: (m1,n1)
        READ_A(s, 1)
        if (st2) stageB(s, 0, kn2);
        bar();
        MFMA_QUAD(1, 1, b1)
        bar();
        // p3: (m1,n0)
        if (st2) stageA(s, 1, kn2);
        bar();
        MFMA_QUAD(1, 0, b0)
        if (st2) { vmw<V3>(); } else { vmw<0>(); }
        bar();
      }
    } else {
      for (int W = 0; W < KT; ++W) {
        const int s = W & 1;
        const int kn1 = (W + 1) * BK, kn2 = (W + 2) * BK;
        const bool st1 = (W + 1 < KT), st2 = (W + 2 < KT);
        // P0: m0 x (WL=2: own B-half | else: n0,n1); stage trio (A1 LAST).
        READ_A(s, 0)
        READ_B(s, 0, b0)
        if constexpr (WL != 2) { READ_B(s, 1, b1) }
        if (st1) { stageA(s ^ 1, 0, kn1); stageB(s ^ 1, 1, kn1); stageA(s ^ 1, 1, kn1); }
        bar();
        MFMA_QUAD(0, 0, b0)
        if constexpr (WL != 2) { MFMA_QUAD(0, 1, b1) }
        if (st1) { vmw<2 * (GA + GB)>(); } else { vmw<0>(); }
        bar();
        // P1: m1; stage B0(W+2) into current slot (B0(W) consumed in P0).
        READ_A(s, 1)
        if (st2) stageB(s, 0, kn2);
        bar();
        if constexpr (WL != 2) { MFMA_QUAD(1, 1, b1) }
        MFMA_QUAD(1, 0, b0)
        if (st2) { vmw<GA + GB>(); } else if (st1) { vmw<GA>(); } else { vmw<0>(); }
        bar();
      }
    }
  }

  // epilogue: acc[M][N].
  // WL=0: M = mh*4+fq, m-off = (M>>2)*64 + (M&3)*16, wave m-base wm*128.
  // WL>=1: M = mh*2+fq, m-off = (M>>1)*32 + (M&1)*16, wave m-base wm*64.
  // WL=2: N in {0,1}, n = by*128 + wn*32 + N*16 + (lane&15).
  const int mg0 = bx * BM + (WL ? wm * 64 : wm * 128) + ((lane >> 4) << 2);
  const int ng0 = by * BN + ((WL == 2) ? wn * 32 : wn * 64) + (lane & 15);
  float* red = (float*)&As[0][0][0];  // STATS scratch: BN rows x NSLOTP f32
#pragma unroll
  for (int N = 0; N < NR; ++N) {
    const int n = ng0 + ((WL == 2) ? N * 16 : ((N >> 1) * 32 + (N & 1) * 16));
    float bn;
    if constexpr (MODE == 3) bn = bias_m ? 0.f : biasSel[n];
    else bn = (BIAS_MODE == 2) ? bias[n] : 0.f;
    const float sc = (SCALEN == 1) ? linv[(long)bz * 2304 + n]
                   : (SCALEN == 2) ? linvs[n - by * BN] : 1.0f;
    float eN = 0.f;
#pragma unroll
    for (int M = 0; M < MR; ++M) {
      const int m = mg0 + (WL ? ((M >> 1) * 32 + (M & 1) * 16) : ((M >> 2) * 64 + (M & 3) * 16));
      const f32x4 av = acc[M][N];
      float vals[4];
#pragma unroll
      for (int j = 0; j < 4; ++j) {
        float addv;
        if constexpr (MODE == 3) addv = bias_m ? biasSel[m + j] : bn;
        else if constexpr (BIAS_MODE == 1) addv = bias[m + j];
        else addv = bn;
        vals[j] = av[j] * alpha + addv;
        if (SCALEN) vals[j] *= sc;
        if (STATS) { vals[j] = __expf(vals[j]); eN += vals[j]; }
      }
      if (OUT_MODE == 0) {
        ushort4 o; o.x = f2bf(vals[0]); o.y = f2bf(vals[1]); o.z = f2bf(vals[2]); o.w = f2bf(vals[3]);
        *(ushort4*)((unsigned short*)Csel + (long)bz * sCz + (long)n * ldcSel + m) = o;
      } else if (OUT_MODE == 2) {
        int pk = __builtin_amdgcn_cvt_pk_fp8_f32(vals[0], vals[1], 0, false);
        pk = __builtin_amdgcn_cvt_pk_fp8_f32(vals[2], vals[3], pk, true);
        *(int*)((unsigned char*)Csel + (long)bz * sCz + (long)n * ldcSel + perm64(m)) = pk;
      } else {
        const float* rp = resid + (long)n * ldcSel + m;
        float4 o; o.x = vals[0] + rp[0]; o.y = vals[1] + rp[1]; o.z = vals[2] + rp[2]; o.w = vals[3] + rp[3];
        *(float4*)((float*)Csel + (long)bz * sCz + (long)n * ldcSel + m) = o;
      }
    }
    if (STATS) {
      const int nloc = n - by * BN;
      const int slot = wm * 4 + (lane >> 4);
      red[nloc * NSLOTP + slot] = eN;
    }
  }
  if (STATS) {
    bar();
    if (tid < BN) {
      float L = 0.f;
#pragma unroll
      for (int s2 = 0; s2 < NSLOT; ++s2) L += red[tid * NSLOTP + s2];
      rowsums[((long)(bz * gx + bx)) * 2304 + by * BN + tid] = L;
    }
  }
#undef READ_A
#undef READ_B
#undef MFMA_QUAD
}

extern "C" void kernel_launch(void* const* d_in, const int* in_sizes, int n_in,
                              void* d_out, int out_size, void* d_ws, size_t ws_size,
                              hipStream_t stream) {
  const float* x = (const float*)d_in[0];
  const float* gamma = (const float*)d_in[1];
  const float* beta = (const float*)d_in[2];
  const float* wq = (const float*)d_in[3];
  const float* bq = (const float*)d_in[4];
  const float* wk = (const float*)d_in[5];
  const float* bk = (const float*)d_in[6];
  const float* wv = (const float*)d_in[7];
  const float* bv = (const float*)d_in[8];
  const float* wo = (const float*)d_in[9];
  const float* bo = (const float*)d_in[10];
  float* out = (float*)d_out;

  char* ws = (char*)d_ws;
  size_t off = 0;
  auto alloc = [&](size_t bytes) {
    char* p = ws + off;
    off = (off + bytes + 255) & ~(size_t)255;
    return p;
  };
  float* part = (float*)alloc(1024 * 2 * sizeof(float));
  unsigned short* wqkb = (unsigned short*)alloc((size_t)2 * 262144 * 2);
  unsigned short* wvb = (unsigned short*)alloc((size_t)262144 * 2);
  unsigned short* wob = (unsigned short*)alloc((size_t)262144 * 2);
  float* bqk = (float*)alloc(1024 * sizeof(float));
  float* rowsums = (float*)alloc((size_t)8 * 18 * 2304 * sizeof(float));
  unsigned short* hnT = (unsigned short*)alloc((size_t)18432 * 512 * 2);
  unsigned char* qkA = (unsigned char*)alloc((size_t)18432 * 1024);      // fp8 k-interleaved
  unsigned char* vT = (unsigned char*)alloc((size_t)512 * 18432);        // fp8 k-interleaved
  unsigned char* Sm = (unsigned char*)alloc((size_t)8 * 2304 * 2304);    // fp8 E k-interleaved
  unsigned short* Ob = hnT;  // alias: hnT fully consumed after qk/v GEMMs
  (void)ws_size; (void)in_sizes; (void)n_in; (void)out_size;

  // R26: stats 1024 blocks (4/CU streaming TLP); gn vectorized f4/us4.
  stats_partial_k<<<dim3(1024), dim3(256), 0, stream>>>(x, part);
  gn_transpose_k<<<dim3(8, 288), dim3(256), 0, stream>>>(x, part, gamma, beta, hnT);
  pack4_bf16_k<<<dim3(256, 5), dim3(256), 0, stream>>>(wq, wk, wv, wo,
                                                       wqkb, wqkb + 262144, wvb, wob,
                                                       bq, bk, bqk);

  // Fused qk+v (MODE3) on WL=2 bf16 (512 thr, 8 waves, 4 waves/SIMD).
  // Blocks [0,1152): qk -- A=[Wq;Wk] bf16, B=hnT -> qkA fp8 [sp][1024].
  // Blocks [1152,1728): v -- A=hnT, B=wvb -> vT fp8 [co][18432].
  gemm256<128, 1, 2, 0, 0, 3, 0, 1, 2><<<dim3(1728), dim3(512), 0, stream>>>(
      wqkb, 512, 0, hnT, 512, 0, (void*)qkA, 1024, 0, bqk,
      (const float*)wvb, (float*)vT, bv, 1.0f, 512, 1152, 0);
  // S: per t: A=k fp8, B=q fp8 -> E=exp(alpha*S) fp8 interleaved + rowsums.
  // WL=2 fp8 (512 thr, 8 waves, 4 blocks/CU): 2592 blocks MODE0.
  gemm256<128, 0, 2, 1, 0, 0, 1, 1, 2><<<dim3(2592), dim3(512), 0, stream>>>(
      qkA + 512, 1024, (long)2304 * 1024, qkA, 1024, (long)2304 * 1024, (void*)Sm, 2304,
      (long)2304 * 2304, nullptr, nullptr, rowsums, nullptr,
      0.044194173824159216f, 512, 18, 18);
  // PV: per t: A=vT fp8, B=E fp8 -> O bf16 [(t,i)*512+c], rows scaled by 1/L.
  // WL=2 fp8, SCALEN=2 (combine folded). 576 blocks MODE0.
  gemm256<128, 0, 0, 0, 2, 0, 1, 1, 2><<<dim3(576), dim3(512), 0, stream>>>(
      vT, 18432, 2304, Sm, 2304, (long)2304 * 2304, (void*)Ob, 512, (long)2304 * 512,
      nullptr, nullptr, rowsums, nullptr, 1.0f, 2304, 4, 18);
  // final: A=O bf16, B=Wo bf16 -> out[co*18432+sp] = x + acc + bo[co].
  // WL=2 bf16, MODE2: 8 x 18 x 4 = 576 blocks.
  gemm256<128, 2, 1, 0, 0, 2, 0, 1, 2><<<dim3(576), dim3(512), 0, stream>>>(
      Ob, 512, 0, wob, 512, 0, (void*)out, 18432, 0, bo, x, nullptr, nullptr,
      1.0f, 512, 18, 4);
}

// Round 18
// 200.553 us; speedup vs baseline: 1.3303x; 1.0059x over previous
//
#include <hip/hip_runtime.h>
#include <hip/hip_bf16.h>
#include <cstdint>
#include <type_traits>

typedef __attribute__((ext_vector_type(8))) __bf16 bf16x8;
typedef __attribute__((ext_vector_type(4))) float f32x4;
typedef __attribute__((ext_vector_type(2))) long longx2;

struct bf2frag { bf16x8 k0, k1; };

__device__ __forceinline__ float bf2f(unsigned short u) {
  union { uint32_t i; float f; } v; v.i = (uint32_t)u << 16; return v.f;
}
__device__ __forceinline__ unsigned short f2bf(float f) {
  union { float f; uint32_t i; } v{f};
  uint32_t r = v.i + 0x7fffu + ((v.i >> 16) & 1u);
  return (unsigned short)(r >> 16);
}

__device__ __forceinline__ void gll(const void* g, void* l) {
  __builtin_amdgcn_global_load_lds(
      (const __attribute__((address_space(1))) uint32_t*)(uintptr_t)g,
      (__attribute__((address_space(3))) uint32_t*)(uint32_t)(uintptr_t)l,
      16, 0, 0);
}

__device__ __forceinline__ void bar() {
  asm volatile("" ::: "memory");
  __builtin_amdgcn_s_barrier();
  asm volatile("" ::: "memory");
}

#define VMCNT(n) asm volatile("s_waitcnt vmcnt(" #n ")" ::: "memory")

template <int N>
__device__ __forceinline__ void vmw() {
  if constexpr (N == 0) { VMCNT(0); }
  else if constexpr (N == 1) { VMCNT(1); }
  else if constexpr (N == 2) { VMCNT(2); }
  else if constexpr (N == 3) { VMCNT(3); }
  else if constexpr (N == 4) { VMCNT(4); }
  else if constexpr (N == 5) { VMCNT(5); }
  else if constexpr (N == 6) { VMCNT(6); }
  else if constexpr (N == 7) { VMCNT(7); }
  else if constexpr (N == 8) { VMCNT(8); }
  else if constexpr (N == 9) { VMCNT(9); }
  else if constexpr (N == 10) { VMCNT(10); }
  else { VMCNT(12); }
}

__device__ __forceinline__ f32x4 mma(bf16x8 a, bf16x8 b, f32x4 c) {
  return __builtin_amdgcn_mfma_f32_16x16x32_bf16(a, b, c, 0, 0, 0);
}
__device__ __forceinline__ f32x4 mma(long a, long b, f32x4 c) {
  return __builtin_amdgcn_mfma_f32_16x16x32_fp8_fp8(a, b, c, 0, 0, 0);
}
__device__ __forceinline__ f32x4 mmak(const bf2frag& a, const bf2frag& b, f32x4 c, int k2) {
  return k2 ? mma(a.k1, b.k1, c) : mma(a.k0, b.k0, c);
}
__device__ __forceinline__ f32x4 mmak(longx2 a, longx2 b, f32x4 c, int k2) {
  return mma(a[k2], b[k2], c);
}

// k-interleave store permutation for fp8 buffers (unit u=8B: slot p(u)=(u&3)*2+(u>>2))
__device__ __forceinline__ int perm64(int m) {
  return (m & ~63) | (((m >> 3) & 3) << 4) | (((m >> 5) & 1) << 3) | (m & 7);
}

// ---------------- Fused prelude: GroupNorm stats + weight pack + bias (R27) ----------------
// stats_partial (1024 blocks) and pack4+bias (1025 blocks) are mutually
// independent and both precede gn/qv -- one dispatch, block-id split (each
// block takes a uniform branch; no divergent syncthreads). 7 launches -> 6.
__global__ __launch_bounds__(256) void prelude_k(const float* __restrict__ x,
                                                 float* __restrict__ part,
                                                 const float* __restrict__ w0,
                                                 const float* __restrict__ w1,
                                                 const float* __restrict__ w2,
                                                 const float* __restrict__ w3,
                                                 unsigned short* __restrict__ o0,
                                                 unsigned short* __restrict__ o1,
                                                 unsigned short* __restrict__ o2,
                                                 unsigned short* __restrict__ o3,
                                                 const float* __restrict__ bq,
                                                 const float* __restrict__ bk,
                                                 float* __restrict__ bqk) {
  const int bid = blockIdx.x;
  if (bid < 1024) {
    // GroupNorm stats: 32 spatial parts/group, 4 blocks/CU streaming TLP (R26).
    const int g = bid >> 5, p = bid & 31;
    const float* base = x + (long)g * 16 * 18432 + (long)p * 576;
    float s = 0.f, ss = 0.f;
    for (int idx = threadIdx.x; idx < 16 * 144; idx += 256) {
      const int c = idx / 144, i4 = idx % 144;
      const float4 v = *(const float4*)(base + (long)c * 18432 + i4 * 4);
      s += v.x + v.y + v.z + v.w;
      ss += v.x * v.x + v.y * v.y + v.z * v.z + v.w * v.w;
    }
    __shared__ float rs[256], rss[256];
    rs[threadIdx.x] = s; rss[threadIdx.x] = ss;
    __syncthreads();
    for (int o = 128; o > 0; o >>= 1) {
      if ((int)threadIdx.x < o) { rs[threadIdx.x] += rs[threadIdx.x + o]; rss[threadIdx.x] += rss[threadIdx.x + o]; }
      __syncthreads();
    }
    if (threadIdx.x == 0) { part[bid * 2] = rs[0]; part[bid * 2 + 1] = rss[0]; }
  } else if (bid < 2048) {
    // fp32 -> bf16 weight pack (4 x 256 block-slices).
    const int i = bid - 1024;
    const int y = i >> 8, xb = i & 255;
    const float* w = (y == 0) ? w0 : (y == 1) ? w1 : (y == 2) ? w2 : w3;
    unsigned short* o = (y == 0) ? o0 : (y == 1) ? o1 : (y == 2) ? o2 : o3;
    const int idx = (xb * 256 + threadIdx.x) * 4;
    const float4 v = *(const float4*)(w + idx);
    ushort4 u; u.x = f2bf(v.x); u.y = f2bf(v.y); u.z = f2bf(v.z); u.w = f2bf(v.w);
    *(ushort4*)(o + idx) = u;
  } else {
    // qk-bias concat.
    const int i = threadIdx.x * 4;
#pragma unroll
    for (int j = 0; j < 4; ++j) {
      const int t = i + j;
      bqk[t] = (t < 512) ? bq[t] : bk[t - 512];
    }
  }
}

// ---------------- GN apply + transpose to (spatial, channel) bf16 ----------------
// R21: stats_final folded in. R26: float4 loads + ushort4 transposed stores.
__global__ __launch_bounds__(256) void gn_transpose_k(const float* __restrict__ x,
                                                      const float* __restrict__ part,
                                                      const float* __restrict__ gamma,
                                                      const float* __restrict__ beta,
                                                      unsigned short* __restrict__ hnT) {
  __shared__ float tile[64][65];
  __shared__ float sm[4], sr[4];
  const int c0 = blockIdx.x * 64, n0 = blockIdx.y * 64;
  const int tid = threadIdx.x;
  if (tid < 4) {
    const int g = (c0 >> 4) + tid;
    float s = 0.f, ss = 0.f;
    for (int p = 0; p < 32; ++p) { s += part[(g * 32 + p) * 2]; ss += part[(g * 32 + p) * 2 + 1]; }
    const float mean = s / 294912.0f;
    const float var = ss / 294912.0f - mean * mean;
    sm[tid] = mean;
    sr[tid] = rsqrtf(var + 1e-6f);
  }
  __syncthreads();
  const int rl = tid >> 4, cl4 = (tid & 15) * 4;
#pragma unroll
  for (int pass = 0; pass < 4; ++pass) {
    const int cc = rl + pass * 16;
    const int c = c0 + cc;
    const float mean = sm[cc >> 4], rstd = sr[cc >> 4];
    const float ga = gamma[c], be = beta[c];
    const float4 v = *(const float4*)(x + (long)c * 18432 + n0 + cl4);
    tile[cc][cl4 + 0] = (v.x - mean) * rstd * ga + be;
    tile[cc][cl4 + 1] = (v.y - mean) * rstd * ga + be;
    tile[cc][cl4 + 2] = (v.z - mean) * rstd * ga + be;
    tile[cc][cl4 + 3] = (v.w - mean) * rstd * ga + be;
  }
  __syncthreads();
#pragma unroll
  for (int pass = 0; pass < 4; ++pass) {
    const int nn = rl + pass * 16;
    ushort4 u;
    u.x = f2bf(tile[cl4 + 0][nn]);
    u.y = f2bf(tile[cl4 + 1][nn]);
    u.z = f2bf(tile[cl4 + 2][nn]);
    u.w = f2bf(tile[cl4 + 3][nn]);
    *(ushort4*)(hnT + (long)(n0 + nn) * 512 + c0 + cl4) = u;
  }
}

// ================= BMxBNxBK NT GEMM, XCD-swizzled, bf16/fp8 =================
// C[n*ldc+m] = alpha*sum_k A[m,k]*B[n,k] (+bias)(+resid)
// WL=0, BM=256: 512 thr, 8 waves (2m x 4n), 1 block/CU, P2=0, setprio ON.
// WL=1: BM=128 x BN=128, 256 thr, 4 waves (2m x 2n, 64x64/wave).
//   fp8 KU=1: 32KB LDS, bounds(256,4). bf16: 64KB, 2 blocks/CU.
// WL=2: BM=128 x BN=128, 512 thr, 8 waves (2m x 4n, 64x32/wave).
//   bf16 (R23 qv, R24 final): 64KB LDS, 2 blocks/CU, 4 waves/SIMD.
//   fp8 (R24 S; R25 PV): 32KB LDS, bounds(512,8), FULL-TILE stages (8192B =
//   1 gll/thread; LDS dest linear, As[slot][0..1] contiguous).
//   WL2-fp8 schedule: prologue [Afull(0),Bfull(0),Bfull(1)], vmcnt(1);
//   P0: read A0+ownB, stage Afull(W+1)->s^1, mfma m0; P1: read A1, stage
//   Bfull(W+2)->s, mfma m1, vmcnt(st2?1:0). Verified on S (R24, VGPR 32).
//   R24/R25 verdict: TLP exonerated (Occupancy 62%, MfmaUtil flat 29);
//   the fp8 GEMM ~5000cy/K-step wall is structural after 9+ probes. STOP.
//   Ladder: R13 S TLP, R14 qk, R15 PV, R17 v+final, R21/22 folds, R23 qv WL2,
//   R26 prelude vectorization, R27 prelude launch fusion.
//   A/B halves use 32-row stripe interleave: grow = (r>>5)*64 + h*32 + (r&31).
// P2=1 (2-phase, WL<2 or bf16): P0: read A0,B; stage [A0,B1,A1](W+1) -> s^1;
//   mfma m0. P1: read A1; stage B0(W+2) -> s; mfma m1.
//   Waits: @P0-end vmcnt(2(GA+GB)); @P1-end vmcnt(GA+GB); tail GA then 0.
// STATS: exp+rowsums, scratch stride NSLOT+1 (R18).
// SCALEN: 1 = *linv[n]; 2 = combine folded into prologue (R21).
// OUT_MODE: 0 bf16, 1 f32+resid, 2 fp8 e4m3 k-interleaved.
// MODE0: bz=bid%8 per XCD; MODE1/2: XCD y/x-chunking.
// MODE3 (R22): fused qk+v single dispatch; blocks < gx run qk (MODE1 8x18),
//   rest run v (MODE2 18x4) with params via resid/rowsums/linv.
template <int BM, int BIAS_MODE, int OUT_MODE, int STATS, int SCALEN, int MODE, int FP8, int P2,
          int WL = 0, int KU = 1>
__global__ __launch_bounds__((BM == 256 || WL == 2) ? 512 : 256,
                             (WL == 1 && FP8) ? (KU == 2 ? 2 : 4) : ((WL == 2 && FP8) ? 8 : 2))
void gemm256(const void* __restrict__ A, long lda, long sAz,
             const void* __restrict__ B, long ldb, long sBz,
             void* __restrict__ Cp, long ldc, long sCz,
             const float* __restrict__ bias,
             const float* __restrict__ resid,
             float* __restrict__ rowsums,
             const float* __restrict__ linv,
             float alpha, int K, int gx, int gy) {
  static_assert(KU == 1 || FP8, "KU=2 only on fp8 path");
  constexpr int EB = FP8 ? 1 : 2;                    // element bytes
  constexpr int THREADS = (BM == 256 || WL == 2) ? 512 : 256;
  constexpr int BN = WL ? 128 : 256;                 // n-tile
  constexpr int BK = 64 * KU;                        // k-step
  constexpr int HBA = (BM / 2) * BK * EB;            // bytes per A half
  constexpr int HBB = (BN / 2) * BK * EB;            // bytes per B half
  constexpr int HBA0 = HBA / KU, HBB0 = HBB / KU;    // per 64-k sub-block
  constexpr bool FT = (WL == 2 && FP8);              // full-tile staging path
  constexpr int GA = FT ? 1 : HBA / (THREADS * 16);  // gll per A stage unit
  constexpr int GB = FT ? 1 : HBB / (THREADS * 16);  // gll per B stage unit
  constexpr int GA0 = FT ? 1 : GA / KU, GB0 = FT ? 1 : GB / KU;
  constexpr int V0 = GB + 2 * GA, V3 = 2 * GB + GA, VP = GB + GA;
  constexpr int NSLOT = WL ? 8 : ((BM == 256) ? 8 : 4);
  constexpr int NSLOTP = NSLOT + 1;                  // R18: odd stride
  constexpr int MR = WL ? 4 : 8;                     // acc M-frags per wave
  constexpr int NR = (WL == 2) ? 2 : 4;              // acc N-frags per wave
  constexpr int FQ = WL ? 2 : 4;                     // A-frags per (mh) phase
  constexpr int PRIO = !P2;                          // setprio only on 1-block path
  __shared__ alignas(16) unsigned char As[2][2][HBA];
  __shared__ alignas(16) unsigned char Bs[2][2][HBB];
  __shared__ float linvs[SCALEN == 2 ? BN : 1];
  using ABt2 = typename std::conditional<FP8, longx2, bf2frag>::type;

  const int tid = threadIdx.x;
  const int lane = tid & 63, wid = tid >> 6;
  const int wm = (WL == 2) ? (wid >> 2) : (WL ? (wid >> 1) : ((BM == 256) ? (wid & 1) : 0));
  const int wn = (WL == 2) ? (wid & 3) : (WL ? (wid & 1) : ((BM == 256) ? (wid >> 1) : wid));
  int bx, by, bz;
  const void* Asel = A;
  const void* Bsel = B;
  void* Csel = Cp;
  const float* biasSel = bias;
  long ldcSel = ldc;
  bool bias_m = (BIAS_MODE == 1);
  {
    const int g8 = blockIdx.x & 7, n = blockIdx.x >> 3;
    if (MODE == 0) { bz = g8; bx = n % gx; by = n / gx; }
    else if (MODE == 1) { bz = 0; bx = n % gx; by = g8 * gy + n / gx; }
    else if (MODE == 2) { bz = 0; by = n % gy; bx = g8 * gx + n / gy; }
    else {  // MODE 3: fused qk+v; gx = number of qk blocks
      bz = 0;
      if ((int)blockIdx.x < gx) {
        bx = n % 8; by = g8 * 18 + n / 8;          // qk: MODE1 gx=8, gy=18
      } else {
        const int b2 = (int)blockIdx.x - gx;
        const int g82 = b2 & 7, n2 = b2 >> 3;
        by = n2 % 4; bx = g82 * 18 + n2 / 4;       // v: MODE2 gx=18, gy=4
        Asel = B;                                   // hnT
        Bsel = (const void*)resid;                  // wvb
        Csel = (void*)rowsums;                      // vT
        biasSel = linv;                             // bv
        ldcSel = 18432;
        bias_m = false;
      }
    }
  }
  const unsigned char* Ab = (const unsigned char*)Asel + ((long)bz * sAz + (long)bx * BM * lda) * EB;
  const unsigned char* Bb = (const unsigned char*)Bsel + ((long)bz * sBz + (long)by * BN * ldb) * EB;

  // R21 (SCALEN==2): fold combine -- compute 1/L for this block's rows first,
  // so the scalar loads retire before any gll enters the vmcnt FIFO.
  if constexpr (SCALEN == 2) {
    if (tid < BN) {
      const int ntile = K / BN;
      float L = 0.f;
      for (int xx = 0; xx < ntile; ++xx)
        L += rowsums[((long)(bz * ntile + xx)) * K + by * BN + tid];
      linvs[tid] = 1.0f / L;
    }
  }

  // ---- staging (global -> LDS, pre-swizzled source; fp8 global is k-interleaved) ----
  auto stageA = [&](int slot, int h, int k0) {
    if constexpr (!FP8) {
      const int ksw = ((tid & 7) << 3) ^ (((tid >> 3) & 7) << 3);
#pragma unroll
      for (int call = 0; call < GA; ++call) {
        const int r = call * (THREADS / 8) + (tid >> 3);
        const int grow = WL ? (((r >> 5) << 6) + h * 32 + (r & 31))
                            : (((r >> 6) << 7) + h * 64 + (r & 63));
        gll(Ab + ((long)grow * lda + k0) * 2 + ksw * 2, &As[slot][h][call * THREADS * 16 + tid * 16]);
      }
    } else {
#pragma unroll
      for (int call = 0; call < GA; ++call) {
        const int sub = call / GA0, c0 = call % GA0;
        const int l = c0 * (THREADS / 4) + (tid >> 2);
        const int grow = WL ? (((l >> 5) << 6) + h * 32 + (l & 31))
                            : (((l >> 6) << 7) + h * 64 + (l & 63));
        const int x = (((l & 3) ^ ((l >> 2) & 3)) << 4);
        gll(Ab + (long)grow * lda + k0 + sub * 64 + (((tid & 3) << 4) ^ x),
            &As[slot][h][call * THREADS * 16 + tid * 16]);
      }
    }
  };
  auto stageB = [&](int slot, int h, int k0) {
    if constexpr (!FP8) {
      const int ksw = ((tid & 7) << 3) ^ (((tid >> 3) & 7) << 3);
#pragma unroll
      for (int call = 0; call < GB; ++call) {
        const int r = call * (THREADS / 8) + (tid >> 3);
        const int grow = ((r >> 5) << 6) + h * 32 + (r & 31);
        gll(Bb + ((long)grow * ldb + k0) * 2 + ksw * 2, &Bs[slot][h][call * THREADS * 16 + tid * 16]);
      }
    } else {
#pragma unroll
      for (int call = 0; call < GB; ++call) {
        const int sub = call / GB0, c0 = call % GB0;
        const int l = c0 * (THREADS / 4) + (tid >> 2);
        const int grow = ((l >> 5) << 6) + h * 32 + (l & 31);
        const int x = (((l & 3) ^ ((l >> 2) & 3)) << 4);
        gll(Bb + (long)grow * ldb + k0 + sub * 64 + (((tid & 3) << 4) ^ x),
            &Bs[slot][h][call * THREADS * 16 + tid * 16]);
      }
    }
  };
  // WL2-fp8 full-tile stages: 1 gll/thread covers both halves (8192B).
  auto stageAF = [&](int slot, int k0) {
    const int hh = tid >> 8, tl = tid & 255;
    const int l = tl >> 2;
    const int grow = ((l >> 5) << 6) + hh * 32 + (l & 31);
    const int x = (((l & 3) ^ ((l >> 2) & 3)) << 4);
    gll(Ab + (long)grow * lda + k0 + (((tid & 3) << 4) ^ x),
        &As[slot][0][0] + tid * 16);
  };
  auto stageBF = [&](int slot, int k0) {
    const int hh = tid >> 8, tl = tid & 255;
    const int l = tl >> 2;
    const int grow = ((l >> 5) << 6) + hh * 32 + (l & 31);
    const int x = (((l & 3) ^ ((l >> 2) & 3)) << 4);
    gll(Bb + (long)grow * ldb + k0 + (((tid & 3) << 4) ^ x),
        &Bs[slot][0][0] + tid * 16);
  };
  // ---- LDS -> fragment reads (same swizzle; fp8 = ONE b128 for both k2 slices) ----
  auto ldA = [&](int slot, int mh, int fq, int sub) -> ABt2 {
    const int r = (WL ? wm * 32 : wm * 64) + fq * 16 + (lane & 15);
    if constexpr (!FP8) {
      bf2frag f;
      const int kk0 = (((lane >> 4) << 3)) ^ ((r & 7) << 3);
      const int kk1 = (32 + ((lane >> 4) << 3)) ^ ((r & 7) << 3);
      f.k0 = *reinterpret_cast<const bf16x8*>(&As[slot][mh][r * 128 + kk0 * 2]);
      f.k1 = *reinterpret_cast<const bf16x8*>(&As[slot][mh][r * 128 + kk1 * 2]);
      return f;
    } else {
      const int x = (((r & 3) ^ ((r >> 2) & 3)) << 4);
      const int kk = ((lane >> 4) << 4) ^ x;
      return *reinterpret_cast<const longx2*>(&As[slot][mh][sub * HBA0 + r * 64 + kk]);
    }
  };
  auto ldB = [&](int slot, int nh, int g, int sub) -> ABt2 {
    // WL=2: wave owns 32 global n-rows = stripe chunk wn>>1, half wn&1.
    const int half = (WL == 2) ? (wn & 1) : nh;
    const int r = ((WL == 2) ? (wn >> 1) : wn) * 32 + g * 16 + (lane & 15);
    if constexpr (!FP8) {
      bf2frag f;
      const int kk0 = (((lane >> 4) << 3)) ^ ((r & 7) << 3);
      const int kk1 = (32 + ((lane >> 4) << 3)) ^ ((r & 7) << 3);
      f.k0 = *reinterpret_cast<const bf16x8*>(&Bs[slot][half][r * 128 + kk0 * 2]);
      f.k1 = *reinterpret_cast<const bf16x8*>(&Bs[slot][half][r * 128 + kk1 * 2]);
      return f;
    } else {
      const int x = (((r & 3) ^ ((r >> 2) & 3)) << 4);
      const int kk = ((lane >> 4) << 4) ^ x;
      return *reinterpret_cast<const longx2*>(&Bs[slot][half][sub * HBB0 + r * 64 + kk]);
    }
  };

  f32x4 acc[MR][NR] = {};
  ABt2 a[FQ * KU], b0[2 * KU], b1[2 * KU];

#define READ_A(SLOT, MH)                                                       \
  _Pragma("unroll") for (int fq = 0; fq < FQ; ++fq)                            \
    _Pragma("unroll") for (int sub = 0; sub < KU; ++sub)                       \
      a[fq * KU + sub] = ldA(SLOT, MH, fq, sub);
#define READ_B(SLOT, NH, DST)                                                  \
  _Pragma("unroll") for (int g = 0; g < 2; ++g)                                \
    _Pragma("unroll") for (int sub = 0; sub < KU; ++sub)                       \
      DST[g * KU + sub] = ldB(SLOT, NH, g, sub);
#define MFMA_QUAD(MH, NH, BARR)                                                \
  if constexpr (PRIO) __builtin_amdgcn_s_setprio(1);                           \
  _Pragma("unroll") for (int fq = 0; fq < FQ; ++fq)                            \
    _Pragma("unroll") for (int g = 0; g < 2; ++g)                              \
      _Pragma("unroll") for (int sub = 0; sub < KU; ++sub)                     \
        _Pragma("unroll") for (int k2 = 0; k2 < 2; ++k2)                       \
          acc[(MH) * FQ + fq][(NH) * 2 + g] =                                  \
              mmak(a[fq * KU + sub], BARR[g * KU + sub],                       \
                   acc[(MH) * FQ + fq][(NH) * 2 + g], k2);                     \
  if constexpr (PRIO) __builtin_amdgcn_s_setprio(0);

  const int KT = K / BK;
  if constexpr (FT) {
    // ---- WL2-fp8: full-tile staging schedule ----
    stageAF(0, 0);
    stageBF(0, 0);
    stageBF(1, BK);
    vmw<1>();
    bar();
    for (int W = 0; W < KT; ++W) {
      const int s = W & 1;
      const int kn1 = (W + 1) * BK, kn2 = (W + 2) * BK;
      const bool st1 = (W + 1 < KT), st2 = (W + 2 < KT);
      // P0: read A0 + own B; stage A-full(W+1) -> s^1.
      READ_A(s, 0)
      READ_B(s, 0, b0)
      if (st1) stageAF(s ^ 1, kn1);
      bar();
      MFMA_QUAD(0, 0, b0)
      bar();
      // P1: read A1; stage B-full(W+2) -> s (all B reads of s done in P0).
      READ_A(s, 1)
      if (st2) stageBF(s, kn2);
      bar();
      MFMA_QUAD(1, 0, b0)
      if (st2) { vmw<1>(); } else { vmw<0>(); }
      bar();
    }
  } else {
    // Prologue queue: [B0(0), A0(0), B1(0), A1(0), B0(1)] (+A1(1) for P2=0)
    stageB(0, 0, 0);
    stageA(0, 0, 0);
    stageB(0, 1, 0);
    stageA(0, 1, 0);
    stageB(1, 0, BK);
    if constexpr (!P2) stageA(1, 1, BK);
    vmw<VP>();
    bar();

    if constexpr (!P2) {
      for (int W = 0; W < KT; ++W) {
        const int s = W & 1;
        const int kn1 = (W + 1) * BK, kn2 = (W + 2) * BK;
        const bool st1 = (W + 1 < KT), st2 = (W + 2 < KT);
        // p0: (m0,n0)
        READ_A(s, 0)
        READ_B(s, 0, b0)
        if (st1) stageA(s ^ 1, 0, kn1);
        bar();
        MFMA_QUAD(0, 0, b0)
        if (st1) { vmw<V0>(); }
        bar();
        // p1: (m0,n1)
        READ_B(s, 1, b1)
        if (st1) stageB(s ^ 1, 1, kn1);
        bar();
        MFMA_QUAD(0, 1, b1)
        bar();
        // p2: (m1,n1)
        READ_A(s, 1)
        if (st2) stageB(s, 0, kn2);
        bar();
        MFMA_QUAD(1, 1, b1)
        bar();
        // p3: (m1,n0)
        if (st2) stageA(s, 1, kn2);
        bar();
        MFMA_QUAD(1, 0, b0)
        if (st2) { vmw<V3>(); } else { vmw<0>(); }
        bar();
      }
    } else {
      for (int W = 0; W < KT; ++W) {
        const int s = W & 1;
        const int kn1 = (W + 1) * BK, kn2 = (W + 2) * BK;
        const bool st1 = (W + 1 < KT), st2 = (W + 2 < KT);
        // P0: m0 x (WL=2: own B-half | else: n0,n1); stage trio (A1 LAST).
        READ_A(s, 0)
        READ_B(s, 0, b0)
        if constexpr (WL != 2) { READ_B(s, 1, b1) }
        if (st1) { stageA(s ^ 1, 0, kn1); stageB(s ^ 1, 1, kn1); stageA(s ^ 1, 1, kn1); }
        bar();
        MFMA_QUAD(0, 0, b0)
        if constexpr (WL != 2) { MFMA_QUAD(0, 1, b1) }
        if (st1) { vmw<2 * (GA + GB)>(); } else { vmw<0>(); }
        bar();
        // P1: m1; stage B0(W+2) into current slot (B0(W) consumed in P0).
        READ_A(s, 1)
        if (st2) stageB(s, 0, kn2);
        bar();
        if constexpr (WL != 2) { MFMA_QUAD(1, 1, b1) }
        MFMA_QUAD(1, 0, b0)
        if (st2) { vmw<GA + GB>(); } else if (st1) { vmw<GA>(); } else { vmw<0>(); }
        bar();
      }
    }
  }

  // epilogue: acc[M][N].
  // WL=0: M = mh*4+fq, m-off = (M>>2)*64 + (M&3)*16, wave m-base wm*128.
  // WL>=1: M = mh*2+fq, m-off = (M>>1)*32 + (M&1)*16, wave m-base wm*64.
  // WL=2: N in {0,1}, n = by*128 + wn*32 + N*16 + (lane&15).
  const int mg0 = bx * BM + (WL ? wm * 64 : wm * 128) + ((lane >> 4) << 2);
  const int ng0 = by * BN + ((WL == 2) ? wn * 32 : wn * 64) + (lane & 15);
  float* red = (float*)&As[0][0][0];  // STATS scratch: BN rows x NSLOTP f32
#pragma unroll
  for (int N = 0; N < NR; ++N) {
    const int n = ng0 + ((WL == 2) ? N * 16 : ((N >> 1) * 32 + (N & 1) * 16));
    float bn;
    if constexpr (MODE == 3) bn = bias_m ? 0.f : biasSel[n];
    else bn = (BIAS_MODE == 2) ? bias[n] : 0.f;
    const float sc = (SCALEN == 1) ? linv[(long)bz * 2304 + n]
                   : (SCALEN == 2) ? linvs[n - by * BN] : 1.0f;
    float eN = 0.f;
#pragma unroll
    for (int M = 0; M < MR; ++M) {
      const int m = mg0 + (WL ? ((M >> 1) * 32 + (M & 1) * 16) : ((M >> 2) * 64 + (M & 3) * 16));
      const f32x4 av = acc[M][N];
      float vals[4];
#pragma unroll
      for (int j = 0; j < 4; ++j) {
        float addv;
        if constexpr (MODE == 3) addv = bias_m ? biasSel[m + j] : bn;
        else if constexpr (BIAS_MODE == 1) addv = bias[m + j];
        else addv = bn;
        vals[j] = av[j] * alpha + addv;
        if (SCALEN) vals[j] *= sc;
        if (STATS) { vals[j] = __expf(vals[j]); eN += vals[j]; }
      }
      if (OUT_MODE == 0) {
        ushort4 o; o.x = f2bf(vals[0]); o.y = f2bf(vals[1]); o.z = f2bf(vals[2]); o.w = f2bf(vals[3]);
        *(ushort4*)((unsigned short*)Csel + (long)bz * sCz + (long)n * ldcSel + m) = o;
      } else if (OUT_MODE == 2) {
        int pk = __builtin_amdgcn_cvt_pk_fp8_f32(vals[0], vals[1], 0, false);
        pk = __builtin_amdgcn_cvt_pk_fp8_f32(vals[2], vals[3], pk, true);
        *(int*)((unsigned char*)Csel + (long)bz * sCz + (long)n * ldcSel + perm64(m)) = pk;
      } else {
        const float* rp = resid + (long)n * ldcSel + m;
        float4 o; o.x = vals[0] + rp[0]; o.y = vals[1] + rp[1]; o.z = vals[2] + rp[2]; o.w = vals[3] + rp[3];
        *(float4*)((float*)Csel + (long)bz * sCz + (long)n * ldcSel + m) = o;
      }
    }
    if (STATS) {
      const int nloc = n - by * BN;
      const int slot = wm * 4 + (lane >> 4);
      red[nloc * NSLOTP + slot] = eN;
    }
  }
  if (STATS) {
    bar();
    if (tid < BN) {
      float L = 0.f;
#pragma unroll
      for (int s2 = 0; s2 < NSLOT; ++s2) L += red[tid * NSLOTP + s2];
      rowsums[((long)(bz * gx + bx)) * 2304 + by * BN + tid] = L;
    }
  }
#undef READ_A
#undef READ_B
#undef MFMA_QUAD
}

extern "C" void kernel_launch(void* const* d_in, const int* in_sizes, int n_in,
                              void* d_out, int out_size, void* d_ws, size_t ws_size,
                              hipStream_t stream) {
  const float* x = (const float*)d_in[0];
  const float* gamma = (const float*)d_in[1];
  const float* beta = (const float*)d_in[2];
  const float* wq = (const float*)d_in[3];
  const float* bq = (const float*)d_in[4];
  const float* wk = (const float*)d_in[5];
  const float* bk = (const float*)d_in[6];
  const float* wv = (const float*)d_in[7];
  const float* bv = (const float*)d_in[8];
  const float* wo = (const float*)d_in[9];
  const float* bo = (const float*)d_in[10];
  float* out = (float*)d_out;

  char* ws = (char*)d_ws;
  size_t off = 0;
  auto alloc = [&](size_t bytes) {
    char* p = ws + off;
    off = (off + bytes + 255) & ~(size_t)255;
    return p;
  };
  float* part = (float*)alloc(1024 * 2 * sizeof(float));
  unsigned short* wqkb = (unsigned short*)alloc((size_t)2 * 262144 * 2);
  unsigned short* wvb = (unsigned short*)alloc((size_t)262144 * 2);
  unsigned short* wob = (unsigned short*)alloc((size_t)262144 * 2);
  float* bqk = (float*)alloc(1024 * sizeof(float));
  float* rowsums = (float*)alloc((size_t)8 * 18 * 2304 * sizeof(float));
  unsigned short* hnT = (unsigned short*)alloc((size_t)18432 * 512 * 2);
  unsigned char* qkA = (unsigned char*)alloc((size_t)18432 * 1024);      // fp8 k-interleaved
  unsigned char* vT = (unsigned char*)alloc((size_t)512 * 18432);        // fp8 k-interleaved
  unsigned char* Sm = (unsigned char*)alloc((size_t)8 * 2304 * 2304);    // fp8 E k-interleaved
  unsigned short* Ob = hnT;  // alias: hnT fully consumed after qk/v GEMMs
  (void)ws_size; (void)in_sizes; (void)n_in; (void)out_size;

  // R27: fused prelude (stats 1024 + pack 1024 + bias 1) -- one dispatch.
  prelude_k<<<dim3(2049), dim3(256), 0, stream>>>(x, part, wq, wk, wv, wo,
                                                  wqkb, wqkb + 262144, wvb, wob,
                                                  bq, bk, bqk);
  gn_transpose_k<<<dim3(8, 288), dim3(256), 0, stream>>>(x, part, gamma, beta, hnT);

  // Fused qk+v (MODE3) on WL=2 bf16 (512 thr, 8 waves, 4 waves/SIMD).
  // Blocks [0,1152): qk -- A=[Wq;Wk] bf16, B=hnT -> qkA fp8 [sp][1024].
  // Blocks [1152,1728): v -- A=hnT, B=wvb -> vT fp8 [co][18432].
  gemm256<128, 1, 2, 0, 0, 3, 0, 1, 2><<<dim3(1728), dim3(512), 0, stream>>>(
      wqkb, 512, 0, hnT, 512, 0, (void*)qkA, 1024, 0, bqk,
      (const float*)wvb, (float*)vT, bv, 1.0f, 512, 1152, 0);
  // S: per t: A=k fp8, B=q fp8 -> E=exp(alpha*S) fp8 interleaved + rowsums.
  // WL=2 fp8 (512 thr, 8 waves, 4 blocks/CU): 2592 blocks MODE0.
  gemm256<128, 0, 2, 1, 0, 0, 1, 1, 2><<<dim3(2592), dim3(512), 0, stream>>>(
      qkA + 512, 1024, (long)2304 * 1024, qkA, 1024, (long)2304 * 1024, (void*)Sm, 2304,
      (long)2304 * 2304, nullptr, nullptr, rowsums, nullptr,
      0.044194173824159216f, 512, 18, 18);
  // PV: per t: A=vT fp8, B=E fp8 -> O bf16 [(t,i)*512+c], rows scaled by 1/L.
  // WL=2 fp8, SCALEN=2 (combine folded). 576 blocks MODE0.
  gemm256<128, 0, 0, 0, 2, 0, 1, 1, 2><<<dim3(576), dim3(512), 0, stream>>>(
      vT, 18432, 2304, Sm, 2304, (long)2304 * 2304, (void*)Ob, 512, (long)2304 * 512,
      nullptr, nullptr, rowsums, nullptr, 1.0f, 2304, 4, 18);
  // final: A=O bf16, B=Wo bf16 -> out[co*18432+sp] = x + acc + bo[co].
  // WL=2 bf16, MODE2: 8 x 18 x 4 = 576 blocks.
  gemm256<128, 2, 1, 0, 0, 2, 0, 1, 2><<<dim3(576), dim3(512), 0, stream>>>(
      Ob, 512, 0, wob, 512, 0, (void*)out, 18432, 0, bo, x, nullptr, nullptr,
      1.0f, 512, 18, 4);
}